// Round 1
// baseline (419.217 us; speedup 1.0000x reference)
//
#include <hip/hip_runtime.h>
#include <math.h>

// Problem constants (from reference)
#define NHEADS 16     // NH
#define BBATCH 2      // B
#define TSEQ   2048   // T
#define HD     16     // HEADDIM
#define DIN    32     // D_INNER
#define DST    64     // D_STATE
#define CONVD  160    // CONV_DIM
#define DPROJ  194    // D_IN_PROJ
#define NHIN   2      // NH_IN
#define DMODEL 256

#define CHUNK  64
#define NCHUNK (TSEQ / CHUNK)   // 32

struct TeamParams {
  const float *Win, *convw, *convb, *dtb, *Alog, *Dp, *nw, *Wout;
};

__device__ __forceinline__ float sigm(float v) { return 1.0f / (1.0f + __expf(-v)); }

// ---------------------------------------------------------------------------
// Phase 1 (PHASE=1): per-chunk zero-init scan -> final state S + decay P.
// Phase 3 (PHASE=3): per-chunk scan init from carried state (S buffer holds
//                    H_in after carry kernel) -> y, gate, rmsnorm, out-proj.
// One workgroup = (team, head, batch, chunk). 256 threads.
// ---------------------------------------------------------------------------
template <int PHASE>
__global__ __launch_bounds__(256)
void mamba_chunk(const float* __restrict__ x, TeamParams tp0, TeamParams tp1,
                 float* __restrict__ Sbuf, float* __restrict__ Pbuf,
                 float* __restrict__ yhead)
{
  __shared__ float xact[CHUNK][CONVD];      // silu(conv(xBC))
  __shared__ float zb[CHUNK][DIN + 1];      // z (padded stride)
  __shared__ float dts[CHUNK][NHIN];        // dt
  __shared__ float dAs[CHUNK][NHIN];        // exp(dt*A)
  __shared__ float wn[HD][DIN + 1];         // Wout * nw (phase 3)
  __shared__ float ub[CHUNK * (DIN + 1)];   // union: u staging (1072 f) / gated-y buf (2112 f)

  const int tid  = threadIdx.x;
  const int wg   = blockIdx.x;
  const int c    = wg % NCHUNK;
  const int b    = (wg / NCHUNK) % BBATCH;
  const int h    = (wg / (NCHUNK * BBATCH)) % NHEADS;
  const int team = wg / (NCHUNK * BBATCH * NHEADS);
  const TeamParams P = team ? tp1 : tp0;
  const int c0 = c * CHUNK;

  if (PHASE == 3) {
    for (int i = tid; i < HD * DIN; i += 256) {
      int o = i >> 5, dn = i & 31;
      wn[o][dn] = P.Wout[((size_t)h * HD + o) * DIN + dn] * P.nw[h * DIN + dn];
    }
  }

  // ---- stage u = x[b, c0-3 .. c0+CHUNK-1, h*16 .. h*16+15] into LDS ----
  for (int i = tid; i < (CHUNK + 3) * HD; i += 256) {
    int tpp = i >> 4, p = i & 15;
    int t = c0 - 3 + tpp;
    ub[i] = (t >= 0) ? x[((size_t)b * TSEQ + t) * DMODEL + h * HD + p] : 0.0f;
  }
  __syncthreads();

  // ---- in-proj + depthwise conv4 + activations ----
  if (tid < DPROJ) {
    const int r = tid;
    float wr[HD];
#pragma unroll
    for (int p = 0; p < HD; ++p) wr[p] = P.Win[((size_t)h * DPROJ + r) * HD + p];

    const bool isconv = (r >= DIN) && (r < DIN + CONVD);
    const int cch = r - DIN;
    float cw0 = 0, cw1 = 0, cw2 = 0, cw3 = 0, cb = 0;
    if (isconv) {
      const float* cwp = &P.convw[((size_t)h * CONVD + cch) * 4];
      cw0 = cwp[0]; cw1 = cwp[1]; cw2 = cwp[2]; cw3 = cwp[3];
      cb = P.convb[h * CONVD + cch];
    }
    float dtbias = 0, Ah = 0;
    if (r >= DIN + CONVD) {
      int hi = r - (DIN + CONVD);
      dtbias = P.dtb[h * NHIN + hi];
      Ah = -expf(P.Alog[h * NHIN + hi]);
    }

    float w0 = 0, w1 = 0, w2 = 0;  // rolling conv window (raw xBC)
    for (int tpp = 0; tpp < CHUNK + 3; ++tpp) {
      float s = 0.0f;
#pragma unroll
      for (int p = 0; p < HD; ++p) s = fmaf(wr[p], ub[tpp * HD + p], s);
      const int t = tpp - 3;
      if (r < DIN) {
        if (t >= 0) zb[t][r] = s;
      } else if (isconv) {
        const float w3 = s;
        if (t >= 0) {
          float cv = cb + w0 * cw0 + w1 * cw1 + w2 * cw2 + w3 * cw3;
          xact[t][cch] = cv * sigm(cv);
        }
        w0 = w1; w1 = w2; w2 = w3;
      } else {
        if (t >= 0) {
          int hi = r - (DIN + CONVD);
          float raw = s + dtbias;
          float dtv = (raw > 20.f) ? raw : log1pf(expf(raw));
          dts[t][hi] = dtv;
          dAs[t][hi] = expf(dtv * Ah);
        }
      }
    }
  }
  __syncthreads();

  // ---- within-chunk scan: thread = (hi, p, ng) owns 8 states n=ng*8.. ----
  const int hi = tid >> 7;
  const int pp = (tid >> 3) & 15;
  const int ng = tid & 7;
  const int nb = ng * 8;
  const size_t sbase =
      ((((((size_t)team * NHEADS + h) * BBATCH + b) * NCHUNK + c) * NHIN + hi) * HD + pp) * DST + nb;

  float hreg[8];
  if (PHASE == 1) {
#pragma unroll
    for (int j = 0; j < 8; ++j) hreg[j] = 0.0f;
  } else {
    const float4 h0 = *reinterpret_cast<const float4*>(&Sbuf[sbase]);
    const float4 h1 = *reinterpret_cast<const float4*>(&Sbuf[sbase + 4]);
    hreg[0] = h0.x; hreg[1] = h0.y; hreg[2] = h0.z; hreg[3] = h0.w;
    hreg[4] = h1.x; hreg[5] = h1.y; hreg[6] = h1.z; hreg[7] = h1.w;
  }
  float Dpv = 0.0f;
  if (PHASE == 3) Dpv = P.Dp[h * NHIN + hi];
  float pprod = 1.0f;

  for (int t = 0; t < CHUNK; ++t) {
    const float dAv = dAs[t][hi];
    const float xv = xact[t][hi * HD + pp];
    const float coef = dts[t][hi] * xv;
    const float4 bm0 = *reinterpret_cast<const float4*>(&xact[t][DIN + nb]);
    const float4 bm1 = *reinterpret_cast<const float4*>(&xact[t][DIN + nb + 4]);
    const float bmv[8] = {bm0.x, bm0.y, bm0.z, bm0.w, bm1.x, bm1.y, bm1.z, bm1.w};
    if (PHASE == 1) {
#pragma unroll
      for (int j = 0; j < 8; ++j) hreg[j] = fmaf(dAv, hreg[j], coef * bmv[j]);
      pprod *= dAv;
    } else {
      const float4 cm0 = *reinterpret_cast<const float4*>(&xact[t][DIN + DST + nb]);
      const float4 cm1 = *reinterpret_cast<const float4*>(&xact[t][DIN + DST + nb + 4]);
      const float cmv[8] = {cm0.x, cm0.y, cm0.z, cm0.w, cm1.x, cm1.y, cm1.z, cm1.w};
      float yp = 0.0f;
#pragma unroll
      for (int j = 0; j < 8; ++j) {
        hreg[j] = fmaf(dAv, hreg[j], coef * bmv[j]);
        yp = fmaf(hreg[j], cmv[j], yp);
      }
      yp += __shfl_down(yp, 4, 8);
      yp += __shfl_down(yp, 2, 8);
      yp += __shfl_down(yp, 1, 8);
      if (ng == 0) ub[t * (DIN + 1) + hi * HD + pp] = fmaf(Dpv, xv, yp);
    }
  }

  if (PHASE == 1) {
    float4 s0 = make_float4(hreg[0], hreg[1], hreg[2], hreg[3]);
    float4 s1 = make_float4(hreg[4], hreg[5], hreg[6], hreg[7]);
    *reinterpret_cast<float4*>(&Sbuf[sbase]) = s0;
    *reinterpret_cast<float4*>(&Sbuf[sbase + 4]) = s1;
    if ((tid & 127) == 0)
      Pbuf[((((size_t)team * NHEADS + h) * BBATCH + b) * NCHUNK + c) * NHIN + hi] = pprod;
  }

  if (PHASE == 3) {
    __syncthreads();
    // gate with silu(z), rmsnorm, out-proj. thread = (tl 0..63 time, tg 0..3)
    const int tg = tid & 3;
    const int tl = tid >> 2;
    float ss = 0.0f;
    float yg[8];
#pragma unroll
    for (int j = 0; j < 8; ++j) {
      int dn = tg * 8 + j;
      float zv = zb[tl][dn];
      float yv = ub[tl * (DIN + 1) + dn];
      float g = yv * (zv * sigm(zv));
      yg[j] = g;
      ss += g * g;
    }
    ss += __shfl_xor(ss, 1, 4);
    ss += __shfl_xor(ss, 2, 4);
    const float rms = rsqrtf(ss * (1.0f / DIN) + 1e-5f);
#pragma unroll
    for (int j = 0; j < 8; ++j) ub[tl * (DIN + 1) + tg * 8 + j] = yg[j];
    __syncthreads();

    float4 ov;
    float* ovp = reinterpret_cast<float*>(&ov);
#pragma unroll
    for (int oo = 0; oo < 4; ++oo) {
      const int o = tg * 4 + oo;
      float acc = 0.0f;
#pragma unroll
      for (int dn = 0; dn < DIN; ++dn)
        acc = fmaf(ub[tl * (DIN + 1) + dn], wn[o][dn], acc);
      ovp[oo] = rms * acc;
    }
    float* yout = &yhead[(((size_t)team * NHEADS + h) * BBATCH + b) * (TSEQ * HD) +
                         (size_t)(c0 + tl) * HD + tg * 4];
    *reinterpret_cast<float4*>(yout) = ov;
  }
}

// ---------------------------------------------------------------------------
// Carry: sequential combine over chunks; transforms S (zero-init finals)
// in place into H_in (carried-in state per chunk). 1 wg = (team, head, batch).
// ---------------------------------------------------------------------------
__global__ __launch_bounds__(256)
void carry_kernel(float* __restrict__ Sbuf, const float* __restrict__ Pbuf)
{
  const int wg = blockIdx.x;            // team*NHEADS*BBATCH
  const int b = wg % BBATCH;
  const int h = (wg / BBATCH) % NHEADS;
  const int team = wg / (BBATCH * NHEADS);
  const int tid = threadIdx.x;
  const int hi = tid >> 7;
  const int pp = (tid >> 3) & 15;
  const int ng = tid & 7;
  const int nb = ng * 8;
  const size_t base0 = ((size_t)team * NHEADS + h) * BBATCH + b;

  float hc[8] = {0, 0, 0, 0, 0, 0, 0, 0};
  for (int c = 0; c < NCHUNK; ++c) {
    const size_t sb = (((base0 * NCHUNK + c) * NHIN + hi) * HD + pp) * DST + nb;
    const float Pv = Pbuf[(base0 * NCHUNK + c) * NHIN + hi];
#pragma unroll
    for (int j = 0; j < 8; ++j) {
      float tmp = Sbuf[sb + j];
      Sbuf[sb + j] = hc[j];
      hc[j] = fmaf(Pv, hc[j], tmp);
    }
  }
}

// ---------------------------------------------------------------------------
// diff = y1 - lam*y2; mean/var over (T, HD) per (head, batch).
// ---------------------------------------------------------------------------
__global__ __launch_bounds__(256)
void diff_stats_kernel(const float* __restrict__ yhead, const float* __restrict__ lam,
                       float* __restrict__ diffb, float* __restrict__ stats)
{
  const int wg = blockIdx.x;  // = h*BBATCH + b
  const int b = wg % BBATCH;
  const int h = wg / BBATCH;
  const int tid = threadIdx.x;
  const size_t y1b = (((size_t)0 * NHEADS + h) * BBATCH + b) * (TSEQ * HD);
  const size_t y2b = (((size_t)1 * NHEADS + h) * BBATCH + b) * (TSEQ * HD);

  float s = 0.0f, s2 = 0.0f;
  for (int i = tid; i < TSEQ * HD; i += 256) {
    const int hd = i & 15;
    const float d = yhead[y1b + i] - lam[h * HD + hd] * yhead[y2b + i];
    diffb[(size_t)wg * (TSEQ * HD) + i] = d;
    s += d;
    s2 += d * d;
  }
  __shared__ float red[8];
#pragma unroll
  for (int off = 32; off; off >>= 1) {
    s += __shfl_down(s, off);
    s2 += __shfl_down(s2, off);
  }
  const int wv = tid >> 6;
  if ((tid & 63) == 0) { red[wv * 2] = s; red[wv * 2 + 1] = s2; }
  __syncthreads();
  if (tid == 0) {
    float S = 0, S2 = 0;
#pragma unroll
    for (int w = 0; w < 4; ++w) { S += red[w * 2]; S2 += red[w * 2 + 1]; }
    const float inv = 1.0f / (TSEQ * HD);
    const float mean = S * inv;
    const float var = S2 * inv - mean * mean;
    stats[wg * 2] = mean;
    stats[wg * 2 + 1] = rsqrtf(var + 1e-5f);
  }
}

// ---------------------------------------------------------------------------
// Apply groupnorm scale/shift, final 256x256 projection, bias, residual.
// 1 wg = 16 timesteps; thread d = output channel.
// ---------------------------------------------------------------------------
#define TT_TILE 16
__global__ __launch_bounds__(256)
void final_kernel(const float* __restrict__ x, const float* __restrict__ diffb,
                  const float* __restrict__ stats, const float* __restrict__ gnw,
                  const float* __restrict__ gnb, const float* __restrict__ projw,
                  const float* __restrict__ projb, float* __restrict__ out)
{
  __shared__ float nd[TT_TILE][DMODEL];
  __shared__ float Wl[DMODEL][33];

  const int wg = blockIdx.x;
  const int nseg = TSEQ / TT_TILE;  // 128
  const int b = wg / nseg;
  const int t0 = (wg % nseg) * TT_TILE;
  const int tid = threadIdx.x;
  const int h = tid >> 4, hd = tid & 15;

  const float mean = stats[(h * BBATCH + b) * 2];
  const float rstd = stats[(h * BBATCH + b) * 2 + 1];
  const float g = gnw[h * HD + hd];
  const float be = gnb[h * HD + hd];
  for (int tt = 0; tt < TT_TILE; ++tt) {
    const float d = diffb[((size_t)(h * BBATCH + b) * TSEQ + t0 + tt) * HD + hd];
    nd[tt][tid] = (d - mean) * rstd * g + be;
  }

  float acc[TT_TILE];
#pragma unroll
  for (int tt = 0; tt < TT_TILE; ++tt) acc[tt] = 0.0f;

  for (int kt = 0; kt < DMODEL; kt += 32) {
    __syncthreads();
    for (int i = tid; i < DMODEL * 32; i += 256) {
      const int dr = i >> 5, kk = i & 31;
      Wl[dr][kk] = projw[(size_t)dr * DMODEL + kt + kk];
    }
    __syncthreads();
#pragma unroll
    for (int kk = 0; kk < 32; ++kk) {
      const float w = Wl[tid][kk];
#pragma unroll
      for (int tt = 0; tt < TT_TILE; ++tt) acc[tt] = fmaf(nd[tt][kt + kk], w, acc[tt]);
    }
  }

  const float pb = projb[tid];
  for (int tt = 0; tt < TT_TILE; ++tt) {
    const size_t o = ((size_t)b * TSEQ + t0 + tt) * DMODEL + tid;
    out[o] = x[o] + pb + acc[tt];
  }
}

// ---------------------------------------------------------------------------
extern "C" void kernel_launch(void* const* d_in, const int* in_sizes, int n_in,
                              void* d_out, int out_size, void* d_ws, size_t ws_size,
                              hipStream_t stream)
{
  const float* x = (const float*)d_in[0];
  TeamParams tp0 { (const float*)d_in[1], (const float*)d_in[2], (const float*)d_in[3],
                   (const float*)d_in[4], (const float*)d_in[5], (const float*)d_in[6],
                   (const float*)d_in[7], (const float*)d_in[8] };
  TeamParams tp1 { (const float*)d_in[9], (const float*)d_in[10], (const float*)d_in[11],
                   (const float*)d_in[12], (const float*)d_in[13], (const float*)d_in[14],
                   (const float*)d_in[15], (const float*)d_in[16] };
  const float* lam   = (const float*)d_in[17];
  const float* gnw   = (const float*)d_in[18];
  const float* gnb   = (const float*)d_in[19];
  const float* projw = (const float*)d_in[20];
  const float* projb = (const float*)d_in[21];

  float* ws = (float*)d_ws;
  float* Sbuf  = ws;                                    // 2*16*2*32*2*16*64 = 4194304 f
  float* Pbuf  = Sbuf + 4194304;                        // 4096 f
  float* yhead = Pbuf + 4096;                           // 2*16*2*2048*16 = 2097152 f
  float* diffb = yhead + 2097152;                       // 16*2*2048*16 = 1048576 f
  float* stats = diffb + 1048576;                       // 64 f

  dim3 blk(256);
  mamba_chunk<1><<<dim3(2 * NHEADS * BBATCH * NCHUNK), blk, 0, stream>>>(x, tp0, tp1, Sbuf, Pbuf, yhead);
  carry_kernel<<<dim3(2 * NHEADS * BBATCH), blk, 0, stream>>>(Sbuf, Pbuf);
  mamba_chunk<3><<<dim3(2 * NHEADS * BBATCH * NCHUNK), blk, 0, stream>>>(x, tp0, tp1, Sbuf, Pbuf, yhead);
  diff_stats_kernel<<<dim3(NHEADS * BBATCH), blk, 0, stream>>>(yhead, lam, diffb, stats);
  final_kernel<<<dim3(BBATCH * (TSEQ / TT_TILE)), blk, 0, stream>>>(x, diffb, stats, gnw, gnb, projw, projb, (float*)d_out);
}

// Round 2
// 317.864 us; speedup vs baseline: 1.3189x; 1.3189x over previous
//
#include <hip/hip_runtime.h>
#include <math.h>

#define NHEADS 16
#define BBATCH 2
#define TSEQ   2048
#define HD     16
#define DIN    32
#define DST    64
#define CONVD  160
#define DPROJ  194
#define NHIN   2
#define DMODEL 256
#define CHUNK  64
#define NCHUNK (TSEQ / CHUNK)          // 32
#define NWG    (2 * NHEADS * BBATCH * NCHUNK)  // 2048

struct TeamParams {
  const float *Win, *convw, *convb, *dtb, *Alog, *Dp, *nw, *Wout;
};

__device__ __forceinline__ float sigm(float v) { return 1.0f / (1.0f + __expf(-v)); }

__device__ __forceinline__ unsigned short f2bf(float f) {
  union { float f; unsigned u; } x; x.f = f;
  unsigned r = x.u + 0x7fffu + ((x.u >> 16) & 1u);
  return (unsigned short)(r >> 16);
}
__device__ __forceinline__ float bf2f(unsigned short b) {
  union { unsigned u; float f; } x; x.u = ((unsigned)b) << 16; return x.f;
}

// ---------------------------------------------------------------------------
// Kernel 1: in-proj (register-blocked GEMM) + conv4 + activations; store
// activations to global (bf16) + (dA,dt) (f32); chunk-local zero-init scan
// -> final state S + decay product P. One wg = (team, head, batch, chunk).
// ---------------------------------------------------------------------------
__global__ __launch_bounds__(256)
void k1_proj_scan(const float* __restrict__ x, TeamParams tp0, TeamParams tp1,
                  float* __restrict__ Sbuf, float* __restrict__ Pbuf,
                  float* __restrict__ adg, unsigned short* __restrict__ xg,
                  unsigned short* __restrict__ zg)
{
  __shared__ float us[68 * 16];        // u staging: slot i -> t = c0-3+i (i<67)
  __shared__ float zxb[68][200];       // in-proj outputs, then in-place silu(conv)
  __shared__ float2 dAdtL[64][2];      // (dA, dt) per (t, hi)

  const int tid  = threadIdx.x;
  const int wg   = blockIdx.x;
  const int c    = wg % NCHUNK;
  const int b    = (wg / NCHUNK) % BBATCH;
  const int h    = (wg / (NCHUNK * BBATCH)) % NHEADS;
  const int team = wg / (NCHUNK * BBATCH * NHEADS);
  const TeamParams P = team ? tp1 : tp0;
  const int c0 = c * CHUNK;

  // ---- stage u ----
  for (int i = tid; i < 68 * 16; i += 256) {
    const int sl = i >> 4, p = i & 15;
    const int t = c0 - 3 + sl;
    us[i] = (sl < 67 && t >= 0) ? x[((size_t)b * TSEQ + t) * DMODEL + h * HD + p] : 0.0f;
  }
  __syncthreads();

  // ---- in-proj: thread (tq 0..16, rq 0..14): 4 slots x 13 rows ----
  if (tid < 255) {
    const int tq = tid / 15, rq = tid % 15;
    const int i0 = tq * 4;
    float uu[4][16];
#pragma unroll
    for (int j = 0; j < 4; ++j) {
#pragma unroll
      for (int p4 = 0; p4 < 4; ++p4) {
        const float4 v = *reinterpret_cast<const float4*>(&us[(i0 + j) * 16 + p4 * 4]);
        uu[j][p4 * 4 + 0] = v.x; uu[j][p4 * 4 + 1] = v.y;
        uu[j][p4 * 4 + 2] = v.z; uu[j][p4 * 4 + 3] = v.w;
      }
    }
    const int r0 = rq * 13;
#pragma unroll
    for (int rr = 0; rr < 13; ++rr) {
      const int r = r0 + rr;
      if (r < DPROJ) {
        const float* wp = &P.Win[((size_t)h * DPROJ + r) * HD];
        const float4 w0 = *reinterpret_cast<const float4*>(wp);
        const float4 w1 = *reinterpret_cast<const float4*>(wp + 4);
        const float4 w2 = *reinterpret_cast<const float4*>(wp + 8);
        const float4 w3 = *reinterpret_cast<const float4*>(wp + 12);
        const float w[16] = {w0.x, w0.y, w0.z, w0.w, w1.x, w1.y, w1.z, w1.w,
                             w2.x, w2.y, w2.z, w2.w, w3.x, w3.y, w3.z, w3.w};
#pragma unroll
        for (int j = 0; j < 4; ++j) {
          float s = 0.0f;
#pragma unroll
          for (int p = 0; p < 16; ++p) s = fmaf(w[p], uu[j][p], s);
          zxb[i0 + j][r] = s;
        }
      }
    }
  }
  __syncthreads();

  // ---- conv4 + silu (in-place, column-private) and dt/dA ----
  if (tid < CONVD) {
    const int ch = tid;
    const float* cwp = &P.convw[((size_t)h * CONVD + ch) * 4];
    const float cw0 = cwp[0], cw1 = cwp[1], cw2 = cwp[2], cw3 = cwp[3];
    const float cb = P.convb[h * CONVD + ch];
    float w0 = 0, w1 = 0, w2 = 0;
    for (int i = 0; i < 67; ++i) {
      const float w3 = zxb[i][32 + ch];
      const int t = i - 3;
      if (t >= 0) {
        const float cv = cb + w0 * cw0 + w1 * cw1 + w2 * cw2 + w3 * cw3;
        zxb[t][32 + ch] = cv * sigm(cv);
      }
      w0 = w1; w1 = w2; w2 = w3;
    }
  } else if (tid < CONVD + NHIN) {
    const int hi = tid - CONVD;
    const float dtbias = P.dtb[h * NHIN + hi];
    const float Ah = -__expf(P.Alog[h * NHIN + hi]);
    for (int i = 3; i < 67; ++i) {
      const float raw = zxb[i][192 + hi] + dtbias;
      const float dtv = (raw > 20.f) ? raw : log1pf(__expf(raw));
      dAdtL[i - 3][hi] = make_float2(__expf(dtv * Ah), dtv);
    }
  }
  __syncthreads();

  if (tid < 128) {
    // ---- phase-1 scan: thread (ppp, ng) owns hi=0 AND hi=1 states ----
    const int ppp = tid >> 3, ng = tid & 7, nb = ng * 8;
    float h0r[8], h1r[8];
#pragma unroll
    for (int j = 0; j < 8; ++j) { h0r[j] = 0.f; h1r[j] = 0.f; }
    float pp0 = 1.f, pp1 = 1.f;
    for (int t = 0; t < 64; ++t) {
      const float2 ad0 = dAdtL[t][0];
      const float2 ad1 = dAdtL[t][1];
      const float xv0 = zxb[t][32 + ppp];
      const float xv1 = zxb[t][48 + ppp];
      const float4 b0 = *reinterpret_cast<const float4*>(&zxb[t][64 + nb]);
      const float4 b1 = *reinterpret_cast<const float4*>(&zxb[t][68 + nb]);
      const float bv[8] = {b0.x, b0.y, b0.z, b0.w, b1.x, b1.y, b1.z, b1.w};
      const float cf0 = ad0.y * xv0, cf1 = ad1.y * xv1;
#pragma unroll
      for (int j = 0; j < 8; ++j) {
        h0r[j] = fmaf(ad0.x, h0r[j], cf0 * bv[j]);
        h1r[j] = fmaf(ad1.x, h1r[j], cf1 * bv[j]);
      }
      pp0 *= ad0.x; pp1 *= ad1.x;
    }
    const size_t base0 = ((size_t)team * NHEADS + h) * BBATCH + b;
    const size_t sb0 = (((base0 * NCHUNK + c) * NHIN + 0) * HD + ppp) * DST + nb;
    const size_t sb1 = (((base0 * NCHUNK + c) * NHIN + 1) * HD + ppp) * DST + nb;
    *reinterpret_cast<float4*>(&Sbuf[sb0])     = make_float4(h0r[0], h0r[1], h0r[2], h0r[3]);
    *reinterpret_cast<float4*>(&Sbuf[sb0 + 4]) = make_float4(h0r[4], h0r[5], h0r[6], h0r[7]);
    *reinterpret_cast<float4*>(&Sbuf[sb1])     = make_float4(h1r[0], h1r[1], h1r[2], h1r[3]);
    *reinterpret_cast<float4*>(&Sbuf[sb1 + 4]) = make_float4(h1r[4], h1r[5], h1r[6], h1r[7]);
    if (tid == 0) {
      Pbuf[(base0 * NCHUNK + c) * NHIN + 0] = pp0;
      Pbuf[(base0 * NCHUNK + c) * NHIN + 1] = pp1;
    }
  } else {
    // ---- concurrent copies to global (threads 128..255) ----
    const int ct = tid - 128;
    const size_t xbase = (size_t)wg * (64 * 160);
    for (int g = ct; g < 2560; g += 128) {
      const int t = g / 40, c4 = (g % 40) * 4;
      const float4 v = *reinterpret_cast<const float4*>(&zxb[t][32 + c4]);
      ushort4 o;
      o.x = f2bf(v.x); o.y = f2bf(v.y); o.z = f2bf(v.z); o.w = f2bf(v.w);
      *reinterpret_cast<ushort4*>(&xg[xbase + (size_t)t * 160 + c4]) = o;
    }
    const size_t zbase = (size_t)wg * (64 * 32);
    for (int g = ct; g < 512; g += 128) {
      const int t = g / 8, c4 = (g % 8) * 4;
      const float4 v = *reinterpret_cast<const float4*>(&zxb[t + 3][c4]);
      ushort4 o;
      o.x = f2bf(v.x * sigm(v.x)); o.y = f2bf(v.y * sigm(v.y));
      o.z = f2bf(v.z * sigm(v.z)); o.w = f2bf(v.w * sigm(v.w));
      *reinterpret_cast<ushort4*>(&zg[zbase + (size_t)t * 32 + c4]) = o;
    }
    {
      const int t = ct >> 1, hi = ct & 1;
      *reinterpret_cast<float2*>(&adg[(size_t)wg * 256 + ct * 2]) = dAdtL[t][hi];
    }
  }
}

// ---------------------------------------------------------------------------
// Carry: sequential combine over chunks; transforms S (zero-init finals)
// in place into H_in. 1 wg = (team, head, batch).
// ---------------------------------------------------------------------------
__global__ __launch_bounds__(256)
void carry_kernel(float* __restrict__ Sbuf, const float* __restrict__ Pbuf)
{
  const int wg = blockIdx.x;
  const int b = wg % BBATCH;
  const int h = (wg / BBATCH) % NHEADS;
  const int team = wg / (BBATCH * NHEADS);
  const int tid = threadIdx.x;
  const int hi = tid >> 7;
  const int pp = (tid >> 3) & 15;
  const int ng = tid & 7;
  const int nb = ng * 8;
  const size_t base0 = ((size_t)team * NHEADS + h) * BBATCH + b;

  float hc[8] = {0, 0, 0, 0, 0, 0, 0, 0};
  for (int c = 0; c < NCHUNK; ++c) {
    const size_t sb = (((base0 * NCHUNK + c) * NHIN + hi) * HD + pp) * DST + nb;
    const float Pv = Pbuf[(base0 * NCHUNK + c) * NHIN + hi];
#pragma unroll
    for (int j = 0; j < 8; ++j) {
      const float tmp = Sbuf[sb + j];
      Sbuf[sb + j] = hc[j];
      hc[j] = fmaf(Pv, hc[j], tmp);
    }
  }
}

// ---------------------------------------------------------------------------
// Kernel 3: load activations; scan with carried state; y + gate + rmsnorm +
// head out-proj -> yhead.
// ---------------------------------------------------------------------------
__global__ __launch_bounds__(256)
void k3_scan_out(const float* __restrict__ Sbuf, const float* __restrict__ adg,
                 const unsigned short* __restrict__ xg,
                 const unsigned short* __restrict__ zg,
                 TeamParams tp0, TeamParams tp1, float* __restrict__ yhead)
{
  __shared__ float xa[64][160];     // silu(conv): x 0..31 | B 32..95 | C 96..159
  __shared__ float ysh[64][33];
  __shared__ float wn[16][33];
  __shared__ float2 dAdtL[64][2];

  const int tid  = threadIdx.x;
  const int wg   = blockIdx.x;
  const int c    = wg % NCHUNK;
  const int b    = (wg / NCHUNK) % BBATCH;
  const int h    = (wg / (NCHUNK * BBATCH)) % NHEADS;
  const int team = wg / (NCHUNK * BBATCH * NHEADS);
  const TeamParams P = team ? tp1 : tp0;
  const int c0 = c * CHUNK;

  for (int i = tid; i < HD * DIN; i += 256) {
    const int o = i >> 5, dn = i & 31;
    wn[o][dn] = P.Wout[((size_t)h * HD + o) * DIN + dn] * P.nw[h * DIN + dn];
  }
  const size_t xbase = (size_t)wg * (64 * 160);
  for (int g = tid; g < 2560; g += 256) {
    const int t = g / 40, c4 = (g % 40) * 4;
    const ushort4 v = *reinterpret_cast<const ushort4*>(&xg[xbase + (size_t)t * 160 + c4]);
    *reinterpret_cast<float4*>(&xa[t][c4]) =
        make_float4(bf2f(v.x), bf2f(v.y), bf2f(v.z), bf2f(v.w));
  }
  if (tid < 128) {
    dAdtL[tid >> 1][tid & 1] = *reinterpret_cast<const float2*>(&adg[(size_t)wg * 256 + tid * 2]);
  }
  __syncthreads();

  if (tid < 128) {
    const int ppp = tid >> 3, ng = tid & 7, nb = ng * 8;
    const size_t base0 = ((size_t)team * NHEADS + h) * BBATCH + b;
    const size_t sb0 = (((base0 * NCHUNK + c) * NHIN + 0) * HD + ppp) * DST + nb;
    const size_t sb1 = (((base0 * NCHUNK + c) * NHIN + 1) * HD + ppp) * DST + nb;
    float h0r[8], h1r[8];
    {
      const float4 a0 = *reinterpret_cast<const float4*>(&Sbuf[sb0]);
      const float4 a1 = *reinterpret_cast<const float4*>(&Sbuf[sb0 + 4]);
      const float4 a2 = *reinterpret_cast<const float4*>(&Sbuf[sb1]);
      const float4 a3 = *reinterpret_cast<const float4*>(&Sbuf[sb1 + 4]);
      h0r[0] = a0.x; h0r[1] = a0.y; h0r[2] = a0.z; h0r[3] = a0.w;
      h0r[4] = a1.x; h0r[5] = a1.y; h0r[6] = a1.z; h0r[7] = a1.w;
      h1r[0] = a2.x; h1r[1] = a2.y; h1r[2] = a2.z; h1r[3] = a2.w;
      h1r[4] = a3.x; h1r[5] = a3.y; h1r[6] = a3.z; h1r[7] = a3.w;
    }
    const float Dp0 = P.Dp[h * NHIN + 0];
    const float Dp1 = P.Dp[h * NHIN + 1];
    for (int t = 0; t < 64; ++t) {
      const float2 ad0 = dAdtL[t][0];
      const float2 ad1 = dAdtL[t][1];
      const float xv0 = xa[t][ppp];
      const float xv1 = xa[t][16 + ppp];
      const float4 b0 = *reinterpret_cast<const float4*>(&xa[t][32 + nb]);
      const float4 b1 = *reinterpret_cast<const float4*>(&xa[t][36 + nb]);
      const float4 q0 = *reinterpret_cast<const float4*>(&xa[t][96 + nb]);
      const float4 q1 = *reinterpret_cast<const float4*>(&xa[t][100 + nb]);
      const float bv[8] = {b0.x, b0.y, b0.z, b0.w, b1.x, b1.y, b1.z, b1.w};
      const float cv[8] = {q0.x, q0.y, q0.z, q0.w, q1.x, q1.y, q1.z, q1.w};
      const float cf0 = ad0.y * xv0, cf1 = ad1.y * xv1;
      float yp0 = 0.f, yp1 = 0.f;
#pragma unroll
      for (int j = 0; j < 8; ++j) {
        h0r[j] = fmaf(ad0.x, h0r[j], cf0 * bv[j]);
        yp0 = fmaf(h0r[j], cv[j], yp0);
        h1r[j] = fmaf(ad1.x, h1r[j], cf1 * bv[j]);
        yp1 = fmaf(h1r[j], cv[j], yp1);
      }
      yp0 += __shfl_down(yp0, 4, 8); yp0 += __shfl_down(yp0, 2, 8); yp0 += __shfl_down(yp0, 1, 8);
      yp1 += __shfl_down(yp1, 4, 8); yp1 += __shfl_down(yp1, 2, 8); yp1 += __shfl_down(yp1, 1, 8);
      if (ng == 0) {
        ysh[t][ppp]      = fmaf(Dp0, xv0, yp0);
        ysh[t][16 + ppp] = fmaf(Dp1, xv1, yp1);
      }
    }
  }
  __syncthreads();

  // ---- epilogue: gate with stored silu(z), rmsnorm, out-proj ----
  const int tg = tid & 3;
  const int tl = tid >> 2;
  const size_t zbase = (size_t)wg * (64 * 32) + (size_t)tl * 32 + tg * 8;
  const ushort4 z0 = *reinterpret_cast<const ushort4*>(&zg[zbase]);
  const ushort4 z1 = *reinterpret_cast<const ushort4*>(&zg[zbase + 4]);
  const float zs[8] = {bf2f(z0.x), bf2f(z0.y), bf2f(z0.z), bf2f(z0.w),
                       bf2f(z1.x), bf2f(z1.y), bf2f(z1.z), bf2f(z1.w)};
  float ss = 0.0f;
  float yg[8];
#pragma unroll
  for (int j = 0; j < 8; ++j) {
    const float g = ysh[tl][tg * 8 + j] * zs[j];
    yg[j] = g;
    ss += g * g;
  }
  ss += __shfl_xor(ss, 1, 4);
  ss += __shfl_xor(ss, 2, 4);
  const float rms = rsqrtf(ss * (1.0f / DIN) + 1e-5f);
#pragma unroll
  for (int j = 0; j < 8; ++j) ysh[tl][tg * 8 + j] = yg[j];
  __syncthreads();

  float4 ov;
  float* ovp = reinterpret_cast<float*>(&ov);
#pragma unroll
  for (int oo = 0; oo < 4; ++oo) {
    const int o = tg * 4 + oo;
    float acc = 0.0f;
#pragma unroll
    for (int dn = 0; dn < DIN; ++dn) acc = fmaf(ysh[tl][dn], wn[o][dn], acc);
    ovp[oo] = rms * acc;
  }
  float* yout = &yhead[(((size_t)team * NHEADS + h) * BBATCH + b) * (TSEQ * HD) +
                       (size_t)(c0 + tl) * HD + tg * 4];
  *reinterpret_cast<float4*>(yout) = ov;
}

// ---------------------------------------------------------------------------
__global__ __launch_bounds__(256)
void diff_stats_kernel(const float* __restrict__ yhead, const float* __restrict__ lam,
                       float* __restrict__ diffb, float* __restrict__ stats)
{
  const int wg = blockIdx.x;  // = h*BBATCH + b
  const int b = wg % BBATCH;
  const int h = wg / BBATCH;
  const int tid = threadIdx.x;
  const size_t y1b = (((size_t)0 * NHEADS + h) * BBATCH + b) * (TSEQ * HD);
  const size_t y2b = (((size_t)1 * NHEADS + h) * BBATCH + b) * (TSEQ * HD);

  float s = 0.0f, s2 = 0.0f;
  for (int i = tid; i < TSEQ * HD; i += 256) {
    const int hd = i & 15;
    const float d = yhead[y1b + i] - lam[h * HD + hd] * yhead[y2b + i];
    diffb[(size_t)wg * (TSEQ * HD) + i] = d;
    s += d;
    s2 += d * d;
  }
  __shared__ float red[8];
#pragma unroll
  for (int off = 32; off; off >>= 1) {
    s += __shfl_down(s, off);
    s2 += __shfl_down(s2, off);
  }
  const int wv = tid >> 6;
  if ((tid & 63) == 0) { red[wv * 2] = s; red[wv * 2 + 1] = s2; }
  __syncthreads();
  if (tid == 0) {
    float S = 0, S2 = 0;
#pragma unroll
    for (int w = 0; w < 4; ++w) { S += red[w * 2]; S2 += red[w * 2 + 1]; }
    const float inv = 1.0f / (TSEQ * HD);
    const float mean = S * inv;
    const float var = S2 * inv - mean * mean;
    stats[wg * 2] = mean;
    stats[wg * 2 + 1] = rsqrtf(var + 1e-5f);
  }
}

#define TT_TILE 16
__global__ __launch_bounds__(256)
void final_kernel(const float* __restrict__ x, const float* __restrict__ diffb,
                  const float* __restrict__ stats, const float* __restrict__ gnw,
                  const float* __restrict__ gnb, const float* __restrict__ projw,
                  const float* __restrict__ projb, float* __restrict__ out)
{
  __shared__ float nd[TT_TILE][DMODEL];
  __shared__ float Wl[DMODEL][33];

  const int wg = blockIdx.x;
  const int nseg = TSEQ / TT_TILE;
  const int b = wg / nseg;
  const int t0 = (wg % nseg) * TT_TILE;
  const int tid = threadIdx.x;
  const int h = tid >> 4, hd = tid & 15;

  const float mean = stats[(h * BBATCH + b) * 2];
  const float rstd = stats[(h * BBATCH + b) * 2 + 1];
  const float g = gnw[h * HD + hd];
  const float be = gnb[h * HD + hd];
  for (int tt = 0; tt < TT_TILE; ++tt) {
    const float d = diffb[((size_t)(h * BBATCH + b) * TSEQ + t0 + tt) * HD + hd];
    nd[tt][tid] = (d - mean) * rstd * g + be;
  }

  float acc[TT_TILE];
#pragma unroll
  for (int tt = 0; tt < TT_TILE; ++tt) acc[tt] = 0.0f;

  for (int kt = 0; kt < DMODEL; kt += 32) {
    __syncthreads();
    for (int i = tid; i < DMODEL * 32; i += 256) {
      const int dr = i >> 5, kk = i & 31;
      Wl[dr][kk] = projw[(size_t)dr * DMODEL + kt + kk];
    }
    __syncthreads();
#pragma unroll
    for (int kk = 0; kk < 32; ++kk) {
      const float w = Wl[tid][kk];
#pragma unroll
      for (int tt = 0; tt < TT_TILE; ++tt) acc[tt] = fmaf(nd[tt][kt + kk], w, acc[tt]);
    }
  }

  const float pb = projb[tid];
  for (int tt = 0; tt < TT_TILE; ++tt) {
    const size_t o = ((size_t)b * TSEQ + t0 + tt) * DMODEL + tid;
    out[o] = x[o] + pb + acc[tt];
  }
}

// ---------------------------------------------------------------------------
extern "C" void kernel_launch(void* const* d_in, const int* in_sizes, int n_in,
                              void* d_out, int out_size, void* d_ws, size_t ws_size,
                              hipStream_t stream)
{
  const float* x = (const float*)d_in[0];
  TeamParams tp0 { (const float*)d_in[1], (const float*)d_in[2], (const float*)d_in[3],
                   (const float*)d_in[4], (const float*)d_in[5], (const float*)d_in[6],
                   (const float*)d_in[7], (const float*)d_in[8] };
  TeamParams tp1 { (const float*)d_in[9], (const float*)d_in[10], (const float*)d_in[11],
                   (const float*)d_in[12], (const float*)d_in[13], (const float*)d_in[14],
                   (const float*)d_in[15], (const float*)d_in[16] };
  const float* lam   = (const float*)d_in[17];
  const float* gnw   = (const float*)d_in[18];
  const float* gnb   = (const float*)d_in[19];
  const float* projw = (const float*)d_in[20];
  const float* projb = (const float*)d_in[21];

  float* ws = (float*)d_ws;
  float* Sbuf  = ws;                                    // 4194304 f
  float* Pbuf  = Sbuf + 4194304;                        // 4096 f
  float* yhead = Pbuf + 4096;                           // 2097152 f
  float* diffb = yhead + 2097152;                       // 1048576 f
  float* stats = diffb + 1048576;                       // 64 f
  float* adg   = stats + 64;                            // 2048*256 = 524288 f
  unsigned short* xg = (unsigned short*)(adg + 524288); // 2048*64*160 bf16
  unsigned short* zg = xg + (size_t)NWG * 64 * 160;     // 2048*64*32 bf16

  dim3 blk(256);
  k1_proj_scan<<<dim3(NWG), blk, 0, stream>>>(x, tp0, tp1, Sbuf, Pbuf, adg, xg, zg);
  carry_kernel<<<dim3(2 * NHEADS * BBATCH), blk, 0, stream>>>(Sbuf, Pbuf);
  k3_scan_out<<<dim3(NWG), blk, 0, stream>>>(Sbuf, adg, xg, zg, tp0, tp1, yhead);
  diff_stats_kernel<<<dim3(NHEADS * BBATCH), blk, 0, stream>>>(yhead, lam, diffb, stats);
  final_kernel<<<dim3(BBATCH * (TSEQ / TT_TILE)), blk, 0, stream>>>(x, diffb, stats, gnw, gnb, projw, projb, (float*)d_out);
}

// Round 3
// 248.064 us; speedup vs baseline: 1.6900x; 1.2814x over previous
//
#include <hip/hip_runtime.h>
#include <math.h>

#define NHEADS 16
#define BBATCH 2
#define TSEQ   2048
#define HD     16
#define DIN    32
#define DST    64
#define CONVD  160
#define DPROJ  194
#define NHIN   2
#define DMODEL 256
#define CHUNK  32
#define NCHUNK (TSEQ / CHUNK)                  // 64
#define NWG    (2 * NHEADS * BBATCH * NCHUNK)  // 4096
#define SLOTS  (CHUNK + 3)                     // 35

struct TeamParams {
  const float *Win, *convw, *convb, *dtb, *Alog, *Dp, *nw, *Wout;
};

__device__ __forceinline__ float sigm(float v) { return 1.0f / (1.0f + __expf(-v)); }

__device__ __forceinline__ unsigned short f2bf(float f) {
  union { float f; unsigned u; } x; x.f = f;
  unsigned r = x.u + 0x7fffu + ((x.u >> 16) & 1u);
  return (unsigned short)(r >> 16);
}
__device__ __forceinline__ float bf2f(unsigned short b) {
  union { unsigned u; float f; } x; x.u = ((unsigned)b) << 16; return x.f;
}
__device__ __forceinline__ ushort4 pack4(float a, float b, float c, float d) {
  return make_ushort4(f2bf(a), f2bf(b), f2bf(c), f2bf(d));
}

// ---------------------------------------------------------------------------
// K1: in-proj GEMM + parallel conv4 + activations -> global (bf16);
// chunk-local zero-init scan -> chunk-final state (bf16) + decay product.
// wg = (team, head, batch, chunk32). 256 threads. LDS ~31 KB -> 5 wg/CU.
// ---------------------------------------------------------------------------
__global__ __launch_bounds__(256)
void k1_proj_scan(const float* __restrict__ x, TeamParams tp0, TeamParams tp1,
                  unsigned short* __restrict__ Sg, float* __restrict__ Pbuf,
                  float2* __restrict__ adg, unsigned short* __restrict__ xg,
                  unsigned short* __restrict__ zg)
{
  __shared__ float us[SLOTS][20];          // u staging (padded rows: bank spread)
  __shared__ float xbc[SLOTS][164];        // cols 0..159 conv-ch (raw->act), 160..161 dt raw
  __shared__ float zb[SLOTS][36];          // z rows
  __shared__ float2 dAdtL[CHUNK][NHIN];    // (dA, dt)

  const int tid  = threadIdx.x;
  const int wg   = blockIdx.x;
  const int c    = wg % NCHUNK;
  const int b    = (wg / NCHUNK) % BBATCH;
  const int h    = (wg / (NCHUNK * BBATCH)) % NHEADS;
  const int team = wg / (NCHUNK * BBATCH * NHEADS);
  const TeamParams P = team ? tp1 : tp0;
  const int c0 = c * CHUNK;

  // ---- stage u ----
  for (int i = tid; i < SLOTS * 16; i += 256) {
    const int sl = i >> 4, p = i & 15;
    const int t = c0 - 3 + sl;
    us[sl][p] = (t >= 0) ? x[((size_t)b * TSEQ + t) * DMODEL + h * HD + p] : 0.0f;
  }
  __syncthreads();

  // ---- in-proj: thread (tq 0..17, rq 0..13): 2 slots x 14 rows ----
  if (tid < 252) {
    const int tq = tid / 14, rq = tid % 14;
    const int i0 = tq * 2;
    const int ns = (i0 + 1 < SLOTS) ? 2 : 1;
    float uu[2][16];
#pragma unroll
    for (int j = 0; j < 2; ++j) {
      if (j < ns) {
#pragma unroll
        for (int p4 = 0; p4 < 4; ++p4) {
          const float4 v = *reinterpret_cast<const float4*>(&us[i0 + j][p4 * 4]);
          uu[j][p4 * 4 + 0] = v.x; uu[j][p4 * 4 + 1] = v.y;
          uu[j][p4 * 4 + 2] = v.z; uu[j][p4 * 4 + 3] = v.w;
        }
      }
    }
    const int r0 = rq * 14;
#pragma unroll
    for (int rr = 0; rr < 14; ++rr) {
      const int r = r0 + rr;
      if (r < DPROJ) {
        const float* wp = &P.Win[((size_t)h * DPROJ + r) * HD];
        const float4 w0 = *reinterpret_cast<const float4*>(wp);
        const float4 w1 = *reinterpret_cast<const float4*>(wp + 4);
        const float4 w2 = *reinterpret_cast<const float4*>(wp + 8);
        const float4 w3 = *reinterpret_cast<const float4*>(wp + 12);
        const float w[16] = {w0.x, w0.y, w0.z, w0.w, w1.x, w1.y, w1.z, w1.w,
                             w2.x, w2.y, w2.z, w2.w, w3.x, w3.y, w3.z, w3.w};
#pragma unroll
        for (int j = 0; j < 2; ++j) {
          if (j < ns) {
            float s = 0.0f;
#pragma unroll
            for (int p = 0; p < 16; ++p) s = fmaf(w[p], uu[j][p], s);
            if (r < DIN) zb[i0 + j][r] = s;
            else xbc[i0 + j][r - DIN] = s;
          }
        }
      }
    }
  }
  __syncthreads();

  // ---- conv4 fully parallel over (t, ch): read phase into regs ----
  float cv[20];
#pragma unroll
  for (int k = 0; k < 20; ++k) {
    const int o = tid + k * 256;          // 0..5119
    const int t = o / CONVD, ch = o - t * CONVD;
    const float4 cw = *reinterpret_cast<const float4*>(&P.convw[((size_t)h * CONVD + ch) * 4]);
    const float cb = P.convb[h * CONVD + ch];
    float v = cb;
    v = fmaf(cw.x, xbc[t][ch], v);
    v = fmaf(cw.y, xbc[t + 1][ch], v);
    v = fmaf(cw.z, xbc[t + 2][ch], v);
    v = fmaf(cw.w, xbc[t + 3][ch], v);
    cv[k] = v * sigm(v);
  }
  // dt / dA (reads cols 160..161 which conv never writes)
  if (tid < 2 * CHUNK) {
    const int t = tid >> 1, hi = tid & 1;
    const float dtbias = P.dtb[h * NHIN + hi];
    const float Ah = -__expf(P.Alog[h * NHIN + hi]);
    const float raw = xbc[3 + t][160 + hi] + dtbias;
    const float dtv = (raw > 20.f) ? raw : log1pf(__expf(raw));
    dAdtL[t][hi] = make_float2(__expf(dtv * Ah), dtv);
  }
  __syncthreads();
  // ---- conv write-back (in place) ----
#pragma unroll
  for (int k = 0; k < 20; ++k) {
    const int o = tid + k * 256;
    const int t = o / CONVD, ch = o - t * CONVD;
    xbc[3 + t][ch] = cv[k];
  }
  __syncthreads();

  if (tid < 128) {
    // ---- zero-init scan: thread (ppp, ng) owns both hi, 8 states each ----
    const int ppp = (tid >> 3) & 15, ng = tid & 7, nb = ng * 8;
    float h0r[8], h1r[8];
#pragma unroll
    for (int j = 0; j < 8; ++j) { h0r[j] = 0.f; h1r[j] = 0.f; }
    float pp0 = 1.f, pp1 = 1.f;
    for (int t = 0; t < CHUNK; ++t) {
      const float2 ad0 = dAdtL[t][0];
      const float2 ad1 = dAdtL[t][1];
      const float xv0 = xbc[3 + t][ppp];
      const float xv1 = xbc[3 + t][16 + ppp];
      const float4 b0 = *reinterpret_cast<const float4*>(&xbc[3 + t][32 + nb]);
      const float4 b1 = *reinterpret_cast<const float4*>(&xbc[3 + t][36 + nb]);
      const float bv[8] = {b0.x, b0.y, b0.z, b0.w, b1.x, b1.y, b1.z, b1.w};
      const float cf0 = ad0.y * xv0, cf1 = ad1.y * xv1;
#pragma unroll
      for (int j = 0; j < 8; ++j) {
        h0r[j] = fmaf(ad0.x, h0r[j], cf0 * bv[j]);
        h1r[j] = fmaf(ad1.x, h1r[j], cf1 * bv[j]);
      }
      pp0 *= ad0.x; pp1 *= ad1.x;
    }
    const size_t base0 = ((size_t)team * NHEADS + h) * BBATCH + b;
    const size_t sb0 = (((base0 * NCHUNK + c) * NHIN + 0) * HD + ppp) * DST + nb;
    const size_t sb1 = (((base0 * NCHUNK + c) * NHIN + 1) * HD + ppp) * DST + nb;
    *reinterpret_cast<ushort4*>(&Sg[sb0])     = pack4(h0r[0], h0r[1], h0r[2], h0r[3]);
    *reinterpret_cast<ushort4*>(&Sg[sb0 + 4]) = pack4(h0r[4], h0r[5], h0r[6], h0r[7]);
    *reinterpret_cast<ushort4*>(&Sg[sb1])     = pack4(h1r[0], h1r[1], h1r[2], h1r[3]);
    *reinterpret_cast<ushort4*>(&Sg[sb1 + 4]) = pack4(h1r[4], h1r[5], h1r[6], h1r[7]);
    if (tid == 0) {
      Pbuf[(base0 * NCHUNK + c) * NHIN + 0] = pp0;
      Pbuf[(base0 * NCHUNK + c) * NHIN + 1] = pp1;
    }
  } else {
    // ---- concurrent global stores (threads 128..255) ----
    const int ct = tid - 128;
    const size_t xbase = (size_t)wg * (CHUNK * CONVD);
#pragma unroll
    for (int k = 0; k < 10; ++k) {
      const int idx = ct + k * 128;               // 0..1279 ushort4s
      const int t = idx / 40, c4 = (idx - t * 40) * 4;
      const float4 v = *reinterpret_cast<const float4*>(&xbc[3 + t][c4]);
      *reinterpret_cast<ushort4*>(&xg[xbase + (size_t)t * CONVD + c4]) =
          pack4(v.x, v.y, v.z, v.w);
    }
    const size_t zbase = (((size_t)team * NHEADS + h) * BBATCH + b) * (TSEQ * DIN) +
                         (size_t)c0 * DIN;
#pragma unroll
    for (int k = 0; k < 2; ++k) {
      const int idx = ct + k * 128;               // 0..255 ushort4s
      const int t = idx >> 3, c4 = (idx & 7) * 4;
      const float4 v = *reinterpret_cast<const float4*>(&zb[3 + t][c4]);
      *reinterpret_cast<ushort4*>(&zg[zbase + (size_t)t * DIN + c4]) =
          pack4(v.x * sigm(v.x), v.y * sigm(v.y), v.z * sigm(v.z), v.w * sigm(v.w));
    }
    if (ct < 64) adg[(size_t)wg * 64 + ct] = dAdtL[ct >> 1][ct & 1];
  }
}

// ---------------------------------------------------------------------------
// Carry: sequential combine over 64 chunks; Sg (chunk finals, bf16) -> H_in.
// ---------------------------------------------------------------------------
__global__ __launch_bounds__(256)
void carry_kernel(unsigned short* __restrict__ Sg, const float* __restrict__ Pbuf)
{
  const int wg = blockIdx.x;
  const int b = wg % BBATCH;
  const int h = (wg / BBATCH) % NHEADS;
  const int team = wg / (BBATCH * NHEADS);
  const int tid = threadIdx.x;
  const int hi = tid >> 7;
  const int pp = (tid >> 3) & 15;
  const int ng = tid & 7;
  const int nb = ng * 8;
  const size_t base0 = ((size_t)team * NHEADS + h) * BBATCH + b;

  float hc[8] = {0, 0, 0, 0, 0, 0, 0, 0};
  for (int c = 0; c < NCHUNK; ++c) {
    const size_t sb = (((base0 * NCHUNK + c) * NHIN + hi) * HD + pp) * DST + nb;
    const float Pv = Pbuf[(base0 * NCHUNK + c) * NHIN + hi];
    const ushort4 a0 = *reinterpret_cast<const ushort4*>(&Sg[sb]);
    const ushort4 a1 = *reinterpret_cast<const ushort4*>(&Sg[sb + 4]);
    const float tmp[8] = {bf2f(a0.x), bf2f(a0.y), bf2f(a0.z), bf2f(a0.w),
                          bf2f(a1.x), bf2f(a1.y), bf2f(a1.z), bf2f(a1.w)};
    *reinterpret_cast<ushort4*>(&Sg[sb])     = pack4(hc[0], hc[1], hc[2], hc[3]);
    *reinterpret_cast<ushort4*>(&Sg[sb + 4]) = pack4(hc[4], hc[5], hc[6], hc[7]);
#pragma unroll
    for (int j = 0; j < 8; ++j) hc[j] = fmaf(Pv, hc[j], tmp[j]);
  }
}

// ---------------------------------------------------------------------------
// K3: load activations; scan with carried state; gate + rmsnorm + out-proj.
// ---------------------------------------------------------------------------
__global__ __launch_bounds__(256)
void k3_scan_out(const unsigned short* __restrict__ Sg, const float2* __restrict__ adg,
                 const unsigned short* __restrict__ xg,
                 const unsigned short* __restrict__ zg,
                 TeamParams tp0, TeamParams tp1, float* __restrict__ yhead)
{
  __shared__ float xa[CHUNK][164];   // x 0..31 | B 32..95 | C 96..159
  __shared__ float ysh[CHUNK][33];
  __shared__ float wn[16][33];
  __shared__ float2 dAdtL[CHUNK][NHIN];

  const int tid  = threadIdx.x;
  const int wg   = blockIdx.x;
  const int c    = wg % NCHUNK;
  const int b    = (wg / NCHUNK) % BBATCH;
  const int h    = (wg / (NCHUNK * BBATCH)) % NHEADS;
  const int team = wg / (NCHUNK * BBATCH * NHEADS);
  const TeamParams P = team ? tp1 : tp0;
  const int c0 = c * CHUNK;

  for (int i = tid; i < HD * DIN; i += 256) {
    const int o = i >> 5, dn = i & 31;
    wn[o][dn] = P.Wout[((size_t)h * HD + o) * DIN + dn] * P.nw[h * DIN + dn];
  }
  const size_t xbase = (size_t)wg * (CHUNK * CONVD);
#pragma unroll
  for (int k = 0; k < 5; ++k) {
    const int idx = tid + k * 256;              // 0..1279
    const int t = idx / 40, c4 = (idx - t * 40) * 4;
    const ushort4 v = *reinterpret_cast<const ushort4*>(&xg[xbase + (size_t)t * CONVD + c4]);
    *reinterpret_cast<float4*>(&xa[t][c4]) =
        make_float4(bf2f(v.x), bf2f(v.y), bf2f(v.z), bf2f(v.w));
  }
  if (tid < 2 * CHUNK) dAdtL[tid >> 1][tid & 1] = adg[(size_t)wg * 64 + tid];
  __syncthreads();

  if (tid < 128) {
    const int ppp = (tid >> 3) & 15, ng = tid & 7, nb = ng * 8;
    const size_t base0 = ((size_t)team * NHEADS + h) * BBATCH + b;
    const size_t sb0 = (((base0 * NCHUNK + c) * NHIN + 0) * HD + ppp) * DST + nb;
    const size_t sb1 = (((base0 * NCHUNK + c) * NHIN + 1) * HD + ppp) * DST + nb;
    float h0r[8], h1r[8];
    {
      const ushort4 a0 = *reinterpret_cast<const ushort4*>(&Sg[sb0]);
      const ushort4 a1 = *reinterpret_cast<const ushort4*>(&Sg[sb0 + 4]);
      const ushort4 a2 = *reinterpret_cast<const ushort4*>(&Sg[sb1]);
      const ushort4 a3 = *reinterpret_cast<const ushort4*>(&Sg[sb1 + 4]);
      h0r[0] = bf2f(a0.x); h0r[1] = bf2f(a0.y); h0r[2] = bf2f(a0.z); h0r[3] = bf2f(a0.w);
      h0r[4] = bf2f(a1.x); h0r[5] = bf2f(a1.y); h0r[6] = bf2f(a1.z); h0r[7] = bf2f(a1.w);
      h1r[0] = bf2f(a2.x); h1r[1] = bf2f(a2.y); h1r[2] = bf2f(a2.z); h1r[3] = bf2f(a2.w);
      h1r[4] = bf2f(a3.x); h1r[5] = bf2f(a3.y); h1r[6] = bf2f(a3.z); h1r[7] = bf2f(a3.w);
    }
    const float Dp0 = P.Dp[h * NHIN + 0];
    const float Dp1 = P.Dp[h * NHIN + 1];
    for (int t = 0; t < CHUNK; ++t) {
      const float2 ad0 = dAdtL[t][0];
      const float2 ad1 = dAdtL[t][1];
      const float xv0 = xa[t][ppp];
      const float xv1 = xa[t][16 + ppp];
      const float4 b0 = *reinterpret_cast<const float4*>(&xa[t][32 + nb]);
      const float4 b1 = *reinterpret_cast<const float4*>(&xa[t][36 + nb]);
      const float4 q0 = *reinterpret_cast<const float4*>(&xa[t][96 + nb]);
      const float4 q1 = *reinterpret_cast<const float4*>(&xa[t][100 + nb]);
      const float bv[8] = {b0.x, b0.y, b0.z, b0.w, b1.x, b1.y, b1.z, b1.w};
      const float cmv[8] = {q0.x, q0.y, q0.z, q0.w, q1.x, q1.y, q1.z, q1.w};
      const float cf0 = ad0.y * xv0, cf1 = ad1.y * xv1;
      float yp0 = 0.f, yp1 = 0.f;
#pragma unroll
      for (int j = 0; j < 8; ++j) {
        h0r[j] = fmaf(ad0.x, h0r[j], cf0 * bv[j]);
        yp0 = fmaf(h0r[j], cmv[j], yp0);
        h1r[j] = fmaf(ad1.x, h1r[j], cf1 * bv[j]);
        yp1 = fmaf(h1r[j], cmv[j], yp1);
      }
      yp0 += __shfl_down(yp0, 4, 8); yp0 += __shfl_down(yp0, 2, 8); yp0 += __shfl_down(yp0, 1, 8);
      yp1 += __shfl_down(yp1, 4, 8); yp1 += __shfl_down(yp1, 2, 8); yp1 += __shfl_down(yp1, 1, 8);
      if (ng == 0) {
        ysh[t][ppp]      = fmaf(Dp0, xv0, yp0);
        ysh[t][16 + ppp] = fmaf(Dp1, xv1, yp1);
      }
    }
  }
  __syncthreads();

  // ---- gate with silu(z), rms, out-proj. thread = (tl 0..31, q 0..7) ----
  const int q = tid & 7, tl = tid >> 3;
  const size_t zbase = (((size_t)team * NHEADS + h) * BBATCH + b) * (TSEQ * DIN) +
                       (size_t)(c0 + tl) * DIN + q * 4;
  const ushort4 z4 = *reinterpret_cast<const ushort4*>(&zg[zbase]);
  const float zs[4] = {bf2f(z4.x), bf2f(z4.y), bf2f(z4.z), bf2f(z4.w)};
  float yg[4];
  float ss = 0.0f;
#pragma unroll
  for (int j = 0; j < 4; ++j) {
    const float g = ysh[tl][q * 4 + j] * zs[j];
    yg[j] = g;
    ss += g * g;
  }
  ss += __shfl_xor(ss, 1, 8);
  ss += __shfl_xor(ss, 2, 8);
  ss += __shfl_xor(ss, 4, 8);
  const float rms = rsqrtf(ss * (1.0f / DIN) + 1e-5f);
#pragma unroll
  for (int j = 0; j < 4; ++j) ysh[tl][q * 4 + j] = yg[j];
  __syncthreads();

  // out-proj: thread (tl, og=q) -> outputs o = og*2, og*2+1
  float acc0 = 0.f, acc1 = 0.f;
#pragma unroll
  for (int dn = 0; dn < DIN; ++dn) {
    const float v = ysh[tl][dn];
    acc0 = fmaf(v, wn[q * 2][dn], acc0);
    acc1 = fmaf(v, wn[q * 2 + 1][dn], acc1);
  }
  float* yout = &yhead[(((size_t)team * NHEADS + h) * BBATCH + b) * (TSEQ * HD) +
                       (size_t)(c0 + tl) * HD + q * 2];
  *reinterpret_cast<float2*>(yout) = make_float2(rms * acc0, rms * acc1);
}

// ---------------------------------------------------------------------------
__global__ __launch_bounds__(1024)
void diff_stats_kernel(const float* __restrict__ yhead, const float* __restrict__ lam,
                       float* __restrict__ diffb, float* __restrict__ stats)
{
  const int wg = blockIdx.x;  // h*2 + b
  const int b = wg & 1;
  const int h = wg >> 1;
  const int tid = threadIdx.x;
  const float4* y1 = reinterpret_cast<const float4*>(
      &yhead[(((size_t)0 * NHEADS + h) * BBATCH + b) * (TSEQ * HD)]);
  const float4* y2 = reinterpret_cast<const float4*>(
      &yhead[(((size_t)1 * NHEADS + h) * BBATCH + b) * (TSEQ * HD)]);
  float4* dd = reinterpret_cast<float4*>(&diffb[(size_t)wg * (TSEQ * HD)]);

  float s = 0.0f, s2 = 0.0f;
  for (int i = tid; i < TSEQ * HD / 4; i += 1024) {
    const float4 a = y1[i];
    const float4 bb = y2[i];
    const float4 l = *reinterpret_cast<const float4*>(&lam[h * HD + (i & 3) * 4]);
    float4 d;
    d.x = a.x - l.x * bb.x; d.y = a.y - l.y * bb.y;
    d.z = a.z - l.z * bb.z; d.w = a.w - l.w * bb.w;
    dd[i] = d;
    s += d.x + d.y + d.z + d.w;
    s2 += d.x * d.x + d.y * d.y + d.z * d.z + d.w * d.w;
  }
  __shared__ float red[32];
#pragma unroll
  for (int off = 32; off; off >>= 1) {
    s += __shfl_down(s, off);
    s2 += __shfl_down(s2, off);
  }
  const int wv = tid >> 6;
  if ((tid & 63) == 0) { red[wv * 2] = s; red[wv * 2 + 1] = s2; }
  __syncthreads();
  if (tid == 0) {
    float S = 0, S2 = 0;
#pragma unroll
    for (int w = 0; w < 16; ++w) { S += red[w * 2]; S2 += red[w * 2 + 1]; }
    const float inv = 1.0f / (TSEQ * HD);
    const float mean = S * inv;
    const float var = S2 * inv - mean * mean;
    stats[wg * 2] = mean;
    stats[wg * 2 + 1] = rsqrtf(var + 1e-5f);
  }
}

#define TT_TILE 16
__global__ __launch_bounds__(256)
void final_kernel(const float* __restrict__ x, const float* __restrict__ diffb,
                  const float* __restrict__ stats, const float* __restrict__ gnw,
                  const float* __restrict__ gnb, const float* __restrict__ projw,
                  const float* __restrict__ projb, float* __restrict__ out)
{
  __shared__ float nd[TT_TILE][DMODEL];
  __shared__ float Wl[DMODEL][33];

  const int wg = blockIdx.x;
  const int nseg = TSEQ / TT_TILE;
  const int b = wg / nseg;
  const int t0 = (wg % nseg) * TT_TILE;
  const int tid = threadIdx.x;
  const int h = tid >> 4, hd = tid & 15;

  const float mean = stats[(h * BBATCH + b) * 2];
  const float rstd = stats[(h * BBATCH + b) * 2 + 1];
  const float g = gnw[h * HD + hd];
  const float be = gnb[h * HD + hd];
  for (int tt = 0; tt < TT_TILE; ++tt) {
    const float d = diffb[((size_t)(h * BBATCH + b) * TSEQ + t0 + tt) * HD + hd];
    nd[tt][tid] = (d - mean) * rstd * g + be;
  }

  float acc[TT_TILE];
#pragma unroll
  for (int tt = 0; tt < TT_TILE; ++tt) acc[tt] = 0.0f;

  for (int kt = 0; kt < DMODEL; kt += 32) {
    __syncthreads();
    for (int i = tid; i < DMODEL * 32; i += 256) {
      const int dr = i >> 5, kk = i & 31;
      Wl[dr][kk] = projw[(size_t)dr * DMODEL + kt + kk];
    }
    __syncthreads();
#pragma unroll
    for (int kk = 0; kk < 32; ++kk) {
      const float w = Wl[tid][kk];
#pragma unroll
      for (int tt = 0; tt < TT_TILE; ++tt) acc[tt] = fmaf(nd[tt][kt + kk], w, acc[tt]);
    }
  }

  const float pb = projb[tid];
  for (int tt = 0; tt < TT_TILE; ++tt) {
    const size_t o = ((size_t)b * TSEQ + t0 + tt) * DMODEL + tid;
    out[o] = x[o] + pb + acc[tt];
  }
}

// ---------------------------------------------------------------------------
extern "C" void kernel_launch(void* const* d_in, const int* in_sizes, int n_in,
                              void* d_out, int out_size, void* d_ws, size_t ws_size,
                              hipStream_t stream)
{
  const float* x = (const float*)d_in[0];
  TeamParams tp0 { (const float*)d_in[1], (const float*)d_in[2], (const float*)d_in[3],
                   (const float*)d_in[4], (const float*)d_in[5], (const float*)d_in[6],
                   (const float*)d_in[7], (const float*)d_in[8] };
  TeamParams tp1 { (const float*)d_in[9], (const float*)d_in[10], (const float*)d_in[11],
                   (const float*)d_in[12], (const float*)d_in[13], (const float*)d_in[14],
                   (const float*)d_in[15], (const float*)d_in[16] };
  const float* lam   = (const float*)d_in[17];
  const float* gnw   = (const float*)d_in[18];
  const float* gnb   = (const float*)d_in[19];
  const float* projw = (const float*)d_in[20];
  const float* projb = (const float*)d_in[21];

  // ws layout (bytes):
  //   Sg     @ 0          : 8,388,608 ushort = 16,777,216 B   (diffb aliases here)
  //   Pbuf   @ 16,777,216 : 8,192 f
  //   yhead  @ 16,809,984 : 2,097,152 f
  //   stats  @ 25,198,592 : 64 f
  //   adg    @ 25,198,848 : 262,144 float2
  //   xg     @ 27,296,000 : 20,971,520 ushort
  //   zg     @ 69,239,040 : 4,194,304 ushort     (total ~74 MB)
  char* wsb = (char*)d_ws;
  unsigned short* Sg = (unsigned short*)wsb;
  float* diffb = (float*)wsb;  // alias: Sg dead after k3
  float* Pbuf  = (float*)(wsb + 16777216);
  float* yhead = (float*)(wsb + 16809984);
  float* stats = (float*)(wsb + 25198592);
  float2* adg  = (float2*)(wsb + 25198848);
  unsigned short* xg = (unsigned short*)(wsb + 27296000);
  unsigned short* zg = (unsigned short*)(wsb + 69239040);

  k1_proj_scan<<<dim3(NWG), dim3(256), 0, stream>>>(x, tp0, tp1, Sg, Pbuf, adg, xg, zg);
  carry_kernel<<<dim3(2 * NHEADS * BBATCH), dim3(256), 0, stream>>>(Sg, Pbuf);
  k3_scan_out<<<dim3(NWG), dim3(256), 0, stream>>>(Sg, adg, xg, zg, tp0, tp1, yhead);
  diff_stats_kernel<<<dim3(NHEADS * BBATCH), dim3(1024), 0, stream>>>(yhead, lam, diffb, stats);
  final_kernel<<<dim3(BBATCH * (TSEQ / TT_TILE)), dim3(256), 0, stream>>>(
      x, diffb, stats, gnw, gnb, projw, projb, (float*)d_out);
}

// Round 4
// 161.565 us; speedup vs baseline: 2.5947x; 1.5354x over previous
//
#include <hip/hip_runtime.h>
#include <math.h>

#define NHEADS 16
#define BBATCH 2
#define TSEQ   2048
#define HD     16
#define DIN    32
#define DST    64
#define CONVD  160
#define DPROJ  194
#define NHIN   2
#define DMODEL 256
#define CHUNK  32
#define NCHUNK (TSEQ / CHUNK)                  // 64
#define NWG    (2 * NHEADS * BBATCH * NCHUNK)  // 4096
#define YS     36                               // ysh row stride

struct TeamParams {
  const float *Win, *convw, *convb, *dtb, *Alog, *Dp, *nw, *Wout;
};

typedef __attribute__((ext_vector_type(8)))  short short8;
typedef __attribute__((ext_vector_type(16))) float f32x16;

__device__ __forceinline__ float sigm(float v) { return 1.0f / (1.0f + __expf(-v)); }

__device__ __forceinline__ unsigned short f2bf(float f) {
  union { float f; unsigned u; } x; x.f = f;
  unsigned r = x.u + 0x7fffu + ((x.u >> 16) & 1u);
  return (unsigned short)(r >> 16);
}
__device__ __forceinline__ float bf2f(unsigned short b) {
  union { unsigned u; float f; } x; x.u = ((unsigned)b) << 16; return x.f;
}
__device__ __forceinline__ ushort4 pack4(float a, float b, float c, float d) {
  return make_ushort4(f2bf(a), f2bf(b), f2bf(c), f2bf(d));
}
__device__ __forceinline__ short8 pack_bf8(float4 a, float4 b) {
  short8 r;
  r[0] = (short)f2bf(a.x); r[1] = (short)f2bf(a.y);
  r[2] = (short)f2bf(a.z); r[3] = (short)f2bf(a.w);
  r[4] = (short)f2bf(b.x); r[5] = (short)f2bf(b.y);
  r[6] = (short)f2bf(b.z); r[7] = (short)f2bf(b.w);
  return r;
}
__device__ __forceinline__ short8 zero8() {
  short8 r;
#pragma unroll
  for (int i = 0; i < 8; ++i) r[i] = 0;
  return r;
}

// ---------------------------------------------------------------------------
// K1: MFMA in-proj (32x32x16 bf16, K=HD=16) + parallel conv4 + activations;
// zero-init chunk scan producing y_intra (incl. D-term) + cum decay + final
// state Sg (bf16) + chunk decay product. Stores C (bf16), silu(z) (bf16),
// y_intra (f32), cums (f32x2). wg = (team, head, batch, chunk32).
// ---------------------------------------------------------------------------
__global__ __launch_bounds__(256)
void k1_proj_scan(const float* __restrict__ x, TeamParams tp0, TeamParams tp1,
                  unsigned short* __restrict__ Sg, float* __restrict__ Pbuf,
                  float2* __restrict__ cumsg, unsigned short* __restrict__ xgC,
                  unsigned short* __restrict__ zg, float* __restrict__ yintra)
{
  __shared__ float xbc[35][164];       // cols 0..159 conv chans (raw->act), 160..161 dt raw
  __shared__ float zb[35][36];         // z (in-proj rows 0..31)
  __shared__ float ysh[CHUNK][YS];     // y_intra
  __shared__ float2 dAdtL[CHUNK][NHIN];

  const int tid  = threadIdx.x;
  const int wg   = blockIdx.x;
  const int c    = wg % NCHUNK;
  const int b    = (wg / NCHUNK) % BBATCH;
  const int h    = (wg / (NCHUNK * BBATCH)) % NHEADS;
  const int team = wg / (NCHUNK * BBATCH * NHEADS);
  const TeamParams P = team ? tp1 : tp0;
  const int c0 = c * CHUNK;

  const int lane = tid & 63;
  const int wv   = tid >> 6;
  const int lrow = lane & 31;
  const int kg   = lane >> 5;   // k-group: k = kg*8 + j

  // ---- A fragments: u rows (slots) as bf16, straight from global x ----
  short8 afr0, afr1;
  {
    const int t = c0 - 3 + lrow;            // m0=0: slots 0..31
    if (t >= 0) {
      const float* xp = &x[((size_t)b * TSEQ + t) * DMODEL + h * HD + kg * 8];
      afr0 = pack_bf8(*reinterpret_cast<const float4*>(xp),
                      *reinterpret_cast<const float4*>(xp + 4));
    } else afr0 = zero8();
    if (lrow < 3) {                          // m0=1: slots 32..34
      const int t1 = c0 + 29 + lrow;
      const float* xp = &x[((size_t)b * TSEQ + t1) * DMODEL + h * HD + kg * 8];
      afr1 = pack_bf8(*reinterpret_cast<const float4*>(xp),
                      *reinterpret_cast<const float4*>(xp + 4));
    } else afr1 = zero8();
  }
  // ---- B fragments: Win rows as bf16 (wave wv owns N-tiles {2wv, 2wv+1} or {6}) ----
  const bool two = (wv < 3);
  const int n0a = two ? wv * 2 : 6;
  const int n0b = wv * 2 + 1;
  short8 bfrA, bfrB = zero8();
  {
    const int r = n0a * 32 + lrow;
    if (r < DPROJ) {
      const float* wp = &P.Win[((size_t)h * DPROJ + r) * HD + kg * 8];
      bfrA = pack_bf8(*reinterpret_cast<const float4*>(wp),
                      *reinterpret_cast<const float4*>(wp + 4));
    } else bfrA = zero8();
    if (two) {
      const int r2 = n0b * 32 + lrow;        // <= 191, always valid
      const float* wp = &P.Win[((size_t)h * DPROJ + r2) * HD + kg * 8];
      bfrB = pack_bf8(*reinterpret_cast<const float4*>(wp),
                      *reinterpret_cast<const float4*>(wp + 4));
    }
  }

  f32x16 z16;
#pragma unroll
  for (int i = 0; i < 16; ++i) z16[i] = 0.0f;

  // D layout (verified): col = lane&31, row = (reg&3) + 8*(reg>>2) + 4*(lane>>5)
  auto writeD = [&](const f32x16& d, int n0, int m0) {
    const int colid = lrow;
    if (m0 == 0) {
#pragma unroll
      for (int rg = 0; rg < 16; ++rg) {
        const int slot = (rg & 3) + 8 * (rg >> 2) + 4 * kg;
        if (n0 == 0)            zb[slot][colid] = d[rg];
        else if (n0 < 6)        xbc[slot][(n0 - 1) * 32 + colid] = d[rg];
        else if (colid < 2)     xbc[slot][160 + colid] = d[rg];
      }
    } else if (kg == 0) {
#pragma unroll
      for (int rg = 0; rg < 3; ++rg) {       // row_off 0,1,2 -> slots 32..34
        const int slot = 32 + rg;
        if (n0 == 0)            zb[slot][colid] = d[rg];
        else if (n0 < 6)        xbc[slot][(n0 - 1) * 32 + colid] = d[rg];
        else if (colid < 2)     xbc[slot][160 + colid] = d[rg];
      }
    }
  };

  {
    f32x16 d;
    d = __builtin_amdgcn_mfma_f32_32x32x16_bf16(afr0, bfrA, z16, 0, 0, 0);
    writeD(d, n0a, 0);
    d = __builtin_amdgcn_mfma_f32_32x32x16_bf16(afr1, bfrA, z16, 0, 0, 0);
    writeD(d, n0a, 1);
    if (two) {
      d = __builtin_amdgcn_mfma_f32_32x32x16_bf16(afr0, bfrB, z16, 0, 0, 0);
      writeD(d, n0b, 0);
      d = __builtin_amdgcn_mfma_f32_32x32x16_bf16(afr1, bfrB, z16, 0, 0, 0);
      writeD(d, n0b, 1);
    }
  }
  __syncthreads();

  // ---- conv4 (parallel, 2-phase in-place) + dt/dA ----
  const int cg = tid >> 3;          // 0..31 -> 5 channels each
  const int tg = tid & 7;           // 0..7  -> 4 timesteps each
  const int ch0 = cg * 5;
  const int t0c = tg * 4;
  float outv[5][4];
#pragma unroll
  for (int q = 0; q < 5; ++q) {
    const int ch = ch0 + q;
    const float4 cw = *reinterpret_cast<const float4*>(&P.convw[((size_t)h * CONVD + ch) * 4]);
    const float cb = P.convb[h * CONVD + ch];
    float vv[7];
#pragma unroll
    for (int i = 0; i < 7; ++i) vv[i] = xbc[t0c + i][ch];
#pragma unroll
    for (int d0 = 0; d0 < 4; ++d0) {
      float v = cb;
      v = fmaf(cw.x, vv[d0], v);
      v = fmaf(cw.y, vv[d0 + 1], v);
      v = fmaf(cw.z, vv[d0 + 2], v);
      v = fmaf(cw.w, vv[d0 + 3], v);
      outv[q][d0] = v * sigm(v);
    }
  }
  if (tid < 2 * CHUNK) {
    const int t = tid >> 1, hi = tid & 1;
    const float dtbias = P.dtb[h * NHIN + hi];
    const float Ah = -__expf(P.Alog[h * NHIN + hi]);
    const float raw = xbc[3 + t][160 + hi] + dtbias;
    const float dtv = (raw > 20.f) ? raw : log1pf(__expf(raw));
    dAdtL[t][hi] = make_float2(__expf(dtv * Ah), dtv);
  }
  __syncthreads();
#pragma unroll
  for (int q = 0; q < 5; ++q)
#pragma unroll
    for (int d0 = 0; d0 < 4; ++d0) xbc[3 + t0c + d0][ch0 + q] = outv[q][d0];
  __syncthreads();

  if (tid < 128) {
    // ---- zero-init scan with y output: thread (ppp, ng), 8 states x 2 hi ----
    const int ppp = (tid >> 3) & 15, ng = tid & 7, nb = ng * 8;
    float h0r[8], h1r[8];
#pragma unroll
    for (int j = 0; j < 8; ++j) { h0r[j] = 0.f; h1r[j] = 0.f; }
    float pp0 = 1.f, pp1 = 1.f;
    const float Dp0 = P.Dp[h * NHIN + 0];
    const float Dp1 = P.Dp[h * NHIN + 1];
    for (int t = 0; t < CHUNK; ++t) {
      const float2 ad0 = dAdtL[t][0];
      const float2 ad1 = dAdtL[t][1];
      const float xv0 = xbc[3 + t][ppp];
      const float xv1 = xbc[3 + t][16 + ppp];
      const float4 b0 = *reinterpret_cast<const float4*>(&xbc[3 + t][32 + nb]);
      const float4 b1 = *reinterpret_cast<const float4*>(&xbc[3 + t][36 + nb]);
      const float4 q0 = *reinterpret_cast<const float4*>(&xbc[3 + t][96 + nb]);
      const float4 q1 = *reinterpret_cast<const float4*>(&xbc[3 + t][100 + nb]);
      const float bv[8] = {b0.x, b0.y, b0.z, b0.w, b1.x, b1.y, b1.z, b1.w};
      const float cv[8] = {q0.x, q0.y, q0.z, q0.w, q1.x, q1.y, q1.z, q1.w};
      const float cf0 = ad0.y * xv0, cf1 = ad1.y * xv1;
      float yp0 = 0.f, yp1 = 0.f;
#pragma unroll
      for (int j = 0; j < 8; ++j) {
        h0r[j] = fmaf(ad0.x, h0r[j], cf0 * bv[j]);
        yp0 = fmaf(h0r[j], cv[j], yp0);
        h1r[j] = fmaf(ad1.x, h1r[j], cf1 * bv[j]);
        yp1 = fmaf(h1r[j], cv[j], yp1);
      }
      yp0 += __shfl_down(yp0, 4, 8); yp0 += __shfl_down(yp0, 2, 8); yp0 += __shfl_down(yp0, 1, 8);
      yp1 += __shfl_down(yp1, 4, 8); yp1 += __shfl_down(yp1, 2, 8); yp1 += __shfl_down(yp1, 1, 8);
      pp0 *= ad0.x; pp1 *= ad1.x;
      if (ng == 0) {
        ysh[t][ppp]      = fmaf(Dp0, xv0, yp0);
        ysh[t][16 + ppp] = fmaf(Dp1, xv1, yp1);
      }
      if (tid == 0) cumsg[(size_t)wg * CHUNK + t] = make_float2(pp0, pp1);
    }
    const size_t base0 = ((size_t)team * NHEADS + h) * BBATCH + b;
    const size_t sb0 = (((base0 * NCHUNK + c) * NHIN + 0) * HD + ppp) * DST + nb;
    const size_t sb1 = (((base0 * NCHUNK + c) * NHIN + 1) * HD + ppp) * DST + nb;
    *reinterpret_cast<ushort4*>(&Sg[sb0])     = pack4(h0r[0], h0r[1], h0r[2], h0r[3]);
    *reinterpret_cast<ushort4*>(&Sg[sb0 + 4]) = pack4(h0r[4], h0r[5], h0r[6], h0r[7]);
    *reinterpret_cast<ushort4*>(&Sg[sb1])     = pack4(h1r[0], h1r[1], h1r[2], h1r[3]);
    *reinterpret_cast<ushort4*>(&Sg[sb1 + 4]) = pack4(h1r[4], h1r[5], h1r[6], h1r[7]);
    if (tid == 0) {
      Pbuf[(base0 * NCHUNK + c) * NHIN + 0] = pp0;
      Pbuf[(base0 * NCHUNK + c) * NHIN + 1] = pp1;
    }
  } else {
    // ---- concurrent stores: C (bf16) and silu(z) (bf16) ----
    const int ct = tid - 128;
#pragma unroll
    for (int k = 0; k < 4; ++k) {
      const int idx = ct + k * 128;               // 0..511: [t][n4]
      const int t = idx >> 4, n4 = (idx & 15) * 4;
      const float4 v = *reinterpret_cast<const float4*>(&xbc[3 + t][96 + n4]);
      *reinterpret_cast<ushort4*>(&xgC[(size_t)wg * (CHUNK * DST) + t * DST + n4]) =
          pack4(v.x, v.y, v.z, v.w);
    }
    const size_t zbase = (((size_t)team * NHEADS + h) * BBATCH + b) * (TSEQ * DIN) +
                         (size_t)c0 * DIN;
#pragma unroll
    for (int k = 0; k < 2; ++k) {
      const int idx = ct + k * 128;               // 0..255
      const int t = idx >> 3, c4 = (idx & 7) * 4;
      const float4 v = *reinterpret_cast<const float4*>(&zb[3 + t][c4]);
      *reinterpret_cast<ushort4*>(&zg[zbase + (size_t)t * DIN + c4]) =
          pack4(v.x * sigm(v.x), v.y * sigm(v.y), v.z * sigm(v.z), v.w * sigm(v.w));
    }
  }
  __syncthreads();

  // ---- y_intra store (f32) ----
  {
    const int t = tid >> 3, c4 = (tid & 7) * 4;
    const float4 v = *reinterpret_cast<const float4*>(&ysh[t][c4]);
    *reinterpret_cast<float4*>(&yintra[(size_t)wg * (CHUNK * DIN) + t * DIN + c4]) = v;
  }
}

// ---------------------------------------------------------------------------
// Carry: sequential combine over 64 chunks; Sg (chunk finals, bf16) -> H_in.
// ---------------------------------------------------------------------------
__global__ __launch_bounds__(256)
void carry_kernel(unsigned short* __restrict__ Sg, const float* __restrict__ Pbuf)
{
  const int wg = blockIdx.x;
  const int b = wg % BBATCH;
  const int h = (wg / BBATCH) % NHEADS;
  const int team = wg / (BBATCH * NHEADS);
  const int tid = threadIdx.x;
  const int hi = tid >> 7;
  const int pp = (tid >> 3) & 15;
  const int ng = tid & 7;
  const int nb = ng * 8;
  const size_t base0 = ((size_t)team * NHEADS + h) * BBATCH + b;

  float hc[8] = {0, 0, 0, 0, 0, 0, 0, 0};
  for (int c = 0; c < NCHUNK; ++c) {
    const size_t sb = (((base0 * NCHUNK + c) * NHIN + hi) * HD + pp) * DST + nb;
    const float Pv = Pbuf[(base0 * NCHUNK + c) * NHIN + hi];
    const ushort4 a0 = *reinterpret_cast<const ushort4*>(&Sg[sb]);
    const ushort4 a1 = *reinterpret_cast<const ushort4*>(&Sg[sb + 4]);
    const float tmp[8] = {bf2f(a0.x), bf2f(a0.y), bf2f(a0.z), bf2f(a0.w),
                          bf2f(a1.x), bf2f(a1.y), bf2f(a1.z), bf2f(a1.w)};
    *reinterpret_cast<ushort4*>(&Sg[sb])     = pack4(hc[0], hc[1], hc[2], hc[3]);
    *reinterpret_cast<ushort4*>(&Sg[sb + 4]) = pack4(hc[4], hc[5], hc[6], hc[7]);
#pragma unroll
    for (int j = 0; j < 8; ++j) hc[j] = fmaf(Pv, hc[j], tmp[j]);
  }
}

// ---------------------------------------------------------------------------
// K3: y = y_intra + cum * (C · H_in)  [4 MFMAs, wave 0], then gate + rms +
// out-proj. No scan.
// ---------------------------------------------------------------------------
__global__ __launch_bounds__(256)
void k3_combine_out(const unsigned short* __restrict__ Sg,
                    const float2* __restrict__ cumsg,
                    const unsigned short* __restrict__ xgC,
                    const unsigned short* __restrict__ zg,
                    TeamParams tp0, TeamParams tp1,
                    const float* __restrict__ yintra, float* __restrict__ yhead)
{
  __shared__ float ysh[CHUNK][YS];
  __shared__ float wn[16][33];
  __shared__ float cums2[CHUNK][2];

  const int tid  = threadIdx.x;
  const int wg   = blockIdx.x;
  const int c    = wg % NCHUNK;
  const int b    = (wg / NCHUNK) % BBATCH;
  const int h    = (wg / (NCHUNK * BBATCH)) % NHEADS;
  const int team = wg / (NCHUNK * BBATCH * NHEADS);
  const TeamParams P = team ? tp1 : tp0;
  const int c0 = c * CHUNK;
  const size_t base0 = ((size_t)team * NHEADS + h) * BBATCH + b;

  // ---- MFMA path (wave 0 only): A = C[t][n], B = H_in[n][col(hi,p)] ----
  f32x16 acc;
  if (tid < 64) {
    const int colid = tid & 31, kg = tid >> 5;
    const unsigned short* ca = &xgC[(size_t)wg * (CHUNK * DST) + (size_t)colid * DST + kg * 8];
    const unsigned short* hb = &Sg[(base0 * NCHUNK + c) * (NHIN * HD * DST) +
                                   (size_t)colid * DST + kg * 8];
#pragma unroll
    for (int i = 0; i < 16; ++i) acc[i] = 0.0f;
    const short8 a0 = *reinterpret_cast<const short8*>(ca);
    const short8 a1 = *reinterpret_cast<const short8*>(ca + 16);
    const short8 a2 = *reinterpret_cast<const short8*>(ca + 32);
    const short8 a3 = *reinterpret_cast<const short8*>(ca + 48);
    const short8 b0 = *reinterpret_cast<const short8*>(hb);
    const short8 b1 = *reinterpret_cast<const short8*>(hb + 16);
    const short8 b2 = *reinterpret_cast<const short8*>(hb + 32);
    const short8 b3 = *reinterpret_cast<const short8*>(hb + 48);
    acc = __builtin_amdgcn_mfma_f32_32x32x16_bf16(a0, b0, acc, 0, 0, 0);
    acc = __builtin_amdgcn_mfma_f32_32x32x16_bf16(a1, b1, acc, 0, 0, 0);
    acc = __builtin_amdgcn_mfma_f32_32x32x16_bf16(a2, b2, acc, 0, 0, 0);
    acc = __builtin_amdgcn_mfma_f32_32x32x16_bf16(a3, b3, acc, 0, 0, 0);
  }

  // ---- staging (all threads) ----
  for (int i = tid; i < HD * DIN; i += 256) {
    const int o = i >> 5, dn = i & 31;
    wn[o][dn] = P.Wout[((size_t)h * HD + o) * DIN + dn] * P.nw[h * DIN + dn];
  }
  {
    const int t = tid >> 3, c4 = (tid & 7) * 4;
    const float4 v = *reinterpret_cast<const float4*>(&yintra[(size_t)wg * (CHUNK * DIN) + tid * 4]);
    *reinterpret_cast<float4*>(&ysh[t][c4]) = v;
  }
  if (tid < CHUNK) {
    const float2 v = cumsg[(size_t)wg * CHUNK + tid];
    cums2[tid][0] = v.x; cums2[tid][1] = v.y;
  }
  __syncthreads();

  // ---- combine: ysh[t][din] += cum[t][hi] * y_inter ----
  if (tid < 64) {
    const int colid = tid & 31, kg = tid >> 5;
    const int hi = colid >> 4;
#pragma unroll
    for (int rg = 0; rg < 16; ++rg) {
      const int t = (rg & 3) + 8 * (rg >> 2) + 4 * kg;
      ysh[t][colid] = fmaf(cums2[t][hi], acc[rg], ysh[t][colid]);
    }
  }
  __syncthreads();

  // ---- gate with silu(z), rms, out-proj. thread = (tl 0..31, q 0..7) ----
  const int q = tid & 7, tl = tid >> 3;
  const size_t zbase = base0 * (TSEQ * DIN) + (size_t)(c0 + tl) * DIN + q * 4;
  const ushort4 z4 = *reinterpret_cast<const ushort4*>(&zg[zbase]);
  const float zs[4] = {bf2f(z4.x), bf2f(z4.y), bf2f(z4.z), bf2f(z4.w)};
  float yg[4];
  float ss = 0.0f;
#pragma unroll
  for (int j = 0; j < 4; ++j) {
    const float g = ysh[tl][q * 4 + j] * zs[j];
    yg[j] = g;
    ss += g * g;
  }
  ss += __shfl_xor(ss, 1, 8);
  ss += __shfl_xor(ss, 2, 8);
  ss += __shfl_xor(ss, 4, 8);
  const float rms = rsqrtf(ss * (1.0f / DIN) + 1e-5f);
#pragma unroll
  for (int j = 0; j < 4; ++j) ysh[tl][q * 4 + j] = yg[j];
  __syncthreads();

  float acc0 = 0.f, acc1 = 0.f;
#pragma unroll
  for (int dn = 0; dn < DIN; ++dn) {
    const float v = ysh[tl][dn];
    acc0 = fmaf(v, wn[q * 2][dn], acc0);
    acc1 = fmaf(v, wn[q * 2 + 1][dn], acc1);
  }
  float* yout = &yhead[base0 * (TSEQ * HD) + (size_t)(c0 + tl) * HD + q * 2];
  *reinterpret_cast<float2*>(yout) = make_float2(rms * acc0, rms * acc1);
}

// ---------------------------------------------------------------------------
__global__ __launch_bounds__(1024)
void diff_stats_kernel(const float* __restrict__ yhead, const float* __restrict__ lam,
                       float* __restrict__ diffb, float* __restrict__ stats)
{
  const int wg = blockIdx.x;  // h*2 + b
  const int b = wg & 1;
  const int h = wg >> 1;
  const int tid = threadIdx.x;
  const float4* y1 = reinterpret_cast<const float4*>(
      &yhead[(((size_t)0 * NHEADS + h) * BBATCH + b) * (TSEQ * HD)]);
  const float4* y2 = reinterpret_cast<const float4*>(
      &yhead[(((size_t)1 * NHEADS + h) * BBATCH + b) * (TSEQ * HD)]);
  float4* dd = reinterpret_cast<float4*>(&diffb[(size_t)wg * (TSEQ * HD)]);

  float s = 0.0f, s2 = 0.0f;
  for (int i = tid; i < TSEQ * HD / 4; i += 1024) {
    const float4 a = y1[i];
    const float4 bb = y2[i];
    const float4 l = *reinterpret_cast<const float4*>(&lam[h * HD + (i & 3) * 4]);
    float4 d;
    d.x = a.x - l.x * bb.x; d.y = a.y - l.y * bb.y;
    d.z = a.z - l.z * bb.z; d.w = a.w - l.w * bb.w;
    dd[i] = d;
    s += d.x + d.y + d.z + d.w;
    s2 += d.x * d.x + d.y * d.y + d.z * d.z + d.w * d.w;
  }
  __shared__ float red[32];
#pragma unroll
  for (int off = 32; off; off >>= 1) {
    s += __shfl_down(s, off);
    s2 += __shfl_down(s2, off);
  }
  const int wv = tid >> 6;
  if ((tid & 63) == 0) { red[wv * 2] = s; red[wv * 2 + 1] = s2; }
  __syncthreads();
  if (tid == 0) {
    float S = 0, S2 = 0;
#pragma unroll
    for (int w = 0; w < 16; ++w) { S += red[w * 2]; S2 += red[w * 2 + 1]; }
    const float inv = 1.0f / (TSEQ * HD);
    const float mean = S * inv;
    const float var = S2 * inv - mean * mean;
    stats[wg * 2] = mean;
    stats[wg * 2 + 1] = rsqrtf(var + 1e-5f);
  }
}

#define TT_TILE 16
__global__ __launch_bounds__(256)
void final_kernel(const float* __restrict__ x, const float* __restrict__ diffb,
                  const float* __restrict__ stats, const float* __restrict__ gnw,
                  const float* __restrict__ gnb, const float* __restrict__ projw,
                  const float* __restrict__ projb, float* __restrict__ out)
{
  __shared__ float nd[TT_TILE][DMODEL];
  __shared__ float Wl[DMODEL][33];

  const int wg = blockIdx.x;
  const int nseg = TSEQ / TT_TILE;
  const int b = wg / nseg;
  const int t0 = (wg % nseg) * TT_TILE;
  const int tid = threadIdx.x;
  const int h = tid >> 4, hd = tid & 15;

  const float mean = stats[(h * BBATCH + b) * 2];
  const float rstd = stats[(h * BBATCH + b) * 2 + 1];
  const float g = gnw[h * HD + hd];
  const float be = gnb[h * HD + hd];
  for (int tt = 0; tt < TT_TILE; ++tt) {
    const float d = diffb[((size_t)(h * BBATCH + b) * TSEQ + t0 + tt) * HD + hd];
    nd[tt][tid] = (d - mean) * rstd * g + be;
  }

  float acc[TT_TILE];
#pragma unroll
  for (int tt = 0; tt < TT_TILE; ++tt) acc[tt] = 0.0f;

  for (int kt = 0; kt < DMODEL; kt += 32) {
    __syncthreads();
    for (int i = tid; i < DMODEL * 32; i += 256) {
      const int dr = i >> 5, kk = i & 31;
      Wl[dr][kk] = projw[(size_t)dr * DMODEL + kt + kk];
    }
    __syncthreads();
#pragma unroll
    for (int kk = 0; kk < 32; ++kk) {
      const float w = Wl[tid][kk];
#pragma unroll
      for (int tt = 0; tt < TT_TILE; ++tt) acc[tt] = fmaf(nd[tt][kt + kk], w, acc[tt]);
    }
  }

  const float pb = projb[tid];
  for (int tt = 0; tt < TT_TILE; ++tt) {
    const size_t o = ((size_t)b * TSEQ + t0 + tt) * DMODEL + tid;
    out[o] = x[o] + pb + acc[tt];
  }
}

// ---------------------------------------------------------------------------
extern "C" void kernel_launch(void* const* d_in, const int* in_sizes, int n_in,
                              void* d_out, int out_size, void* d_ws, size_t ws_size,
                              hipStream_t stream)
{
  const float* x = (const float*)d_in[0];
  TeamParams tp0 { (const float*)d_in[1], (const float*)d_in[2], (const float*)d_in[3],
                   (const float*)d_in[4], (const float*)d_in[5], (const float*)d_in[6],
                   (const float*)d_in[7], (const float*)d_in[8] };
  TeamParams tp1 { (const float*)d_in[9], (const float*)d_in[10], (const float*)d_in[11],
                   (const float*)d_in[12], (const float*)d_in[13], (const float*)d_in[14],
                   (const float*)d_in[15], (const float*)d_in[16] };
  const float* lam   = (const float*)d_in[17];
  const float* gnw   = (const float*)d_in[18];
  const float* gnb   = (const float*)d_in[19];
  const float* projw = (const float*)d_in[20];
  const float* projb = (const float*)d_in[21];

  // ws layout (bytes):
  //   Sg     @ 0           16,777,216   (diffb 4 MB aliases here; Sg dead after k3)
  //   Pbuf   @ 16,777,216      32,768
  //   yhead  @ 16,809,984   8,388,608
  //   stats  @ 25,198,592         256
  //   cumsg  @ 25,198,848   1,048,576
  //   xgC    @ 26,247,424  16,777,216
  //   zg     @ 43,024,640   8,388,608
  //   yintra @ 51,413,248  16,777,216   (total ~68 MB)
  char* wsb = (char*)d_ws;
  unsigned short* Sg = (unsigned short*)wsb;
  float* diffb = (float*)wsb;
  float* Pbuf  = (float*)(wsb + 16777216);
  float* yhead = (float*)(wsb + 16809984);
  float* stats = (float*)(wsb + 25198592);
  float2* cumsg = (float2*)(wsb + 25198848);
  unsigned short* xgC = (unsigned short*)(wsb + 26247424);
  unsigned short* zg  = (unsigned short*)(wsb + 43024640);
  float* yintra = (float*)(wsb + 51413248);

  k1_proj_scan<<<dim3(NWG), dim3(256), 0, stream>>>(x, tp0, tp1, Sg, Pbuf, cumsg, xgC, zg, yintra);
  carry_kernel<<<dim3(2 * NHEADS * BBATCH), dim3(256), 0, stream>>>(Sg, Pbuf);
  k3_combine_out<<<dim3(NWG), dim3(256), 0, stream>>>(Sg, cumsg, xgC, zg, tp0, tp1, yintra, yhead);
  diff_stats_kernel<<<dim3(NHEADS * BBATCH), dim3(1024), 0, stream>>>(yhead, lam, diffb, stats);
  final_kernel<<<dim3(BBATCH * (TSEQ / TT_TILE)), dim3(256), 0, stream>>>(
      x, diffb, stats, gnw, gnb, projw, projb, (float*)d_out);
}

// Round 5
// 136.956 us; speedup vs baseline: 3.0610x; 1.1797x over previous
//
#include <hip/hip_runtime.h>
#include <math.h>

#define NHEADS 16
#define BBATCH 2
#define TSEQ   2048
#define HD     16
#define DIN    32
#define DST    64
#define CONVD  160
#define DPROJ  194
#define NHIN   2
#define DMODEL 256
#define CHUNK  32
#define NCHUNK (TSEQ / CHUNK)                  // 64
#define NWG    (2 * NHEADS * BBATCH * NCHUNK)  // 4096
#define YS     36

struct TeamParams {
  const float *Win, *convw, *convb, *dtb, *Alog, *Dp, *nw, *Wout;
};

typedef __attribute__((ext_vector_type(8)))  _Float16 half8;
typedef __attribute__((ext_vector_type(16))) float    f32x16;

__device__ __forceinline__ float sigm(float v) { return 1.0f / (1.0f + __expf(-v)); }

__device__ __forceinline__ half8 pack_h8(float4 a, float4 b) {
  half8 r;
  r[0] = (_Float16)a.x; r[1] = (_Float16)a.y; r[2] = (_Float16)a.z; r[3] = (_Float16)a.w;
  r[4] = (_Float16)b.x; r[5] = (_Float16)b.y; r[6] = (_Float16)b.z; r[7] = (_Float16)b.w;
  return r;
}
__device__ __forceinline__ half8 zero_h8() {
  half8 r;
#pragma unroll
  for (int i = 0; i < 8; ++i) r[i] = (_Float16)0.f;
  return r;
}

// ---------------------------------------------------------------------------
// K1: MFMA in-proj (f16 32x32x16) + parallel conv4 + SSD chunk computation:
//   cl[t]  = prefix(dt*A)         (shfl scan)
//   G      = C·B^T                (4 MFMA)
//   y_intra= (L∘G)·(dt x) + D x   (4 MFMA)   L[t,s]=exp(cl[t]-cl[s]), s<=t
//   S^T    = (w dt x)^T·B         (4 MFMA)   w[s]=exp(cl[31]-cl[s])
// No serial scan. wg = (team, head, batch, chunk32), 256 threads, 3 barriers.
// ---------------------------------------------------------------------------
__global__ __launch_bounds__(256)
void k1_proj_ssd(const float* __restrict__ x, TeamParams tp0, TeamParams tp1,
                 _Float16* __restrict__ Sg, float* __restrict__ Pbuf,
                 float2* __restrict__ cumsg, _Float16* __restrict__ xgC,
                 _Float16* __restrict__ zg, float* __restrict__ yintra)
{
  __shared__ _Float16 xbcH[35][168];  // in-proj out (raw) -> conv act; cols 0..159
  __shared__ _Float16 zbH[35][40];    // silu(z)
  __shared__ float    dtraw[35][2];
  __shared__ float    clL[2][32];     // cumulative log-decay
  __shared__ float    dtL[2][32];
  __shared__ _Float16 Gm[2][32][40];  // masked L∘G
  __shared__ _Float16 XtL[32][40];    // (dt*x)^T  rows r=hi*16+p, cols s
  __shared__ _Float16 WXt[32][40];    // (w*dt*x)^T
  __shared__ _Float16 BmT[64][40];    // B^T: [n][s]
  __shared__ _Float16 StL[32][68];    // S^T staging rows r, cols n

  const int tid  = threadIdx.x;
  const int wg   = blockIdx.x;
  const int c    = wg % NCHUNK;
  const int b    = (wg / NCHUNK) % BBATCH;
  const int h    = (wg / (NCHUNK * BBATCH)) % NHEADS;
  const int team = wg / (NCHUNK * BBATCH * NHEADS);
  const TeamParams P = team ? tp1 : tp0;
  const int c0 = c * CHUNK;
  const size_t base0 = ((size_t)team * NHEADS + h) * BBATCH + b;

  const int lane = tid & 63;
  const int wv   = tid >> 6;
  const int lrow = lane & 31;
  const int kg   = lane >> 5;

  // ================= phase 1: in-proj MFMA =================
  half8 afr0, afr1;
  {
    const int t = c0 - 3 + lrow;
    if (t >= 0) {
      const float* xp = &x[((size_t)b * TSEQ + t) * DMODEL + h * HD + kg * 8];
      afr0 = pack_h8(*reinterpret_cast<const float4*>(xp),
                     *reinterpret_cast<const float4*>(xp + 4));
    } else afr0 = zero_h8();
    if (lrow < 3) {
      const int t1 = c0 + 29 + lrow;
      const float* xp = &x[((size_t)b * TSEQ + t1) * DMODEL + h * HD + kg * 8];
      afr1 = pack_h8(*reinterpret_cast<const float4*>(xp),
                     *reinterpret_cast<const float4*>(xp + 4));
    } else afr1 = zero_h8();
  }
  const bool two = (wv < 3);
  const int n0a = two ? wv * 2 : 6;
  const int n0b = wv * 2 + 1;
  half8 bfrA, bfrB = zero_h8();
  {
    const int r = n0a * 32 + lrow;
    if (r < DPROJ) {
      const float* wp = &P.Win[((size_t)h * DPROJ + r) * HD + kg * 8];
      bfrA = pack_h8(*reinterpret_cast<const float4*>(wp),
                     *reinterpret_cast<const float4*>(wp + 4));
    } else bfrA = zero_h8();
    if (two) {
      const int r2 = n0b * 32 + lrow;
      const float* wp = &P.Win[((size_t)h * DPROJ + r2) * HD + kg * 8];
      bfrB = pack_h8(*reinterpret_cast<const float4*>(wp),
                     *reinterpret_cast<const float4*>(wp + 4));
    }
  }

  f32x16 z16;
#pragma unroll
  for (int i = 0; i < 16; ++i) z16[i] = 0.0f;

  auto writeD = [&](const f32x16& d, int n0, int m0) {
    const int colid = lrow;
    if (m0 == 0) {
#pragma unroll
      for (int rg = 0; rg < 16; ++rg) {
        const int slot = (rg & 3) + 8 * (rg >> 2) + 4 * kg;
        const float v = d[rg];
        if (n0 == 0)            zbH[slot][colid] = (_Float16)(v * sigm(v));
        else if (n0 < 6)        xbcH[slot][(n0 - 1) * 32 + colid] = (_Float16)v;
        else if (colid < 2)     dtraw[slot][colid] = v;
      }
    } else if (kg == 0) {
#pragma unroll
      for (int rg = 0; rg < 3; ++rg) {
        const int slot = 32 + rg;
        const float v = d[rg];
        if (n0 == 0)            zbH[slot][colid] = (_Float16)(v * sigm(v));
        else if (n0 < 6)        xbcH[slot][(n0 - 1) * 32 + colid] = (_Float16)v;
        else if (colid < 2)     dtraw[slot][colid] = v;
      }
    }
  };

  {
    f32x16 d;
    d = __builtin_amdgcn_mfma_f32_32x32x16_f16(afr0, bfrA, z16, 0, 0, 0);
    writeD(d, n0a, 0);
    d = __builtin_amdgcn_mfma_f32_32x32x16_f16(afr1, bfrA, z16, 0, 0, 0);
    writeD(d, n0a, 1);
    if (two) {
      d = __builtin_amdgcn_mfma_f32_32x32x16_f16(afr0, bfrB, z16, 0, 0, 0);
      writeD(d, n0b, 0);
      d = __builtin_amdgcn_mfma_f32_32x32x16_f16(afr1, bfrB, z16, 0, 0, 0);
      writeD(d, n0b, 1);
    }
  }
  __syncthreads();   // B1

  // ================= phase 2: conv read + dt prefix-scan =================
  const int cg = tid & 31, tg = tid >> 3 >> 2;   // tg = tid>>5, 0..7
  const int ch0 = cg * 5, t0c = tg * 4;
  float outv[5][4];
#pragma unroll
  for (int q = 0; q < 5; ++q) {
    const int ch = ch0 + q;
    const float4 cw = *reinterpret_cast<const float4*>(&P.convw[((size_t)h * CONVD + ch) * 4]);
    const float cb = P.convb[h * CONVD + ch];
    float vv[7];
#pragma unroll
    for (int i = 0; i < 7; ++i) vv[i] = (float)xbcH[t0c + i][ch];
#pragma unroll
    for (int d0 = 0; d0 < 4; ++d0) {
      float v = cb;
      v = fmaf(cw.x, vv[d0], v);
      v = fmaf(cw.y, vv[d0 + 1], v);
      v = fmaf(cw.z, vv[d0 + 2], v);
      v = fmaf(cw.w, vv[d0 + 3], v);
      outv[q][d0] = v * sigm(v);
    }
  }
  if (tid < 64) {
    const int t = tid & 31, hi = tid >> 5;
    const float dtbias = P.dtb[h * NHIN + hi];
    const float Ah = -__expf(P.Alog[h * NHIN + hi]);
    const float raw = dtraw[3 + t][hi] + dtbias;
    const float dtv = (raw > 20.f) ? raw : log1pf(__expf(raw));
    dtL[hi][t] = dtv;
    float s = dtv * Ah;
#pragma unroll
    for (int d = 1; d < 32; d <<= 1) {
      const float v = __shfl_up(s, d, 32);
      if (t >= d) s += v;
    }
    clL[hi][t] = s;
  }
  __syncthreads();   // B2

  // ================= phase 3: conv write-back + operand tiles =================
#pragma unroll
  for (int q = 0; q < 5; ++q) {
    const int ch = ch0 + q;
#pragma unroll
    for (int d0 = 0; d0 < 4; ++d0) {
      const int t = t0c + d0;
      xbcH[3 + t][ch] = (_Float16)outv[q][d0];
    }
    if (ch < DIN) {
      const int hi = ch >> 4;
      const float cl31 = clL[hi][31];
#pragma unroll
      for (int d0 = 0; d0 < 4; ++d0) {
        const int t = t0c + d0;
        const float dtv = dtL[hi][t];
        const float w = __expf(cl31 - clL[hi][t]);
        XtL[ch][t] = (_Float16)(dtv * outv[q][d0]);
        WXt[ch][t] = (_Float16)(w * dtv * outv[q][d0]);
      }
    } else if (ch < DIN + DST) {
#pragma unroll
      for (int d0 = 0; d0 < 4; ++d0) BmT[ch - DIN][t0c + d0] = (_Float16)outv[q][d0];
    }
  }
  __syncthreads();   // B3

  // ================= phase 4: wave-specialized =================
  if (wv == 0) {
    // ---- G = C·B^T ----
    f32x16 g;
#pragma unroll
    for (int i = 0; i < 16; ++i) g[i] = 0.0f;
#pragma unroll
    for (int kk = 0; kk < 4; ++kk) {
      const half8 af = *reinterpret_cast<const half8*>(&xbcH[3 + lrow][96 + kk * 16 + kg * 8]);
      const half8 bf = *reinterpret_cast<const half8*>(&xbcH[3 + lrow][32 + kk * 16 + kg * 8]);
      g = __builtin_amdgcn_mfma_f32_32x32x16_f16(af, bf, g, 0, 0, 0);
    }
    // ---- mask L∘G ----
    const float cls0 = clL[0][lrow], cls1 = clL[1][lrow];
#pragma unroll
    for (int rg = 0; rg < 16; ++rg) {
      const int t = (rg & 3) + 8 * (rg >> 2) + 4 * kg;
      const float gg = g[rg];
      float l0 = 0.f, l1 = 0.f;
      if (lrow <= t) { l0 = __expf(clL[0][t] - cls0); l1 = __expf(clL[1][t] - cls1); }
      Gm[0][t][lrow] = (_Float16)(l0 * gg);
      Gm[1][t][lrow] = (_Float16)(l1 * gg);
    }
    // ---- y_intra = (L∘G)·Xdt + D·x ----
    const half8 xb0 = *reinterpret_cast<const half8*>(&XtL[lrow][kg * 8]);
    const half8 xb1 = *reinterpret_cast<const half8*>(&XtL[lrow][16 + kg * 8]);
    float* yo = &yintra[(size_t)wg * (CHUNK * DIN)];
    {
      f32x16 acc;
#pragma unroll
      for (int i = 0; i < 16; ++i) acc[i] = 0.0f;
      acc = __builtin_amdgcn_mfma_f32_32x32x16_f16(
          *reinterpret_cast<const half8*>(&Gm[0][lrow][kg * 8]), xb0, acc, 0, 0, 0);
      acc = __builtin_amdgcn_mfma_f32_32x32x16_f16(
          *reinterpret_cast<const half8*>(&Gm[0][lrow][16 + kg * 8]), xb1, acc, 0, 0, 0);
      if (lrow < 16) {
        const float Dp0 = P.Dp[h * NHIN + 0];
#pragma unroll
        for (int rg = 0; rg < 16; ++rg) {
          const int t = (rg & 3) + 8 * (rg >> 2) + 4 * kg;
          yo[t * DIN + lrow] = acc[rg] + Dp0 * (float)xbcH[3 + t][lrow];
        }
      }
    }
    {
      f32x16 acc;
#pragma unroll
      for (int i = 0; i < 16; ++i) acc[i] = 0.0f;
      acc = __builtin_amdgcn_mfma_f32_32x32x16_f16(
          *reinterpret_cast<const half8*>(&Gm[1][lrow][kg * 8]), xb0, acc, 0, 0, 0);
      acc = __builtin_amdgcn_mfma_f32_32x32x16_f16(
          *reinterpret_cast<const half8*>(&Gm[1][lrow][16 + kg * 8]), xb1, acc, 0, 0, 0);
      if (lrow >= 16) {
        const float Dp1 = P.Dp[h * NHIN + 1];
#pragma unroll
        for (int rg = 0; rg < 16; ++rg) {
          const int t = (rg & 3) + 8 * (rg >> 2) + 4 * kg;
          yo[t * DIN + lrow] = acc[rg] + Dp1 * (float)xbcH[3 + t][lrow];
        }
      }
    }
  } else if (wv == 1) {
    // ---- S^T = (w dt x)^T · B ----
    const half8 wa0 = *reinterpret_cast<const half8*>(&WXt[lrow][kg * 8]);
    const half8 wa1 = *reinterpret_cast<const half8*>(&WXt[lrow][16 + kg * 8]);
    {
      f32x16 acc;
#pragma unroll
      for (int i = 0; i < 16; ++i) acc[i] = 0.0f;
      acc = __builtin_amdgcn_mfma_f32_32x32x16_f16(
          wa0, *reinterpret_cast<const half8*>(&BmT[lrow][kg * 8]), acc, 0, 0, 0);
      acc = __builtin_amdgcn_mfma_f32_32x32x16_f16(
          wa1, *reinterpret_cast<const half8*>(&BmT[lrow][16 + kg * 8]), acc, 0, 0, 0);
#pragma unroll
      for (int rg = 0; rg < 16; ++rg) {
        const int m = (rg & 3) + 8 * (rg >> 2) + 4 * kg;
        StL[m][lrow] = (_Float16)acc[rg];
      }
    }
    {
      f32x16 acc;
#pragma unroll
      for (int i = 0; i < 16; ++i) acc[i] = 0.0f;
      acc = __builtin_amdgcn_mfma_f32_32x32x16_f16(
          wa0, *reinterpret_cast<const half8*>(&BmT[32 + lrow][kg * 8]), acc, 0, 0, 0);
      acc = __builtin_amdgcn_mfma_f32_32x32x16_f16(
          wa1, *reinterpret_cast<const half8*>(&BmT[32 + lrow][16 + kg * 8]), acc, 0, 0, 0);
#pragma unroll
      for (int rg = 0; rg < 16; ++rg) {
        const int m = (rg & 3) + 8 * (rg >> 2) + 4 * kg;
        StL[m][32 + lrow] = (_Float16)acc[rg];
      }
    }
    // ---- StL -> Sg (coalesced) ----
    const size_t base2 = (base0 * NCHUNK + c) * (NHIN * HD * DST);
#pragma unroll
    for (int k = 0; k < 8; ++k) {
      const int idx = lane + k * 64;
      const int row = idx >> 4, c4 = (idx & 15) * 4;
      *reinterpret_cast<ushort4*>(&Sg[base2 + row * DST + c4]) =
          *reinterpret_cast<const ushort4*>(&StL[row][c4]);
    }
  } else if (wv == 2) {
    if (lane < 32) {
      cumsg[(size_t)wg * CHUNK + lane] =
          make_float2(__expf(clL[0][lane]), __expf(clL[1][lane]));
    } else if (lane == 32) {
      Pbuf[(base0 * NCHUNK + c) * NHIN + 0] = __expf(clL[0][31]);
    } else if (lane == 33) {
      Pbuf[(base0 * NCHUNK + c) * NHIN + 1] = __expf(clL[1][31]);
    }
#pragma unroll
    for (int k = 0; k < 8; ++k) {
      const int idx = lane + k * 64;
      const int t = idx >> 4, c4 = (idx & 15) * 4;
      *reinterpret_cast<ushort4*>(&xgC[(size_t)wg * (CHUNK * DST) + t * DST + c4]) =
          *reinterpret_cast<const ushort4*>(&xbcH[3 + t][96 + c4]);
    }
  } else {
    const size_t zbase = base0 * (TSEQ * DIN) + (size_t)c0 * DIN;
#pragma unroll
    for (int k = 0; k < 4; ++k) {
      const int idx = lane + k * 64;
      const int t = idx >> 3, c4 = (idx & 7) * 4;
      *reinterpret_cast<ushort4*>(&zg[zbase + t * DIN + c4]) =
          *reinterpret_cast<const ushort4*>(&zbH[3 + t][c4]);
    }
  }
}

// ---------------------------------------------------------------------------
// Carry: sequential combine over 64 chunks; Sg (chunk finals, f16) -> H_in.
// ---------------------------------------------------------------------------
__global__ __launch_bounds__(256)
void carry_kernel(_Float16* __restrict__ Sg, const float* __restrict__ Pbuf)
{
  const int wg = blockIdx.x;
  const int b = wg % BBATCH;
  const int h = (wg / BBATCH) % NHEADS;
  const int team = wg / (BBATCH * NHEADS);
  const int tid = threadIdx.x;
  const int hi = tid >> 7;
  const int pp = (tid >> 3) & 15;
  const int ng = tid & 7;
  const int nb = ng * 8;
  const size_t base0 = ((size_t)team * NHEADS + h) * BBATCH + b;

  float hc[8] = {0, 0, 0, 0, 0, 0, 0, 0};
  for (int c = 0; c < NCHUNK; ++c) {
    const size_t sb = (((base0 * NCHUNK + c) * NHIN + hi) * HD + pp) * DST + nb;
    const float Pv = Pbuf[(base0 * NCHUNK + c) * NHIN + hi];
    const half8 a = *reinterpret_cast<const half8*>(&Sg[sb]);
    half8 o;
#pragma unroll
    for (int j = 0; j < 8; ++j) o[j] = (_Float16)hc[j];
    *reinterpret_cast<half8*>(&Sg[sb]) = o;
#pragma unroll
    for (int j = 0; j < 8; ++j) hc[j] = fmaf(Pv, hc[j], (float)a[j]);
  }
}

// ---------------------------------------------------------------------------
// K3: y = y_intra + cum * (C · H_in)  [4 f16 MFMAs, wave 0], gate + rms +
// out-proj.
// ---------------------------------------------------------------------------
__global__ __launch_bounds__(256)
void k3_combine_out(const _Float16* __restrict__ Sg,
                    const float2* __restrict__ cumsg,
                    const _Float16* __restrict__ xgC,
                    const _Float16* __restrict__ zg,
                    TeamParams tp0, TeamParams tp1,
                    const float* __restrict__ yintra, float* __restrict__ yhead)
{
  __shared__ float ysh[CHUNK][YS];
  __shared__ float wn[16][33];
  __shared__ float cums2[CHUNK][2];

  const int tid  = threadIdx.x;
  const int wg   = blockIdx.x;
  const int c    = wg % NCHUNK;
  const int b    = (wg / NCHUNK) % BBATCH;
  const int h    = (wg / (NCHUNK * BBATCH)) % NHEADS;
  const int team = wg / (NCHUNK * BBATCH * NHEADS);
  const TeamParams P = team ? tp1 : tp0;
  const int c0 = c * CHUNK;
  const size_t base0 = ((size_t)team * NHEADS + h) * BBATCH + b;

  f32x16 acc;
  if (tid < 64) {
    const int colid = tid & 31, kg = tid >> 5;
    const _Float16* ca = &xgC[(size_t)wg * (CHUNK * DST) + (size_t)colid * DST + kg * 8];
    const _Float16* hb = &Sg[(base0 * NCHUNK + c) * (NHIN * HD * DST) +
                             (size_t)colid * DST + kg * 8];
#pragma unroll
    for (int i = 0; i < 16; ++i) acc[i] = 0.0f;
    const half8 a0 = *reinterpret_cast<const half8*>(ca);
    const half8 a1 = *reinterpret_cast<const half8*>(ca + 16);
    const half8 a2 = *reinterpret_cast<const half8*>(ca + 32);
    const half8 a3 = *reinterpret_cast<const half8*>(ca + 48);
    const half8 b0 = *reinterpret_cast<const half8*>(hb);
    const half8 b1 = *reinterpret_cast<const half8*>(hb + 16);
    const half8 b2 = *reinterpret_cast<const half8*>(hb + 32);
    const half8 b3 = *reinterpret_cast<const half8*>(hb + 48);
    acc = __builtin_amdgcn_mfma_f32_32x32x16_f16(a0, b0, acc, 0, 0, 0);
    acc = __builtin_amdgcn_mfma_f32_32x32x16_f16(a1, b1, acc, 0, 0, 0);
    acc = __builtin_amdgcn_mfma_f32_32x32x16_f16(a2, b2, acc, 0, 0, 0);
    acc = __builtin_amdgcn_mfma_f32_32x32x16_f16(a3, b3, acc, 0, 0, 0);
  }

  for (int i = tid; i < HD * DIN; i += 256) {
    const int o = i >> 5, dn = i & 31;
    wn[o][dn] = P.Wout[((size_t)h * HD + o) * DIN + dn] * P.nw[h * DIN + dn];
  }
  {
    const int t = tid >> 3, c4 = (tid & 7) * 4;
    const float4 v = *reinterpret_cast<const float4*>(&yintra[(size_t)wg * (CHUNK * DIN) + tid * 4]);
    *reinterpret_cast<float4*>(&ysh[t][c4]) = v;
  }
  if (tid < CHUNK) {
    const float2 v = cumsg[(size_t)wg * CHUNK + tid];
    cums2[tid][0] = v.x; cums2[tid][1] = v.y;
  }
  __syncthreads();

  if (tid < 64) {
    const int colid = tid & 31, kg = tid >> 5;
    const int hi = colid >> 4;
#pragma unroll
    for (int rg = 0; rg < 16; ++rg) {
      const int t = (rg & 3) + 8 * (rg >> 2) + 4 * kg;
      ysh[t][colid] = fmaf(cums2[t][hi], acc[rg], ysh[t][colid]);
    }
  }
  __syncthreads();

  const int q = tid & 7, tl = tid >> 3;
  const size_t zbase = base0 * (TSEQ * DIN) + (size_t)(c0 + tl) * DIN + q * 4;
  const _Float16* zp = &zg[zbase];
  float yg[4];
  float ss = 0.0f;
#pragma unroll
  for (int j = 0; j < 4; ++j) {
    const float g = ysh[tl][q * 4 + j] * (float)zp[j];
    yg[j] = g;
    ss += g * g;
  }
  ss += __shfl_xor(ss, 1, 8);
  ss += __shfl_xor(ss, 2, 8);
  ss += __shfl_xor(ss, 4, 8);
  const float rms = rsqrtf(ss * (1.0f / DIN) + 1e-5f);
#pragma unroll
  for (int j = 0; j < 4; ++j) ysh[tl][q * 4 + j] = yg[j];
  __syncthreads();

  float acc0 = 0.f, acc1 = 0.f;
#pragma unroll
  for (int dn = 0; dn < DIN; ++dn) {
    const float v = ysh[tl][dn];
    acc0 = fmaf(v, wn[q * 2][dn], acc0);
    acc1 = fmaf(v, wn[q * 2 + 1][dn], acc1);
  }
  float* yout = &yhead[base0 * (TSEQ * HD) + (size_t)(c0 + tl) * HD + q * 2];
  *reinterpret_cast<float2*>(yout) = make_float2(rms * acc0, rms * acc1);
}

// ---------------------------------------------------------------------------
__global__ __launch_bounds__(1024)
void diff_stats_kernel(const float* __restrict__ yhead, const float* __restrict__ lam,
                       float* __restrict__ diffb, float* __restrict__ stats)
{
  const int wg = blockIdx.x;  // h*2 + b
  const int b = wg & 1;
  const int h = wg >> 1;
  const int tid = threadIdx.x;
  const float4* y1 = reinterpret_cast<const float4*>(
      &yhead[(((size_t)0 * NHEADS + h) * BBATCH + b) * (TSEQ * HD)]);
  const float4* y2 = reinterpret_cast<const float4*>(
      &yhead[(((size_t)1 * NHEADS + h) * BBATCH + b) * (TSEQ * HD)]);
  float4* dd = reinterpret_cast<float4*>(&diffb[(size_t)wg * (TSEQ * HD)]);

  float s = 0.0f, s2 = 0.0f;
  for (int i = tid; i < TSEQ * HD / 4; i += 1024) {
    const float4 a = y1[i];
    const float4 bb = y2[i];
    const float4 l = *reinterpret_cast<const float4*>(&lam[h * HD + (i & 3) * 4]);
    float4 d;
    d.x = a.x - l.x * bb.x; d.y = a.y - l.y * bb.y;
    d.z = a.z - l.z * bb.z; d.w = a.w - l.w * bb.w;
    dd[i] = d;
    s += d.x + d.y + d.z + d.w;
    s2 += d.x * d.x + d.y * d.y + d.z * d.z + d.w * d.w;
  }
  __shared__ float red[32];
#pragma unroll
  for (int off = 32; off; off >>= 1) {
    s += __shfl_down(s, off);
    s2 += __shfl_down(s2, off);
  }
  const int wv = tid >> 6;
  if ((tid & 63) == 0) { red[wv * 2] = s; red[wv * 2 + 1] = s2; }
  __syncthreads();
  if (tid == 0) {
    float S = 0, S2 = 0;
#pragma unroll
    for (int w = 0; w < 16; ++w) { S += red[w * 2]; S2 += red[w * 2 + 1]; }
    const float inv = 1.0f / (TSEQ * HD);
    const float mean = S * inv;
    const float var = S2 * inv - mean * mean;
    stats[wg * 2] = mean;
    stats[wg * 2 + 1] = rsqrtf(var + 1e-5f);
  }
}

#define TT_TILE 16
__global__ __launch_bounds__(256)
void final_kernel(const float* __restrict__ x, const float* __restrict__ diffb,
                  const float* __restrict__ stats, const float* __restrict__ gnw,
                  const float* __restrict__ gnb, const float* __restrict__ projw,
                  const float* __restrict__ projb, float* __restrict__ out)
{
  __shared__ float nd[TT_TILE][DMODEL];
  __shared__ float Wl[DMODEL][33];

  const int wg = blockIdx.x;
  const int nseg = TSEQ / TT_TILE;
  const int b = wg / nseg;
  const int t0 = (wg % nseg) * TT_TILE;
  const int tid = threadIdx.x;
  const int h = tid >> 4, hd = tid & 15;

  const float mean = stats[(h * BBATCH + b) * 2];
  const float rstd = stats[(h * BBATCH + b) * 2 + 1];
  const float g = gnw[h * HD + hd];
  const float be = gnb[h * HD + hd];
  for (int tt = 0; tt < TT_TILE; ++tt) {
    const float d = diffb[((size_t)(h * BBATCH + b) * TSEQ + t0 + tt) * HD + hd];
    nd[tt][tid] = (d - mean) * rstd * g + be;
  }

  float acc[TT_TILE];
#pragma unroll
  for (int tt = 0; tt < TT_TILE; ++tt) acc[tt] = 0.0f;

  for (int kt = 0; kt < DMODEL; kt += 32) {
    __syncthreads();
    for (int i = tid; i < DMODEL * 32; i += 256) {
      const int dr = i >> 5, kk = i & 31;
      Wl[dr][kk] = projw[(size_t)dr * DMODEL + kt + kk];
    }
    __syncthreads();
#pragma unroll
    for (int kk = 0; kk < 32; ++kk) {
      const float w = Wl[tid][kk];
#pragma unroll
      for (int tt = 0; tt < TT_TILE; ++tt) acc[tt] = fmaf(nd[tt][kt + kk], w, acc[tt]);
    }
  }

  const float pb = projb[tid];
  for (int tt = 0; tt < TT_TILE; ++tt) {
    const size_t o = ((size_t)b * TSEQ + t0 + tt) * DMODEL + tid;
    out[o] = x[o] + pb + acc[tt];
  }
}

// ---------------------------------------------------------------------------
extern "C" void kernel_launch(void* const* d_in, const int* in_sizes, int n_in,
                              void* d_out, int out_size, void* d_ws, size_t ws_size,
                              hipStream_t stream)
{
  const float* x = (const float*)d_in[0];
  TeamParams tp0 { (const float*)d_in[1], (const float*)d_in[2], (const float*)d_in[3],
                   (const float*)d_in[4], (const float*)d_in[5], (const float*)d_in[6],
                   (const float*)d_in[7], (const float*)d_in[8] };
  TeamParams tp1 { (const float*)d_in[9], (const float*)d_in[10], (const float*)d_in[11],
                   (const float*)d_in[12], (const float*)d_in[13], (const float*)d_in[14],
                   (const float*)d_in[15], (const float*)d_in[16] };
  const float* lam   = (const float*)d_in[17];
  const float* gnw   = (const float*)d_in[18];
  const float* gnb   = (const float*)d_in[19];
  const float* projw = (const float*)d_in[20];
  const float* projb = (const float*)d_in[21];

  // ws layout (bytes):
  //   Sg     @ 0           16,777,216   (diffb 4MB aliases; Sg dead after k3)
  //   Pbuf   @ 16,777,216      32,768
  //   yhead  @ 16,809,984   8,388,608
  //   stats  @ 25,198,592         256
  //   cumsg  @ 25,198,848   1,048,576
  //   xgC    @ 26,247,424  16,777,216
  //   zg     @ 43,024,640   8,388,608
  //   yintra @ 51,413,248  16,777,216   (total ~68 MB)
  char* wsb = (char*)d_ws;
  _Float16* Sg = (_Float16*)wsb;
  float* diffb = (float*)wsb;
  float* Pbuf  = (float*)(wsb + 16777216);
  float* yhead = (float*)(wsb + 16809984);
  float* stats = (float*)(wsb + 25198592);
  float2* cumsg = (float2*)(wsb + 25198848);
  _Float16* xgC = (_Float16*)(wsb + 26247424);
  _Float16* zg  = (_Float16*)(wsb + 43024640);
  float* yintra = (float*)(wsb + 51413248);

  k1_proj_ssd<<<dim3(NWG), dim3(256), 0, stream>>>(x, tp0, tp1, Sg, Pbuf, cumsg, xgC, zg, yintra);
  carry_kernel<<<dim3(2 * NHEADS * BBATCH), dim3(256), 0, stream>>>(Sg, Pbuf);
  k3_combine_out<<<dim3(NWG), dim3(256), 0, stream>>>(Sg, cumsg, xgC, zg, tp0, tp1, yintra, yhead);
  diff_stats_kernel<<<dim3(NHEADS * BBATCH), dim3(1024), 0, stream>>>(yhead, lam, diffb, stats);
  final_kernel<<<dim3(BBATCH * (TSEQ / TT_TILE)), dim3(256), 0, stream>>>(
      x, diffb, stats, gnw, gnb, projw, projb, (float*)d_out);
}

// Round 6
// 127.237 us; speedup vs baseline: 3.2948x; 1.0764x over previous
//
#include <hip/hip_runtime.h>
#include <math.h>

#define NHEADS 16
#define BBATCH 2
#define TSEQ   2048
#define HD     16
#define DIN    32
#define DST    64
#define CONVD  160
#define DPROJ  194
#define NHIN   2
#define DMODEL 256
#define CHUNK  32
#define NCHUNK (TSEQ / CHUNK)                  // 64
#define NWG    (2 * NHEADS * BBATCH * NCHUNK)  // 4096
#define YS     36

struct TeamParams {
  const float *Win, *convw, *convb, *dtb, *Alog, *Dp, *nw, *Wout;
};

typedef __attribute__((ext_vector_type(4)))  _Float16 half4;
typedef __attribute__((ext_vector_type(8)))  _Float16 half8;
typedef __attribute__((ext_vector_type(16))) float    f32x16;

__device__ __forceinline__ float sigm(float v) { return 1.0f / (1.0f + __expf(-v)); }

__device__ __forceinline__ half8 pack_h8(float4 a, float4 b) {
  half8 r;
  r[0] = (_Float16)a.x; r[1] = (_Float16)a.y; r[2] = (_Float16)a.z; r[3] = (_Float16)a.w;
  r[4] = (_Float16)b.x; r[5] = (_Float16)b.y; r[6] = (_Float16)b.z; r[7] = (_Float16)b.w;
  return r;
}
__device__ __forceinline__ half8 zero_h8() {
  half8 r;
#pragma unroll
  for (int i = 0; i < 8; ++i) r[i] = (_Float16)0.f;
  return r;
}
// LDS fragment load via two 8B-aligned b64 reads (strides chosen 2-way-safe)
__device__ __forceinline__ half8 ld8(const _Float16* p) {
  const half4 a = *reinterpret_cast<const half4*>(p);
  const half4 b = *reinterpret_cast<const half4*>(p + 4);
  half8 r;
  r[0] = a[0]; r[1] = a[1]; r[2] = a[2]; r[3] = a[3];
  r[4] = b[0]; r[5] = b[1]; r[6] = b[2]; r[7] = b[3];
  return r;
}

// ---------------------------------------------------------------------------
// K1: MFMA in-proj (f16 32x32x16, tiles: xBC ch 0..159 + dt; z dropped) +
// parallel conv4 + SSD chunk computation (no serial scan):
//   cl[t] = prefix(dt*A); G = C·B^T; y_intra = (L∘G)·(dt x) + D x;
//   S^T = (w dt x)^T·B.
// Stores: Sg (f16), cums, P, C (f16), yintra (f16).
// wg = (team, head, batch, chunk32), 256 threads, 3 barriers, ~31 KB LDS.
// ---------------------------------------------------------------------------
__global__ __launch_bounds__(256, 5)
void k1_proj_ssd(const float* __restrict__ x, TeamParams tp0, TeamParams tp1,
                 _Float16* __restrict__ Sg, float* __restrict__ Pbuf,
                 float2* __restrict__ cumsg, _Float16* __restrict__ xgC,
                 _Float16* __restrict__ yintra)
{
  __shared__ _Float16 xbcH[35][172];  // xBC raw -> act; cols: x 0..31 | B 32..95 | C 96..159
  __shared__ float    dtraw[35][2];
  __shared__ float    clL[2][32];
  __shared__ float    dtL[2][32];
  __shared__ _Float16 Gm[2][32][36];  // masked L∘G  [hi][t][s]
  __shared__ _Float16 XtL[32][36];    // (dt*x)^T    [p][s]
  __shared__ _Float16 WXt[32][36];    // (w*dt*x)^T  [p][s]
  __shared__ _Float16 BmT[64][36];    // B^T         [n][s]
  __shared__ _Float16 StL[32][68];    // S^T staging [row][n]

  const int tid  = threadIdx.x;
  const int wg   = blockIdx.x;
  const int c    = wg % NCHUNK;
  const int b    = (wg / NCHUNK) % BBATCH;
  const int h    = (wg / (NCHUNK * BBATCH)) % NHEADS;
  const int team = wg / (NCHUNK * BBATCH * NHEADS);
  const TeamParams P = team ? tp1 : tp0;
  const int c0 = c * CHUNK;
  const size_t base0 = ((size_t)team * NHEADS + h) * BBATCH + b;

  const int lane = tid & 63;
  const int wv   = tid >> 6;
  const int lrow = lane & 31;
  const int kg   = lane >> 5;

  // ================= phase 1: in-proj MFMA (6 tiles over 4 waves) ==========
  half8 afr0, afr1;
  {
    const int t = c0 - 3 + lrow;
    if (t >= 0) {
      const float* xp = &x[((size_t)b * TSEQ + t) * DMODEL + h * HD + kg * 8];
      afr0 = pack_h8(*reinterpret_cast<const float4*>(xp),
                     *reinterpret_cast<const float4*>(xp + 4));
    } else afr0 = zero_h8();
    if (lrow < 3) {
      const int t1 = c0 + 29 + lrow;
      const float* xp = &x[((size_t)b * TSEQ + t1) * DMODEL + h * HD + kg * 8];
      afr1 = pack_h8(*reinterpret_cast<const float4*>(xp),
                     *reinterpret_cast<const float4*>(xp + 4));
    } else afr1 = zero_h8();
  }
  // tile n covers xBC channels 32n..32n+31 (Win rows 32+32n..); tile 5 = dt
  const int  tA   = (wv < 2) ? wv * 2 : (wv == 2 ? 4 : 5);
  const bool hasB = (wv < 2);
  const int  tB   = wv * 2 + 1;
  half8 bfrA, bfrB = zero_h8();
  {
    const int rA = 32 + tA * 32 + lrow;
    if (rA < DPROJ) {
      const float* wp = &P.Win[((size_t)h * DPROJ + rA) * HD + kg * 8];
      bfrA = pack_h8(*reinterpret_cast<const float4*>(wp),
                     *reinterpret_cast<const float4*>(wp + 4));
    } else bfrA = zero_h8();
    if (hasB) {
      const int rB = 32 + tB * 32 + lrow;
      const float* wp = &P.Win[((size_t)h * DPROJ + rB) * HD + kg * 8];
      bfrB = pack_h8(*reinterpret_cast<const float4*>(wp),
                     *reinterpret_cast<const float4*>(wp + 4));
    }
  }

  f32x16 z16;
#pragma unroll
  for (int i = 0; i < 16; ++i) z16[i] = 0.0f;

  auto writeD = [&](const f32x16& d, int tile, int m0) {
    const int colid = lrow;
    if (m0 == 0) {
#pragma unroll
      for (int rg = 0; rg < 16; ++rg) {
        const int slot = (rg & 3) + 8 * (rg >> 2) + 4 * kg;
        const float v = d[rg];
        if (tile < 5)         xbcH[slot][tile * 32 + colid] = (_Float16)v;
        else if (colid < 2)   dtraw[slot][colid] = v;
      }
    } else if (kg == 0) {
#pragma unroll
      for (int rg = 0; rg < 3; ++rg) {
        const int slot = 32 + rg;
        const float v = d[rg];
        if (tile < 5)         xbcH[slot][tile * 32 + colid] = (_Float16)v;
        else if (colid < 2)   dtraw[slot][colid] = v;
      }
    }
  };

  {
    f32x16 d;
    d = __builtin_amdgcn_mfma_f32_32x32x16_f16(afr0, bfrA, z16, 0, 0, 0);
    writeD(d, tA, 0);
    d = __builtin_amdgcn_mfma_f32_32x32x16_f16(afr1, bfrA, z16, 0, 0, 0);
    writeD(d, tA, 1);
    if (hasB) {
      d = __builtin_amdgcn_mfma_f32_32x32x16_f16(afr0, bfrB, z16, 0, 0, 0);
      writeD(d, tB, 0);
      d = __builtin_amdgcn_mfma_f32_32x32x16_f16(afr1, bfrB, z16, 0, 0, 0);
      writeD(d, tB, 1);
    }
  }
  __syncthreads();   // B1

  // ================= phase 2: conv read + dt prefix-scan ===================
  const int cg = tid & 31, tg = tid >> 5;
  const int ch0 = cg * 5, t0c = tg * 4;
  float outv[5][4];
#pragma unroll
  for (int q = 0; q < 5; ++q) {
    const int ch = ch0 + q;
    const float4 cw = *reinterpret_cast<const float4*>(&P.convw[((size_t)h * CONVD + ch) * 4]);
    const float cb = P.convb[h * CONVD + ch];
    float vv[7];
#pragma unroll
    for (int i = 0; i < 7; ++i) vv[i] = (float)xbcH[t0c + i][ch];
#pragma unroll
    for (int d0 = 0; d0 < 4; ++d0) {
      float v = cb;
      v = fmaf(cw.x, vv[d0], v);
      v = fmaf(cw.y, vv[d0 + 1], v);
      v = fmaf(cw.z, vv[d0 + 2], v);
      v = fmaf(cw.w, vv[d0 + 3], v);
      outv[q][d0] = v * sigm(v);
    }
  }
  if (tid < 64) {
    const int t = tid & 31, hi = tid >> 5;
    const float dtbias = P.dtb[h * NHIN + hi];
    const float Ah = -__expf(P.Alog[h * NHIN + hi]);
    const float raw = dtraw[3 + t][hi] + dtbias;
    const float dtv = (raw > 20.f) ? raw : log1pf(__expf(raw));
    dtL[hi][t] = dtv;
    float s = dtv * Ah;
#pragma unroll
    for (int d = 1; d < 32; d <<= 1) {
      const float v = __shfl_up(s, d, 32);
      if (t >= d) s += v;
    }
    clL[hi][t] = s;
  }
  __syncthreads();   // B2

  // ================= phase 3: act write-back + operand tiles ===============
#pragma unroll
  for (int q = 0; q < 5; ++q) {
    const int ch = ch0 + q;
#pragma unroll
    for (int d0 = 0; d0 < 4; ++d0) xbcH[3 + t0c + d0][ch] = (_Float16)outv[q][d0];
    if (ch < DIN) {
      const int hi = ch >> 4;
      const float cl31 = clL[hi][31];
#pragma unroll
      for (int d0 = 0; d0 < 4; ++d0) {
        const int t = t0c + d0;
        const float dtv = dtL[hi][t];
        const float w = __expf(cl31 - clL[hi][t]);
        XtL[ch][t] = (_Float16)(dtv * outv[q][d0]);
        WXt[ch][t] = (_Float16)(w * dtv * outv[q][d0]);
      }
    } else if (ch < DIN + DST) {
#pragma unroll
      for (int d0 = 0; d0 < 4; ++d0) BmT[ch - DIN][t0c + d0] = (_Float16)outv[q][d0];
    }
  }
  __syncthreads();   // B3

  // ================= phase 4: wave-specialized =============================
  if (wv == 0) {
    // ---- G = C·B^T ----
    f32x16 g;
#pragma unroll
    for (int i = 0; i < 16; ++i) g[i] = 0.0f;
#pragma unroll
    for (int kk = 0; kk < 4; ++kk) {
      const half8 af = ld8(&xbcH[3 + lrow][96 + kk * 16 + kg * 8]);
      const half8 bf = ld8(&xbcH[3 + lrow][32 + kk * 16 + kg * 8]);
      g = __builtin_amdgcn_mfma_f32_32x32x16_f16(af, bf, g, 0, 0, 0);
    }
    // ---- mask L∘G ----
    const float cls0 = clL[0][lrow], cls1 = clL[1][lrow];
#pragma unroll
    for (int rg = 0; rg < 16; ++rg) {
      const int t = (rg & 3) + 8 * (rg >> 2) + 4 * kg;
      const float gg = g[rg];
      float l0 = 0.f, l1 = 0.f;
      if (lrow <= t) { l0 = __expf(clL[0][t] - cls0); l1 = __expf(clL[1][t] - cls1); }
      Gm[0][t][lrow] = (_Float16)(l0 * gg);
      Gm[1][t][lrow] = (_Float16)(l1 * gg);
    }
    // ---- y_intra = (L∘G)·Xdt + D·x -> yintra f16 ----
    const half8 xb0 = ld8(&XtL[lrow][kg * 8]);
    const half8 xb1 = ld8(&XtL[lrow][16 + kg * 8]);
    _Float16* yo = &yintra[(size_t)wg * (CHUNK * DIN)];
    {
      f32x16 acc;
#pragma unroll
      for (int i = 0; i < 16; ++i) acc[i] = 0.0f;
      acc = __builtin_amdgcn_mfma_f32_32x32x16_f16(ld8(&Gm[0][lrow][kg * 8]), xb0, acc, 0, 0, 0);
      acc = __builtin_amdgcn_mfma_f32_32x32x16_f16(ld8(&Gm[0][lrow][16 + kg * 8]), xb1, acc, 0, 0, 0);
      if (lrow < 16) {
        const float Dp0 = P.Dp[h * NHIN + 0];
#pragma unroll
        for (int rg = 0; rg < 16; ++rg) {
          const int t = (rg & 3) + 8 * (rg >> 2) + 4 * kg;
          yo[t * DIN + lrow] = (_Float16)(acc[rg] + Dp0 * (float)xbcH[3 + t][lrow]);
        }
      }
    }
    {
      f32x16 acc;
#pragma unroll
      for (int i = 0; i < 16; ++i) acc[i] = 0.0f;
      acc = __builtin_amdgcn_mfma_f32_32x32x16_f16(ld8(&Gm[1][lrow][kg * 8]), xb0, acc, 0, 0, 0);
      acc = __builtin_amdgcn_mfma_f32_32x32x16_f16(ld8(&Gm[1][lrow][16 + kg * 8]), xb1, acc, 0, 0, 0);
      if (lrow >= 16) {
        const float Dp1 = P.Dp[h * NHIN + 1];
#pragma unroll
        for (int rg = 0; rg < 16; ++rg) {
          const int t = (rg & 3) + 8 * (rg >> 2) + 4 * kg;
          yo[t * DIN + lrow] = (_Float16)(acc[rg] + Dp1 * (float)xbcH[3 + t][lrow]);
        }
      }
    }
  } else if (wv == 1 || wv == 2) {
    // ---- S^T = (w dt x)^T · B (split across waves 1/2) ----
    const int nhalf = (wv - 1) * 32;
    const half8 wa0 = ld8(&WXt[lrow][kg * 8]);
    const half8 wa1 = ld8(&WXt[lrow][16 + kg * 8]);
    f32x16 acc;
#pragma unroll
    for (int i = 0; i < 16; ++i) acc[i] = 0.0f;
    acc = __builtin_amdgcn_mfma_f32_32x32x16_f16(
        wa0, ld8(&BmT[nhalf + lrow][kg * 8]), acc, 0, 0, 0);
    acc = __builtin_amdgcn_mfma_f32_32x32x16_f16(
        wa1, ld8(&BmT[nhalf + lrow][16 + kg * 8]), acc, 0, 0, 0);
#pragma unroll
    for (int rg = 0; rg < 16; ++rg) {
      const int m = (rg & 3) + 8 * (rg >> 2) + 4 * kg;
      StL[m][nhalf + lrow] = (_Float16)acc[rg];
    }
    __builtin_amdgcn_s_barrier();  // only waits within... use explicit sync below
    // (wave writes its own half; store below reads only its own half -> safe)
    const size_t base2 = (base0 * NCHUNK + c) * (NHIN * HD * DST);
#pragma unroll
    for (int k = 0; k < 4; ++k) {
      const int idx = lane + k * 64;
      const int row = idx >> 3, c4 = (idx & 7) * 4 + nhalf;
      *reinterpret_cast<ushort4*>(&Sg[base2 + row * DST + c4]) =
          *reinterpret_cast<const ushort4*>(&StL[row][c4]);
    }
  } else {
    if (lane < 32) {
      cumsg[(size_t)wg * CHUNK + lane] =
          make_float2(__expf(clL[0][lane]), __expf(clL[1][lane]));
    } else if (lane == 32) {
      Pbuf[(base0 * NCHUNK + c) * NHIN + 0] = __expf(clL[0][31]);
    } else if (lane == 33) {
      Pbuf[(base0 * NCHUNK + c) * NHIN + 1] = __expf(clL[1][31]);
    }
#pragma unroll
    for (int k = 0; k < 8; ++k) {
      const int idx = lane + k * 64;
      const int t = idx >> 4, c4 = (idx & 15) * 4;
      *reinterpret_cast<ushort4*>(&xgC[(size_t)wg * (CHUNK * DST) + t * DST + c4]) =
          *reinterpret_cast<const ushort4*>(&xbcH[3 + t][96 + c4]);
    }
  }
}

// ---------------------------------------------------------------------------
// Carry: sequential combine over 64 chunks; Sg (chunk finals, f16) -> H_in.
// ---------------------------------------------------------------------------
__global__ __launch_bounds__(256)
void carry_kernel(_Float16* __restrict__ Sg, const float* __restrict__ Pbuf)
{
  const int wg = blockIdx.x;
  const int b = wg % BBATCH;
  const int h = (wg / BBATCH) % NHEADS;
  const int team = wg / (BBATCH * NHEADS);
  const int tid = threadIdx.x;
  const int hi = tid >> 7;
  const int pp = (tid >> 3) & 15;
  const int ng = tid & 7;
  const int nb = ng * 8;
  const size_t base0 = ((size_t)team * NHEADS + h) * BBATCH + b;

  float hc[8] = {0, 0, 0, 0, 0, 0, 0, 0};
  for (int c = 0; c < NCHUNK; ++c) {
    const size_t sb = (((base0 * NCHUNK + c) * NHIN + hi) * HD + pp) * DST + nb;
    const float Pv = Pbuf[(base0 * NCHUNK + c) * NHIN + hi];
    const half8 a = *reinterpret_cast<const half8*>(&Sg[sb]);
    half8 o;
#pragma unroll
    for (int j = 0; j < 8; ++j) o[j] = (_Float16)hc[j];
    *reinterpret_cast<half8*>(&Sg[sb]) = o;
#pragma unroll
    for (int j = 0; j < 8; ++j) hc[j] = fmaf(Pv, hc[j], (float)a[j]);
  }
}

// ---------------------------------------------------------------------------
// K3: wave0: y = y_intra + cum*(C·H_in) [4 MFMA]; wave1: z = silu(x·Win_z^T)
// [1 MFMA]; then gate + rms + out-proj.
// ---------------------------------------------------------------------------
__global__ __launch_bounds__(256)
void k3_combine_out(const _Float16* __restrict__ Sg,
                    const float2* __restrict__ cumsg,
                    const _Float16* __restrict__ xgC,
                    const float* __restrict__ x,
                    TeamParams tp0, TeamParams tp1,
                    const _Float16* __restrict__ yintra, float* __restrict__ yhead)
{
  __shared__ float    ysh[CHUNK][YS];
  __shared__ float    wn[16][33];
  __shared__ float    cums2[CHUNK][2];
  __shared__ _Float16 zsh[32][40];

  const int tid  = threadIdx.x;
  const int wg   = blockIdx.x;
  const int c    = wg % NCHUNK;
  const int b    = (wg / NCHUNK) % BBATCH;
  const int h    = (wg / (NCHUNK * BBATCH)) % NHEADS;
  const int team = wg / (NCHUNK * BBATCH * NHEADS);
  const TeamParams P = team ? tp1 : tp0;
  const int c0 = c * CHUNK;
  const size_t base0 = ((size_t)team * NHEADS + h) * BBATCH + b;

  f32x16 acc;
  if (tid < 64) {
    // ---- C · H_in ----
    const int colid = tid & 31, kg = tid >> 5;
    const _Float16* ca = &xgC[(size_t)wg * (CHUNK * DST) + (size_t)colid * DST + kg * 8];
    const _Float16* hb = &Sg[(base0 * NCHUNK + c) * (NHIN * HD * DST) +
                             (size_t)colid * DST + kg * 8];
#pragma unroll
    for (int i = 0; i < 16; ++i) acc[i] = 0.0f;
    acc = __builtin_amdgcn_mfma_f32_32x32x16_f16(
        *reinterpret_cast<const half8*>(ca), *reinterpret_cast<const half8*>(hb), acc, 0, 0, 0);
    acc = __builtin_amdgcn_mfma_f32_32x32x16_f16(
        *reinterpret_cast<const half8*>(ca + 16), *reinterpret_cast<const half8*>(hb + 16), acc, 0, 0, 0);
    acc = __builtin_amdgcn_mfma_f32_32x32x16_f16(
        *reinterpret_cast<const half8*>(ca + 32), *reinterpret_cast<const half8*>(hb + 32), acc, 0, 0, 0);
    acc = __builtin_amdgcn_mfma_f32_32x32x16_f16(
        *reinterpret_cast<const half8*>(ca + 48), *reinterpret_cast<const half8*>(hb + 48), acc, 0, 0, 0);
  } else if (tid < 128) {
    // ---- z = silu(x · Win_z^T) ----
    const int l = tid - 64, lrow = l & 31, kg = l >> 5;
    const float* xp = &x[((size_t)b * TSEQ + c0 + lrow) * DMODEL + h * HD + kg * 8];
    const half8 afr = pack_h8(*reinterpret_cast<const float4*>(xp),
                              *reinterpret_cast<const float4*>(xp + 4));
    const float* wp = &P.Win[((size_t)h * DPROJ + lrow) * HD + kg * 8];
    const half8 bfr = pack_h8(*reinterpret_cast<const float4*>(wp),
                              *reinterpret_cast<const float4*>(wp + 4));
    f32x16 zacc;
#pragma unroll
    for (int i = 0; i < 16; ++i) zacc[i] = 0.0f;
    zacc = __builtin_amdgcn_mfma_f32_32x32x16_f16(afr, bfr, zacc, 0, 0, 0);
#pragma unroll
    for (int rg = 0; rg < 16; ++rg) {
      const int t = (rg & 3) + 8 * (rg >> 2) + 4 * kg;
      const float v = zacc[rg];
      zsh[t][lrow] = (_Float16)(v * sigm(v));
    }
  }

  // ---- staging (all threads) ----
  for (int i = tid; i < HD * DIN; i += 256) {
    const int o = i >> 5, dn = i & 31;
    wn[o][dn] = P.Wout[((size_t)h * HD + o) * DIN + dn] * P.nw[h * DIN + dn];
  }
  {
    const int t = tid >> 3, c4 = (tid & 7) * 4;
    const half4 v = *reinterpret_cast<const half4*>(&yintra[(size_t)wg * (CHUNK * DIN) + tid * 4]);
    ysh[t][c4 + 0] = (float)v[0]; ysh[t][c4 + 1] = (float)v[1];
    ysh[t][c4 + 2] = (float)v[2]; ysh[t][c4 + 3] = (float)v[3];
  }
  if (tid < CHUNK) {
    const float2 v = cumsg[(size_t)wg * CHUNK + tid];
    cums2[tid][0] = v.x; cums2[tid][1] = v.y;
  }
  __syncthreads();

  if (tid < 64) {
    const int colid = tid & 31, kg = tid >> 5;
    const int hi = colid >> 4;
#pragma unroll
    for (int rg = 0; rg < 16; ++rg) {
      const int t = (rg & 3) + 8 * (rg >> 2) + 4 * kg;
      ysh[t][colid] = fmaf(cums2[t][hi], acc[rg], ysh[t][colid]);
    }
  }
  __syncthreads();

  // ---- gate with silu(z), rms. thread = (tl 0..31, q 0..7) ----
  const int q = tid & 7, tl = tid >> 3;
  const half4 z4 = *reinterpret_cast<const half4*>(&zsh[tl][q * 4]);
  float yg[4];
  float ss = 0.0f;
#pragma unroll
  for (int j = 0; j < 4; ++j) {
    const float g = ysh[tl][q * 4 + j] * (float)z4[j];
    yg[j] = g;
    ss += g * g;
  }
  ss += __shfl_xor(ss, 1, 8);
  ss += __shfl_xor(ss, 2, 8);
  ss += __shfl_xor(ss, 4, 8);
  const float rms = rsqrtf(ss * (1.0f / DIN) + 1e-5f);
#pragma unroll
  for (int j = 0; j < 4; ++j) ysh[tl][q * 4 + j] = yg[j];
  __syncthreads();

  float acc0 = 0.f, acc1 = 0.f;
#pragma unroll
  for (int dn = 0; dn < DIN; ++dn) {
    const float v = ysh[tl][dn];
    acc0 = fmaf(v, wn[q * 2][dn], acc0);
    acc1 = fmaf(v, wn[q * 2 + 1][dn], acc1);
  }
  float* yout = &yhead[base0 * (TSEQ * HD) + (size_t)(c0 + tl) * HD + q * 2];
  *reinterpret_cast<float2*>(yout) = make_float2(rms * acc0, rms * acc1);
}

// ---------------------------------------------------------------------------
__global__ __launch_bounds__(1024)
void diff_stats_kernel(const float* __restrict__ yhead, const float* __restrict__ lam,
                       float* __restrict__ diffb, float* __restrict__ stats)
{
  const int wg = blockIdx.x;  // h*2 + b
  const int b = wg & 1;
  const int h = wg >> 1;
  const int tid = threadIdx.x;
  const float4* y1 = reinterpret_cast<const float4*>(
      &yhead[(((size_t)0 * NHEADS + h) * BBATCH + b) * (TSEQ * HD)]);
  const float4* y2 = reinterpret_cast<const float4*>(
      &yhead[(((size_t)1 * NHEADS + h) * BBATCH + b) * (TSEQ * HD)]);
  float4* dd = reinterpret_cast<float4*>(&diffb[(size_t)wg * (TSEQ * HD)]);

  float s = 0.0f, s2 = 0.0f;
  for (int i = tid; i < TSEQ * HD / 4; i += 1024) {
    const float4 a = y1[i];
    const float4 bb = y2[i];
    const float4 l = *reinterpret_cast<const float4*>(&lam[h * HD + (i & 3) * 4]);
    float4 d;
    d.x = a.x - l.x * bb.x; d.y = a.y - l.y * bb.y;
    d.z = a.z - l.z * bb.z; d.w = a.w - l.w * bb.w;
    dd[i] = d;
    s += d.x + d.y + d.z + d.w;
    s2 += d.x * d.x + d.y * d.y + d.z * d.z + d.w * d.w;
  }
  __shared__ float red[32];
#pragma unroll
  for (int off = 32; off; off >>= 1) {
    s += __shfl_down(s, off);
    s2 += __shfl_down(s2, off);
  }
  const int wv = tid >> 6;
  if ((tid & 63) == 0) { red[wv * 2] = s; red[wv * 2 + 1] = s2; }
  __syncthreads();
  if (tid == 0) {
    float S = 0, S2 = 0;
#pragma unroll
    for (int w = 0; w < 16; ++w) { S += red[w * 2]; S2 += red[w * 2 + 1]; }
    const float inv = 1.0f / (TSEQ * HD);
    const float mean = S * inv;
    const float var = S2 * inv - mean * mean;
    stats[wg * 2] = mean;
    stats[wg * 2 + 1] = rsqrtf(var + 1e-5f);
  }
}

#define TT_TILE 16
__global__ __launch_bounds__(256)
void final_kernel(const float* __restrict__ x, const float* __restrict__ diffb,
                  const float* __restrict__ stats, const float* __restrict__ gnw,
                  const float* __restrict__ gnb, const float* __restrict__ projw,
                  const float* __restrict__ projb, float* __restrict__ out)
{
  __shared__ float nd[TT_TILE][DMODEL];
  __shared__ float Wl[DMODEL][33];

  const int wg = blockIdx.x;
  const int nseg = TSEQ / TT_TILE;
  const int b = wg / nseg;
  const int t0 = (wg % nseg) * TT_TILE;
  const int tid = threadIdx.x;
  const int h = tid >> 4, hd = tid & 15;

  const float mean = stats[(h * BBATCH + b) * 2];
  const float rstd = stats[(h * BBATCH + b) * 2 + 1];
  const float g = gnw[h * HD + hd];
  const float be = gnb[h * HD + hd];
  for (int tt = 0; tt < TT_TILE; ++tt) {
    const float d = diffb[((size_t)(h * BBATCH + b) * TSEQ + t0 + tt) * HD + hd];
    nd[tt][tid] = (d - mean) * rstd * g + be;
  }

  float acc[TT_TILE];
#pragma unroll
  for (int tt = 0; tt < TT_TILE; ++tt) acc[tt] = 0.0f;

  for (int kt = 0; kt < DMODEL; kt += 32) {
    __syncthreads();
    for (int i = tid; i < DMODEL * 32; i += 256) {
      const int dr = i >> 5, kk = i & 31;
      Wl[dr][kk] = projw[(size_t)dr * DMODEL + kt + kk];
    }
    __syncthreads();
#pragma unroll
    for (int kk = 0; kk < 32; ++kk) {
      const float w = Wl[tid][kk];
#pragma unroll
      for (int tt = 0; tt < TT_TILE; ++tt) acc[tt] = fmaf(nd[tt][kt + kk], w, acc[tt]);
    }
  }

  const float pb = projb[tid];
  for (int tt = 0; tt < TT_TILE; ++tt) {
    const size_t o = ((size_t)b * TSEQ + t0 + tt) * DMODEL + tid;
    out[o] = x[o] + pb + acc[tt];
  }
}

// ---------------------------------------------------------------------------
extern "C" void kernel_launch(void* const* d_in, const int* in_sizes, int n_in,
                              void* d_out, int out_size, void* d_ws, size_t ws_size,
                              hipStream_t stream)
{
  const float* x = (const float*)d_in[0];
  TeamParams tp0 { (const float*)d_in[1], (const float*)d_in[2], (const float*)d_in[3],
                   (const float*)d_in[4], (const float*)d_in[5], (const float*)d_in[6],
                   (const float*)d_in[7], (const float*)d_in[8] };
  TeamParams tp1 { (const float*)d_in[9], (const float*)d_in[10], (const float*)d_in[11],
                   (const float*)d_in[12], (const float*)d_in[13], (const float*)d_in[14],
                   (const float*)d_in[15], (const float*)d_in[16] };
  const float* lam   = (const float*)d_in[17];
  const float* gnw   = (const float*)d_in[18];
  const float* gnb   = (const float*)d_in[19];
  const float* projw = (const float*)d_in[20];
  const float* projb = (const float*)d_in[21];

  // ws layout (bytes):
  //   Sg      @ 0           16,777,216   (diffb 4MB aliases; Sg dead after k3)
  //   Pbuf    @ 16,777,216      32,768
  //   yhead   @ 16,809,984   8,388,608
  //   stats   @ 25,198,592         256
  //   cumsg   @ 25,198,848   1,048,576
  //   xgC     @ 26,247,424  16,777,216
  //   yintra  @ 43,024,640   8,388,608   (total ~51.4 MB)
  char* wsb = (char*)d_ws;
  _Float16* Sg = (_Float16*)wsb;
  float* diffb = (float*)wsb;
  float* Pbuf  = (float*)(wsb + 16777216);
  float* yhead = (float*)(wsb + 16809984);
  float* stats = (float*)(wsb + 25198592);
  float2* cumsg = (float2*)(wsb + 25198848);
  _Float16* xgC = (_Float16*)(wsb + 26247424);
  _Float16* yintra = (_Float16*)(wsb + 43024640);

  k1_proj_ssd<<<dim3(NWG), dim3(256), 0, stream>>>(x, tp0, tp1, Sg, Pbuf, cumsg, xgC, yintra);
  carry_kernel<<<dim3(2 * NHEADS * BBATCH), dim3(256), 0, stream>>>(Sg, Pbuf);
  k3_combine_out<<<dim3(NWG), dim3(256), 0, stream>>>(Sg, cumsg, xgC, x, tp0, tp1, yintra, yhead);
  diff_stats_kernel<<<dim3(NHEADS * BBATCH), dim3(1024), 0, stream>>>(yhead, lam, diffb, stats);
  final_kernel<<<dim3(BBATCH * (TSEQ / TT_TILE)), dim3(256), 0, stream>>>(
      x, diffb, stats, gnw, gnb, projw, projb, (float*)d_out);
}

// Round 7
// 123.490 us; speedup vs baseline: 3.3947x; 1.0303x over previous
//
#include <hip/hip_runtime.h>
#include <math.h>

#define NHEADS 16
#define BBATCH 2
#define TSEQ   2048
#define HD     16
#define DIN    32
#define DST    64
#define CONVD  160
#define DPROJ  194
#define NHIN   2
#define DMODEL 256
#define CHUNK  32
#define NCHUNK (TSEQ / CHUNK)                  // 64
#define NWG    (2 * NHEADS * BBATCH * NCHUNK)  // 4096 (k1)
#define NWG3   (NHEADS * BBATCH * NCHUNK)      // 2048 (k3 fused)
#define YS     36

struct TeamParams {
  const float *Win, *convw, *convb, *dtb, *Alog, *Dp, *nw, *Wout;
};

typedef __attribute__((ext_vector_type(4)))  _Float16 half4;
typedef __attribute__((ext_vector_type(8)))  _Float16 half8;
typedef __attribute__((ext_vector_type(16))) float    f32x16;

__device__ __forceinline__ float sigm(float v) { return 1.0f / (1.0f + __expf(-v)); }

__device__ __forceinline__ half8 pack_h8(float4 a, float4 b) {
  half8 r;
  r[0] = (_Float16)a.x; r[1] = (_Float16)a.y; r[2] = (_Float16)a.z; r[3] = (_Float16)a.w;
  r[4] = (_Float16)b.x; r[5] = (_Float16)b.y; r[6] = (_Float16)b.z; r[7] = (_Float16)b.w;
  return r;
}
__device__ __forceinline__ half8 zero_h8() {
  half8 r;
#pragma unroll
  for (int i = 0; i < 8; ++i) r[i] = (_Float16)0.f;
  return r;
}
__device__ __forceinline__ half8 ld8(const _Float16* p) {
  const half4 a = *reinterpret_cast<const half4*>(p);
  const half4 b = *reinterpret_cast<const half4*>(p + 4);
  half8 r;
  r[0] = a[0]; r[1] = a[1]; r[2] = a[2]; r[3] = a[3];
  r[4] = b[0]; r[5] = b[1]; r[6] = b[2]; r[7] = b[3];
  return r;
}

// ---------------------------------------------------------------------------
// K1: MFMA in-proj (f16 32x32x16) + parallel conv4 + SSD chunk computation.
// Stores: Sg (chunk-final states, f16), P, cums, C (f16), yintra (f16).
// ---------------------------------------------------------------------------
__global__ __launch_bounds__(256, 5)
void k1_proj_ssd(const float* __restrict__ x, TeamParams tp0, TeamParams tp1,
                 _Float16* __restrict__ Sg, float* __restrict__ Pbuf,
                 float2* __restrict__ cumsg, _Float16* __restrict__ xgC,
                 _Float16* __restrict__ yintra)
{
  __shared__ _Float16 xbcH[35][172];  // x 0..31 | B 32..95 | C 96..159
  __shared__ float    dtraw[35][2];
  __shared__ float    clL[2][32];
  __shared__ float    dtL[2][32];
  __shared__ _Float16 Gm[2][32][36];
  __shared__ _Float16 XtL[32][36];
  __shared__ _Float16 WXt[32][36];
  __shared__ _Float16 BmT[64][36];
  __shared__ _Float16 StL[32][68];

  const int tid  = threadIdx.x;
  const int wg   = blockIdx.x;
  const int c    = wg % NCHUNK;
  const int b    = (wg / NCHUNK) % BBATCH;
  const int h    = (wg / (NCHUNK * BBATCH)) % NHEADS;
  const int team = wg / (NCHUNK * BBATCH * NHEADS);
  const TeamParams P = team ? tp1 : tp0;
  const int c0 = c * CHUNK;
  const size_t base0 = ((size_t)team * NHEADS + h) * BBATCH + b;

  const int lane = tid & 63;
  const int wv   = tid >> 6;
  const int lrow = lane & 31;
  const int kg   = lane >> 5;

  // ================= phase 1: in-proj MFMA =================
  half8 afr0, afr1;
  {
    const int t = c0 - 3 + lrow;
    if (t >= 0) {
      const float* xp = &x[((size_t)b * TSEQ + t) * DMODEL + h * HD + kg * 8];
      afr0 = pack_h8(*reinterpret_cast<const float4*>(xp),
                     *reinterpret_cast<const float4*>(xp + 4));
    } else afr0 = zero_h8();
    if (lrow < 3) {
      const int t1 = c0 + 29 + lrow;
      const float* xp = &x[((size_t)b * TSEQ + t1) * DMODEL + h * HD + kg * 8];
      afr1 = pack_h8(*reinterpret_cast<const float4*>(xp),
                     *reinterpret_cast<const float4*>(xp + 4));
    } else afr1 = zero_h8();
  }
  const int  tA   = (wv < 2) ? wv * 2 : (wv == 2 ? 4 : 5);
  const bool hasB = (wv < 2);
  const int  tB   = wv * 2 + 1;
  half8 bfrA, bfrB = zero_h8();
  {
    const int rA = 32 + tA * 32 + lrow;
    if (rA < DPROJ) {
      const float* wp = &P.Win[((size_t)h * DPROJ + rA) * HD + kg * 8];
      bfrA = pack_h8(*reinterpret_cast<const float4*>(wp),
                     *reinterpret_cast<const float4*>(wp + 4));
    } else bfrA = zero_h8();
    if (hasB) {
      const int rB = 32 + tB * 32 + lrow;
      const float* wp = &P.Win[((size_t)h * DPROJ + rB) * HD + kg * 8];
      bfrB = pack_h8(*reinterpret_cast<const float4*>(wp),
                     *reinterpret_cast<const float4*>(wp + 4));
    }
  }

  f32x16 z16;
#pragma unroll
  for (int i = 0; i < 16; ++i) z16[i] = 0.0f;

  auto writeD = [&](const f32x16& d, int tile, int m0) {
    const int colid = lrow;
    if (m0 == 0) {
#pragma unroll
      for (int rg = 0; rg < 16; ++rg) {
        const int slot = (rg & 3) + 8 * (rg >> 2) + 4 * kg;
        const float v = d[rg];
        if (tile < 5)         xbcH[slot][tile * 32 + colid] = (_Float16)v;
        else if (colid < 2)   dtraw[slot][colid] = v;
      }
    } else if (kg == 0) {
#pragma unroll
      for (int rg = 0; rg < 3; ++rg) {
        const int slot = 32 + rg;
        const float v = d[rg];
        if (tile < 5)         xbcH[slot][tile * 32 + colid] = (_Float16)v;
        else if (colid < 2)   dtraw[slot][colid] = v;
      }
    }
  };

  {
    f32x16 d;
    d = __builtin_amdgcn_mfma_f32_32x32x16_f16(afr0, bfrA, z16, 0, 0, 0);
    writeD(d, tA, 0);
    d = __builtin_amdgcn_mfma_f32_32x32x16_f16(afr1, bfrA, z16, 0, 0, 0);
    writeD(d, tA, 1);
    if (hasB) {
      d = __builtin_amdgcn_mfma_f32_32x32x16_f16(afr0, bfrB, z16, 0, 0, 0);
      writeD(d, tB, 0);
      d = __builtin_amdgcn_mfma_f32_32x32x16_f16(afr1, bfrB, z16, 0, 0, 0);
      writeD(d, tB, 1);
    }
  }
  __syncthreads();   // B1

  // ================= phase 2: conv read + dt prefix-scan ===================
  const int cg = tid & 31, tg = tid >> 5;
  const int ch0 = cg * 5, t0c = tg * 4;
  float outv[5][4];
#pragma unroll
  for (int q = 0; q < 5; ++q) {
    const int ch = ch0 + q;
    const float4 cw = *reinterpret_cast<const float4*>(&P.convw[((size_t)h * CONVD + ch) * 4]);
    const float cb = P.convb[h * CONVD + ch];
    float vv[7];
#pragma unroll
    for (int i = 0; i < 7; ++i) vv[i] = (float)xbcH[t0c + i][ch];
#pragma unroll
    for (int d0 = 0; d0 < 4; ++d0) {
      float v = cb;
      v = fmaf(cw.x, vv[d0], v);
      v = fmaf(cw.y, vv[d0 + 1], v);
      v = fmaf(cw.z, vv[d0 + 2], v);
      v = fmaf(cw.w, vv[d0 + 3], v);
      outv[q][d0] = v * sigm(v);
    }
  }
  if (tid < 64) {
    const int t = tid & 31, hi = tid >> 5;
    const float dtbias = P.dtb[h * NHIN + hi];
    const float Ah = -__expf(P.Alog[h * NHIN + hi]);
    const float raw = dtraw[3 + t][hi] + dtbias;
    const float dtv = (raw > 20.f) ? raw : log1pf(__expf(raw));
    dtL[hi][t] = dtv;
    float s = dtv * Ah;
#pragma unroll
    for (int d = 1; d < 32; d <<= 1) {
      const float v = __shfl_up(s, d, 32);
      if (t >= d) s += v;
    }
    clL[hi][t] = s;
  }
  __syncthreads();   // B2

  // ================= phase 3: act write-back + operand tiles ===============
#pragma unroll
  for (int q = 0; q < 5; ++q) {
    const int ch = ch0 + q;
#pragma unroll
    for (int d0 = 0; d0 < 4; ++d0) xbcH[3 + t0c + d0][ch] = (_Float16)outv[q][d0];
    if (ch < DIN) {
      const int hi = ch >> 4;
      const float cl31 = clL[hi][31];
      half4 xt, wx;
#pragma unroll
      for (int d0 = 0; d0 < 4; ++d0) {
        const int t = t0c + d0;
        const float dtv = dtL[hi][t];
        const float w = __expf(cl31 - clL[hi][t]);
        xt[d0] = (_Float16)(dtv * outv[q][d0]);
        wx[d0] = (_Float16)(w * dtv * outv[q][d0]);
      }
      *reinterpret_cast<half4*>(&XtL[ch][t0c]) = xt;
      *reinterpret_cast<half4*>(&WXt[ch][t0c]) = wx;
    } else if (ch < DIN + DST) {
      half4 bm;
#pragma unroll
      for (int d0 = 0; d0 < 4; ++d0) bm[d0] = (_Float16)outv[q][d0];
      *reinterpret_cast<half4*>(&BmT[ch - DIN][t0c]) = bm;
    }
  }
  __syncthreads();   // B3

  // ================= phase 4: wave-specialized =============================
  if (wv == 0) {
    f32x16 g;
#pragma unroll
    for (int i = 0; i < 16; ++i) g[i] = 0.0f;
#pragma unroll
    for (int kk = 0; kk < 4; ++kk) {
      const half8 af = ld8(&xbcH[3 + lrow][96 + kk * 16 + kg * 8]);
      const half8 bf = ld8(&xbcH[3 + lrow][32 + kk * 16 + kg * 8]);
      g = __builtin_amdgcn_mfma_f32_32x32x16_f16(af, bf, g, 0, 0, 0);
    }
    const float cls0 = clL[0][lrow], cls1 = clL[1][lrow];
#pragma unroll
    for (int rg = 0; rg < 16; ++rg) {
      const int t = (rg & 3) + 8 * (rg >> 2) + 4 * kg;
      const float gg = g[rg];
      float l0 = 0.f, l1 = 0.f;
      if (lrow <= t) { l0 = __expf(clL[0][t] - cls0); l1 = __expf(clL[1][t] - cls1); }
      Gm[0][t][lrow] = (_Float16)(l0 * gg);
      Gm[1][t][lrow] = (_Float16)(l1 * gg);
    }
    const half8 xb0 = ld8(&XtL[lrow][kg * 8]);
    const half8 xb1 = ld8(&XtL[lrow][16 + kg * 8]);
    _Float16* yo = &yintra[(size_t)wg * (CHUNK * DIN)];
    {
      f32x16 acc;
#pragma unroll
      for (int i = 0; i < 16; ++i) acc[i] = 0.0f;
      acc = __builtin_amdgcn_mfma_f32_32x32x16_f16(ld8(&Gm[0][lrow][kg * 8]), xb0, acc, 0, 0, 0);
      acc = __builtin_amdgcn_mfma_f32_32x32x16_f16(ld8(&Gm[0][lrow][16 + kg * 8]), xb1, acc, 0, 0, 0);
      if (lrow < 16) {
        const float Dp0 = P.Dp[h * NHIN + 0];
#pragma unroll
        for (int rg = 0; rg < 16; ++rg) {
          const int t = (rg & 3) + 8 * (rg >> 2) + 4 * kg;
          yo[t * DIN + lrow] = (_Float16)(acc[rg] + Dp0 * (float)xbcH[3 + t][lrow]);
        }
      }
    }
    {
      f32x16 acc;
#pragma unroll
      for (int i = 0; i < 16; ++i) acc[i] = 0.0f;
      acc = __builtin_amdgcn_mfma_f32_32x32x16_f16(ld8(&Gm[1][lrow][kg * 8]), xb0, acc, 0, 0, 0);
      acc = __builtin_amdgcn_mfma_f32_32x32x16_f16(ld8(&Gm[1][lrow][16 + kg * 8]), xb1, acc, 0, 0, 0);
      if (lrow >= 16) {
        const float Dp1 = P.Dp[h * NHIN + 1];
#pragma unroll
        for (int rg = 0; rg < 16; ++rg) {
          const int t = (rg & 3) + 8 * (rg >> 2) + 4 * kg;
          yo[t * DIN + lrow] = (_Float16)(acc[rg] + Dp1 * (float)xbcH[3 + t][lrow]);
        }
      }
    }
  } else if (wv == 1 || wv == 2) {
    // S^T halves; NO cross-wave dependency -> no barrier needed
    const int nhalf = (wv - 1) * 32;
    const half8 wa0 = ld8(&WXt[lrow][kg * 8]);
    const half8 wa1 = ld8(&WXt[lrow][16 + kg * 8]);
    f32x16 acc;
#pragma unroll
    for (int i = 0; i < 16; ++i) acc[i] = 0.0f;
    acc = __builtin_amdgcn_mfma_f32_32x32x16_f16(
        wa0, ld8(&BmT[nhalf + lrow][kg * 8]), acc, 0, 0, 0);
    acc = __builtin_amdgcn_mfma_f32_32x32x16_f16(
        wa1, ld8(&BmT[nhalf + lrow][16 + kg * 8]), acc, 0, 0, 0);
#pragma unroll
    for (int rg = 0; rg < 16; ++rg) {
      const int m = (rg & 3) + 8 * (rg >> 2) + 4 * kg;
      StL[m][nhalf + lrow] = (_Float16)acc[rg];
    }
    const size_t base2 = (base0 * NCHUNK + c) * (NHIN * HD * DST);
#pragma unroll
    for (int k = 0; k < 4; ++k) {
      const int idx = lane + k * 64;
      const int row = idx >> 3, c4 = (idx & 7) * 4 + nhalf;
      *reinterpret_cast<ushort4*>(&Sg[base2 + row * DST + c4]) =
          *reinterpret_cast<const ushort4*>(&StL[row][c4]);
    }
  } else {
    if (lane < 32) {
      cumsg[(size_t)wg * CHUNK + lane] =
          make_float2(__expf(clL[0][lane]), __expf(clL[1][lane]));
    } else if (lane == 32) {
      Pbuf[(base0 * NCHUNK + c) * NHIN + 0] = __expf(clL[0][31]);
    } else if (lane == 33) {
      Pbuf[(base0 * NCHUNK + c) * NHIN + 1] = __expf(clL[1][31]);
    }
#pragma unroll
    for (int k = 0; k < 8; ++k) {
      const int idx = lane + k * 64;
      const int t = idx >> 4, c4 = (idx & 15) * 4;
      *reinterpret_cast<ushort4*>(&xgC[(size_t)wg * (CHUNK * DST) + t * DST + c4]) =
          *reinterpret_cast<const ushort4*>(&xbcH[3 + t][96 + c4]);
    }
  }
}

// ---------------------------------------------------------------------------
// Carry: combine over 64 chunks, batched 8-deep prefetch for latency hiding.
// ---------------------------------------------------------------------------
__global__ __launch_bounds__(256)
void carry_kernel(_Float16* __restrict__ Sg, const float* __restrict__ Pbuf)
{
  const int wg = blockIdx.x;
  const int b = wg % BBATCH;
  const int h = (wg / BBATCH) % NHEADS;
  const int team = wg / (BBATCH * NHEADS);
  const int tid = threadIdx.x;
  const int hi = tid >> 7;
  const int pp = (tid >> 3) & 15;
  const int ng = tid & 7;
  const int nb = ng * 8;
  const size_t base0 = ((size_t)team * NHEADS + h) * BBATCH + b;

  float hc[8] = {0, 0, 0, 0, 0, 0, 0, 0};
  for (int cb = 0; cb < NCHUNK; cb += 8) {
    half8 a[8];
    float Pv[8];
#pragma unroll
    for (int j = 0; j < 8; ++j) {
      const size_t sb = (((base0 * NCHUNK + cb + j) * NHIN + hi) * HD + pp) * DST + nb;
      a[j] = *reinterpret_cast<const half8*>(&Sg[sb]);
      Pv[j] = Pbuf[(base0 * NCHUNK + cb + j) * NHIN + hi];
    }
#pragma unroll
    for (int j = 0; j < 8; ++j) {
      const size_t sb = (((base0 * NCHUNK + cb + j) * NHIN + hi) * HD + pp) * DST + nb;
      half8 o;
#pragma unroll
      for (int k = 0; k < 8; ++k) o[k] = (_Float16)hc[k];
      *reinterpret_cast<half8*>(&Sg[sb]) = o;
#pragma unroll
      for (int k = 0; k < 8; ++k) hc[k] = fmaf(Pv[j], hc[k], (float)a[j][k]);
    }
  }
}

// ---------------------------------------------------------------------------
// K3 fused: both teams in one wg = (h, b, chunk). waves 0/1: C·H_in MFMA per
// team; waves 2/3: z MFMA per team. Then gate+rms+out-proj per team, diff,
// partial stats. No yhead.
// ---------------------------------------------------------------------------
__global__ __launch_bounds__(256)
void k3_fused(const _Float16* __restrict__ Sg, const float2* __restrict__ cumsg,
              const _Float16* __restrict__ xgC, const float* __restrict__ x,
              TeamParams tp0, TeamParams tp1,
              const _Float16* __restrict__ yintra, const float* __restrict__ lam,
              float* __restrict__ diffb, float2* __restrict__ pstat)
{
  __shared__ float    ysh[2][CHUNK][YS];
  __shared__ float    wn[2][16][33];
  __shared__ float    cums2[2][CHUNK][2];
  __shared__ _Float16 zsh[2][32][40];
  __shared__ float    youtL[2][CHUNK][20];
  __shared__ float    red2[8];

  const int tid  = threadIdx.x;
  const int wg   = blockIdx.x;
  const int c    = wg % NCHUNK;
  const int b    = (wg / NCHUNK) % BBATCH;
  const int h    = wg / (NCHUNK * BBATCH);
  const int c0 = c * CHUNK;
  const int lane = tid & 63;
  const int wv   = tid >> 6;

  const size_t wgT0 = (((size_t)0 * NHEADS + h) * BBATCH + b) * NCHUNK + c;
  const size_t wgT1 = (((size_t)1 * NHEADS + h) * BBATCH + b) * NCHUNK + c;

  f32x16 acc;
  if (wv < 2) {
    // ---- C · H_in for team wv ----
    const size_t wgT = wv ? wgT1 : wgT0;
    const int colid = lane & 31, kg = lane >> 5;
    const _Float16* ca = &xgC[wgT * (CHUNK * DST) + (size_t)colid * DST + kg * 8];
    const _Float16* hb = &Sg[wgT * (NHIN * HD * DST) + (size_t)colid * DST + kg * 8];
#pragma unroll
    for (int i = 0; i < 16; ++i) acc[i] = 0.0f;
    acc = __builtin_amdgcn_mfma_f32_32x32x16_f16(
        *reinterpret_cast<const half8*>(ca), *reinterpret_cast<const half8*>(hb), acc, 0, 0, 0);
    acc = __builtin_amdgcn_mfma_f32_32x32x16_f16(
        *reinterpret_cast<const half8*>(ca + 16), *reinterpret_cast<const half8*>(hb + 16), acc, 0, 0, 0);
    acc = __builtin_amdgcn_mfma_f32_32x32x16_f16(
        *reinterpret_cast<const half8*>(ca + 32), *reinterpret_cast<const half8*>(hb + 32), acc, 0, 0, 0);
    acc = __builtin_amdgcn_mfma_f32_32x32x16_f16(
        *reinterpret_cast<const half8*>(ca + 48), *reinterpret_cast<const half8*>(hb + 48), acc, 0, 0, 0);
  } else {
    // ---- z = silu(x · Win_z^T) for team wv-2 ----
    const int team = wv - 2;
    const TeamParams P = team ? tp1 : tp0;
    const int lrow = lane & 31, kg = lane >> 5;
    const float* xp = &x[((size_t)b * TSEQ + c0 + lrow) * DMODEL + h * HD + kg * 8];
    const half8 afr = pack_h8(*reinterpret_cast<const float4*>(xp),
                              *reinterpret_cast<const float4*>(xp + 4));
    const float* wp = &P.Win[((size_t)h * DPROJ + lrow) * HD + kg * 8];
    const half8 bfr = pack_h8(*reinterpret_cast<const float4*>(wp),
                              *reinterpret_cast<const float4*>(wp + 4));
    f32x16 zacc;
#pragma unroll
    for (int i = 0; i < 16; ++i) zacc[i] = 0.0f;
    zacc = __builtin_amdgcn_mfma_f32_32x32x16_f16(afr, bfr, zacc, 0, 0, 0);
#pragma unroll
    for (int rg = 0; rg < 16; ++rg) {
      const int t = (rg & 3) + 8 * (rg >> 2) + 4 * kg;
      const float v = zacc[rg];
      zsh[team][t][lrow] = (_Float16)(v * sigm(v));
    }
  }

  // ---- staging (all threads) ----
  {
    const TeamParams P0 = tp0, P1 = tp1;
#pragma unroll
    for (int k = 0; k < 4; ++k) {
      const int i = tid + k * 256;     // 0..1023
      const int tm = i >> 9, o = (i >> 5) & 15, dn = i & 31;
      const TeamParams& PP = tm ? P1 : P0;
      wn[tm][o][dn] = PP.Wout[((size_t)h * HD + o) * DIN + dn] * PP.nw[h * DIN + dn];
    }
  }
  {
    const int tm = tid >> 7, li = tid & 127;
    const int t = li >> 2, c8 = (li & 3) * 8;
    const size_t wgT = tm ? wgT1 : wgT0;
    const half8 v = *reinterpret_cast<const half8*>(&yintra[wgT * (CHUNK * DIN) + li * 8]);
#pragma unroll
    for (int j = 0; j < 8; ++j) ysh[tm][t][c8 + j] = (float)v[j];
  }
  if (tid < 64) {
    const int tm = tid >> 5, t = tid & 31;
    const size_t wgT = tm ? wgT1 : wgT0;
    const float2 v = cumsg[wgT * CHUNK + t];
    cums2[tm][t][0] = v.x; cums2[tm][t][1] = v.y;
  }
  __syncthreads();

  // ---- combine ----
  if (wv < 2) {
    const int team = wv;
    const int colid = lane & 31, kg = lane >> 5;
    const int hi = colid >> 4;
#pragma unroll
    for (int rg = 0; rg < 16; ++rg) {
      const int t = (rg & 3) + 8 * (rg >> 2) + 4 * kg;
      ysh[team][t][colid] = fmaf(cums2[team][t][hi], acc[rg], ysh[team][t][colid]);
    }
  }
  __syncthreads();

  // ---- gate + rms (rms folded into ysh) ----
  {
    const int tm = tid >> 7, l = tid & 127;
    const int q = l & 3, tl = l >> 2;
    const int dn0 = q * 8;
    float yg[8];
    float ss = 0.0f;
#pragma unroll
    for (int j = 0; j < 8; ++j) {
      const float g = ysh[tm][tl][dn0 + j] * (float)zsh[tm][tl][dn0 + j];
      yg[j] = g;
      ss += g * g;
    }
    ss += __shfl_xor(ss, 1, 4);
    ss += __shfl_xor(ss, 2, 4);
    const float rms = rsqrtf(ss * (1.0f / DIN) + 1e-5f);
#pragma unroll
    for (int j = 0; j < 8; ++j) ysh[tm][tl][dn0 + j] = yg[j] * rms;
  }
  __syncthreads();

  // ---- out-proj -> youtL ----
  {
    const int tm = tid >> 7, l = tid & 127;
    const int q = l & 3, tl = l >> 2;
#pragma unroll
    for (int oo = 0; oo < 4; ++oo) {
      const int o = q * 4 + oo;
      float a = 0.0f;
#pragma unroll
      for (int dn = 0; dn < DIN; ++dn) a = fmaf(ysh[tm][tl][dn], wn[tm][o][dn], a);
      youtL[tm][tl][o] = a;
    }
  }
  __syncthreads();

  // ---- diff + partial stats ----
  float s = 0.0f, s2 = 0.0f;
  if (tid < 128) {
    const int t = tid >> 2, hd0 = (tid & 3) * 4;
    const float4 l4 = *reinterpret_cast<const float4*>(&lam[h * HD + hd0]);
    const float* y0 = &youtL[0][t][hd0];
    const float* y1 = &youtL[1][t][hd0];
    float4 d;
    d.x = y0[0] - l4.x * y1[0];
    d.y = y0[1] - l4.y * y1[1];
    d.z = y0[2] - l4.z * y1[2];
    d.w = y0[3] - l4.w * y1[3];
    *reinterpret_cast<float4*>(
        &diffb[(((size_t)(h * BBATCH + b)) * TSEQ + c0 + t) * HD + hd0]) = d;
    s = d.x + d.y + d.z + d.w;
    s2 = d.x * d.x + d.y * d.y + d.z * d.z + d.w * d.w;
  }
#pragma unroll
  for (int off = 1; off < 64; off <<= 1) {
    s += __shfl_xor(s, off);
    s2 += __shfl_xor(s2, off);
  }
  if (lane == 0) { red2[wv * 2] = s; red2[wv * 2 + 1] = s2; }
  __syncthreads();
  if (tid == 0) pstat[wg] = make_float2(red2[0] + red2[2], red2[1] + red2[3]);
}

// ---------------------------------------------------------------------------
__global__ __launch_bounds__(64)
void stats_reduce(const float2* __restrict__ pstat, float* __restrict__ stats)
{
  const int hb = blockIdx.x;     // 0..31
  const int t = threadIdx.x;     // 0..63
  const float2 v = pstat[hb * NCHUNK + t];
  float s = v.x, s2 = v.y;
#pragma unroll
  for (int off = 1; off < 64; off <<= 1) {
    s += __shfl_xor(s, off);
    s2 += __shfl_xor(s2, off);
  }
  if (t == 0) {
    const float inv = 1.0f / (TSEQ * HD);
    const float mean = s * inv;
    const float var = s2 * inv - mean * mean;
    stats[hb * 2] = mean;
    stats[hb * 2 + 1] = rsqrtf(var + 1e-5f);
  }
}

// ---------------------------------------------------------------------------
#define TT_TILE 16
__global__ __launch_bounds__(256)
void final_kernel(const float* __restrict__ x, const float* __restrict__ diffb,
                  const float* __restrict__ stats, const float* __restrict__ gnw,
                  const float* __restrict__ gnb, const float* __restrict__ projw,
                  const float* __restrict__ projb, float* __restrict__ out)
{
  __shared__ float nd[TT_TILE][DMODEL];
  __shared__ float Wl[DMODEL][33];

  const int wg = blockIdx.x;
  const int nseg = TSEQ / TT_TILE;
  const int b = wg / nseg;
  const int t0 = (wg % nseg) * TT_TILE;
  const int tid = threadIdx.x;
  const int h = tid >> 4, hd = tid & 15;

  const float mean = stats[(h * BBATCH + b) * 2];
  const float rstd = stats[(h * BBATCH + b) * 2 + 1];
  const float g = gnw[h * HD + hd];
  const float be = gnb[h * HD + hd];
  for (int tt = 0; tt < TT_TILE; ++tt) {
    const float d = diffb[((size_t)(h * BBATCH + b) * TSEQ + t0 + tt) * HD + hd];
    nd[tt][tid] = (d - mean) * rstd * g + be;
  }

  float acc[TT_TILE];
#pragma unroll
  for (int tt = 0; tt < TT_TILE; ++tt) acc[tt] = 0.0f;

  for (int kt = 0; kt < DMODEL; kt += 32) {
    __syncthreads();
    for (int i = tid; i < DMODEL * 32; i += 256) {
      const int dr = i >> 5, kk = i & 31;
      Wl[dr][kk] = projw[(size_t)dr * DMODEL + kt + kk];
    }
    __syncthreads();
#pragma unroll
    for (int kk = 0; kk < 32; ++kk) {
      const float w = Wl[tid][kk];
#pragma unroll
      for (int tt = 0; tt < TT_TILE; ++tt) acc[tt] = fmaf(nd[tt][kt + kk], w, acc[tt]);
    }
  }

  const float pb = projb[tid];
  for (int tt = 0; tt < TT_TILE; ++tt) {
    const size_t o = ((size_t)b * TSEQ + t0 + tt) * DMODEL + tid;
    out[o] = x[o] + pb + acc[tt];
  }
}

// ---------------------------------------------------------------------------
extern "C" void kernel_launch(void* const* d_in, const int* in_sizes, int n_in,
                              void* d_out, int out_size, void* d_ws, size_t ws_size,
                              hipStream_t stream)
{
  const float* x = (const float*)d_in[0];
  TeamParams tp0 { (const float*)d_in[1], (const float*)d_in[2], (const float*)d_in[3],
                   (const float*)d_in[4], (const float*)d_in[5], (const float*)d_in[6],
                   (const float*)d_in[7], (const float*)d_in[8] };
  TeamParams tp1 { (const float*)d_in[9], (const float*)d_in[10], (const float*)d_in[11],
                   (const float*)d_in[12], (const float*)d_in[13], (const float*)d_in[14],
                   (const float*)d_in[15], (const float*)d_in[16] };
  const float* lam   = (const float*)d_in[17];
  const float* gnw   = (const float*)d_in[18];
  const float* gnb   = (const float*)d_in[19];
  const float* projw = (const float*)d_in[20];
  const float* projb = (const float*)d_in[21];

  // ws layout (bytes):
  //   Sg      @ 0           16,777,216
  //   Pbuf    @ 16,777,216      32,768
  //   cumsg   @ 16,809,984   1,048,576
  //   xgC     @ 17,858,560  16,777,216
  //   yintra  @ 34,635,776   8,388,608
  //   diffb   @ 43,024,384   4,194,304
  //   pstat   @ 47,218,688      16,384
  //   stats   @ 47,235,072         256   (total ~47.2 MB)
  char* wsb = (char*)d_ws;
  _Float16* Sg    = (_Float16*)wsb;
  float* Pbuf     = (float*)(wsb + 16777216);
  float2* cumsg   = (float2*)(wsb + 16809984);
  _Float16* xgC   = (_Float16*)(wsb + 17858560);
  _Float16* yintra= (_Float16*)(wsb + 34635776);
  float* diffb    = (float*)(wsb + 43024384);
  float2* pstat   = (float2*)(wsb + 47218688);
  float* stats    = (float*)(wsb + 47235072);

  k1_proj_ssd<<<dim3(NWG), dim3(256), 0, stream>>>(x, tp0, tp1, Sg, Pbuf, cumsg, xgC, yintra);
  carry_kernel<<<dim3(2 * NHEADS * BBATCH), dim3(256), 0, stream>>>(Sg, Pbuf);
  k3_fused<<<dim3(NWG3), dim3(256), 0, stream>>>(Sg, cumsg, xgC, x, tp0, tp1, yintra, lam, diffb, pstat);
  stats_reduce<<<dim3(NHEADS * BBATCH), dim3(64), 0, stream>>>(pstat, stats);
  final_kernel<<<dim3(BBATCH * (TSEQ / TT_TILE)), dim3(256), 0, stream>>>(
      x, diffb, stats, gnw, gnb, projw, projb, (float*)d_out);
}

// Round 8
// 108.042 us; speedup vs baseline: 3.8801x; 1.1430x over previous
//
#include <hip/hip_runtime.h>
#include <math.h>

#define NHEADS 16
#define BBATCH 2
#define TSEQ   2048
#define HD     16
#define DIN    32
#define DST    64
#define CONVD  160
#define DPROJ  194
#define NHIN   2
#define DMODEL 256
#define CHUNK  32
#define NCHUNK (TSEQ / CHUNK)                  // 64
#define NWG    (2 * NHEADS * BBATCH * NCHUNK)  // 4096 (k1)
#define NWG3   (NHEADS * BBATCH * NCHUNK)      // 2048 (k3 fused)
#define YS     36

struct TeamParams {
  const float *Win, *convw, *convb, *dtb, *Alog, *Dp, *nw, *Wout;
};

typedef __attribute__((ext_vector_type(4)))  _Float16 half4;
typedef __attribute__((ext_vector_type(8)))  _Float16 half8;
typedef __attribute__((ext_vector_type(16))) float    f32x16;

__device__ __forceinline__ float sigm(float v) { return 1.0f / (1.0f + __expf(-v)); }

__device__ __forceinline__ half8 pack_h8(float4 a, float4 b) {
  half8 r;
  r[0] = (_Float16)a.x; r[1] = (_Float16)a.y; r[2] = (_Float16)a.z; r[3] = (_Float16)a.w;
  r[4] = (_Float16)b.x; r[5] = (_Float16)b.y; r[6] = (_Float16)b.z; r[7] = (_Float16)b.w;
  return r;
}
__device__ __forceinline__ half8 zero_h8() {
  half8 r;
#pragma unroll
  for (int i = 0; i < 8; ++i) r[i] = (_Float16)0.f;
  return r;
}
__device__ __forceinline__ half8 ld8(const _Float16* p) {
  const half4 a = *reinterpret_cast<const half4*>(p);
  const half4 b = *reinterpret_cast<const half4*>(p + 4);
  half8 r;
  r[0] = a[0]; r[1] = a[1]; r[2] = a[2]; r[3] = a[3];
  r[4] = b[0]; r[5] = b[1]; r[6] = b[2]; r[7] = b[3];
  return r;
}

// ---------------------------------------------------------------------------
// K1: MFMA in-proj (f16 32x32x16, staged [ch][slot] for vector LDS stores) +
// vectorized conv4 + SSD chunk computation (4a/4b wave-balanced).
// ---------------------------------------------------------------------------
__global__ __launch_bounds__(256, 5)
void k1_proj_ssd(const float* __restrict__ x, TeamParams tp0, TeamParams tp1,
                 _Float16* __restrict__ Sg, float* __restrict__ Pbuf,
                 float2* __restrict__ cumsg, _Float16* __restrict__ xgC,
                 _Float16* __restrict__ yintra)
{
  __shared__ _Float16 rawT[160][36];   // in-proj raw xBC, [ch][slot]; dead after B2
  __shared__ _Float16 actH[32][164];   // silu(conv), [t][ch]
  __shared__ _Float16 Gm[2][32][36];   // masked L∘G
  __shared__ _Float16 StL[32][68];     // S^T staging
  __shared__ float    dtraw[35][2];
  __shared__ float    clL[2][32];
  __shared__ float    dtL[2][32];

  // aliases over rawT (valid after barrier B2):
  _Float16 (*XtL)[36] = &rawT[0];      // (dt*x)^T   rows 0..31
  _Float16 (*WXt)[36] = &rawT[32];     // (w*dt*x)^T rows 32..63
  _Float16 (*BmT)[36] = &rawT[64];     // B^T        rows 64..127

  const int tid  = threadIdx.x;
  const int wg   = blockIdx.x;
  const int c    = wg % NCHUNK;
  const int b    = (wg / NCHUNK) % BBATCH;
  const int h    = (wg / (NCHUNK * BBATCH)) % NHEADS;
  const int team = wg / (NCHUNK * BBATCH * NHEADS);
  const TeamParams P = team ? tp1 : tp0;
  const int c0 = c * CHUNK;
  const size_t base0 = ((size_t)team * NHEADS + h) * BBATCH + b;

  const int lane = tid & 63;
  const int wv   = tid >> 6;
  const int lrow = lane & 31;
  const int kg   = lane >> 5;

  // ================= phase 1: in-proj MFMA =================
  half8 afr0, afr1;
  {
    const int t = c0 - 3 + lrow;
    if (t >= 0) {
      const float* xp = &x[((size_t)b * TSEQ + t) * DMODEL + h * HD + kg * 8];
      afr0 = pack_h8(*reinterpret_cast<const float4*>(xp),
                     *reinterpret_cast<const float4*>(xp + 4));
    } else afr0 = zero_h8();
    if (lrow < 3) {
      const int t1 = c0 + 29 + lrow;
      const float* xp = &x[((size_t)b * TSEQ + t1) * DMODEL + h * HD + kg * 8];
      afr1 = pack_h8(*reinterpret_cast<const float4*>(xp),
                     *reinterpret_cast<const float4*>(xp + 4));
    } else afr1 = zero_h8();
  }
  const int  tA   = (wv < 2) ? wv * 2 : (wv == 2 ? 4 : 5);
  const bool hasB = (wv < 2);
  const int  tB   = wv * 2 + 1;
  half8 bfrA, bfrB = zero_h8();
  {
    const int rA = 32 + tA * 32 + lrow;
    if (rA < DPROJ) {
      const float* wp = &P.Win[((size_t)h * DPROJ + rA) * HD + kg * 8];
      bfrA = pack_h8(*reinterpret_cast<const float4*>(wp),
                     *reinterpret_cast<const float4*>(wp + 4));
    } else bfrA = zero_h8();
    if (hasB) {
      const int rB = 32 + tB * 32 + lrow;
      const float* wp = &P.Win[((size_t)h * DPROJ + rB) * HD + kg * 8];
      bfrB = pack_h8(*reinterpret_cast<const float4*>(wp),
                     *reinterpret_cast<const float4*>(wp + 4));
    }
  }

  f32x16 z16;
#pragma unroll
  for (int i = 0; i < 16; ++i) z16[i] = 0.0f;

  // D layout: col = lane&31, row(slot) = (rg&3) + 8*(rg>>2) + 4*kg
  auto writeD = [&](const f32x16& d, int tile, int m0) {
    if (tile < 5) {
      const int ch = tile * 32 + lrow;
      if (m0 == 0) {
#pragma unroll
        for (int m = 0; m < 4; ++m) {
          half4 v;
#pragma unroll
          for (int i = 0; i < 4; ++i) v[i] = (_Float16)d[4 * m + i];
          *reinterpret_cast<half4*>(&rawT[ch][4 * kg + 8 * m]) = v;
        }
      } else if (kg == 0) {
#pragma unroll
        for (int rg = 0; rg < 3; ++rg) rawT[ch][32 + rg] = (_Float16)d[rg];
      }
    } else if (lrow < 2) {
      if (m0 == 0) {
#pragma unroll
        for (int rg = 0; rg < 16; ++rg)
          dtraw[(rg & 3) + 8 * (rg >> 2) + 4 * kg][lrow] = d[rg];
      } else if (kg == 0) {
#pragma unroll
        for (int rg = 0; rg < 3; ++rg) dtraw[32 + rg][lrow] = d[rg];
      }
    }
  };

  {
    f32x16 d;
    d = __builtin_amdgcn_mfma_f32_32x32x16_f16(afr0, bfrA, z16, 0, 0, 0);
    writeD(d, tA, 0);
    d = __builtin_amdgcn_mfma_f32_32x32x16_f16(afr1, bfrA, z16, 0, 0, 0);
    writeD(d, tA, 1);
    if (hasB) {
      d = __builtin_amdgcn_mfma_f32_32x32x16_f16(afr0, bfrB, z16, 0, 0, 0);
      writeD(d, tB, 0);
      d = __builtin_amdgcn_mfma_f32_32x32x16_f16(afr1, bfrB, z16, 0, 0, 0);
      writeD(d, tB, 1);
    }
  }
  __syncthreads();   // B1

  // ================= phase 2: conv (vector reads) + dt prefix-scan =========
  const int cg = tid & 31, tg = tid >> 5;
  const int ch0 = cg * 5, t0c = tg * 4;
  float outv[5][4];
#pragma unroll
  for (int q = 0; q < 5; ++q) {
    const int ch = ch0 + q;
    const float4 cw = *reinterpret_cast<const float4*>(&P.convw[((size_t)h * CONVD + ch) * 4]);
    const float cb = P.convb[h * CONVD + ch];
    const half4 r0 = *reinterpret_cast<const half4*>(&rawT[ch][t0c]);
    const half4 r1 = *reinterpret_cast<const half4*>(&rawT[ch][t0c + 4]);
    float vv[7];
#pragma unroll
    for (int i = 0; i < 4; ++i) vv[i] = (float)r0[i];
#pragma unroll
    for (int i = 0; i < 3; ++i) vv[4 + i] = (float)r1[i];
#pragma unroll
    for (int d0 = 0; d0 < 4; ++d0) {
      float v = cb;
      v = fmaf(cw.x, vv[d0], v);
      v = fmaf(cw.y, vv[d0 + 1], v);
      v = fmaf(cw.z, vv[d0 + 2], v);
      v = fmaf(cw.w, vv[d0 + 3], v);
      outv[q][d0] = v * sigm(v);
    }
  }
  if (tid < 64) {
    const int t = tid & 31, hi = tid >> 5;
    const float dtbias = P.dtb[h * NHIN + hi];
    const float Ah = -__expf(P.Alog[h * NHIN + hi]);
    const float raw = dtraw[3 + t][hi] + dtbias;
    const float dtv = (raw > 20.f) ? raw : log1pf(__expf(raw));
    dtL[hi][t] = dtv;
    float s = dtv * Ah;
#pragma unroll
    for (int d = 1; d < 32; d <<= 1) {
      const float v = __shfl_up(s, d, 32);
      if (t >= d) s += v;
    }
    clL[hi][t] = s;
  }
  __syncthreads();   // B2  (rawT raw data dead; aliases become live)

  // ================= phase 3: act + operand tiles ==========================
#pragma unroll
  for (int q = 0; q < 5; ++q) {
    const int ch = ch0 + q;
#pragma unroll
    for (int d0 = 0; d0 < 4; ++d0) actH[t0c + d0][ch] = (_Float16)outv[q][d0];
    if (ch < DIN) {
      const int hi = ch >> 4;
      const float cl31 = clL[hi][31];
      half4 xt, wx;
#pragma unroll
      for (int d0 = 0; d0 < 4; ++d0) {
        const int t = t0c + d0;
        const float dtv = dtL[hi][t];
        const float w = __expf(cl31 - clL[hi][t]);
        xt[d0] = (_Float16)(dtv * outv[q][d0]);
        wx[d0] = (_Float16)(w * dtv * outv[q][d0]);
      }
      *reinterpret_cast<half4*>(&XtL[ch][t0c]) = xt;
      *reinterpret_cast<half4*>(&WXt[ch][t0c]) = wx;
    } else if (ch < DIN + DST) {
      half4 bm;
#pragma unroll
      for (int d0 = 0; d0 < 4; ++d0) bm[d0] = (_Float16)outv[q][d0];
      *reinterpret_cast<half4*>(&BmT[ch - DIN][t0c]) = bm;
    }
  }
  __syncthreads();   // B3

  // ================= phase 4a ==============================================
  if (wv == 0) {
    // G = C·B^T, mask both hi
    f32x16 g;
#pragma unroll
    for (int i = 0; i < 16; ++i) g[i] = 0.0f;
#pragma unroll
    for (int kk = 0; kk < 4; ++kk) {
      const half8 af = ld8(&actH[lrow][96 + kk * 16 + kg * 8]);
      const half8 bf = ld8(&actH[lrow][32 + kk * 16 + kg * 8]);
      g = __builtin_amdgcn_mfma_f32_32x32x16_f16(af, bf, g, 0, 0, 0);
    }
    const float cls0 = clL[0][lrow], cls1 = clL[1][lrow];
#pragma unroll
    for (int rg = 0; rg < 16; ++rg) {
      const int t = (rg & 3) + 8 * (rg >> 2) + 4 * kg;
      const float gg = g[rg];
      float l0 = 0.f, l1 = 0.f;
      if (lrow <= t) { l0 = __expf(clL[0][t] - cls0); l1 = __expf(clL[1][t] - cls1); }
      Gm[0][t][lrow] = (_Float16)(l0 * gg);
      Gm[1][t][lrow] = (_Float16)(l1 * gg);
    }
  } else if (wv == 1 || wv == 2) {
    // S^T = (w dt x)^T · B, half per wave
    const int nhalf = (wv - 1) * 32;
    const half8 wa0 = ld8(&WXt[lrow][kg * 8]);
    const half8 wa1 = ld8(&WXt[lrow][16 + kg * 8]);
    f32x16 acc;
#pragma unroll
    for (int i = 0; i < 16; ++i) acc[i] = 0.0f;
    acc = __builtin_amdgcn_mfma_f32_32x32x16_f16(
        wa0, ld8(&BmT[nhalf + lrow][kg * 8]), acc, 0, 0, 0);
    acc = __builtin_amdgcn_mfma_f32_32x32x16_f16(
        wa1, ld8(&BmT[nhalf + lrow][16 + kg * 8]), acc, 0, 0, 0);
#pragma unroll
    for (int rg = 0; rg < 16; ++rg) {
      const int m = (rg & 3) + 8 * (rg >> 2) + 4 * kg;
      StL[m][nhalf + lrow] = (_Float16)acc[rg];
    }
  } else {
    // C store + cums/P
    if (lane < 32) {
      cumsg[(size_t)wg * CHUNK + lane] =
          make_float2(__expf(clL[0][lane]), __expf(clL[1][lane]));
    } else if (lane == 32) {
      Pbuf[(base0 * NCHUNK + c) * NHIN + 0] = __expf(clL[0][31]);
    } else if (lane == 33) {
      Pbuf[(base0 * NCHUNK + c) * NHIN + 1] = __expf(clL[1][31]);
    }
#pragma unroll
    for (int k = 0; k < 8; ++k) {
      const int idx = lane + k * 64;
      const int t = idx >> 4, c4 = (idx & 15) * 4;
      *reinterpret_cast<ushort4*>(&xgC[(size_t)wg * (CHUNK * DST) + t * DST + c4]) =
          *reinterpret_cast<const ushort4*>(&actH[t][96 + c4]);
    }
  }
  __syncthreads();   // B4

  // ================= phase 4b ==============================================
  if (wv < 2) {
    // y_intra for hi = wv
    const int hi = wv;
    const half8 xb0 = ld8(&XtL[lrow][kg * 8]);
    const half8 xb1 = ld8(&XtL[lrow][16 + kg * 8]);
    f32x16 acc;
#pragma unroll
    for (int i = 0; i < 16; ++i) acc[i] = 0.0f;
    acc = __builtin_amdgcn_mfma_f32_32x32x16_f16(ld8(&Gm[hi][lrow][kg * 8]), xb0, acc, 0, 0, 0);
    acc = __builtin_amdgcn_mfma_f32_32x32x16_f16(ld8(&Gm[hi][lrow][16 + kg * 8]), xb1, acc, 0, 0, 0);
    const bool own = (lrow >> 4) == hi;
    if (own) {
      const float Dp = P.Dp[h * NHIN + hi];
      _Float16* yo = &yintra[(size_t)wg * (CHUNK * DIN)];
#pragma unroll
      for (int rg = 0; rg < 16; ++rg) {
        const int t = (rg & 3) + 8 * (rg >> 2) + 4 * kg;
        yo[t * DIN + lrow] = (_Float16)(acc[rg] + Dp * (float)actH[t][lrow]);
      }
    }
  } else if (wv == 2) {
    const size_t base2 = (base0 * NCHUNK + c) * (NHIN * HD * DST);
#pragma unroll
    for (int k = 0; k < 8; ++k) {
      const int idx = lane + k * 64;
      const int row = idx >> 4, c4 = (idx & 15) * 4;
      *reinterpret_cast<ushort4*>(&Sg[base2 + row * DST + c4]) =
          *reinterpret_cast<const ushort4*>(&StL[row][c4]);
    }
  }
}

// ---------------------------------------------------------------------------
// Carry: combine over 64 chunks, batched 8-deep prefetch.
// ---------------------------------------------------------------------------
__global__ __launch_bounds__(256)
void carry_kernel(_Float16* __restrict__ Sg, const float* __restrict__ Pbuf)
{
  const int wg = blockIdx.x;
  const int b = wg % BBATCH;
  const int h = (wg / BBATCH) % NHEADS;
  const int team = wg / (BBATCH * NHEADS);
  const int tid = threadIdx.x;
  const int hi = tid >> 7;
  const int pp = (tid >> 3) & 15;
  const int ng = tid & 7;
  const int nb = ng * 8;
  const size_t base0 = ((size_t)team * NHEADS + h) * BBATCH + b;

  float hc[8] = {0, 0, 0, 0, 0, 0, 0, 0};
  for (int cb = 0; cb < NCHUNK; cb += 8) {
    half8 a[8];
    float Pv[8];
#pragma unroll
    for (int j = 0; j < 8; ++j) {
      const size_t sb = (((base0 * NCHUNK + cb + j) * NHIN + hi) * HD + pp) * DST + nb;
      a[j] = *reinterpret_cast<const half8*>(&Sg[sb]);
      Pv[j] = Pbuf[(base0 * NCHUNK + cb + j) * NHIN + hi];
    }
#pragma unroll
    for (int j = 0; j < 8; ++j) {
      const size_t sb = (((base0 * NCHUNK + cb + j) * NHIN + hi) * HD + pp) * DST + nb;
      half8 o;
#pragma unroll
      for (int k = 0; k < 8; ++k) o[k] = (_Float16)hc[k];
      *reinterpret_cast<half8*>(&Sg[sb]) = o;
#pragma unroll
      for (int k = 0; k < 8; ++k) hc[k] = fmaf(Pv[j], hc[k], (float)a[j][k]);
    }
  }
}

// ---------------------------------------------------------------------------
// K3 fused: both teams per wg; C·H_in + z MFMAs, gate+rms+out-proj, diff,
// partial stats.
// ---------------------------------------------------------------------------
__global__ __launch_bounds__(256)
void k3_fused(const _Float16* __restrict__ Sg, const float2* __restrict__ cumsg,
              const _Float16* __restrict__ xgC, const float* __restrict__ x,
              TeamParams tp0, TeamParams tp1,
              const _Float16* __restrict__ yintra, const float* __restrict__ lam,
              float* __restrict__ diffb, float2* __restrict__ pstat)
{
  __shared__ float    ysh[2][CHUNK][YS];
  __shared__ float    wn[2][16][33];
  __shared__ float    cums2[2][CHUNK][2];
  __shared__ _Float16 zsh[2][32][40];
  __shared__ float    youtL[2][CHUNK][20];
  __shared__ float    red2[8];

  const int tid  = threadIdx.x;
  const int wg   = blockIdx.x;
  const int c    = wg % NCHUNK;
  const int b    = (wg / NCHUNK) % BBATCH;
  const int h    = wg / (NCHUNK * BBATCH);
  const int c0 = c * CHUNK;
  const int lane = tid & 63;
  const int wv   = tid >> 6;

  const size_t wgT0 = (((size_t)0 * NHEADS + h) * BBATCH + b) * NCHUNK + c;
  const size_t wgT1 = (((size_t)1 * NHEADS + h) * BBATCH + b) * NCHUNK + c;

  f32x16 acc;
  if (wv < 2) {
    const size_t wgT = wv ? wgT1 : wgT0;
    const int colid = lane & 31, kg = lane >> 5;
    const _Float16* ca = &xgC[wgT * (CHUNK * DST) + (size_t)colid * DST + kg * 8];
    const _Float16* hb = &Sg[wgT * (NHIN * HD * DST) + (size_t)colid * DST + kg * 8];
#pragma unroll
    for (int i = 0; i < 16; ++i) acc[i] = 0.0f;
    acc = __builtin_amdgcn_mfma_f32_32x32x16_f16(
        *reinterpret_cast<const half8*>(ca), *reinterpret_cast<const half8*>(hb), acc, 0, 0, 0);
    acc = __builtin_amdgcn_mfma_f32_32x32x16_f16(
        *reinterpret_cast<const half8*>(ca + 16), *reinterpret_cast<const half8*>(hb + 16), acc, 0, 0, 0);
    acc = __builtin_amdgcn_mfma_f32_32x32x16_f16(
        *reinterpret_cast<const half8*>(ca + 32), *reinterpret_cast<const half8*>(hb + 32), acc, 0, 0, 0);
    acc = __builtin_amdgcn_mfma_f32_32x32x16_f16(
        *reinterpret_cast<const half8*>(ca + 48), *reinterpret_cast<const half8*>(hb + 48), acc, 0, 0, 0);
  } else {
    const int team = wv - 2;
    const TeamParams P = team ? tp1 : tp0;
    const int lrow = lane & 31, kg = lane >> 5;
    const float* xp = &x[((size_t)b * TSEQ + c0 + lrow) * DMODEL + h * HD + kg * 8];
    const half8 afr = pack_h8(*reinterpret_cast<const float4*>(xp),
                              *reinterpret_cast<const float4*>(xp + 4));
    const float* wp = &P.Win[((size_t)h * DPROJ + lrow) * HD + kg * 8];
    const half8 bfr = pack_h8(*reinterpret_cast<const float4*>(wp),
                              *reinterpret_cast<const float4*>(wp + 4));
    f32x16 zacc;
#pragma unroll
    for (int i = 0; i < 16; ++i) zacc[i] = 0.0f;
    zacc = __builtin_amdgcn_mfma_f32_32x32x16_f16(afr, bfr, zacc, 0, 0, 0);
#pragma unroll
    for (int rg = 0; rg < 16; ++rg) {
      const int t = (rg & 3) + 8 * (rg >> 2) + 4 * kg;
      const float v = zacc[rg];
      zsh[team][t][lrow] = (_Float16)(v * sigm(v));
    }
  }

  {
    const TeamParams P0 = tp0, P1 = tp1;
#pragma unroll
    for (int k = 0; k < 4; ++k) {
      const int i = tid + k * 256;
      const int tm = i >> 9, o = (i >> 5) & 15, dn = i & 31;
      const TeamParams& PP = tm ? P1 : P0;
      wn[tm][o][dn] = PP.Wout[((size_t)h * HD + o) * DIN + dn] * PP.nw[h * DIN + dn];
    }
  }
  {
    const int tm = tid >> 7, li = tid & 127;
    const int t = li >> 2, c8 = (li & 3) * 8;
    const size_t wgT = tm ? wgT1 : wgT0;
    const half8 v = *reinterpret_cast<const half8*>(&yintra[wgT * (CHUNK * DIN) + li * 8]);
#pragma unroll
    for (int j = 0; j < 8; ++j) ysh[tm][t][c8 + j] = (float)v[j];
  }
  if (tid < 64) {
    const int tm = tid >> 5, t = tid & 31;
    const size_t wgT = tm ? wgT1 : wgT0;
    const float2 v = cumsg[wgT * CHUNK + t];
    cums2[tm][t][0] = v.x; cums2[tm][t][1] = v.y;
  }
  __syncthreads();

  if (wv < 2) {
    const int team = wv;
    const int colid = lane & 31, kg = lane >> 5;
    const int hi = colid >> 4;
#pragma unroll
    for (int rg = 0; rg < 16; ++rg) {
      const int t = (rg & 3) + 8 * (rg >> 2) + 4 * kg;
      ysh[team][t][colid] = fmaf(cums2[team][t][hi], acc[rg], ysh[team][t][colid]);
    }
  }
  __syncthreads();

  {
    const int tm = tid >> 7, l = tid & 127;
    const int q = l & 3, tl = l >> 2;
    const int dn0 = q * 8;
    float yg[8];
    float ss = 0.0f;
#pragma unroll
    for (int j = 0; j < 8; ++j) {
      const float g = ysh[tm][tl][dn0 + j] * (float)zsh[tm][tl][dn0 + j];
      yg[j] = g;
      ss += g * g;
    }
    ss += __shfl_xor(ss, 1, 4);
    ss += __shfl_xor(ss, 2, 4);
    const float rms = rsqrtf(ss * (1.0f / DIN) + 1e-5f);
#pragma unroll
    for (int j = 0; j < 8; ++j) ysh[tm][tl][dn0 + j] = yg[j] * rms;
  }
  __syncthreads();

  {
    const int tm = tid >> 7, l = tid & 127;
    const int q = l & 3, tl = l >> 2;
#pragma unroll
    for (int oo = 0; oo < 4; ++oo) {
      const int o = q * 4 + oo;
      float a = 0.0f;
#pragma unroll
      for (int dn = 0; dn < DIN; ++dn) a = fmaf(ysh[tm][tl][dn], wn[tm][o][dn], a);
      youtL[tm][tl][o] = a;
    }
  }
  __syncthreads();

  float s = 0.0f, s2 = 0.0f;
  if (tid < 128) {
    const int t = tid >> 2, hd0 = (tid & 3) * 4;
    const float4 l4 = *reinterpret_cast<const float4*>(&lam[h * HD + hd0]);
    const float* y0 = &youtL[0][t][hd0];
    const float* y1 = &youtL[1][t][hd0];
    float4 d;
    d.x = y0[0] - l4.x * y1[0];
    d.y = y0[1] - l4.y * y1[1];
    d.z = y0[2] - l4.z * y1[2];
    d.w = y0[3] - l4.w * y1[3];
    *reinterpret_cast<float4*>(
        &diffb[(((size_t)(h * BBATCH + b)) * TSEQ + c0 + t) * HD + hd0]) = d;
    s = d.x + d.y + d.z + d.w;
    s2 = d.x * d.x + d.y * d.y + d.z * d.z + d.w * d.w;
  }
#pragma unroll
  for (int off = 1; off < 64; off <<= 1) {
    s += __shfl_xor(s, off);
    s2 += __shfl_xor(s2, off);
  }
  if (lane == 0) { red2[wv * 2] = s; red2[wv * 2 + 1] = s2; }
  __syncthreads();
  if (tid == 0) pstat[wg] = make_float2(red2[0] + red2[2], red2[1] + red2[3]);
}

// ---------------------------------------------------------------------------
// Final: in-kernel stats reduction (deterministic) + groupnorm + proj + res.
// ---------------------------------------------------------------------------
#define TT_TILE 16
__global__ __launch_bounds__(256)
void final_kernel(const float* __restrict__ x, const float* __restrict__ diffb,
                  const float2* __restrict__ pstat, const float* __restrict__ gnw,
                  const float* __restrict__ gnb, const float* __restrict__ projw,
                  const float* __restrict__ projb, float* __restrict__ out)
{
  __shared__ float nd[TT_TILE][DMODEL];
  __shared__ float Wl[DMODEL][33];
  __shared__ float statL[NHEADS][2];

  const int wg = blockIdx.x;
  const int nseg = TSEQ / TT_TILE;
  const int b = wg / nseg;
  const int t0 = (wg % nseg) * TT_TILE;
  const int tid = threadIdx.x;
  const int h = tid >> 4, hd = tid & 15;

  // ---- stats: 16 threads per h reduce 64 pstat entries ----
  {
    float s = 0.0f, s2 = 0.0f;
    for (int k = hd; k < NCHUNK; k += 16) {
      const float2 v = pstat[((size_t)h * BBATCH + b) * NCHUNK + k];
      s += v.x; s2 += v.y;
    }
    s += __shfl_xor(s, 1, 16);  s2 += __shfl_xor(s2, 1, 16);
    s += __shfl_xor(s, 2, 16);  s2 += __shfl_xor(s2, 2, 16);
    s += __shfl_xor(s, 4, 16);  s2 += __shfl_xor(s2, 4, 16);
    s += __shfl_xor(s, 8, 16);  s2 += __shfl_xor(s2, 8, 16);
    if (hd == 0) {
      const float inv = 1.0f / (TSEQ * HD);
      const float mean = s * inv;
      const float var = s2 * inv - mean * mean;
      statL[h][0] = mean;
      statL[h][1] = rsqrtf(var + 1e-5f);
    }
  }
  __syncthreads();

  const float mean = statL[h][0];
  const float rstd = statL[h][1];
  const float g = gnw[h * HD + hd];
  const float be = gnb[h * HD + hd];
  for (int tt = 0; tt < TT_TILE; ++tt) {
    const float d = diffb[((size_t)(h * BBATCH + b) * TSEQ + t0 + tt) * HD + hd];
    nd[tt][tid] = (d - mean) * rstd * g + be;
  }

  float acc[TT_TILE];
#pragma unroll
  for (int tt = 0; tt < TT_TILE; ++tt) acc[tt] = 0.0f;

  for (int kt = 0; kt < DMODEL; kt += 32) {
    __syncthreads();
    for (int i = tid; i < DMODEL * 32; i += 256) {
      const int dr = i >> 5, kk = i & 31;
      Wl[dr][kk] = projw[(size_t)dr * DMODEL + kt + kk];
    }
    __syncthreads();
#pragma unroll
    for (int kk = 0; kk < 32; ++kk) {
      const float w = Wl[tid][kk];
#pragma unroll
      for (int tt = 0; tt < TT_TILE; ++tt) acc[tt] = fmaf(nd[tt][kt + kk], w, acc[tt]);
    }
  }

  const float pb = projb[tid];
  for (int tt = 0; tt < TT_TILE; ++tt) {
    const size_t o = ((size_t)b * TSEQ + t0 + tt) * DMODEL + tid;
    out[o] = x[o] + pb + acc[tt];
  }
}

// ---------------------------------------------------------------------------
extern "C" void kernel_launch(void* const* d_in, const int* in_sizes, int n_in,
                              void* d_out, int out_size, void* d_ws, size_t ws_size,
                              hipStream_t stream)
{
  const float* x = (const float*)d_in[0];
  TeamParams tp0 { (const float*)d_in[1], (const float*)d_in[2], (const float*)d_in[3],
                   (const float*)d_in[4], (const float*)d_in[5], (const float*)d_in[6],
                   (const float*)d_in[7], (const float*)d_in[8] };
  TeamParams tp1 { (const float*)d_in[9], (const float*)d_in[10], (const float*)d_in[11],
                   (const float*)d_in[12], (const float*)d_in[13], (const float*)d_in[14],
                   (const float*)d_in[15], (const float*)d_in[16] };
  const float* lam   = (const float*)d_in[17];
  const float* gnw   = (const float*)d_in[18];
  const float* gnb   = (const float*)d_in[19];
  const float* projw = (const float*)d_in[20];
  const float* projb = (const float*)d_in[21];

  // ws layout (bytes):
  //   Sg      @ 0           16,777,216
  //   Pbuf    @ 16,777,216      32,768
  //   cumsg   @ 16,809,984   1,048,576
  //   xgC     @ 17,858,560  16,777,216
  //   yintra  @ 34,635,776   8,388,608
  //   diffb   @ 43,024,384   4,194,304
  //   pstat   @ 47,218,688      16,384   (total ~47.2 MB)
  char* wsb = (char*)d_ws;
  _Float16* Sg    = (_Float16*)wsb;
  float* Pbuf     = (float*)(wsb + 16777216);
  float2* cumsg   = (float2*)(wsb + 16809984);
  _Float16* xgC   = (_Float16*)(wsb + 17858560);
  _Float16* yintra= (_Float16*)(wsb + 34635776);
  float* diffb    = (float*)(wsb + 43024384);
  float2* pstat   = (float2*)(wsb + 47218688);

  k1_proj_ssd<<<dim3(NWG), dim3(256), 0, stream>>>(x, tp0, tp1, Sg, Pbuf, cumsg, xgC, yintra);
  carry_kernel<<<dim3(2 * NHEADS * BBATCH), dim3(256), 0, stream>>>(Sg, Pbuf);
  k3_fused<<<dim3(NWG3), dim3(256), 0, stream>>>(Sg, cumsg, xgC, x, tp0, tp1, yintra, lam, diffb, pstat);
  final_kernel<<<dim3(BBATCH * (TSEQ / TT_TILE)), dim3(256), 0, stream>>>(
      x, diffb, pstat, gnw, gnb, projw, projb, (float*)d_out);
}

// Round 9
// 91.084 us; speedup vs baseline: 4.6025x; 1.1862x over previous
//
#include <hip/hip_runtime.h>
#include <math.h>

#define NHEADS 16
#define BBATCH 2
#define TSEQ   2048
#define HD     16
#define DIN    32
#define DST    64
#define CONVD  160
#define DPROJ  194
#define NHIN   2
#define DMODEL 256
#define CHUNK  32
#define NCHUNK (TSEQ / CHUNK)                  // 64
#define NWG    (2 * NHEADS * BBATCH * NCHUNK)  // 4096 (k1)
#define NWG3   (NHEADS * BBATCH * NCHUNK)      // 2048 (k3 fused)
#define YS     36

struct TeamParams {
  const float *Win, *convw, *convb, *dtb, *Alog, *Dp, *nw, *Wout;
};

typedef __attribute__((ext_vector_type(4)))  _Float16 half4;
typedef __attribute__((ext_vector_type(8)))  _Float16 half8;
typedef __attribute__((ext_vector_type(16))) float    f32x16;

__device__ __forceinline__ float sigm(float v) { return 1.0f / (1.0f + __expf(-v)); }

__device__ __forceinline__ half8 pack_h8(float4 a, float4 b) {
  half8 r;
  r[0] = (_Float16)a.x; r[1] = (_Float16)a.y; r[2] = (_Float16)a.z; r[3] = (_Float16)a.w;
  r[4] = (_Float16)b.x; r[5] = (_Float16)b.y; r[6] = (_Float16)b.z; r[7] = (_Float16)b.w;
  return r;
}
__device__ __forceinline__ half8 zero_h8() {
  half8 r;
#pragma unroll
  for (int i = 0; i < 8; ++i) r[i] = (_Float16)0.f;
  return r;
}
__device__ __forceinline__ half8 ld8(const _Float16* p) {
  const half4 a = *reinterpret_cast<const half4*>(p);
  const half4 b = *reinterpret_cast<const half4*>(p + 4);
  half8 r;
  r[0] = a[0]; r[1] = a[1]; r[2] = a[2]; r[3] = a[3];
  r[4] = b[0]; r[5] = b[1]; r[6] = b[2]; r[7] = b[3];
  return r;
}

// ---------------------------------------------------------------------------
// K1: MFMA in-proj (f16 32x32x16, staged [ch][slot] for vector LDS stores) +
// vectorized conv4 + SSD chunk computation (4a/4b wave-balanced).
// ---------------------------------------------------------------------------
__global__ __launch_bounds__(256, 5)
void k1_proj_ssd(const float* __restrict__ x, TeamParams tp0, TeamParams tp1,
                 _Float16* __restrict__ Sg, float* __restrict__ Pbuf,
                 float2* __restrict__ cumsg, _Float16* __restrict__ xgC,
                 _Float16* __restrict__ yintra)
{
  __shared__ _Float16 rawT[160][36];   // in-proj raw xBC, [ch][slot]; dead after B2
  __shared__ _Float16 actH[32][164];   // silu(conv), [t][ch]
  __shared__ _Float16 Gm[2][32][36];   // masked L∘G
  __shared__ _Float16 StL[32][68];     // S^T staging
  __shared__ float    dtraw[35][2];
  __shared__ float    clL[2][32];
  __shared__ float    dtL[2][32];

  _Float16 (*XtL)[36] = &rawT[0];
  _Float16 (*WXt)[36] = &rawT[32];
  _Float16 (*BmT)[36] = &rawT[64];

  const int tid  = threadIdx.x;
  const int wg   = blockIdx.x;
  const int c    = wg % NCHUNK;
  const int b    = (wg / NCHUNK) % BBATCH;
  const int h    = (wg / (NCHUNK * BBATCH)) % NHEADS;
  const int team = wg / (NCHUNK * BBATCH * NHEADS);
  const TeamParams P = team ? tp1 : tp0;
  const int c0 = c * CHUNK;
  const size_t base0 = ((size_t)team * NHEADS + h) * BBATCH + b;

  const int lane = tid & 63;
  const int wv   = tid >> 6;
  const int lrow = lane & 31;
  const int kg   = lane >> 5;

  // ================= phase 1: in-proj MFMA =================
  half8 afr0, afr1;
  {
    const int t = c0 - 3 + lrow;
    if (t >= 0) {
      const float* xp = &x[((size_t)b * TSEQ + t) * DMODEL + h * HD + kg * 8];
      afr0 = pack_h8(*reinterpret_cast<const float4*>(xp),
                     *reinterpret_cast<const float4*>(xp + 4));
    } else afr0 = zero_h8();
    if (lrow < 3) {
      const int t1 = c0 + 29 + lrow;
      const float* xp = &x[((size_t)b * TSEQ + t1) * DMODEL + h * HD + kg * 8];
      afr1 = pack_h8(*reinterpret_cast<const float4*>(xp),
                     *reinterpret_cast<const float4*>(xp + 4));
    } else afr1 = zero_h8();
  }
  const int  tA   = (wv < 2) ? wv * 2 : (wv == 2 ? 4 : 5);
  const bool hasB = (wv < 2);
  const int  tB   = wv * 2 + 1;
  half8 bfrA, bfrB = zero_h8();
  {
    const int rA = 32 + tA * 32 + lrow;
    if (rA < DPROJ) {
      const float* wp = &P.Win[((size_t)h * DPROJ + rA) * HD + kg * 8];
      bfrA = pack_h8(*reinterpret_cast<const float4*>(wp),
                     *reinterpret_cast<const float4*>(wp + 4));
    } else bfrA = zero_h8();
    if (hasB) {
      const int rB = 32 + tB * 32 + lrow;
      const float* wp = &P.Win[((size_t)h * DPROJ + rB) * HD + kg * 8];
      bfrB = pack_h8(*reinterpret_cast<const float4*>(wp),
                     *reinterpret_cast<const float4*>(wp + 4));
    }
  }

  f32x16 z16;
#pragma unroll
  for (int i = 0; i < 16; ++i) z16[i] = 0.0f;

  auto writeD = [&](const f32x16& d, int tile, int m0) {
    if (tile < 5) {
      const int ch = tile * 32 + lrow;
      if (m0 == 0) {
#pragma unroll
        for (int m = 0; m < 4; ++m) {
          half4 v;
#pragma unroll
          for (int i = 0; i < 4; ++i) v[i] = (_Float16)d[4 * m + i];
          *reinterpret_cast<half4*>(&rawT[ch][4 * kg + 8 * m]) = v;
        }
      } else if (kg == 0) {
#pragma unroll
        for (int rg = 0; rg < 3; ++rg) rawT[ch][32 + rg] = (_Float16)d[rg];
      }
    } else if (lrow < 2) {
      if (m0 == 0) {
#pragma unroll
        for (int rg = 0; rg < 16; ++rg)
          dtraw[(rg & 3) + 8 * (rg >> 2) + 4 * kg][lrow] = d[rg];
      } else if (kg == 0) {
#pragma unroll
        for (int rg = 0; rg < 3; ++rg) dtraw[32 + rg][lrow] = d[rg];
      }
    }
  };

  {
    f32x16 d;
    d = __builtin_amdgcn_mfma_f32_32x32x16_f16(afr0, bfrA, z16, 0, 0, 0);
    writeD(d, tA, 0);
    d = __builtin_amdgcn_mfma_f32_32x32x16_f16(afr1, bfrA, z16, 0, 0, 0);
    writeD(d, tA, 1);
    if (hasB) {
      d = __builtin_amdgcn_mfma_f32_32x32x16_f16(afr0, bfrB, z16, 0, 0, 0);
      writeD(d, tB, 0);
      d = __builtin_amdgcn_mfma_f32_32x32x16_f16(afr1, bfrB, z16, 0, 0, 0);
      writeD(d, tB, 1);
    }
  }
  __syncthreads();   // B1

  // ================= phase 2: conv (vector reads) + dt prefix-scan =========
  const int cg = tid & 31, tg = tid >> 5;
  const int ch0 = cg * 5, t0c = tg * 4;
  float outv[5][4];
#pragma unroll
  for (int q = 0; q < 5; ++q) {
    const int ch = ch0 + q;
    const float4 cw = *reinterpret_cast<const float4*>(&P.convw[((size_t)h * CONVD + ch) * 4]);
    const float cb = P.convb[h * CONVD + ch];
    const half4 r0 = *reinterpret_cast<const half4*>(&rawT[ch][t0c]);
    const half4 r1 = *reinterpret_cast<const half4*>(&rawT[ch][t0c + 4]);
    float vv[7];
#pragma unroll
    for (int i = 0; i < 4; ++i) vv[i] = (float)r0[i];
#pragma unroll
    for (int i = 0; i < 3; ++i) vv[4 + i] = (float)r1[i];
#pragma unroll
    for (int d0 = 0; d0 < 4; ++d0) {
      float v = cb;
      v = fmaf(cw.x, vv[d0], v);
      v = fmaf(cw.y, vv[d0 + 1], v);
      v = fmaf(cw.z, vv[d0 + 2], v);
      v = fmaf(cw.w, vv[d0 + 3], v);
      outv[q][d0] = v * sigm(v);
    }
  }
  if (tid < 64) {
    const int t = tid & 31, hi = tid >> 5;
    const float dtbias = P.dtb[h * NHIN + hi];
    const float Ah = -__expf(P.Alog[h * NHIN + hi]);
    const float raw = dtraw[3 + t][hi] + dtbias;
    const float dtv = (raw > 20.f) ? raw : log1pf(__expf(raw));
    dtL[hi][t] = dtv;
    float s = dtv * Ah;
#pragma unroll
    for (int d = 1; d < 32; d <<= 1) {
      const float v = __shfl_up(s, d, 32);
      if (t >= d) s += v;
    }
    clL[hi][t] = s;
  }
  __syncthreads();   // B2

  // ================= phase 3: act + operand tiles ==========================
#pragma unroll
  for (int q = 0; q < 5; ++q) {
    const int ch = ch0 + q;
#pragma unroll
    for (int d0 = 0; d0 < 4; ++d0) actH[t0c + d0][ch] = (_Float16)outv[q][d0];
    if (ch < DIN) {
      const int hi = ch >> 4;
      const float cl31 = clL[hi][31];
      half4 xt, wx;
#pragma unroll
      for (int d0 = 0; d0 < 4; ++d0) {
        const int t = t0c + d0;
        const float dtv = dtL[hi][t];
        const float w = __expf(cl31 - clL[hi][t]);
        xt[d0] = (_Float16)(dtv * outv[q][d0]);
        wx[d0] = (_Float16)(w * dtv * outv[q][d0]);
      }
      *reinterpret_cast<half4*>(&XtL[ch][t0c]) = xt;
      *reinterpret_cast<half4*>(&WXt[ch][t0c]) = wx;
    } else if (ch < DIN + DST) {
      half4 bm;
#pragma unroll
      for (int d0 = 0; d0 < 4; ++d0) bm[d0] = (_Float16)outv[q][d0];
      *reinterpret_cast<half4*>(&BmT[ch - DIN][t0c]) = bm;
    }
  }
  __syncthreads();   // B3

  // ================= phase 4a ==============================================
  if (wv == 0) {
    f32x16 g;
#pragma unroll
    for (int i = 0; i < 16; ++i) g[i] = 0.0f;
#pragma unroll
    for (int kk = 0; kk < 4; ++kk) {
      const half8 af = ld8(&actH[lrow][96 + kk * 16 + kg * 8]);
      const half8 bf = ld8(&actH[lrow][32 + kk * 16 + kg * 8]);
      g = __builtin_amdgcn_mfma_f32_32x32x16_f16(af, bf, g, 0, 0, 0);
    }
    const float cls0 = clL[0][lrow], cls1 = clL[1][lrow];
#pragma unroll
    for (int rg = 0; rg < 16; ++rg) {
      const int t = (rg & 3) + 8 * (rg >> 2) + 4 * kg;
      const float gg = g[rg];
      float l0 = 0.f, l1 = 0.f;
      if (lrow <= t) { l0 = __expf(clL[0][t] - cls0); l1 = __expf(clL[1][t] - cls1); }
      Gm[0][t][lrow] = (_Float16)(l0 * gg);
      Gm[1][t][lrow] = (_Float16)(l1 * gg);
    }
  } else if (wv == 1 || wv == 2) {
    const int nhalf = (wv - 1) * 32;
    const half8 wa0 = ld8(&WXt[lrow][kg * 8]);
    const half8 wa1 = ld8(&WXt[lrow][16 + kg * 8]);
    f32x16 acc;
#pragma unroll
    for (int i = 0; i < 16; ++i) acc[i] = 0.0f;
    acc = __builtin_amdgcn_mfma_f32_32x32x16_f16(
        wa0, ld8(&BmT[nhalf + lrow][kg * 8]), acc, 0, 0, 0);
    acc = __builtin_amdgcn_mfma_f32_32x32x16_f16(
        wa1, ld8(&BmT[nhalf + lrow][16 + kg * 8]), acc, 0, 0, 0);
#pragma unroll
    for (int rg = 0; rg < 16; ++rg) {
      const int m = (rg & 3) + 8 * (rg >> 2) + 4 * kg;
      StL[m][nhalf + lrow] = (_Float16)acc[rg];
    }
  } else {
    if (lane < 32) {
      cumsg[(size_t)wg * CHUNK + lane] =
          make_float2(__expf(clL[0][lane]), __expf(clL[1][lane]));
    } else if (lane == 32) {
      Pbuf[(base0 * NCHUNK + c) * NHIN + 0] = __expf(clL[0][31]);
    } else if (lane == 33) {
      Pbuf[(base0 * NCHUNK + c) * NHIN + 1] = __expf(clL[1][31]);
    }
#pragma unroll
    for (int k = 0; k < 8; ++k) {
      const int idx = lane + k * 64;
      const int t = idx >> 4, c4 = (idx & 15) * 4;
      *reinterpret_cast<ushort4*>(&xgC[(size_t)wg * (CHUNK * DST) + t * DST + c4]) =
          *reinterpret_cast<const ushort4*>(&actH[t][96 + c4]);
    }
  }
  __syncthreads();   // B4

  // ================= phase 4b ==============================================
  if (wv < 2) {
    const int hi = wv;
    const half8 xb0 = ld8(&XtL[lrow][kg * 8]);
    const half8 xb1 = ld8(&XtL[lrow][16 + kg * 8]);
    f32x16 acc;
#pragma unroll
    for (int i = 0; i < 16; ++i) acc[i] = 0.0f;
    acc = __builtin_amdgcn_mfma_f32_32x32x16_f16(ld8(&Gm[hi][lrow][kg * 8]), xb0, acc, 0, 0, 0);
    acc = __builtin_amdgcn_mfma_f32_32x32x16_f16(ld8(&Gm[hi][lrow][16 + kg * 8]), xb1, acc, 0, 0, 0);
    const bool own = (lrow >> 4) == hi;
    if (own) {
      const float Dp = P.Dp[h * NHIN + hi];
      _Float16* yo = &yintra[(size_t)wg * (CHUNK * DIN)];
#pragma unroll
      for (int rg = 0; rg < 16; ++rg) {
        const int t = (rg & 3) + 8 * (rg >> 2) + 4 * kg;
        yo[t * DIN + lrow] = (_Float16)(acc[rg] + Dp * (float)actH[t][lrow]);
      }
    }
  } else if (wv == 2) {
    const size_t base2 = (base0 * NCHUNK + c) * (NHIN * HD * DST);
#pragma unroll
    for (int k = 0; k < 8; ++k) {
      const int idx = lane + k * 64;
      const int row = idx >> 4, c4 = (idx & 15) * 4;
      *reinterpret_cast<ushort4*>(&Sg[base2 + row * DST + c4]) =
          *reinterpret_cast<const ushort4*>(&StL[row][c4]);
    }
  }
}

// ---------------------------------------------------------------------------
// Carry: combine over 64 chunks, batched 8-deep prefetch.
// ---------------------------------------------------------------------------
__global__ __launch_bounds__(256)
void carry_kernel(_Float16* __restrict__ Sg, const float* __restrict__ Pbuf)
{
  const int wg = blockIdx.x;
  const int b = wg % BBATCH;
  const int h = (wg / BBATCH) % NHEADS;
  const int team = wg / (BBATCH * NHEADS);
  const int tid = threadIdx.x;
  const int hi = tid >> 7;
  const int pp = (tid >> 3) & 15;
  const int ng = tid & 7;
  const int nb = ng * 8;
  const size_t base0 = ((size_t)team * NHEADS + h) * BBATCH + b;

  float hc[8] = {0, 0, 0, 0, 0, 0, 0, 0};
  for (int cb = 0; cb < NCHUNK; cb += 8) {
    half8 a[8];
    float Pv[8];
#pragma unroll
    for (int j = 0; j < 8; ++j) {
      const size_t sb = (((base0 * NCHUNK + cb + j) * NHIN + hi) * HD + pp) * DST + nb;
      a[j] = *reinterpret_cast<const half8*>(&Sg[sb]);
      Pv[j] = Pbuf[(base0 * NCHUNK + cb + j) * NHIN + hi];
    }
#pragma unroll
    for (int j = 0; j < 8; ++j) {
      const size_t sb = (((base0 * NCHUNK + cb + j) * NHIN + hi) * HD + pp) * DST + nb;
      half8 o;
#pragma unroll
      for (int k = 0; k < 8; ++k) o[k] = (_Float16)hc[k];
      *reinterpret_cast<half8*>(&Sg[sb]) = o;
#pragma unroll
      for (int k = 0; k < 8; ++k) hc[k] = fmaf(Pv[j], hc[k], (float)a[j][k]);
    }
  }
}

// ---------------------------------------------------------------------------
// K3 fused: both teams per wg; C·H_in + z MFMAs, gate+rms+out-proj, diff,
// partial stats.
// ---------------------------------------------------------------------------
__global__ __launch_bounds__(256)
void k3_fused(const _Float16* __restrict__ Sg, const float2* __restrict__ cumsg,
              const _Float16* __restrict__ xgC, const float* __restrict__ x,
              TeamParams tp0, TeamParams tp1,
              const _Float16* __restrict__ yintra, const float* __restrict__ lam,
              float* __restrict__ diffb, float2* __restrict__ pstat)
{
  __shared__ float    ysh[2][CHUNK][YS];
  __shared__ float    wn[2][16][33];
  __shared__ float    cums2[2][CHUNK][2];
  __shared__ _Float16 zsh[2][32][40];
  __shared__ float    youtL[2][CHUNK][20];
  __shared__ float    red2[8];

  const int tid  = threadIdx.x;
  const int wg   = blockIdx.x;
  const int c    = wg % NCHUNK;
  const int b    = (wg / NCHUNK) % BBATCH;
  const int h    = wg / (NCHUNK * BBATCH);
  const int c0 = c * CHUNK;
  const int lane = tid & 63;
  const int wv   = tid >> 6;

  const size_t wgT0 = (((size_t)0 * NHEADS + h) * BBATCH + b) * NCHUNK + c;
  const size_t wgT1 = (((size_t)1 * NHEADS + h) * BBATCH + b) * NCHUNK + c;

  f32x16 acc;
  if (wv < 2) {
    const size_t wgT = wv ? wgT1 : wgT0;
    const int colid = lane & 31, kg = lane >> 5;
    const _Float16* ca = &xgC[wgT * (CHUNK * DST) + (size_t)colid * DST + kg * 8];
    const _Float16* hb = &Sg[wgT * (NHIN * HD * DST) + (size_t)colid * DST + kg * 8];
#pragma unroll
    for (int i = 0; i < 16; ++i) acc[i] = 0.0f;
    acc = __builtin_amdgcn_mfma_f32_32x32x16_f16(
        *reinterpret_cast<const half8*>(ca), *reinterpret_cast<const half8*>(hb), acc, 0, 0, 0);
    acc = __builtin_amdgcn_mfma_f32_32x32x16_f16(
        *reinterpret_cast<const half8*>(ca + 16), *reinterpret_cast<const half8*>(hb + 16), acc, 0, 0, 0);
    acc = __builtin_amdgcn_mfma_f32_32x32x16_f16(
        *reinterpret_cast<const half8*>(ca + 32), *reinterpret_cast<const half8*>(hb + 32), acc, 0, 0, 0);
    acc = __builtin_amdgcn_mfma_f32_32x32x16_f16(
        *reinterpret_cast<const half8*>(ca + 48), *reinterpret_cast<const half8*>(hb + 48), acc, 0, 0, 0);
  } else {
    const int team = wv - 2;
    const TeamParams P = team ? tp1 : tp0;
    const int lrow = lane & 31, kg = lane >> 5;
    const float* xp = &x[((size_t)b * TSEQ + c0 + lrow) * DMODEL + h * HD + kg * 8];
    const half8 afr = pack_h8(*reinterpret_cast<const float4*>(xp),
                              *reinterpret_cast<const float4*>(xp + 4));
    const float* wp = &P.Win[((size_t)h * DPROJ + lrow) * HD + kg * 8];
    const half8 bfr = pack_h8(*reinterpret_cast<const float4*>(wp),
                              *reinterpret_cast<const float4*>(wp + 4));
    f32x16 zacc;
#pragma unroll
    for (int i = 0; i < 16; ++i) zacc[i] = 0.0f;
    zacc = __builtin_amdgcn_mfma_f32_32x32x16_f16(afr, bfr, zacc, 0, 0, 0);
#pragma unroll
    for (int rg = 0; rg < 16; ++rg) {
      const int t = (rg & 3) + 8 * (rg >> 2) + 4 * kg;
      const float v = zacc[rg];
      zsh[team][t][lrow] = (_Float16)(v * sigm(v));
    }
  }

  {
    const TeamParams P0 = tp0, P1 = tp1;
#pragma unroll
    for (int k = 0; k < 4; ++k) {
      const int i = tid + k * 256;
      const int tm = i >> 9, o = (i >> 5) & 15, dn = i & 31;
      const TeamParams& PP = tm ? P1 : P0;
      wn[tm][o][dn] = PP.Wout[((size_t)h * HD + o) * DIN + dn] * PP.nw[h * DIN + dn];
    }
  }
  {
    const int tm = tid >> 7, li = tid & 127;
    const int t = li >> 2, c8 = (li & 3) * 8;
    const size_t wgT = tm ? wgT1 : wgT0;
    const half8 v = *reinterpret_cast<const half8*>(&yintra[wgT * (CHUNK * DIN) + li * 8]);
#pragma unroll
    for (int j = 0; j < 8; ++j) ysh[tm][t][c8 + j] = (float)v[j];
  }
  if (tid < 64) {
    const int tm = tid >> 5, t = tid & 31;
    const size_t wgT = tm ? wgT1 : wgT0;
    const float2 v = cumsg[wgT * CHUNK + t];
    cums2[tm][t][0] = v.x; cums2[tm][t][1] = v.y;
  }
  __syncthreads();

  if (wv < 2) {
    const int team = wv;
    const int colid = lane & 31, kg = lane >> 5;
    const int hi = colid >> 4;
#pragma unroll
    for (int rg = 0; rg < 16; ++rg) {
      const int t = (rg & 3) + 8 * (rg >> 2) + 4 * kg;
      ysh[team][t][colid] = fmaf(cums2[team][t][hi], acc[rg], ysh[team][t][colid]);
    }
  }
  __syncthreads();

  {
    const int tm = tid >> 7, l = tid & 127;
    const int q = l & 3, tl = l >> 2;
    const int dn0 = q * 8;
    float yg[8];
    float ss = 0.0f;
#pragma unroll
    for (int j = 0; j < 8; ++j) {
      const float g = ysh[tm][tl][dn0 + j] * (float)zsh[tm][tl][dn0 + j];
      yg[j] = g;
      ss += g * g;
    }
    ss += __shfl_xor(ss, 1, 4);
    ss += __shfl_xor(ss, 2, 4);
    const float rms = rsqrtf(ss * (1.0f / DIN) + 1e-5f);
#pragma unroll
    for (int j = 0; j < 8; ++j) ysh[tm][tl][dn0 + j] = yg[j] * rms;
  }
  __syncthreads();

  {
    const int tm = tid >> 7, l = tid & 127;
    const int q = l & 3, tl = l >> 2;
#pragma unroll
    for (int oo = 0; oo < 4; ++oo) {
      const int o = q * 4 + oo;
      float a = 0.0f;
#pragma unroll
      for (int dn = 0; dn < DIN; ++dn) a = fmaf(ysh[tm][tl][dn], wn[tm][o][dn], a);
      youtL[tm][tl][o] = a;
    }
  }
  __syncthreads();

  float s = 0.0f, s2 = 0.0f;
  if (tid < 128) {
    const int t = tid >> 2, hd0 = (tid & 3) * 4;
    const float4 l4 = *reinterpret_cast<const float4*>(&lam[h * HD + hd0]);
    const float* y0 = &youtL[0][t][hd0];
    const float* y1 = &youtL[1][t][hd0];
    float4 d;
    d.x = y0[0] - l4.x * y1[0];
    d.y = y0[1] - l4.y * y1[1];
    d.z = y0[2] - l4.z * y1[2];
    d.w = y0[3] - l4.w * y1[3];
    *reinterpret_cast<float4*>(
        &diffb[(((size_t)(h * BBATCH + b)) * TSEQ + c0 + t) * HD + hd0]) = d;
    s = d.x + d.y + d.z + d.w;
    s2 = d.x * d.x + d.y * d.y + d.z * d.z + d.w * d.w;
  }
#pragma unroll
  for (int off = 1; off < 64; off <<= 1) {
    s += __shfl_xor(s, off);
    s2 += __shfl_xor(s2, off);
  }
  if (lane == 0) { red2[wv * 2] = s; red2[wv * 2 + 1] = s2; }
  __syncthreads();
  if (tid == 0) pstat[wg] = make_float2(red2[0] + red2[2], red2[1] + red2[3]);
}

// ---------------------------------------------------------------------------
// Final (MFMA): stats reduce + groupnorm-apply (f16) + [32x256]x[256x256]
// f16 MFMA GEMM + bias + residual. wg = (b, t-tile32, col-half128).
// ---------------------------------------------------------------------------
#define NFW (BBATCH * (TSEQ / 32) * 2)   // 256
__global__ __launch_bounds__(256)
void final_mfma(const float* __restrict__ x, const float* __restrict__ diffb,
                const float2* __restrict__ pstat, const float* __restrict__ gnw,
                const float* __restrict__ gnb, const float* __restrict__ projw,
                const float* __restrict__ projb, float* __restrict__ out)
{
  __shared__ _Float16 ndH[32][268];    // groupnorm'd diff, f16 (stride 268: 2-way banks)
  __shared__ float statL[NHEADS][2];

  const int wg = blockIdx.x;
  const int chalf = wg & 1;
  const int tt = (wg >> 1) & 63;
  const int b = wg >> 7;
  const int t0 = tt * 32;
  const int tid = threadIdx.x;
  const int lane = tid & 63;
  const int wv = tid >> 6;

  // ---- stats: thread (h = tid>>4, k0 = tid&15) reduces pstat ----
  {
    const int h = tid >> 4, k0 = tid & 15;
    float s = 0.0f, s2 = 0.0f;
    for (int k = k0; k < NCHUNK; k += 16) {
      const float2 v = pstat[((size_t)h * BBATCH + b) * NCHUNK + k];
      s += v.x; s2 += v.y;
    }
    s += __shfl_xor(s, 1, 16);  s2 += __shfl_xor(s2, 1, 16);
    s += __shfl_xor(s, 2, 16);  s2 += __shfl_xor(s2, 2, 16);
    s += __shfl_xor(s, 4, 16);  s2 += __shfl_xor(s2, 4, 16);
    s += __shfl_xor(s, 8, 16);  s2 += __shfl_xor(s2, 8, 16);
    if (k0 == 0) {
      const float inv = 1.0f / (TSEQ * HD);
      const float mean = s * inv;
      const float var = s2 * inv - mean * mean;
      statL[h][0] = mean;
      statL[h][1] = rsqrtf(var + 1e-5f);
    }
  }
  __syncthreads();

  // ---- stage nd (thread = d column) ----
  {
    const int d = tid, h = d >> 4, hd = d & 15;
    const float mean = statL[h][0];
    const float rstd = statL[h][1];
    const float g = gnw[d];
    const float be = gnb[d];
    const float* dp = &diffb[((size_t)(h * BBATCH + b) * TSEQ + t0) * HD + hd];
#pragma unroll
    for (int t = 0; t < 32; ++t)
      ndH[t][d] = (_Float16)((dp[t * HD] - mean) * rstd * g + be);
  }
  __syncthreads();

  // ---- GEMM: wave wv -> output cols n0..n0+31 ----
  const int lrow = lane & 31, kg = lane >> 5;
  const int n0 = chalf * 128 + wv * 32;
  const int d = n0 + lrow;
  f32x16 acc;
#pragma unroll
  for (int i = 0; i < 16; ++i) acc[i] = 0.0f;
  const float* wp0 = &projw[(size_t)d * DMODEL + kg * 8];
#pragma unroll
  for (int kt = 0; kt < DMODEL; kt += 16) {
    const half8 af = ld8(&ndH[lrow][kt + kg * 8]);
    const half8 bf = pack_h8(*reinterpret_cast<const float4*>(wp0 + kt),
                             *reinterpret_cast<const float4*>(wp0 + kt + 4));
    acc = __builtin_amdgcn_mfma_f32_32x32x16_f16(af, bf, acc, 0, 0, 0);
  }

  // ---- epilogue: + x + bias ----
  const float pb = projb[d];
#pragma unroll
  for (int rg = 0; rg < 16; ++rg) {
    const int t = (rg & 3) + 8 * (rg >> 2) + 4 * kg;
    const size_t o = ((size_t)b * TSEQ + t0 + t) * DMODEL + d;
    out[o] = x[o] + pb + acc[rg];
  }
}

// ---------------------------------------------------------------------------
extern "C" void kernel_launch(void* const* d_in, const int* in_sizes, int n_in,
                              void* d_out, int out_size, void* d_ws, size_t ws_size,
                              hipStream_t stream)
{
  const float* x = (const float*)d_in[0];
  TeamParams tp0 { (const float*)d_in[1], (const float*)d_in[2], (const float*)d_in[3],
                   (const float*)d_in[4], (const float*)d_in[5], (const float*)d_in[6],
                   (const float*)d_in[7], (const float*)d_in[8] };
  TeamParams tp1 { (const float*)d_in[9], (const float*)d_in[10], (const float*)d_in[11],
                   (const float*)d_in[12], (const float*)d_in[13], (const float*)d_in[14],
                   (const float*)d_in[15], (const float*)d_in[16] };
  const float* lam   = (const float*)d_in[17];
  const float* gnw   = (const float*)d_in[18];
  const float* gnb   = (const float*)d_in[19];
  const float* projw = (const float*)d_in[20];
  const float* projb = (const float*)d_in[21];

  // ws layout (bytes):
  //   Sg      @ 0           16,777,216
  //   Pbuf    @ 16,777,216      32,768
  //   cumsg   @ 16,809,984   1,048,576
  //   xgC     @ 17,858,560  16,777,216
  //   yintra  @ 34,635,776   8,388,608
  //   diffb   @ 43,024,384   4,194,304
  //   pstat   @ 47,218,688      16,384   (total ~47.2 MB)
  char* wsb = (char*)d_ws;
  _Float16* Sg    = (_Float16*)wsb;
  float* Pbuf     = (float*)(wsb + 16777216);
  float2* cumsg   = (float2*)(wsb + 16809984);
  _Float16* xgC   = (_Float16*)(wsb + 17858560);
  _Float16* yintra= (_Float16*)(wsb + 34635776);
  float* diffb    = (float*)(wsb + 43024384);
  float2* pstat   = (float2*)(wsb + 47218688);

  k1_proj_ssd<<<dim3(NWG), dim3(256), 0, stream>>>(x, tp0, tp1, Sg, Pbuf, cumsg, xgC, yintra);
  carry_kernel<<<dim3(2 * NHEADS * BBATCH), dim3(256), 0, stream>>>(Sg, Pbuf);
  k3_fused<<<dim3(NWG3), dim3(256), 0, stream>>>(Sg, cumsg, xgC, x, tp0, tp1, yintra, lam, diffb, pstat);
  final_mfma<<<dim3(NFW), dim3(256), 0, stream>>>(
      x, diffb, pstat, gnw, gnb, projw, projb, (float*)d_out);
}

// Round 10
// 88.983 us; speedup vs baseline: 4.7112x; 1.0236x over previous
//
#include <hip/hip_runtime.h>
#include <math.h>

#define NHEADS 16
#define BBATCH 2
#define TSEQ   2048
#define HD     16
#define DIN    32
#define DST    64
#define CONVD  160
#define DPROJ  194
#define NHIN   2
#define DMODEL 256
#define CHUNK  32
#define NCHUNK (TSEQ / CHUNK)                  // 64
#define NWG    (2 * NHEADS * BBATCH * NCHUNK)  // 4096 (k1)
#define NWG3   (NHEADS * BBATCH * NCHUNK)      // 2048 (k3 fused)
#define YS     36

struct TeamParams {
  const float *Win, *convw, *convb, *dtb, *Alog, *Dp, *nw, *Wout;
};

typedef __attribute__((ext_vector_type(4)))  _Float16 half4;
typedef __attribute__((ext_vector_type(8)))  _Float16 half8;
typedef __attribute__((ext_vector_type(16))) float    f32x16;

__device__ __forceinline__ float sigm(float v) { return 1.0f / (1.0f + __expf(-v)); }

__device__ __forceinline__ half8 pack_h8(float4 a, float4 b) {
  half8 r;
  r[0] = (_Float16)a.x; r[1] = (_Float16)a.y; r[2] = (_Float16)a.z; r[3] = (_Float16)a.w;
  r[4] = (_Float16)b.x; r[5] = (_Float16)b.y; r[6] = (_Float16)b.z; r[7] = (_Float16)b.w;
  return r;
}
__device__ __forceinline__ half8 zero_h8() {
  half8 r;
#pragma unroll
  for (int i = 0; i < 8; ++i) r[i] = (_Float16)0.f;
  return r;
}
__device__ __forceinline__ half8 ld8(const _Float16* p) {
  const half4 a = *reinterpret_cast<const half4*>(p);
  const half4 b = *reinterpret_cast<const half4*>(p + 4);
  half8 r;
  r[0] = a[0]; r[1] = a[1]; r[2] = a[2]; r[3] = a[3];
  r[4] = b[0]; r[5] = b[1]; r[6] = b[2]; r[7] = b[3];
  return r;
}

// ---------------------------------------------------------------------------
// K1: conv-FUSED in-proj MFMA (K=64 over 4 shifted x windows; B rows =
// convw[ch,k]*Win[ch,:]) + SSD chunk computation. No raw staging, no separate
// conv phase. 4 barriers, wave-specialized phases.
// ---------------------------------------------------------------------------
__global__ __launch_bounds__(256, 4)
void k1_proj_ssd(const float* __restrict__ x, TeamParams tp0, TeamParams tp1,
                 _Float16* __restrict__ Sg, float* __restrict__ Pbuf,
                 float2* __restrict__ cumsg, _Float16* __restrict__ xgC,
                 _Float16* __restrict__ yintra)
{
  __shared__ _Float16 xvT[32][36];   // silu x-act   [ch 0..31][t]
  __shared__ _Float16 BmT[64][36];   // silu B-act   [n][t]
  __shared__ _Float16 actB[32][68];  // silu B-act   [t][n]   (for G)
  __shared__ _Float16 actC[32][68];  // silu C-act   [t][n]
  __shared__ _Float16 XtL[32][36];   // (dt*x)^T     [p][t]
  __shared__ _Float16 WXt[32][36];   // (w*dt*x)^T   [p][t]
  __shared__ _Float16 Gm[2][32][36]; // masked L∘G   [hi][t][s]
  __shared__ _Float16 StL[32][68];   // S^T staging  [m][n]
  __shared__ float    dtraw[32][2];
  __shared__ float    clL[2][32], dtL2[2][32], dwL[2][32];

  const int tid  = threadIdx.x;
  const int wg   = blockIdx.x;
  const int c    = wg % NCHUNK;
  const int b    = (wg / NCHUNK) % BBATCH;
  const int h    = (wg / (NCHUNK * BBATCH)) % NHEADS;
  const int team = wg / (NCHUNK * BBATCH * NHEADS);
  const TeamParams P = team ? tp1 : tp0;
  const int c0 = c * CHUNK;
  const size_t base0 = ((size_t)team * NHEADS + h) * BBATCH + b;

  const int lane = tid & 63;
  const int wv   = tid >> 6;
  const int lrow = lane & 31;
  const int kg   = lane >> 5;

  f32x16 z16;
#pragma unroll
  for (int i = 0; i < 16; ++i) z16[i] = 0.0f;
  f32x16 g = z16;   // wv0's G accumulator, lives across barriers

  // ---- A fragments: 4 shifted x windows (j = conv tap = t offset -3+j) ----
  half8 afr[4];
#pragma unroll
  for (int j = 0; j < 4; ++j) {
    const int tp = c0 + lrow - 3 + j;
    if (tp >= 0) {
      const float* xp = &x[((size_t)b * TSEQ + tp) * DMODEL + h * HD + kg * 8];
      afr[j] = pack_h8(*reinterpret_cast<const float4*>(xp),
                       *reinterpret_cast<const float4*>(xp + 4));
    } else afr[j] = zero_h8();
  }

  // ================= phase 1: conv-fused in-proj MFMA ======================
  // conv tile: out[t][ch] = silu(convb + sum_j (convw[ch,j]*Win[32+ch])·u[t-3+j])
  auto doTile = [&](int tile) {
    const int ch = tile * 32 + lrow;
    const float* wp = &P.Win[((size_t)h * DPROJ + 32 + ch) * HD + kg * 8];
    const float4 w0 = *reinterpret_cast<const float4*>(wp);
    const float4 w1 = *reinterpret_cast<const float4*>(wp + 4);
    const float wf[8] = {w0.x, w0.y, w0.z, w0.w, w1.x, w1.y, w1.z, w1.w};
    const float4 cw = *reinterpret_cast<const float4*>(&P.convw[((size_t)h * CONVD + ch) * 4]);
    const float cwk[4] = {cw.x, cw.y, cw.z, cw.w};
    const float cb = P.convb[h * CONVD + ch];
    f32x16 acc = z16;
#pragma unroll
    for (int j = 0; j < 4; ++j) {
      half8 bf;
#pragma unroll
      for (int i = 0; i < 8; ++i) bf[i] = (_Float16)(cwk[j] * wf[i]);
      acc = __builtin_amdgcn_mfma_f32_32x32x16_f16(afr[j], bf, acc, 0, 0, 0);
    }
    _Float16 sv[16];
#pragma unroll
    for (int rg = 0; rg < 16; ++rg) {
      const float vv = acc[rg] + cb;
      sv[rg] = (_Float16)(vv * sigm(vv));
    }
    if (tile == 0) {
#pragma unroll
      for (int m = 0; m < 4; ++m) {
        half4 v; v[0] = sv[4*m]; v[1] = sv[4*m+1]; v[2] = sv[4*m+2]; v[3] = sv[4*m+3];
        *reinterpret_cast<half4*>(&xvT[lrow][4 * kg + 8 * m]) = v;
      }
    } else if (tile <= 2) {
      const int n = ch - 32;
#pragma unroll
      for (int m = 0; m < 4; ++m) {
        half4 v; v[0] = sv[4*m]; v[1] = sv[4*m+1]; v[2] = sv[4*m+2]; v[3] = sv[4*m+3];
        *reinterpret_cast<half4*>(&BmT[n][4 * kg + 8 * m]) = v;
      }
#pragma unroll
      for (int rg = 0; rg < 16; ++rg) {
        const int t = (rg & 3) + 8 * (rg >> 2) + 4 * kg;
        actB[t][n] = sv[rg];
      }
    } else {
      const int n = ch - 96;
#pragma unroll
      for (int rg = 0; rg < 16; ++rg) {
        const int t = (rg & 3) + 8 * (rg >> 2) + 4 * kg;
        actC[t][n] = sv[rg];
      }
    }
  };

  if (wv == 0) {
    doTile(0);
    // dt rows (192,193): identity conv, no bias, no silu
    half8 bf5 = zero_h8();
    if (lrow < 2) {
      const float* wp = &P.Win[((size_t)h * DPROJ + 192 + lrow) * HD + kg * 8];
      bf5 = pack_h8(*reinterpret_cast<const float4*>(wp),
                    *reinterpret_cast<const float4*>(wp + 4));
    }
    const f32x16 a5 = __builtin_amdgcn_mfma_f32_32x32x16_f16(afr[3], bf5, z16, 0, 0, 0);
    if (lrow < 2) {
#pragma unroll
      for (int rg = 0; rg < 16; ++rg) {
        const int t = (rg & 3) + 8 * (rg >> 2) + 4 * kg;
        dtraw[t][lrow] = a5[rg];
      }
    }
  } else if (wv == 1) {
    doTile(1);
  } else if (wv == 2) {
    doTile(2);
  } else {
    doTile(3);
    doTile(4);
  }
  __syncthreads();   // B1

  // ================= phase 2: G-MFMA (wv0) | scan (wv1) | xgC (wv2) ========
  if (wv == 0) {
#pragma unroll
    for (int kk = 0; kk < 4; ++kk) {
      const half8 af = ld8(&actC[lrow][kk * 16 + kg * 8]);
      const half8 bf = ld8(&actB[lrow][kk * 16 + kg * 8]);
      g = __builtin_amdgcn_mfma_f32_32x32x16_f16(af, bf, g, 0, 0, 0);
    }
  } else if (wv == 1) {
    const int t = lane & 31, hi = lane >> 5;
    const float dtbias = P.dtb[h * NHIN + hi];
    const float Ah = -__expf(P.Alog[h * NHIN + hi]);
    const float raw = dtraw[t][hi] + dtbias;
    const float dtv = (raw > 20.f) ? raw : log1pf(__expf(raw));
    float s = dtv * Ah;
#pragma unroll
    for (int d = 1; d < 32; d <<= 1) {
      const float v = __shfl_up(s, d, 32);
      if (t >= d) s += v;
    }
    const float cl31 = __shfl(s, 31, 32);
    const float w = __expf(cl31 - s);
    const float ecl = __expf(s);
    clL[hi][t] = s;
    dtL2[hi][t] = dtv;
    dwL[hi][t] = w * dtv;
    const float eo = __shfl(ecl, (lane & 31) + 32, 64);
    if (lane < 32) cumsg[(size_t)wg * CHUNK + t] = make_float2(ecl, eo);
    if (t == 31) Pbuf[(base0 * NCHUNK + c) * NHIN + hi] = ecl;
  } else if (wv == 2) {
#pragma unroll
    for (int k = 0; k < 8; ++k) {
      const int idx = lane + k * 64;
      const int t = idx >> 4, c4 = (idx & 15) * 4;
      *reinterpret_cast<ushort4*>(&xgC[(size_t)wg * (CHUNK * DST) + t * DST + c4]) =
          *reinterpret_cast<const ushort4*>(&actC[t][c4]);
    }
  }
  __syncthreads();   // B2

  // ================= phase 3: mask Gm (wv0) | Xt/WXt (wv1+wv2) =============
  if (wv == 0) {
    const float cls0 = clL[0][lrow], cls1 = clL[1][lrow];
#pragma unroll
    for (int rg = 0; rg < 16; ++rg) {
      const int t = (rg & 3) + 8 * (rg >> 2) + 4 * kg;
      const float gg = g[rg];
      float l0 = 0.f, l1 = 0.f;
      if (lrow <= t) { l0 = __expf(clL[0][t] - cls0); l1 = __expf(clL[1][t] - cls1); }
      Gm[0][t][lrow] = (_Float16)(l0 * gg);
      Gm[1][t][lrow] = (_Float16)(l1 * gg);
    }
  } else if (wv == 1 || wv == 2) {
    const int idx = tid - 64;          // 0..127
    const int ch = idx & 31, tq = idx >> 5;
    const int hi = ch >> 4;
#pragma unroll
    for (int hh = 0; hh < 2; ++hh) {
      const int t4 = tq * 8 + hh * 4;
      const half4 xv4 = *reinterpret_cast<const half4*>(&xvT[ch][t4]);
      half4 xt, wx;
#pragma unroll
      for (int i = 0; i < 4; ++i) {
        const int t = t4 + i;
        const float xv = (float)xv4[i];
        xt[i] = (_Float16)(dtL2[hi][t] * xv);
        wx[i] = (_Float16)(dwL[hi][t] * xv);
      }
      *reinterpret_cast<half4*>(&XtL[ch][t4]) = xt;
      *reinterpret_cast<half4*>(&WXt[ch][t4]) = wx;
    }
  }
  __syncthreads();   // B3

  // ================= phase 4a: y_intra (wv0,wv3) | S^T (wv1,wv2) ===========
  if (wv == 0 || wv == 3) {
    const int hi = (wv == 0) ? 0 : 1;
    const half8 xb0 = ld8(&XtL[lrow][kg * 8]);
    const half8 xb1 = ld8(&XtL[lrow][16 + kg * 8]);
    f32x16 acc = z16;
    acc = __builtin_amdgcn_mfma_f32_32x32x16_f16(ld8(&Gm[hi][lrow][kg * 8]), xb0, acc, 0, 0, 0);
    acc = __builtin_amdgcn_mfma_f32_32x32x16_f16(ld8(&Gm[hi][lrow][16 + kg * 8]), xb1, acc, 0, 0, 0);
    if ((lrow >> 4) == hi) {
      const float Dp = P.Dp[h * NHIN + hi];
      _Float16* yo = &yintra[(size_t)wg * (CHUNK * DIN)];
#pragma unroll
      for (int rg = 0; rg < 16; ++rg) {
        const int t = (rg & 3) + 8 * (rg >> 2) + 4 * kg;
        yo[t * DIN + lrow] = (_Float16)(acc[rg] + Dp * (float)xvT[lrow][t]);
      }
    }
  } else {
    const int nhalf = (wv - 1) * 32;   // wv1 -> 0, wv2 -> 32
    const half8 wa0 = ld8(&WXt[lrow][kg * 8]);
    const half8 wa1 = ld8(&WXt[lrow][16 + kg * 8]);
    f32x16 acc = z16;
    acc = __builtin_amdgcn_mfma_f32_32x32x16_f16(
        wa0, ld8(&BmT[nhalf + lrow][kg * 8]), acc, 0, 0, 0);
    acc = __builtin_amdgcn_mfma_f32_32x32x16_f16(
        wa1, ld8(&BmT[nhalf + lrow][16 + kg * 8]), acc, 0, 0, 0);
#pragma unroll
    for (int rg = 0; rg < 16; ++rg) {
      const int m = (rg & 3) + 8 * (rg >> 2) + 4 * kg;
      StL[m][nhalf + lrow] = (_Float16)acc[rg];
    }
  }
  __syncthreads();   // B4

  // ================= phase 4b: Sg store ====================================
  if (wv == 1 || wv == 2) {
    const int nhalf = (wv - 1) * 32;
    const size_t base2 = (base0 * NCHUNK + c) * (NHIN * HD * DST);
#pragma unroll
    for (int k = 0; k < 4; ++k) {
      const int idx = lane + k * 64;
      const int row = idx >> 3, c4 = (idx & 7) * 4 + nhalf;
      *reinterpret_cast<ushort4*>(&Sg[base2 + row * DST + c4]) =
          *reinterpret_cast<const ushort4*>(&StL[row][c4]);
    }
  }
}

// ---------------------------------------------------------------------------
// Carry: 256 wgs x 64 threads (states independent); 8-deep prefetch.
// ---------------------------------------------------------------------------
__global__ __launch_bounds__(64)
void carry_kernel(_Float16* __restrict__ Sg, const float* __restrict__ Pbuf)
{
  const int wg = blockIdx.x;
  const int q = wg & 3;
  const int rest = wg >> 2;
  const int b = rest % BBATCH;
  const int h = (rest / BBATCH) % NHEADS;
  const int team = rest / (BBATCH * NHEADS);
  const int lane = threadIdx.x;
  const int off = q * 512 + lane * 8;
  const int hi = q >> 1;
  const size_t base0 = ((size_t)team * NHEADS + h) * BBATCH + b;

  float hc[8] = {0, 0, 0, 0, 0, 0, 0, 0};
  for (int cb = 0; cb < NCHUNK; cb += 8) {
    half8 a[8];
    float Pv[8];
#pragma unroll
    for (int j = 0; j < 8; ++j) {
      const size_t sb = (base0 * NCHUNK + cb + j) * (NHIN * HD * DST) + off;
      a[j] = *reinterpret_cast<const half8*>(&Sg[sb]);
      Pv[j] = Pbuf[(base0 * NCHUNK + cb + j) * NHIN + hi];
    }
#pragma unroll
    for (int j = 0; j < 8; ++j) {
      const size_t sb = (base0 * NCHUNK + cb + j) * (NHIN * HD * DST) + off;
      half8 o;
#pragma unroll
      for (int k = 0; k < 8; ++k) o[k] = (_Float16)hc[k];
      *reinterpret_cast<half8*>(&Sg[sb]) = o;
#pragma unroll
      for (int k = 0; k < 8; ++k) hc[k] = fmaf(Pv[j], hc[k], (float)a[j][k]);
    }
  }
}

// ---------------------------------------------------------------------------
// K3 fused: both teams per wg; C·H_in + z MFMAs, gate+rms+out-proj, diff,
// partial stats.
// ---------------------------------------------------------------------------
__global__ __launch_bounds__(256)
void k3_fused(const _Float16* __restrict__ Sg, const float2* __restrict__ cumsg,
              const _Float16* __restrict__ xgC, const float* __restrict__ x,
              TeamParams tp0, TeamParams tp1,
              const _Float16* __restrict__ yintra, const float* __restrict__ lam,
              float* __restrict__ diffb, float2* __restrict__ pstat)
{
  __shared__ float    ysh[2][CHUNK][YS];
  __shared__ float    wn[2][16][33];
  __shared__ float    cums2[2][CHUNK][2];
  __shared__ _Float16 zsh[2][32][40];
  __shared__ float    youtL[2][CHUNK][20];
  __shared__ float    red2[8];

  const int tid  = threadIdx.x;
  const int wg   = blockIdx.x;
  const int c    = wg % NCHUNK;
  const int b    = (wg / NCHUNK) % BBATCH;
  const int h    = wg / (NCHUNK * BBATCH);
  const int c0 = c * CHUNK;
  const int lane = tid & 63;
  const int wv   = tid >> 6;

  const size_t wgT0 = (((size_t)0 * NHEADS + h) * BBATCH + b) * NCHUNK + c;
  const size_t wgT1 = (((size_t)1 * NHEADS + h) * BBATCH + b) * NCHUNK + c;

  f32x16 acc;
  if (wv < 2) {
    const size_t wgT = wv ? wgT1 : wgT0;
    const int colid = lane & 31, kg = lane >> 5;
    const _Float16* ca = &xgC[wgT * (CHUNK * DST) + (size_t)colid * DST + kg * 8];
    const _Float16* hb = &Sg[wgT * (NHIN * HD * DST) + (size_t)colid * DST + kg * 8];
#pragma unroll
    for (int i = 0; i < 16; ++i) acc[i] = 0.0f;
    acc = __builtin_amdgcn_mfma_f32_32x32x16_f16(
        *reinterpret_cast<const half8*>(ca), *reinterpret_cast<const half8*>(hb), acc, 0, 0, 0);
    acc = __builtin_amdgcn_mfma_f32_32x32x16_f16(
        *reinterpret_cast<const half8*>(ca + 16), *reinterpret_cast<const half8*>(hb + 16), acc, 0, 0, 0);
    acc = __builtin_amdgcn_mfma_f32_32x32x16_f16(
        *reinterpret_cast<const half8*>(ca + 32), *reinterpret_cast<const half8*>(hb + 32), acc, 0, 0, 0);
    acc = __builtin_amdgcn_mfma_f32_32x32x16_f16(
        *reinterpret_cast<const half8*>(ca + 48), *reinterpret_cast<const half8*>(hb + 48), acc, 0, 0, 0);
  } else {
    const int team = wv - 2;
    const TeamParams P = team ? tp1 : tp0;
    const int lrow = lane & 31, kg = lane >> 5;
    const float* xp = &x[((size_t)b * TSEQ + c0 + lrow) * DMODEL + h * HD + kg * 8];
    const half8 afr = pack_h8(*reinterpret_cast<const float4*>(xp),
                              *reinterpret_cast<const float4*>(xp + 4));
    const float* wp = &P.Win[((size_t)h * DPROJ + lrow) * HD + kg * 8];
    const half8 bfr = pack_h8(*reinterpret_cast<const float4*>(wp),
                              *reinterpret_cast<const float4*>(wp + 4));
    f32x16 zacc;
#pragma unroll
    for (int i = 0; i < 16; ++i) zacc[i] = 0.0f;
    zacc = __builtin_amdgcn_mfma_f32_32x32x16_f16(afr, bfr, zacc, 0, 0, 0);
#pragma unroll
    for (int rg = 0; rg < 16; ++rg) {
      const int t = (rg & 3) + 8 * (rg >> 2) + 4 * kg;
      const float v = zacc[rg];
      zsh[team][t][lrow] = (_Float16)(v * sigm(v));
    }
  }

  {
    const TeamParams P0 = tp0, P1 = tp1;
#pragma unroll
    for (int k = 0; k < 4; ++k) {
      const int i = tid + k * 256;
      const int tm = i >> 9, o = (i >> 5) & 15, dn = i & 31;
      const TeamParams& PP = tm ? P1 : P0;
      wn[tm][o][dn] = PP.Wout[((size_t)h * HD + o) * DIN + dn] * PP.nw[h * DIN + dn];
    }
  }
  {
    const int tm = tid >> 7, li = tid & 127;
    const int t = li >> 2, c8 = (li & 3) * 8;
    const size_t wgT = tm ? wgT1 : wgT0;
    const half8 v = *reinterpret_cast<const half8*>(&yintra[wgT * (CHUNK * DIN) + li * 8]);
#pragma unroll
    for (int j = 0; j < 8; ++j) ysh[tm][t][c8 + j] = (float)v[j];
  }
  if (tid < 64) {
    const int tm = tid >> 5, t = tid & 31;
    const size_t wgT = tm ? wgT1 : wgT0;
    const float2 v = cumsg[wgT * CHUNK + t];
    cums2[tm][t][0] = v.x; cums2[tm][t][1] = v.y;
  }
  __syncthreads();

  if (wv < 2) {
    const int team = wv;
    const int colid = lane & 31, kg = lane >> 5;
    const int hi = colid >> 4;
#pragma unroll
    for (int rg = 0; rg < 16; ++rg) {
      const int t = (rg & 3) + 8 * (rg >> 2) + 4 * kg;
      ysh[team][t][colid] = fmaf(cums2[team][t][hi], acc[rg], ysh[team][t][colid]);
    }
  }
  __syncthreads();

  {
    const int tm = tid >> 7, l = tid & 127;
    const int q = l & 3, tl = l >> 2;
    const int dn0 = q * 8;
    float yg[8];
    float ss = 0.0f;
#pragma unroll
    for (int j = 0; j < 8; ++j) {
      const float g = ysh[tm][tl][dn0 + j] * (float)zsh[tm][tl][dn0 + j];
      yg[j] = g;
      ss += g * g;
    }
    ss += __shfl_xor(ss, 1, 4);
    ss += __shfl_xor(ss, 2, 4);
    const float rms = rsqrtf(ss * (1.0f / DIN) + 1e-5f);
#pragma unroll
    for (int j = 0; j < 8; ++j) ysh[tm][tl][dn0 + j] = yg[j] * rms;
  }
  __syncthreads();

  {
    const int tm = tid >> 7, l = tid & 127;
    const int q = l & 3, tl = l >> 2;
#pragma unroll
    for (int oo = 0; oo < 4; ++oo) {
      const int o = q * 4 + oo;
      float a = 0.0f;
#pragma unroll
      for (int dn = 0; dn < DIN; ++dn) a = fmaf(ysh[tm][tl][dn], wn[tm][o][dn], a);
      youtL[tm][tl][o] = a;
    }
  }
  __syncthreads();

  float s = 0.0f, s2 = 0.0f;
  if (tid < 128) {
    const int t = tid >> 2, hd0 = (tid & 3) * 4;
    const float4 l4 = *reinterpret_cast<const float4*>(&lam[h * HD + hd0]);
    const float* y0 = &youtL[0][t][hd0];
    const float* y1 = &youtL[1][t][hd0];
    float4 d;
    d.x = y0[0] - l4.x * y1[0];
    d.y = y0[1] - l4.y * y1[1];
    d.z = y0[2] - l4.z * y1[2];
    d.w = y0[3] - l4.w * y1[3];
    *reinterpret_cast<float4*>(
        &diffb[(((size_t)(h * BBATCH + b)) * TSEQ + c0 + t) * HD + hd0]) = d;
    s = d.x + d.y + d.z + d.w;
    s2 = d.x * d.x + d.y * d.y + d.z * d.z + d.w * d.w;
  }
#pragma unroll
  for (int off = 1; off < 64; off <<= 1) {
    s += __shfl_xor(s, off);
    s2 += __shfl_xor(s2, off);
  }
  if (lane == 0) { red2[wv * 2] = s; red2[wv * 2 + 1] = s2; }
  __syncthreads();
  if (tid == 0) pstat[wg] = make_float2(red2[0] + red2[2], red2[1] + red2[3]);
}

// ---------------------------------------------------------------------------
// Final (MFMA): stats reduce + groupnorm-apply (f16) + [32x256]x[256x256]
// f16 MFMA GEMM + bias + residual. wg = (b, t-tile32, col-half128).
// ---------------------------------------------------------------------------
#define NFW (BBATCH * (TSEQ / 32) * 2)   // 256
__global__ __launch_bounds__(256)
void final_mfma(const float* __restrict__ x, const float* __restrict__ diffb,
                const float2* __restrict__ pstat, const float* __restrict__ gnw,
                const float* __restrict__ gnb, const float* __restrict__ projw,
                const float* __restrict__ projb, float* __restrict__ out)
{
  __shared__ _Float16 ndH[32][268];
  __shared__ float statL[NHEADS][2];

  const int wg = blockIdx.x;
  const int chalf = wg & 1;
  const int tt = (wg >> 1) & 63;
  const int b = wg >> 7;
  const int t0 = tt * 32;
  const int tid = threadIdx.x;
  const int lane = tid & 63;
  const int wv = tid >> 6;

  {
    const int h = tid >> 4, k0 = tid & 15;
    float s = 0.0f, s2 = 0.0f;
    for (int k = k0; k < NCHUNK; k += 16) {
      const float2 v = pstat[((size_t)h * BBATCH + b) * NCHUNK + k];
      s += v.x; s2 += v.y;
    }
    s += __shfl_xor(s, 1, 16);  s2 += __shfl_xor(s2, 1, 16);
    s += __shfl_xor(s, 2, 16);  s2 += __shfl_xor(s2, 2, 16);
    s += __shfl_xor(s, 4, 16);  s2 += __shfl_xor(s2, 4, 16);
    s += __shfl_xor(s, 8, 16);  s2 += __shfl_xor(s2, 8, 16);
    if (k0 == 0) {
      const float inv = 1.0f / (TSEQ * HD);
      const float mean = s * inv;
      const float var = s2 * inv - mean * mean;
      statL[h][0] = mean;
      statL[h][1] = rsqrtf(var + 1e-5f);
    }
  }
  __syncthreads();

  {
    const int d = tid, h = d >> 4, hd = d & 15;
    const float mean = statL[h][0];
    const float rstd = statL[h][1];
    const float g = gnw[d];
    const float be = gnb[d];
    const float* dp = &diffb[((size_t)(h * BBATCH + b) * TSEQ + t0) * HD + hd];
#pragma unroll
    for (int t = 0; t < 32; ++t)
      ndH[t][d] = (_Float16)((dp[t * HD] - mean) * rstd * g + be);
  }
  __syncthreads();

  const int lrow = lane & 31, kg = lane >> 5;
  const int n0 = chalf * 128 + wv * 32;
  const int d = n0 + lrow;
  f32x16 acc;
#pragma unroll
  for (int i = 0; i < 16; ++i) acc[i] = 0.0f;
  const float* wp0 = &projw[(size_t)d * DMODEL + kg * 8];
#pragma unroll
  for (int kt = 0; kt < DMODEL; kt += 16) {
    const half8 af = ld8(&ndH[lrow][kt + kg * 8]);
    const half8 bf = pack_h8(*reinterpret_cast<const float4*>(wp0 + kt),
                             *reinterpret_cast<const float4*>(wp0 + kt + 4));
    acc = __builtin_amdgcn_mfma_f32_32x32x16_f16(af, bf, acc, 0, 0, 0);
  }

  const float pb = projb[d];
#pragma unroll
  for (int rg = 0; rg < 16; ++rg) {
    const int t = (rg & 3) + 8 * (rg >> 2) + 4 * kg;
    const size_t o = ((size_t)b * TSEQ + t0 + t) * DMODEL + d;
    out[o] = x[o] + pb + acc[rg];
  }
}

// ---------------------------------------------------------------------------
extern "C" void kernel_launch(void* const* d_in, const int* in_sizes, int n_in,
                              void* d_out, int out_size, void* d_ws, size_t ws_size,
                              hipStream_t stream)
{
  const float* x = (const float*)d_in[0];
  TeamParams tp0 { (const float*)d_in[1], (const float*)d_in[2], (const float*)d_in[3],
                   (const float*)d_in[4], (const float*)d_in[5], (const float*)d_in[6],
                   (const float*)d_in[7], (const float*)d_in[8] };
  TeamParams tp1 { (const float*)d_in[9], (const float*)d_in[10], (const float*)d_in[11],
                   (const float*)d_in[12], (const float*)d_in[13], (const float*)d_in[14],
                   (const float*)d_in[15], (const float*)d_in[16] };
  const float* lam   = (const float*)d_in[17];
  const float* gnw   = (const float*)d_in[18];
  const float* gnb   = (const float*)d_in[19];
  const float* projw = (const float*)d_in[20];
  const float* projb = (const float*)d_in[21];

  // ws layout (bytes): Sg @0 (16.8M), Pbuf @16,777,216 (32K), cumsg @16,809,984
  // (1M), xgC @17,858,560 (16.8M), yintra @34,635,776 (8.4M), diffb @43,024,384
  // (4.2M), pstat @47,218,688 (16K)  — total ~47.2 MB
  char* wsb = (char*)d_ws;
  _Float16* Sg    = (_Float16*)wsb;
  float* Pbuf     = (float*)(wsb + 16777216);
  float2* cumsg   = (float2*)(wsb + 16809984);
  _Float16* xgC   = (_Float16*)(wsb + 17858560);
  _Float16* yintra= (_Float16*)(wsb + 34635776);
  float* diffb    = (float*)(wsb + 43024384);
  float2* pstat   = (float2*)(wsb + 47218688);

  k1_proj_ssd<<<dim3(NWG), dim3(256), 0, stream>>>(x, tp0, tp1, Sg, Pbuf, cumsg, xgC, yintra);
  carry_kernel<<<dim3(2 * NHEADS * BBATCH * 4), dim3(64), 0, stream>>>(Sg, Pbuf);
  k3_fused<<<dim3(NWG3), dim3(256), 0, stream>>>(Sg, cumsg, xgC, x, tp0, tp1, yintra, lam, diffb, pstat);
  final_mfma<<<dim3(NFW), dim3(256), 0, stream>>>(
      x, diffb, pstat, gnw, gnb, projw, projb, (float*)d_out);
}

// Round 11
// 86.284 us; speedup vs baseline: 4.8586x; 1.0313x over previous
//
#include <hip/hip_runtime.h>
#include <math.h>

#define NHEADS 16
#define BBATCH 2
#define TSEQ   2048
#define HD     16
#define DIN    32
#define DST    64
#define CONVD  160
#define DPROJ  194
#define NHIN   2
#define DMODEL 256
#define CHUNK  32
#define NCHUNK (TSEQ / CHUNK)                  // 64
#define NWG    (2 * NHEADS * BBATCH * NCHUNK)  // 4096 (k1)
#define NWG3   (NHEADS * BBATCH * NCHUNK)      // 2048 (k3 fused)
#define YS     36

struct TeamParams {
  const float *Win, *convw, *convb, *dtb, *Alog, *Dp, *nw, *Wout;
};

typedef __attribute__((ext_vector_type(4)))  _Float16 half4;
typedef __attribute__((ext_vector_type(8)))  _Float16 half8;
typedef __attribute__((ext_vector_type(16))) float    f32x16;

__device__ __forceinline__ float sigm(float v) { return 1.0f / (1.0f + __expf(-v)); }

__device__ __forceinline__ half8 pack_h8(float4 a, float4 b) {
  half8 r;
  r[0] = (_Float16)a.x; r[1] = (_Float16)a.y; r[2] = (_Float16)a.z; r[3] = (_Float16)a.w;
  r[4] = (_Float16)b.x; r[5] = (_Float16)b.y; r[6] = (_Float16)b.z; r[7] = (_Float16)b.w;
  return r;
}
__device__ __forceinline__ half8 zero_h8() {
  half8 r;
#pragma unroll
  for (int i = 0; i < 8; ++i) r[i] = (_Float16)0.f;
  return r;
}
__device__ __forceinline__ half8 ld8(const _Float16* p) {
  const half4 a = *reinterpret_cast<const half4*>(p);
  const half4 b = *reinterpret_cast<const half4*>(p + 4);
  half8 r;
  r[0] = a[0]; r[1] = a[1]; r[2] = a[2]; r[3] = a[3];
  r[4] = b[0]; r[5] = b[1]; r[6] = b[2]; r[7] = b[3];
  return r;
}

// ---------------------------------------------------------------------------
// Prep: hoist all wg-invariant packing to global f16/f32 tensors.
//   xH   : x as f16                      [B][T][DMODEL]
//   WcF  : convw[ch,tap]*Win[32+ch,:]    [th][tap][ch 0..159][16]
//   WzF  : Win rows 0..31                [th][32][16]
//   WdtF : Win rows 192..193             [th][2][16]
//   wnF  : Wout*nw                       [th][16][32] f32
// ---------------------------------------------------------------------------
__global__ __launch_bounds__(256)
void prep_kernel(const float* __restrict__ x, TeamParams tp0, TeamParams tp1,
                 _Float16* __restrict__ xH, _Float16* __restrict__ WcF,
                 _Float16* __restrict__ WzF, _Float16* __restrict__ WdtF,
                 float* __restrict__ wnF)
{
  const int gid = blockIdx.x * 256 + threadIdx.x;
  const int gsz = gridDim.x * 256;
  for (int i = gid; i < (BBATCH * TSEQ * DMODEL) / 8; i += gsz) {
    const float4 a = *reinterpret_cast<const float4*>(&x[(size_t)i * 8]);
    const float4 b = *reinterpret_cast<const float4*>(&x[(size_t)i * 8 + 4]);
    *reinterpret_cast<half8*>(&xH[(size_t)i * 8]) = pack_h8(a, b);
  }
  for (int i = gid; i < 2 * NHEADS * 4 * CONVD * 2; i += gsz) {   // 40960
    const int k8 = i & 1;
    const int r = i >> 1;
    const int ch = r % CONVD;
    const int tap = (r / CONVD) & 3;
    const int th = r / (CONVD * 4);
    const int team = th >> 4, h = th & 15;
    const TeamParams P = team ? tp1 : tp0;
    const float cw = P.convw[((size_t)h * CONVD + ch) * 4 + tap];
    const float* wp = &P.Win[((size_t)h * DPROJ + 32 + ch) * HD + k8 * 8];
    half8 v;
#pragma unroll
    for (int j = 0; j < 8; ++j) v[j] = (_Float16)(cw * wp[j]);
    *reinterpret_cast<half8*>(&WcF[(size_t)r * 16 + k8 * 8]) = v;
  }
  for (int i = gid; i < 2 * NHEADS * 32 * 2; i += gsz) {          // 2048
    const int k8 = i & 1;
    const int r = i >> 1;
    const int row = r & 31;
    const int th = r >> 5;
    const int team = th >> 4, h = th & 15;
    const TeamParams P = team ? tp1 : tp0;
    const float* wp = &P.Win[((size_t)h * DPROJ + row) * HD + k8 * 8];
    half8 v;
#pragma unroll
    for (int j = 0; j < 8; ++j) v[j] = (_Float16)wp[j];
    *reinterpret_cast<half8*>(&WzF[(size_t)r * 16 + k8 * 8]) = v;
  }
  for (int i = gid; i < 2 * NHEADS * 2 * 2; i += gsz) {           // 128
    const int k8 = i & 1;
    const int r = i >> 1;
    const int row = r & 1;
    const int th = r >> 1;
    const int team = th >> 4, h = th & 15;
    const TeamParams P = team ? tp1 : tp0;
    const float* wp = &P.Win[((size_t)h * DPROJ + 192 + row) * HD + k8 * 8];
    half8 v;
#pragma unroll
    for (int j = 0; j < 8; ++j) v[j] = (_Float16)wp[j];
    *reinterpret_cast<half8*>(&WdtF[(size_t)r * 16 + k8 * 8]) = v;
  }
  for (int i = gid; i < 2 * NHEADS * HD * DIN / 4; i += gsz) {    // 4096
    const int dn4 = (i & 7) * 4;
    const int o = (i >> 3) & 15;
    const int th = i >> 7;
    const int team = th >> 4, h = th & 15;
    const TeamParams P = team ? tp1 : tp0;
    float4 v;
    float* vp = reinterpret_cast<float*>(&v);
#pragma unroll
    for (int j = 0; j < 4; ++j)
      vp[j] = P.Wout[((size_t)h * HD + o) * DIN + dn4 + j] * P.nw[h * DIN + dn4 + j];
    *reinterpret_cast<float4*>(&wnF[((size_t)th * HD + o) * DIN + dn4]) = v;
  }
}

// ---------------------------------------------------------------------------
// K1: conv-fused in-proj MFMA with PRECOMPUTED f16 operands + SSD chunk
// computation. 4 barriers, wave-specialized phases.
// ---------------------------------------------------------------------------
__global__ __launch_bounds__(256, 5)
void k1_proj_ssd(const _Float16* __restrict__ xH, const _Float16* __restrict__ WcF,
                 const _Float16* __restrict__ WdtF, TeamParams tp0, TeamParams tp1,
                 _Float16* __restrict__ Sg, float* __restrict__ Pbuf,
                 float2* __restrict__ cumsg, _Float16* __restrict__ xgC,
                 _Float16* __restrict__ yintra)
{
  __shared__ _Float16 xvT[32][36];   // silu x-act   [ch 0..31][t]
  __shared__ _Float16 BmT[64][36];   // silu B-act   [n][t]
  __shared__ _Float16 actB[32][68];  // silu B-act   [t][n]
  __shared__ _Float16 actC[32][68];  // silu C-act   [t][n]
  __shared__ _Float16 XtL[32][36];   // (dt*x)^T
  __shared__ _Float16 WXt[32][36];   // (w*dt*x)^T
  __shared__ _Float16 Gm[2][32][36]; // masked L∘G
  __shared__ _Float16 StL[32][68];   // S^T staging
  __shared__ float    dtraw[32][2];
  __shared__ float    clL[2][32], dtL2[2][32], dwL[2][32];

  const int tid  = threadIdx.x;
  const int wg   = blockIdx.x;
  const int c    = wg % NCHUNK;
  const int b    = (wg / NCHUNK) % BBATCH;
  const int h    = (wg / (NCHUNK * BBATCH)) % NHEADS;
  const int team = wg / (NCHUNK * BBATCH * NHEADS);
  const TeamParams P = team ? tp1 : tp0;
  const int th = team * NHEADS + h;
  const int c0 = c * CHUNK;
  const size_t base0 = ((size_t)team * NHEADS + h) * BBATCH + b;

  const int lane = tid & 63;
  const int wv   = tid >> 6;
  const int lrow = lane & 31;
  const int kg   = lane >> 5;

  f32x16 z16;
#pragma unroll
  for (int i = 0; i < 16; ++i) z16[i] = 0.0f;
  f32x16 g = z16;

  // ---- A fragments: 4 shifted x windows, direct f16 loads ----
  half8 afr[4];
#pragma unroll
  for (int j = 0; j < 4; ++j) {
    const int tp = c0 + lrow - 3 + j;
    afr[j] = (tp >= 0)
        ? *reinterpret_cast<const half8*>(&xH[((size_t)b * TSEQ + tp) * DMODEL + h * HD + kg * 8])
        : zero_h8();
  }

  // ================= phase 1: conv-fused in-proj MFMA ======================
  auto doTile = [&](int tile) {
    const int ch = tile * 32 + lrow;
    const float cb = P.convb[h * CONVD + ch];
    f32x16 acc = z16;
#pragma unroll
    for (int j = 0; j < 4; ++j) {
      const half8 bf = *reinterpret_cast<const half8*>(
          &WcF[((size_t)(th * 4 + j) * CONVD + ch) * 16 + kg * 8]);
      acc = __builtin_amdgcn_mfma_f32_32x32x16_f16(afr[j], bf, acc, 0, 0, 0);
    }
    _Float16 sv[16];
#pragma unroll
    for (int rg = 0; rg < 16; ++rg) {
      const float vv = acc[rg] + cb;
      sv[rg] = (_Float16)(vv * sigm(vv));
    }
    if (tile == 0) {
#pragma unroll
      for (int m = 0; m < 4; ++m) {
        half4 v; v[0] = sv[4*m]; v[1] = sv[4*m+1]; v[2] = sv[4*m+2]; v[3] = sv[4*m+3];
        *reinterpret_cast<half4*>(&xvT[lrow][4 * kg + 8 * m]) = v;
      }
    } else if (tile <= 2) {
      const int n = ch - 32;
#pragma unroll
      for (int m = 0; m < 4; ++m) {
        half4 v; v[0] = sv[4*m]; v[1] = sv[4*m+1]; v[2] = sv[4*m+2]; v[3] = sv[4*m+3];
        *reinterpret_cast<half4*>(&BmT[n][4 * kg + 8 * m]) = v;
      }
#pragma unroll
      for (int rg = 0; rg < 16; ++rg) {
        const int t = (rg & 3) + 8 * (rg >> 2) + 4 * kg;
        actB[t][n] = sv[rg];
      }
    } else {
      const int n = ch - 96;
#pragma unroll
      for (int rg = 0; rg < 16; ++rg) {
        const int t = (rg & 3) + 8 * (rg >> 2) + 4 * kg;
        actC[t][n] = sv[rg];
      }
    }
  };

  if (wv == 0) {
    doTile(0);
    half8 bf5 = zero_h8();
    if (lrow < 2)
      bf5 = *reinterpret_cast<const half8*>(&WdtF[((size_t)th * 2 + lrow) * 16 + kg * 8]);
    const f32x16 a5 = __builtin_amdgcn_mfma_f32_32x32x16_f16(afr[3], bf5, z16, 0, 0, 0);
    if (lrow < 2) {
#pragma unroll
      for (int rg = 0; rg < 16; ++rg) {
        const int t = (rg & 3) + 8 * (rg >> 2) + 4 * kg;
        dtraw[t][lrow] = a5[rg];
      }
    }
  } else if (wv == 1) {
    doTile(1);
  } else if (wv == 2) {
    doTile(2);
  } else {
    doTile(3);
    doTile(4);
  }
  __syncthreads();   // B1

  // ================= phase 2: G-MFMA (wv0) | scan (wv1) | xgC (wv2) ========
  if (wv == 0) {
#pragma unroll
    for (int kk = 0; kk < 4; ++kk) {
      const half8 af = ld8(&actC[lrow][kk * 16 + kg * 8]);
      const half8 bf = ld8(&actB[lrow][kk * 16 + kg * 8]);
      g = __builtin_amdgcn_mfma_f32_32x32x16_f16(af, bf, g, 0, 0, 0);
    }
  } else if (wv == 1) {
    const int t = lane & 31, hi = lane >> 5;
    const float dtbias = P.dtb[h * NHIN + hi];
    const float Ah = -__expf(P.Alog[h * NHIN + hi]);
    const float raw = dtraw[t][hi] + dtbias;
    const float dtv = (raw > 20.f) ? raw : log1pf(__expf(raw));
    float s = dtv * Ah;
#pragma unroll
    for (int d = 1; d < 32; d <<= 1) {
      const float v = __shfl_up(s, d, 32);
      if (t >= d) s += v;
    }
    const float cl31 = __shfl(s, 31, 32);
    const float w = __expf(cl31 - s);
    const float ecl = __expf(s);
    clL[hi][t] = s;
    dtL2[hi][t] = dtv;
    dwL[hi][t] = w * dtv;
    const float eo = __shfl(ecl, (lane & 31) + 32, 64);
    if (lane < 32) cumsg[(size_t)wg * CHUNK + t] = make_float2(ecl, eo);
    if (t == 31) Pbuf[(base0 * NCHUNK + c) * NHIN + hi] = ecl;
  } else if (wv == 2) {
#pragma unroll
    for (int k = 0; k < 8; ++k) {
      const int idx = lane + k * 64;
      const int t = idx >> 4, c4 = (idx & 15) * 4;
      *reinterpret_cast<ushort4*>(&xgC[(size_t)wg * (CHUNK * DST) + t * DST + c4]) =
          *reinterpret_cast<const ushort4*>(&actC[t][c4]);
    }
  }
  __syncthreads();   // B2

  // ================= phase 3: mask Gm (wv0) | Xt/WXt (wv1+wv2) =============
  if (wv == 0) {
    const float cls0 = clL[0][lrow], cls1 = clL[1][lrow];
#pragma unroll
    for (int rg = 0; rg < 16; ++rg) {
      const int t = (rg & 3) + 8 * (rg >> 2) + 4 * kg;
      const float gg = g[rg];
      float l0 = 0.f, l1 = 0.f;
      if (lrow <= t) { l0 = __expf(clL[0][t] - cls0); l1 = __expf(clL[1][t] - cls1); }
      Gm[0][t][lrow] = (_Float16)(l0 * gg);
      Gm[1][t][lrow] = (_Float16)(l1 * gg);
    }
  } else if (wv == 1 || wv == 2) {
    const int idx = tid - 64;
    const int ch = idx & 31, tq = idx >> 5;
    const int hi = ch >> 4;
#pragma unroll
    for (int hh = 0; hh < 2; ++hh) {
      const int t4 = tq * 8 + hh * 4;
      const half4 xv4 = *reinterpret_cast<const half4*>(&xvT[ch][t4]);
      half4 xt, wx;
#pragma unroll
      for (int i = 0; i < 4; ++i) {
        const int t = t4 + i;
        const float xv = (float)xv4[i];
        xt[i] = (_Float16)(dtL2[hi][t] * xv);
        wx[i] = (_Float16)(dwL[hi][t] * xv);
      }
      *reinterpret_cast<half4*>(&XtL[ch][t4]) = xt;
      *reinterpret_cast<half4*>(&WXt[ch][t4]) = wx;
    }
  }
  __syncthreads();   // B3

  // ================= phase 4a: y_intra (wv0,wv3) | S^T (wv1,wv2) ===========
  if (wv == 0 || wv == 3) {
    const int hi = (wv == 0) ? 0 : 1;
    const half8 xb0 = ld8(&XtL[lrow][kg * 8]);
    const half8 xb1 = ld8(&XtL[lrow][16 + kg * 8]);
    f32x16 acc = z16;
    acc = __builtin_amdgcn_mfma_f32_32x32x16_f16(ld8(&Gm[hi][lrow][kg * 8]), xb0, acc, 0, 0, 0);
    acc = __builtin_amdgcn_mfma_f32_32x32x16_f16(ld8(&Gm[hi][lrow][16 + kg * 8]), xb1, acc, 0, 0, 0);
    if ((lrow >> 4) == hi) {
      const float Dp = P.Dp[h * NHIN + hi];
      _Float16* yo = &yintra[(size_t)wg * (CHUNK * DIN)];
#pragma unroll
      for (int rg = 0; rg < 16; ++rg) {
        const int t = (rg & 3) + 8 * (rg >> 2) + 4 * kg;
        yo[t * DIN + lrow] = (_Float16)(acc[rg] + Dp * (float)xvT[lrow][t]);
      }
    }
  } else {
    const int nhalf = (wv - 1) * 32;
    const half8 wa0 = ld8(&WXt[lrow][kg * 8]);
    const half8 wa1 = ld8(&WXt[lrow][16 + kg * 8]);
    f32x16 acc = z16;
    acc = __builtin_amdgcn_mfma_f32_32x32x16_f16(
        wa0, ld8(&BmT[nhalf + lrow][kg * 8]), acc, 0, 0, 0);
    acc = __builtin_amdgcn_mfma_f32_32x32x16_f16(
        wa1, ld8(&BmT[nhalf + lrow][16 + kg * 8]), acc, 0, 0, 0);
#pragma unroll
    for (int rg = 0; rg < 16; ++rg) {
      const int m = (rg & 3) + 8 * (rg >> 2) + 4 * kg;
      StL[m][nhalf + lrow] = (_Float16)acc[rg];
    }
  }
  __syncthreads();   // B4

  // ================= phase 4b: Sg store ====================================
  if (wv == 1 || wv == 2) {
    const int nhalf = (wv - 1) * 32;
    const size_t base2 = (base0 * NCHUNK + c) * (NHIN * HD * DST);
#pragma unroll
    for (int k = 0; k < 4; ++k) {
      const int idx = lane + k * 64;
      const int row = idx >> 3, c4 = (idx & 7) * 4 + nhalf;
      *reinterpret_cast<ushort4*>(&Sg[base2 + row * DST + c4]) =
          *reinterpret_cast<const ushort4*>(&StL[row][c4]);
    }
  }
}

// ---------------------------------------------------------------------------
// Carry: 256 wgs x 64 threads; 8-deep prefetch.
// ---------------------------------------------------------------------------
__global__ __launch_bounds__(64)
void carry_kernel(_Float16* __restrict__ Sg, const float* __restrict__ Pbuf)
{
  const int wg = blockIdx.x;
  const int q = wg & 3;
  const int rest = wg >> 2;
  const int b = rest % BBATCH;
  const int h = (rest / BBATCH) % NHEADS;
  const int team = rest / (BBATCH * NHEADS);
  const int lane = threadIdx.x;
  const int off = q * 512 + lane * 8;
  const int hi = q >> 1;
  const size_t base0 = ((size_t)team * NHEADS + h) * BBATCH + b;

  float hc[8] = {0, 0, 0, 0, 0, 0, 0, 0};
  for (int cb = 0; cb < NCHUNK; cb += 8) {
    half8 a[8];
    float Pv[8];
#pragma unroll
    for (int j = 0; j < 8; ++j) {
      const size_t sb = (base0 * NCHUNK + cb + j) * (NHIN * HD * DST) + off;
      a[j] = *reinterpret_cast<const half8*>(&Sg[sb]);
      Pv[j] = Pbuf[(base0 * NCHUNK + cb + j) * NHIN + hi];
    }
#pragma unroll
    for (int j = 0; j < 8; ++j) {
      const size_t sb = (base0 * NCHUNK + cb + j) * (NHIN * HD * DST) + off;
      half8 o;
#pragma unroll
      for (int k = 0; k < 8; ++k) o[k] = (_Float16)hc[k];
      *reinterpret_cast<half8*>(&Sg[sb]) = o;
#pragma unroll
      for (int k = 0; k < 8; ++k) hc[k] = fmaf(Pv[j], hc[k], (float)a[j][k]);
    }
  }
}

// ---------------------------------------------------------------------------
// K3 fused: both teams per wg; C·H_in + z MFMAs (precomputed f16 operands),
// gate+rms+out-proj, diff, partial stats.
// ---------------------------------------------------------------------------
__global__ __launch_bounds__(256)
void k3_fused(const _Float16* __restrict__ Sg, const float2* __restrict__ cumsg,
              const _Float16* __restrict__ xgC, const _Float16* __restrict__ xH,
              const _Float16* __restrict__ WzF, const float* __restrict__ wnF,
              const _Float16* __restrict__ yintra, const float* __restrict__ lam,
              float* __restrict__ diffb, float2* __restrict__ pstat)
{
  __shared__ float    ysh[2][CHUNK][YS];
  __shared__ float    wn[2][16][33];
  __shared__ float    cums2[2][CHUNK][2];
  __shared__ _Float16 zsh[2][32][40];
  __shared__ float    youtL[2][CHUNK][20];
  __shared__ float    red2[8];

  const int tid  = threadIdx.x;
  const int wg   = blockIdx.x;
  const int c    = wg % NCHUNK;
  const int b    = (wg / NCHUNK) % BBATCH;
  const int h    = wg / (NCHUNK * BBATCH);
  const int c0 = c * CHUNK;
  const int lane = tid & 63;
  const int wv   = tid >> 6;

  const size_t wgT0 = (((size_t)0 * NHEADS + h) * BBATCH + b) * NCHUNK + c;
  const size_t wgT1 = (((size_t)1 * NHEADS + h) * BBATCH + b) * NCHUNK + c;

  f32x16 acc;
  if (wv < 2) {
    const size_t wgT = wv ? wgT1 : wgT0;
    const int colid = lane & 31, kg = lane >> 5;
    const _Float16* ca = &xgC[wgT * (CHUNK * DST) + (size_t)colid * DST + kg * 8];
    const _Float16* hb = &Sg[wgT * (NHIN * HD * DST) + (size_t)colid * DST + kg * 8];
#pragma unroll
    for (int i = 0; i < 16; ++i) acc[i] = 0.0f;
    acc = __builtin_amdgcn_mfma_f32_32x32x16_f16(
        *reinterpret_cast<const half8*>(ca), *reinterpret_cast<const half8*>(hb), acc, 0, 0, 0);
    acc = __builtin_amdgcn_mfma_f32_32x32x16_f16(
        *reinterpret_cast<const half8*>(ca + 16), *reinterpret_cast<const half8*>(hb + 16), acc, 0, 0, 0);
    acc = __builtin_amdgcn_mfma_f32_32x32x16_f16(
        *reinterpret_cast<const half8*>(ca + 32), *reinterpret_cast<const half8*>(hb + 32), acc, 0, 0, 0);
    acc = __builtin_amdgcn_mfma_f32_32x32x16_f16(
        *reinterpret_cast<const half8*>(ca + 48), *reinterpret_cast<const half8*>(hb + 48), acc, 0, 0, 0);
  } else {
    const int team = wv - 2;
    const int th = team * NHEADS + h;
    const int lrow = lane & 31, kg = lane >> 5;
    const half8 afr = *reinterpret_cast<const half8*>(
        &xH[((size_t)b * TSEQ + c0 + lrow) * DMODEL + h * HD + kg * 8]);
    const half8 bfr = *reinterpret_cast<const half8*>(
        &WzF[((size_t)th * 32 + lrow) * 16 + kg * 8]);
    f32x16 zacc;
#pragma unroll
    for (int i = 0; i < 16; ++i) zacc[i] = 0.0f;
    zacc = __builtin_amdgcn_mfma_f32_32x32x16_f16(afr, bfr, zacc, 0, 0, 0);
#pragma unroll
    for (int rg = 0; rg < 16; ++rg) {
      const int t = (rg & 3) + 8 * (rg >> 2) + 4 * kg;
      const float v = zacc[rg];
      zsh[team][t][lrow] = (_Float16)(v * sigm(v));
    }
  }

  {
#pragma unroll
    for (int k = 0; k < 4; ++k) {
      const int i = tid + k * 256;
      const int tm = i >> 9, o = (i >> 5) & 15, dn = i & 31;
      wn[tm][o][dn] = wnF[((size_t)(tm * NHEADS + h) * HD + o) * DIN + dn];
    }
  }
  {
    const int tm = tid >> 7, li = tid & 127;
    const int t = li >> 2, c8 = (li & 3) * 8;
    const size_t wgT = tm ? wgT1 : wgT0;
    const half8 v = *reinterpret_cast<const half8*>(&yintra[wgT * (CHUNK * DIN) + li * 8]);
#pragma unroll
    for (int j = 0; j < 8; ++j) ysh[tm][t][c8 + j] = (float)v[j];
  }
  if (tid < 64) {
    const int tm = tid >> 5, t = tid & 31;
    const size_t wgT = tm ? wgT1 : wgT0;
    const float2 v = cumsg[wgT * CHUNK + t];
    cums2[tm][t][0] = v.x; cums2[tm][t][1] = v.y;
  }
  __syncthreads();

  if (wv < 2) {
    const int team = wv;
    const int colid = lane & 31, kg = lane >> 5;
    const int hi = colid >> 4;
#pragma unroll
    for (int rg = 0; rg < 16; ++rg) {
      const int t = (rg & 3) + 8 * (rg >> 2) + 4 * kg;
      ysh[team][t][colid] = fmaf(cums2[team][t][hi], acc[rg], ysh[team][t][colid]);
    }
  }
  __syncthreads();

  {
    const int tm = tid >> 7, l = tid & 127;
    const int q = l & 3, tl = l >> 2;
    const int dn0 = q * 8;
    float yg[8];
    float ss = 0.0f;
#pragma unroll
    for (int j = 0; j < 8; ++j) {
      const float g = ysh[tm][tl][dn0 + j] * (float)zsh[tm][tl][dn0 + j];
      yg[j] = g;
      ss += g * g;
    }
    ss += __shfl_xor(ss, 1, 4);
    ss += __shfl_xor(ss, 2, 4);
    const float rms = rsqrtf(ss * (1.0f / DIN) + 1e-5f);
#pragma unroll
    for (int j = 0; j < 8; ++j) ysh[tm][tl][dn0 + j] = yg[j] * rms;
  }
  __syncthreads();

  {
    const int tm = tid >> 7, l = tid & 127;
    const int q = l & 3, tl = l >> 2;
#pragma unroll
    for (int oo = 0; oo < 4; ++oo) {
      const int o = q * 4 + oo;
      float a = 0.0f;
#pragma unroll
      for (int dn = 0; dn < DIN; ++dn) a = fmaf(ysh[tm][tl][dn], wn[tm][o][dn], a);
      youtL[tm][tl][o] = a;
    }
  }
  __syncthreads();

  float s = 0.0f, s2 = 0.0f;
  if (tid < 128) {
    const int t = tid >> 2, hd0 = (tid & 3) * 4;
    const float4 l4 = *reinterpret_cast<const float4*>(&lam[h * HD + hd0]);
    const float* y0 = &youtL[0][t][hd0];
    const float* y1 = &youtL[1][t][hd0];
    float4 d;
    d.x = y0[0] - l4.x * y1[0];
    d.y = y0[1] - l4.y * y1[1];
    d.z = y0[2] - l4.z * y1[2];
    d.w = y0[3] - l4.w * y1[3];
    *reinterpret_cast<float4*>(
        &diffb[(((size_t)(h * BBATCH + b)) * TSEQ + c0 + t) * HD + hd0]) = d;
    s = d.x + d.y + d.z + d.w;
    s2 = d.x * d.x + d.y * d.y + d.z * d.z + d.w * d.w;
  }
#pragma unroll
  for (int off = 1; off < 64; off <<= 1) {
    s += __shfl_xor(s, off);
    s2 += __shfl_xor(s2, off);
  }
  if (lane == 0) { red2[wv * 2] = s; red2[wv * 2 + 1] = s2; }
  __syncthreads();
  if (tid == 0) pstat[wg] = make_float2(red2[0] + red2[2], red2[1] + red2[3]);
}

// ---------------------------------------------------------------------------
// Final (MFMA): stats reduce + groupnorm-apply (f16) + [32x256]x[256x256]
// f16 MFMA GEMM + bias + residual.
// ---------------------------------------------------------------------------
#define NFW (BBATCH * (TSEQ / 32) * 2)   // 256
__global__ __launch_bounds__(256)
void final_mfma(const float* __restrict__ x, const float* __restrict__ diffb,
                const float2* __restrict__ pstat, const float* __restrict__ gnw,
                const float* __restrict__ gnb, const float* __restrict__ projw,
                const float* __restrict__ projb, float* __restrict__ out)
{
  __shared__ _Float16 ndH[32][268];
  __shared__ float statL[NHEADS][2];

  const int wg = blockIdx.x;
  const int chalf = wg & 1;
  const int tt = (wg >> 1) & 63;
  const int b = wg >> 7;
  const int t0 = tt * 32;
  const int tid = threadIdx.x;
  const int lane = tid & 63;
  const int wv = tid >> 6;

  {
    const int h = tid >> 4, k0 = tid & 15;
    float s = 0.0f, s2 = 0.0f;
    for (int k = k0; k < NCHUNK; k += 16) {
      const float2 v = pstat[((size_t)h * BBATCH + b) * NCHUNK + k];
      s += v.x; s2 += v.y;
    }
    s += __shfl_xor(s, 1, 16);  s2 += __shfl_xor(s2, 1, 16);
    s += __shfl_xor(s, 2, 16);  s2 += __shfl_xor(s2, 2, 16);
    s += __shfl_xor(s, 4, 16);  s2 += __shfl_xor(s2, 4, 16);
    s += __shfl_xor(s, 8, 16);  s2 += __shfl_xor(s2, 8, 16);
    if (k0 == 0) {
      const float inv = 1.0f / (TSEQ * HD);
      const float mean = s * inv;
      const float var = s2 * inv - mean * mean;
      statL[h][0] = mean;
      statL[h][1] = rsqrtf(var + 1e-5f);
    }
  }
  __syncthreads();

  {
    const int d = tid, h = d >> 4, hd = d & 15;
    const float mean = statL[h][0];
    const float rstd = statL[h][1];
    const float g = gnw[d];
    const float be = gnb[d];
    const float* dp = &diffb[((size_t)(h * BBATCH + b) * TSEQ + t0) * HD + hd];
#pragma unroll
    for (int t = 0; t < 32; ++t)
      ndH[t][d] = (_Float16)((dp[t * HD] - mean) * rstd * g + be);
  }
  __syncthreads();

  const int lrow = lane & 31, kg = lane >> 5;
  const int n0 = chalf * 128 + wv * 32;
  const int d = n0 + lrow;
  f32x16 acc;
#pragma unroll
  for (int i = 0; i < 16; ++i) acc[i] = 0.0f;
  const float* wp0 = &projw[(size_t)d * DMODEL + kg * 8];
#pragma unroll
  for (int kt = 0; kt < DMODEL; kt += 16) {
    const half8 af = ld8(&ndH[lrow][kt + kg * 8]);
    const half8 bf = pack_h8(*reinterpret_cast<const float4*>(wp0 + kt),
                             *reinterpret_cast<const float4*>(wp0 + kt + 4));
    acc = __builtin_amdgcn_mfma_f32_32x32x16_f16(af, bf, acc, 0, 0, 0);
  }

  const float pb = projb[d];
#pragma unroll
  for (int rg = 0; rg < 16; ++rg) {
    const int t = (rg & 3) + 8 * (rg >> 2) + 4 * kg;
    const size_t o = ((size_t)b * TSEQ + t0 + t) * DMODEL + d;
    out[o] = x[o] + pb + acc[rg];
  }
}

// ---------------------------------------------------------------------------
extern "C" void kernel_launch(void* const* d_in, const int* in_sizes, int n_in,
                              void* d_out, int out_size, void* d_ws, size_t ws_size,
                              hipStream_t stream)
{
  const float* x = (const float*)d_in[0];
  TeamParams tp0 { (const float*)d_in[1], (const float*)d_in[2], (const float*)d_in[3],
                   (const float*)d_in[4], (const float*)d_in[5], (const float*)d_in[6],
                   (const float*)d_in[7], (const float*)d_in[8] };
  TeamParams tp1 { (const float*)d_in[9], (const float*)d_in[10], (const float*)d_in[11],
                   (const float*)d_in[12], (const float*)d_in[13], (const float*)d_in[14],
                   (const float*)d_in[15], (const float*)d_in[16] };
  const float* lam   = (const float*)d_in[17];
  const float* gnw   = (const float*)d_in[18];
  const float* gnb   = (const float*)d_in[19];
  const float* projw = (const float*)d_in[20];
  const float* projb = (const float*)d_in[21];

  // ws layout (bytes):
  //   Sg      @ 0           16,777,216
  //   Pbuf    @ 16,777,216      32,768
  //   cumsg   @ 16,809,984   1,048,576
  //   xgC     @ 17,858,560  16,777,216
  //   yintra  @ 34,635,776   8,388,608
  //   diffb   @ 43,024,384   4,194,304
  //   pstat   @ 47,218,688      16,384
  //   xH      @ 47,235,072   2,097,152
  //   WcF     @ 49,332,224     655,360
  //   WzF     @ 49,987,584      32,768
  //   WdtF    @ 50,020,352       2,048
  //   wnF     @ 50,022,400      65,536   (total ~50.1 MB)
  char* wsb = (char*)d_ws;
  _Float16* Sg    = (_Float16*)wsb;
  float* Pbuf     = (float*)(wsb + 16777216);
  float2* cumsg   = (float2*)(wsb + 16809984);
  _Float16* xgC   = (_Float16*)(wsb + 17858560);
  _Float16* yintra= (_Float16*)(wsb + 34635776);
  float* diffb    = (float*)(wsb + 43024384);
  float2* pstat   = (float2*)(wsb + 47218688);
  _Float16* xH    = (_Float16*)(wsb + 47235072);
  _Float16* WcF   = (_Float16*)(wsb + 49332224);
  _Float16* WzF   = (_Float16*)(wsb + 49987584);
  _Float16* WdtF  = (_Float16*)(wsb + 50020352);
  float* wnF      = (float*)(wsb + 50022400);

  prep_kernel<<<dim3(320), dim3(256), 0, stream>>>(x, tp0, tp1, xH, WcF, WzF, WdtF, wnF);
  k1_proj_ssd<<<dim3(NWG), dim3(256), 0, stream>>>(xH, WcF, WdtF, tp0, tp1, Sg, Pbuf, cumsg, xgC, yintra);
  carry_kernel<<<dim3(2 * NHEADS * BBATCH * 4), dim3(64), 0, stream>>>(Sg, Pbuf);
  k3_fused<<<dim3(NWG3), dim3(256), 0, stream>>>(Sg, cumsg, xgC, xH, WzF, wnF, yintra, lam, diffb, pstat);
  final_mfma<<<dim3(NFW), dim3(256), 0, stream>>>(
      x, diffb, pstat, gnw, gnb, projw, projb, (float*)d_out);
}

// Round 12
// 85.462 us; speedup vs baseline: 4.9053x; 1.0096x over previous
//
#include <hip/hip_runtime.h>
#include <math.h>

#define NHEADS 16
#define BBATCH 2
#define TSEQ   2048
#define HD     16
#define DIN    32
#define DST    64
#define CONVD  160
#define DPROJ  194
#define NHIN   2
#define DMODEL 256
#define CHUNK  32
#define NCHUNK (TSEQ / CHUNK)                  // 64
#define NWG    (2 * NHEADS * BBATCH * NCHUNK)  // 4096 (k1)
#define NWG3   (NHEADS * BBATCH * NCHUNK)      // 2048 (k3 fused)
#define YS     36

struct TeamParams {
  const float *Win, *convw, *convb, *dtb, *Alog, *Dp, *nw, *Wout;
};

typedef __attribute__((ext_vector_type(4)))  _Float16 half4;
typedef __attribute__((ext_vector_type(8)))  _Float16 half8;
typedef __attribute__((ext_vector_type(16))) float    f32x16;

__device__ __forceinline__ float sigm(float v) { return 1.0f / (1.0f + __expf(-v)); }

__device__ __forceinline__ half8 pack_h8(float4 a, float4 b) {
  half8 r;
  r[0] = (_Float16)a.x; r[1] = (_Float16)a.y; r[2] = (_Float16)a.z; r[3] = (_Float16)a.w;
  r[4] = (_Float16)b.x; r[5] = (_Float16)b.y; r[6] = (_Float16)b.z; r[7] = (_Float16)b.w;
  return r;
}
__device__ __forceinline__ half8 zero_h8() {
  half8 r;
#pragma unroll
  for (int i = 0; i < 8; ++i) r[i] = (_Float16)0.f;
  return r;
}
__device__ __forceinline__ half8 ld8(const _Float16* p) {
  const half4 a = *reinterpret_cast<const half4*>(p);
  const half4 b = *reinterpret_cast<const half4*>(p + 4);
  half8 r;
  r[0] = a[0]; r[1] = a[1]; r[2] = a[2]; r[3] = a[3];
  r[4] = b[0]; r[5] = b[1]; r[6] = b[2]; r[7] = b[3];
  return r;
}

// ---------------------------------------------------------------------------
// Prep: hoist all wg-invariant packing to global f16/f32 tensors.
// ---------------------------------------------------------------------------
__global__ __launch_bounds__(256)
void prep_kernel(const float* __restrict__ x, TeamParams tp0, TeamParams tp1,
                 _Float16* __restrict__ xH, _Float16* __restrict__ WcF,
                 _Float16* __restrict__ WzF, _Float16* __restrict__ WdtF,
                 float* __restrict__ wnF)
{
  const int gid = blockIdx.x * 256 + threadIdx.x;
  const int gsz = gridDim.x * 256;
  for (int i = gid; i < (BBATCH * TSEQ * DMODEL) / 8; i += gsz) {
    const float4 a = *reinterpret_cast<const float4*>(&x[(size_t)i * 8]);
    const float4 b = *reinterpret_cast<const float4*>(&x[(size_t)i * 8 + 4]);
    *reinterpret_cast<half8*>(&xH[(size_t)i * 8]) = pack_h8(a, b);
  }
  for (int i = gid; i < 2 * NHEADS * 4 * CONVD * 2; i += gsz) {
    const int k8 = i & 1;
    const int r = i >> 1;
    const int ch = r % CONVD;
    const int tap = (r / CONVD) & 3;
    const int th = r / (CONVD * 4);
    const int team = th >> 4, h = th & 15;
    const TeamParams P = team ? tp1 : tp0;
    const float cw = P.convw[((size_t)h * CONVD + ch) * 4 + tap];
    const float* wp = &P.Win[((size_t)h * DPROJ + 32 + ch) * HD + k8 * 8];
    half8 v;
#pragma unroll
    for (int j = 0; j < 8; ++j) v[j] = (_Float16)(cw * wp[j]);
    *reinterpret_cast<half8*>(&WcF[(size_t)r * 16 + k8 * 8]) = v;
  }
  for (int i = gid; i < 2 * NHEADS * 32 * 2; i += gsz) {
    const int k8 = i & 1;
    const int r = i >> 1;
    const int row = r & 31;
    const int th = r >> 5;
    const int team = th >> 4, h = th & 15;
    const TeamParams P = team ? tp1 : tp0;
    const float* wp = &P.Win[((size_t)h * DPROJ + row) * HD + k8 * 8];
    half8 v;
#pragma unroll
    for (int j = 0; j < 8; ++j) v[j] = (_Float16)wp[j];
    *reinterpret_cast<half8*>(&WzF[(size_t)r * 16 + k8 * 8]) = v;
  }
  for (int i = gid; i < 2 * NHEADS * 2 * 2; i += gsz) {
    const int k8 = i & 1;
    const int r = i >> 1;
    const int row = r & 1;
    const int th = r >> 1;
    const int team = th >> 4, h = th & 15;
    const TeamParams P = team ? tp1 : tp0;
    const float* wp = &P.Win[((size_t)h * DPROJ + 192 + row) * HD + k8 * 8];
    half8 v;
#pragma unroll
    for (int j = 0; j < 8; ++j) v[j] = (_Float16)wp[j];
    *reinterpret_cast<half8*>(&WdtF[(size_t)r * 16 + k8 * 8]) = v;
  }
  for (int i = gid; i < 2 * NHEADS * HD * DIN / 4; i += gsz) {
    const int dn4 = (i & 7) * 4;
    const int o = (i >> 3) & 15;
    const int th = i >> 7;
    const int team = th >> 4, h = th & 15;
    const TeamParams P = team ? tp1 : tp0;
    float4 v;
    float* vp = reinterpret_cast<float*>(&v);
#pragma unroll
    for (int j = 0; j < 4; ++j)
      vp[j] = P.Wout[((size_t)h * HD + o) * DIN + dn4 + j] * P.nw[h * DIN + dn4 + j];
    *reinterpret_cast<float4*>(&wnF[((size_t)th * HD + o) * DIN + dn4]) = v;
  }
}

// ---------------------------------------------------------------------------
// K1: conv-fused in-proj MFMA + SSD chunk computation. LDS-aliased buffers
// (~21.5 KB -> 7 wg/CU), 3 barriers, wave-specialized phases.
// ---------------------------------------------------------------------------
__global__ __launch_bounds__(256, 7)
void k1_proj_ssd(const _Float16* __restrict__ xH, const _Float16* __restrict__ WcF,
                 const _Float16* __restrict__ WdtF, TeamParams tp0, TeamParams tp1,
                 _Float16* __restrict__ Sg, float* __restrict__ Pbuf,
                 float2* __restrict__ cumsg, _Float16* __restrict__ xgC,
                 _Float16* __restrict__ yintra)
{
  __shared__ _Float16 xvT[32][36];       // silu x-act [ch][t]           (ph1 -> ph4a)
  __shared__ _Float16 BmT[64][36];       // silu B-act [n][t]            (ph1 -> ph4a)
  __shared__ _Float16 bufA[2][32][36];   // ph1-2: actB [t][n] ; ph3+: Gm
  __shared__ _Float16 bufB[32][68];      // ph1-2: actC [t][n] ; ph4a: StL
  __shared__ _Float16 XtL[32][36];       // (dt*x)^T
  __shared__ _Float16 WXt[32][36];       // (w*dt*x)^T
  __shared__ float    dtraw[32][2];
  __shared__ float    clL[2][32], dtL2[2][32], dwL[2][32];

  _Float16 (*actB)[68] = reinterpret_cast<_Float16(*)[68]>(&bufA[0][0][0]);
  _Float16 (*actC)[68] = bufB;
  _Float16 (*Gm)[32][36] = bufA;
  _Float16 (*StL)[68] = bufB;

  const int tid  = threadIdx.x;
  const int wg   = blockIdx.x;
  const int c    = wg % NCHUNK;
  const int b    = (wg / NCHUNK) % BBATCH;
  const int h    = (wg / (NCHUNK * BBATCH)) % NHEADS;
  const int team = wg / (NCHUNK * BBATCH * NHEADS);
  const TeamParams P = team ? tp1 : tp0;
  const int th = team * NHEADS + h;
  const int c0 = c * CHUNK;
  const size_t base0 = ((size_t)team * NHEADS + h) * BBATCH + b;

  const int lane = tid & 63;
  const int wv   = tid >> 6;
  const int lrow = lane & 31;
  const int kg   = lane >> 5;

  f32x16 z16;
#pragma unroll
  for (int i = 0; i < 16; ++i) z16[i] = 0.0f;
  f32x16 g = z16;

  // ---- A fragments: 4 shifted x windows, direct f16 loads ----
  half8 afr[4];
#pragma unroll
  for (int j = 0; j < 4; ++j) {
    const int tp = c0 + lrow - 3 + j;
    afr[j] = (tp >= 0)
        ? *reinterpret_cast<const half8*>(&xH[((size_t)b * TSEQ + tp) * DMODEL + h * HD + kg * 8])
        : zero_h8();
  }

  // ================= phase 1: conv-fused in-proj MFMA ======================
  auto doTile = [&](int tile) {
    const int ch = tile * 32 + lrow;
    const float cb = P.convb[h * CONVD + ch];
    f32x16 acc = z16;
#pragma unroll
    for (int j = 0; j < 4; ++j) {
      const half8 bf = *reinterpret_cast<const half8*>(
          &WcF[((size_t)(th * 4 + j) * CONVD + ch) * 16 + kg * 8]);
      acc = __builtin_amdgcn_mfma_f32_32x32x16_f16(afr[j], bf, acc, 0, 0, 0);
    }
    _Float16 sv[16];
#pragma unroll
    for (int rg = 0; rg < 16; ++rg) {
      const float vv = acc[rg] + cb;
      sv[rg] = (_Float16)(vv * sigm(vv));
    }
    if (tile == 0) {
#pragma unroll
      for (int m = 0; m < 4; ++m) {
        half4 v; v[0] = sv[4*m]; v[1] = sv[4*m+1]; v[2] = sv[4*m+2]; v[3] = sv[4*m+3];
        *reinterpret_cast<half4*>(&xvT[lrow][4 * kg + 8 * m]) = v;
      }
    } else if (tile <= 2) {
      const int n = ch - 32;
#pragma unroll
      for (int m = 0; m < 4; ++m) {
        half4 v; v[0] = sv[4*m]; v[1] = sv[4*m+1]; v[2] = sv[4*m+2]; v[3] = sv[4*m+3];
        *reinterpret_cast<half4*>(&BmT[n][4 * kg + 8 * m]) = v;
      }
#pragma unroll
      for (int rg = 0; rg < 16; ++rg) {
        const int t = (rg & 3) + 8 * (rg >> 2) + 4 * kg;
        actB[t][n] = sv[rg];
      }
    } else {
      const int n = ch - 96;
#pragma unroll
      for (int rg = 0; rg < 16; ++rg) {
        const int t = (rg & 3) + 8 * (rg >> 2) + 4 * kg;
        actC[t][n] = sv[rg];
      }
    }
  };

  if (wv == 0) {
    doTile(0);
    half8 bf5 = zero_h8();
    if (lrow < 2)
      bf5 = *reinterpret_cast<const half8*>(&WdtF[((size_t)th * 2 + lrow) * 16 + kg * 8]);
    const f32x16 a5 = __builtin_amdgcn_mfma_f32_32x32x16_f16(afr[3], bf5, z16, 0, 0, 0);
    if (lrow < 2) {
#pragma unroll
      for (int rg = 0; rg < 16; ++rg) {
        const int t = (rg & 3) + 8 * (rg >> 2) + 4 * kg;
        dtraw[t][lrow] = a5[rg];
      }
    }
  } else if (wv == 1) {
    doTile(1);
  } else if (wv == 2) {
    doTile(2);
  } else {
    doTile(3);
    doTile(4);
  }
  __syncthreads();   // B1

  // ================= phase 2: G-MFMA (wv0) | scan (wv1) | xgC (wv2) ========
  if (wv == 0) {
#pragma unroll
    for (int kk = 0; kk < 4; ++kk) {
      const half8 af = ld8(&actC[lrow][kk * 16 + kg * 8]);
      const half8 bf = ld8(&actB[lrow][kk * 16 + kg * 8]);
      g = __builtin_amdgcn_mfma_f32_32x32x16_f16(af, bf, g, 0, 0, 0);
    }
  } else if (wv == 1) {
    const int t = lane & 31, hi = lane >> 5;
    const float dtbias = P.dtb[h * NHIN + hi];
    const float Ah = -__expf(P.Alog[h * NHIN + hi]);
    const float raw = dtraw[t][hi] + dtbias;
    const float dtv = (raw > 20.f) ? raw : log1pf(__expf(raw));
    float s = dtv * Ah;
#pragma unroll
    for (int d = 1; d < 32; d <<= 1) {
      const float v = __shfl_up(s, d, 32);
      if (t >= d) s += v;
    }
    const float cl31 = __shfl(s, 31, 32);
    const float w = __expf(cl31 - s);
    const float ecl = __expf(s);
    clL[hi][t] = s;
    dtL2[hi][t] = dtv;
    dwL[hi][t] = w * dtv;
    const float eo = __shfl(ecl, (lane & 31) + 32, 64);
    if (lane < 32) cumsg[(size_t)wg * CHUNK + t] = make_float2(ecl, eo);
    if (t == 31) Pbuf[(base0 * NCHUNK + c) * NHIN + hi] = ecl;
  } else if (wv == 2) {
#pragma unroll
    for (int k = 0; k < 8; ++k) {
      const int idx = lane + k * 64;
      const int t = idx >> 4, c4 = (idx & 15) * 4;
      *reinterpret_cast<ushort4*>(&xgC[(size_t)wg * (CHUNK * DST) + t * DST + c4]) =
          *reinterpret_cast<const ushort4*>(&actC[t][c4]);
    }
  }
  __syncthreads();   // B2  (actB/actC dead; Gm/StL aliases become live)

  // ================= phase 3: mask Gm (wv0) | Xt/WXt (wv1+wv2) =============
  if (wv == 0) {
    const float cls0 = clL[0][lrow], cls1 = clL[1][lrow];
#pragma unroll
    for (int rg = 0; rg < 16; ++rg) {
      const int t = (rg & 3) + 8 * (rg >> 2) + 4 * kg;
      const float gg = g[rg];
      float l0 = 0.f, l1 = 0.f;
      if (lrow <= t) { l0 = __expf(clL[0][t] - cls0); l1 = __expf(clL[1][t] - cls1); }
      Gm[0][t][lrow] = (_Float16)(l0 * gg);
      Gm[1][t][lrow] = (_Float16)(l1 * gg);
    }
  } else if (wv == 1 || wv == 2) {
    const int idx = tid - 64;
    const int ch = idx & 31, tq = idx >> 5;
    const int hi = ch >> 4;
#pragma unroll
    for (int hh = 0; hh < 2; ++hh) {
      const int t4 = tq * 8 + hh * 4;
      const half4 xv4 = *reinterpret_cast<const half4*>(&xvT[ch][t4]);
      half4 xt, wx;
#pragma unroll
      for (int i = 0; i < 4; ++i) {
        const int t = t4 + i;
        const float xv = (float)xv4[i];
        xt[i] = (_Float16)(dtL2[hi][t] * xv);
        wx[i] = (_Float16)(dwL[hi][t] * xv);
      }
      *reinterpret_cast<half4*>(&XtL[ch][t4]) = xt;
      *reinterpret_cast<half4*>(&WXt[ch][t4]) = wx;
    }
  }
  __syncthreads();   // B3

  // ======= phase 4: y_intra (wv0,wv3) | S^T + Sg store (wv1,wv2) ===========
  if (wv == 0 || wv == 3) {
    const int hi = (wv == 0) ? 0 : 1;
    const half8 xb0 = ld8(&XtL[lrow][kg * 8]);
    const half8 xb1 = ld8(&XtL[lrow][16 + kg * 8]);
    f32x16 acc = z16;
    acc = __builtin_amdgcn_mfma_f32_32x32x16_f16(ld8(&Gm[hi][lrow][kg * 8]), xb0, acc, 0, 0, 0);
    acc = __builtin_amdgcn_mfma_f32_32x32x16_f16(ld8(&Gm[hi][lrow][16 + kg * 8]), xb1, acc, 0, 0, 0);
    if ((lrow >> 4) == hi) {
      const float Dp = P.Dp[h * NHIN + hi];
      _Float16* yo = &yintra[(size_t)wg * (CHUNK * DIN)];
#pragma unroll
      for (int rg = 0; rg < 16; ++rg) {
        const int t = (rg & 3) + 8 * (rg >> 2) + 4 * kg;
        yo[t * DIN + lrow] = (_Float16)(acc[rg] + Dp * (float)xvT[lrow][t]);
      }
    }
  } else {
    const int nhalf = (wv - 1) * 32;
    const half8 wa0 = ld8(&WXt[lrow][kg * 8]);
    const half8 wa1 = ld8(&WXt[lrow][16 + kg * 8]);
    f32x16 acc = z16;
    acc = __builtin_amdgcn_mfma_f32_32x32x16_f16(
        wa0, ld8(&BmT[nhalf + lrow][kg * 8]), acc, 0, 0, 0);
    acc = __builtin_amdgcn_mfma_f32_32x32x16_f16(
        wa1, ld8(&BmT[nhalf + lrow][16 + kg * 8]), acc, 0, 0, 0);
#pragma unroll
    for (int rg = 0; rg < 16; ++rg) {
      const int m = (rg & 3) + 8 * (rg >> 2) + 4 * kg;
      StL[m][nhalf + lrow] = (_Float16)acc[rg];
    }
    // same-wave LDS RAW (own nhalf columns only) -> no barrier needed
    const size_t base2 = (base0 * NCHUNK + c) * (NHIN * HD * DST);
#pragma unroll
    for (int k = 0; k < 4; ++k) {
      const int idx = lane + k * 64;
      const int row = idx >> 3, c4 = (idx & 7) * 4 + nhalf;
      *reinterpret_cast<ushort4*>(&Sg[base2 + row * DST + c4]) =
          *reinterpret_cast<const ushort4*>(&StL[row][c4]);
    }
  }
}

// ---------------------------------------------------------------------------
// Carry: 256 wgs x 64 threads; 8-deep prefetch.
// ---------------------------------------------------------------------------
__global__ __launch_bounds__(64)
void carry_kernel(_Float16* __restrict__ Sg, const float* __restrict__ Pbuf)
{
  const int wg = blockIdx.x;
  const int q = wg & 3;
  const int rest = wg >> 2;
  const int b = rest % BBATCH;
  const int h = (rest / BBATCH) % NHEADS;
  const int team = rest / (BBATCH * NHEADS);
  const int lane = threadIdx.x;
  const int off = q * 512 + lane * 8;
  const int hi = q >> 1;
  const size_t base0 = ((size_t)team * NHEADS + h) * BBATCH + b;

  float hc[8] = {0, 0, 0, 0, 0, 0, 0, 0};
  for (int cb = 0; cb < NCHUNK; cb += 8) {
    half8 a[8];
    float Pv[8];
#pragma unroll
    for (int j = 0; j < 8; ++j) {
      const size_t sb = (base0 * NCHUNK + cb + j) * (NHIN * HD * DST) + off;
      a[j] = *reinterpret_cast<const half8*>(&Sg[sb]);
      Pv[j] = Pbuf[(base0 * NCHUNK + cb + j) * NHIN + hi];
    }
#pragma unroll
    for (int j = 0; j < 8; ++j) {
      const size_t sb = (base0 * NCHUNK + cb + j) * (NHIN * HD * DST) + off;
      half8 o;
#pragma unroll
      for (int k = 0; k < 8; ++k) o[k] = (_Float16)hc[k];
      *reinterpret_cast<half8*>(&Sg[sb]) = o;
#pragma unroll
      for (int k = 0; k < 8; ++k) hc[k] = fmaf(Pv[j], hc[k], (float)a[j][k]);
    }
  }
}

// ---------------------------------------------------------------------------
// K3 fused: both teams per wg; C·H_in + z MFMAs (precomputed f16 operands),
// gate+rms+out-proj, diff, partial stats.
// ---------------------------------------------------------------------------
__global__ __launch_bounds__(256)
void k3_fused(const _Float16* __restrict__ Sg, const float2* __restrict__ cumsg,
              const _Float16* __restrict__ xgC, const _Float16* __restrict__ xH,
              const _Float16* __restrict__ WzF, const float* __restrict__ wnF,
              const _Float16* __restrict__ yintra, const float* __restrict__ lam,
              float* __restrict__ diffb, float2* __restrict__ pstat)
{
  __shared__ float    ysh[2][CHUNK][YS];
  __shared__ float    wn[2][16][33];
  __shared__ float    cums2[2][CHUNK][2];
  __shared__ _Float16 zsh[2][32][40];
  __shared__ float    youtL[2][CHUNK][20];
  __shared__ float    red2[8];

  const int tid  = threadIdx.x;
  const int wg   = blockIdx.x;
  const int c    = wg % NCHUNK;
  const int b    = (wg / NCHUNK) % BBATCH;
  const int h    = wg / (NCHUNK * BBATCH);
  const int c0 = c * CHUNK;
  const int lane = tid & 63;
  const int wv   = tid >> 6;

  const size_t wgT0 = (((size_t)0 * NHEADS + h) * BBATCH + b) * NCHUNK + c;
  const size_t wgT1 = (((size_t)1 * NHEADS + h) * BBATCH + b) * NCHUNK + c;

  f32x16 acc;
  if (wv < 2) {
    const size_t wgT = wv ? wgT1 : wgT0;
    const int colid = lane & 31, kg = lane >> 5;
    const _Float16* ca = &xgC[wgT * (CHUNK * DST) + (size_t)colid * DST + kg * 8];
    const _Float16* hb = &Sg[wgT * (NHIN * HD * DST) + (size_t)colid * DST + kg * 8];
#pragma unroll
    for (int i = 0; i < 16; ++i) acc[i] = 0.0f;
    acc = __builtin_amdgcn_mfma_f32_32x32x16_f16(
        *reinterpret_cast<const half8*>(ca), *reinterpret_cast<const half8*>(hb), acc, 0, 0, 0);
    acc = __builtin_amdgcn_mfma_f32_32x32x16_f16(
        *reinterpret_cast<const half8*>(ca + 16), *reinterpret_cast<const half8*>(hb + 16), acc, 0, 0, 0);
    acc = __builtin_amdgcn_mfma_f32_32x32x16_f16(
        *reinterpret_cast<const half8*>(ca + 32), *reinterpret_cast<const half8*>(hb + 32), acc, 0, 0, 0);
    acc = __builtin_amdgcn_mfma_f32_32x32x16_f16(
        *reinterpret_cast<const half8*>(ca + 48), *reinterpret_cast<const half8*>(hb + 48), acc, 0, 0, 0);
  } else {
    const int team = wv - 2;
    const int th = team * NHEADS + h;
    const int lrow = lane & 31, kg = lane >> 5;
    const half8 afr = *reinterpret_cast<const half8*>(
        &xH[((size_t)b * TSEQ + c0 + lrow) * DMODEL + h * HD + kg * 8]);
    const half8 bfr = *reinterpret_cast<const half8*>(
        &WzF[((size_t)th * 32 + lrow) * 16 + kg * 8]);
    f32x16 zacc;
#pragma unroll
    for (int i = 0; i < 16; ++i) zacc[i] = 0.0f;
    zacc = __builtin_amdgcn_mfma_f32_32x32x16_f16(afr, bfr, zacc, 0, 0, 0);
#pragma unroll
    for (int rg = 0; rg < 16; ++rg) {
      const int t = (rg & 3) + 8 * (rg >> 2) + 4 * kg;
      const float v = zacc[rg];
      zsh[team][t][lrow] = (_Float16)(v * sigm(v));
    }
  }

  {
#pragma unroll
    for (int k = 0; k < 4; ++k) {
      const int i = tid + k * 256;
      const int tm = i >> 9, o = (i >> 5) & 15, dn = i & 31;
      wn[tm][o][dn] = wnF[((size_t)(tm * NHEADS + h) * HD + o) * DIN + dn];
    }
  }
  {
    const int tm = tid >> 7, li = tid & 127;
    const int t = li >> 2, c8 = (li & 3) * 8;
    const size_t wgT = tm ? wgT1 : wgT0;
    const half8 v = *reinterpret_cast<const half8*>(&yintra[wgT * (CHUNK * DIN) + li * 8]);
#pragma unroll
    for (int j = 0; j < 8; ++j) ysh[tm][t][c8 + j] = (float)v[j];
  }
  if (tid < 64) {
    const int tm = tid >> 5, t = tid & 31;
    const size_t wgT = tm ? wgT1 : wgT0;
    const float2 v = cumsg[wgT * CHUNK + t];
    cums2[tm][t][0] = v.x; cums2[tm][t][1] = v.y;
  }
  __syncthreads();

  if (wv < 2) {
    const int team = wv;
    const int colid = lane & 31, kg = lane >> 5;
    const int hi = colid >> 4;
#pragma unroll
    for (int rg = 0; rg < 16; ++rg) {
      const int t = (rg & 3) + 8 * (rg >> 2) + 4 * kg;
      ysh[team][t][colid] = fmaf(cums2[team][t][hi], acc[rg], ysh[team][t][colid]);
    }
  }
  __syncthreads();

  {
    const int tm = tid >> 7, l = tid & 127;
    const int q = l & 3, tl = l >> 2;
    const int dn0 = q * 8;
    float yg[8];
    float ss = 0.0f;
#pragma unroll
    for (int j = 0; j < 8; ++j) {
      const float g = ysh[tm][tl][dn0 + j] * (float)zsh[tm][tl][dn0 + j];
      yg[j] = g;
      ss += g * g;
    }
    ss += __shfl_xor(ss, 1, 4);
    ss += __shfl_xor(ss, 2, 4);
    const float rms = rsqrtf(ss * (1.0f / DIN) + 1e-5f);
#pragma unroll
    for (int j = 0; j < 8; ++j) ysh[tm][tl][dn0 + j] = yg[j] * rms;
  }
  __syncthreads();

  {
    const int tm = tid >> 7, l = tid & 127;
    const int q = l & 3, tl = l >> 2;
#pragma unroll
    for (int oo = 0; oo < 4; ++oo) {
      const int o = q * 4 + oo;
      float a = 0.0f;
#pragma unroll
      for (int dn = 0; dn < DIN; ++dn) a = fmaf(ysh[tm][tl][dn], wn[tm][o][dn], a);
      youtL[tm][tl][o] = a;
    }
  }
  __syncthreads();

  float s = 0.0f, s2 = 0.0f;
  if (tid < 128) {
    const int t = tid >> 2, hd0 = (tid & 3) * 4;
    const float4 l4 = *reinterpret_cast<const float4*>(&lam[h * HD + hd0]);
    const float* y0 = &youtL[0][t][hd0];
    const float* y1 = &youtL[1][t][hd0];
    float4 d;
    d.x = y0[0] - l4.x * y1[0];
    d.y = y0[1] - l4.y * y1[1];
    d.z = y0[2] - l4.z * y1[2];
    d.w = y0[3] - l4.w * y1[3];
    *reinterpret_cast<float4*>(
        &diffb[(((size_t)(h * BBATCH + b)) * TSEQ + c0 + t) * HD + hd0]) = d;
    s = d.x + d.y + d.z + d.w;
    s2 = d.x * d.x + d.y * d.y + d.z * d.z + d.w * d.w;
  }
#pragma unroll
  for (int off = 1; off < 64; off <<= 1) {
    s += __shfl_xor(s, off);
    s2 += __shfl_xor(s2, off);
  }
  if (lane == 0) { red2[wv * 2] = s; red2[wv * 2 + 1] = s2; }
  __syncthreads();
  if (tid == 0) pstat[wg] = make_float2(red2[0] + red2[2], red2[1] + red2[3]);
}

// ---------------------------------------------------------------------------
// Final (MFMA): stats reduce + groupnorm-apply (f16) + [32x256]x[256x256]
// f16 MFMA GEMM + bias + residual.
// ---------------------------------------------------------------------------
#define NFW (BBATCH * (TSEQ / 32) * 2)   // 256
__global__ __launch_bounds__(256)
void final_mfma(const float* __restrict__ x, const float* __restrict__ diffb,
                const float2* __restrict__ pstat, const float* __restrict__ gnw,
                const float* __restrict__ gnb, const float* __restrict__ projw,
                const float* __restrict__ projb, float* __restrict__ out)
{
  __shared__ _Float16 ndH[32][268];
  __shared__ float statL[NHEADS][2];

  const int wg = blockIdx.x;
  const int chalf = wg & 1;
  const int tt = (wg >> 1) & 63;
  const int b = wg >> 7;
  const int t0 = tt * 32;
  const int tid = threadIdx.x;
  const int lane = tid & 63;
  const int wv = tid >> 6;

  {
    const int h = tid >> 4, k0 = tid & 15;
    float s = 0.0f, s2 = 0.0f;
    for (int k = k0; k < NCHUNK; k += 16) {
      const float2 v = pstat[((size_t)h * BBATCH + b) * NCHUNK + k];
      s += v.x; s2 += v.y;
    }
    s += __shfl_xor(s, 1, 16);  s2 += __shfl_xor(s2, 1, 16);
    s += __shfl_xor(s, 2, 16);  s2 += __shfl_xor(s2, 2, 16);
    s += __shfl_xor(s, 4, 16);  s2 += __shfl_xor(s2, 4, 16);
    s += __shfl_xor(s, 8, 16);  s2 += __shfl_xor(s2, 8, 16);
    if (k0 == 0) {
      const float inv = 1.0f / (TSEQ * HD);
      const float mean = s * inv;
      const float var = s2 * inv - mean * mean;
      statL[h][0] = mean;
      statL[h][1] = rsqrtf(var + 1e-5f);
    }
  }
  __syncthreads();

  {
    const int d = tid, h = d >> 4, hd = d & 15;
    const float mean = statL[h][0];
    const float rstd = statL[h][1];
    const float g = gnw[d];
    const float be = gnb[d];
    const float* dp = &diffb[((size_t)(h * BBATCH + b) * TSEQ + t0) * HD + hd];
#pragma unroll
    for (int t = 0; t < 32; ++t)
      ndH[t][d] = (_Float16)((dp[t * HD] - mean) * rstd * g + be);
  }
  __syncthreads();

  const int lrow = lane & 31, kg = lane >> 5;
  const int n0 = chalf * 128 + wv * 32;
  const int d = n0 + lrow;
  f32x16 acc;
#pragma unroll
  for (int i = 0; i < 16; ++i) acc[i] = 0.0f;
  const float* wp0 = &projw[(size_t)d * DMODEL + kg * 8];
#pragma unroll
  for (int kt = 0; kt < DMODEL; kt += 16) {
    const half8 af = ld8(&ndH[lrow][kt + kg * 8]);
    const half8 bf = pack_h8(*reinterpret_cast<const float4*>(wp0 + kt),
                             *reinterpret_cast<const float4*>(wp0 + kt + 4));
    acc = __builtin_amdgcn_mfma_f32_32x32x16_f16(af, bf, acc, 0, 0, 0);
  }

  const float pb = projb[d];
#pragma unroll
  for (int rg = 0; rg < 16; ++rg) {
    const int t = (rg & 3) + 8 * (rg >> 2) + 4 * kg;
    const size_t o = ((size_t)b * TSEQ + t0 + t) * DMODEL + d;
    out[o] = x[o] + pb + acc[rg];
  }
}

// ---------------------------------------------------------------------------
extern "C" void kernel_launch(void* const* d_in, const int* in_sizes, int n_in,
                              void* d_out, int out_size, void* d_ws, size_t ws_size,
                              hipStream_t stream)
{
  const float* x = (const float*)d_in[0];
  TeamParams tp0 { (const float*)d_in[1], (const float*)d_in[2], (const float*)d_in[3],
                   (const float*)d_in[4], (const float*)d_in[5], (const float*)d_in[6],
                   (const float*)d_in[7], (const float*)d_in[8] };
  TeamParams tp1 { (const float*)d_in[9], (const float*)d_in[10], (const float*)d_in[11],
                   (const float*)d_in[12], (const float*)d_in[13], (const float*)d_in[14],
                   (const float*)d_in[15], (const float*)d_in[16] };
  const float* lam   = (const float*)d_in[17];
  const float* gnw   = (const float*)d_in[18];
  const float* gnb   = (const float*)d_in[19];
  const float* projw = (const float*)d_in[20];
  const float* projb = (const float*)d_in[21];

  // ws layout (bytes):
  //   Sg      @ 0           16,777,216
  //   Pbuf    @ 16,777,216      32,768
  //   cumsg   @ 16,809,984   1,048,576
  //   xgC     @ 17,858,560  16,777,216
  //   yintra  @ 34,635,776   8,388,608
  //   diffb   @ 43,024,384   4,194,304
  //   pstat   @ 47,218,688      16,384
  //   xH      @ 47,235,072   2,097,152
  //   WcF     @ 49,332,224     655,360
  //   WzF     @ 49,987,584      32,768
  //   WdtF    @ 50,020,352       2,048
  //   wnF     @ 50,022,400      65,536   (total ~50.1 MB)
  char* wsb = (char*)d_ws;
  _Float16* Sg    = (_Float16*)wsb;
  float* Pbuf     = (float*)(wsb + 16777216);
  float2* cumsg   = (float2*)(wsb + 16809984);
  _Float16* xgC   = (_Float16*)(wsb + 17858560);
  _Float16* yintra= (_Float16*)(wsb + 34635776);
  float* diffb    = (float*)(wsb + 43024384);
  float2* pstat   = (float2*)(wsb + 47218688);
  _Float16* xH    = (_Float16*)(wsb + 47235072);
  _Float16* WcF   = (_Float16*)(wsb + 49332224);
  _Float16* WzF   = (_Float16*)(wsb + 49987584);
  _Float16* WdtF  = (_Float16*)(wsb + 50020352);
  float* wnF      = (float*)(wsb + 50022400);

  prep_kernel<<<dim3(320), dim3(256), 0, stream>>>(x, tp0, tp1, xH, WcF, WzF, WdtF, wnF);
  k1_proj_ssd<<<dim3(NWG), dim3(256), 0, stream>>>(xH, WcF, WdtF, tp0, tp1, Sg, Pbuf, cumsg, xgC, yintra);
  carry_kernel<<<dim3(2 * NHEADS * BBATCH * 4), dim3(64), 0, stream>>>(Sg, Pbuf);
  k3_fused<<<dim3(NWG3), dim3(256), 0, stream>>>(Sg, cumsg, xgC, xH, WzF, wnF, yintra, lam, diffb, pstat);
  final_mfma<<<dim3(NFW), dim3(256), 0, stream>>>(
      x, diffb, pstat, gnw, gnb, projw, projb, (float*)d_out);
}

// Round 13
// 79.588 us; speedup vs baseline: 5.2674x; 1.0738x over previous
//
#include <hip/hip_runtime.h>
#include <math.h>

#define NHEADS 16
#define BBATCH 2
#define TSEQ   2048
#define HD     16
#define DIN    32
#define DST    64
#define CONVD  160
#define DPROJ  194
#define NHIN   2
#define DMODEL 256
#define CHUNK  32
#define NCHUNK (TSEQ / CHUNK)                  // 64
#define NWG    (2 * NHEADS * BBATCH * NCHUNK)  // 4096 (k1)
#define NWG3   (NHEADS * BBATCH * NCHUNK)      // 2048 (k3 fused)
#define YS     36

struct TeamParams {
  const float *Win, *convw, *convb, *dtb, *Alog, *Dp, *nw, *Wout;
};

typedef __attribute__((ext_vector_type(4)))  _Float16 half4;
typedef __attribute__((ext_vector_type(8)))  _Float16 half8;
typedef __attribute__((ext_vector_type(16))) float    f32x16;

__device__ __forceinline__ float sigm(float v) { return 1.0f / (1.0f + __expf(-v)); }

__device__ __forceinline__ half8 pack_h8(float4 a, float4 b) {
  half8 r;
  r[0] = (_Float16)a.x; r[1] = (_Float16)a.y; r[2] = (_Float16)a.z; r[3] = (_Float16)a.w;
  r[4] = (_Float16)b.x; r[5] = (_Float16)b.y; r[6] = (_Float16)b.z; r[7] = (_Float16)b.w;
  return r;
}
__device__ __forceinline__ half8 zero_h8() {
  half8 r;
#pragma unroll
  for (int i = 0; i < 8; ++i) r[i] = (_Float16)0.f;
  return r;
}
__device__ __forceinline__ half8 ld8(const _Float16* p) {
  const half4 a = *reinterpret_cast<const half4*>(p);
  const half4 b = *reinterpret_cast<const half4*>(p + 4);
  half8 r;
  r[0] = a[0]; r[1] = a[1]; r[2] = a[2]; r[3] = a[3];
  r[4] = b[0]; r[5] = b[1]; r[6] = b[2]; r[7] = b[3];
  return r;
}

// ---------------------------------------------------------------------------
// Prep: hoist all wg-invariant packing to global f16 tensors.
// ---------------------------------------------------------------------------
__global__ __launch_bounds__(256)
void prep_kernel(const float* __restrict__ x, TeamParams tp0, TeamParams tp1,
                 _Float16* __restrict__ xH, _Float16* __restrict__ WcF,
                 _Float16* __restrict__ WzF, _Float16* __restrict__ WdtF,
                 _Float16* __restrict__ wnH)
{
  const int gid = blockIdx.x * 256 + threadIdx.x;
  const int gsz = gridDim.x * 256;
  for (int i = gid; i < (BBATCH * TSEQ * DMODEL) / 8; i += gsz) {
    const float4 a = *reinterpret_cast<const float4*>(&x[(size_t)i * 8]);
    const float4 b = *reinterpret_cast<const float4*>(&x[(size_t)i * 8 + 4]);
    *reinterpret_cast<half8*>(&xH[(size_t)i * 8]) = pack_h8(a, b);
  }
  for (int i = gid; i < 2 * NHEADS * 4 * CONVD * 2; i += gsz) {
    const int k8 = i & 1;
    const int r = i >> 1;
    const int ch = r % CONVD;
    const int tap = (r / CONVD) & 3;
    const int th = r / (CONVD * 4);
    const int team = th >> 4, h = th & 15;
    const TeamParams P = team ? tp1 : tp0;
    const float cw = P.convw[((size_t)h * CONVD + ch) * 4 + tap];
    const float* wp = &P.Win[((size_t)h * DPROJ + 32 + ch) * HD + k8 * 8];
    half8 v;
#pragma unroll
    for (int j = 0; j < 8; ++j) v[j] = (_Float16)(cw * wp[j]);
    *reinterpret_cast<half8*>(&WcF[(size_t)r * 16 + k8 * 8]) = v;
  }
  for (int i = gid; i < 2 * NHEADS * 32 * 2; i += gsz) {
    const int k8 = i & 1;
    const int r = i >> 1;
    const int row = r & 31;
    const int th = r >> 5;
    const int team = th >> 4, h = th & 15;
    const TeamParams P = team ? tp1 : tp0;
    const float* wp = &P.Win[((size_t)h * DPROJ + row) * HD + k8 * 8];
    half8 v;
#pragma unroll
    for (int j = 0; j < 8; ++j) v[j] = (_Float16)wp[j];
    *reinterpret_cast<half8*>(&WzF[(size_t)r * 16 + k8 * 8]) = v;
  }
  for (int i = gid; i < 2 * NHEADS * 2 * 2; i += gsz) {
    const int k8 = i & 1;
    const int r = i >> 1;
    const int row = r & 1;
    const int th = r >> 1;
    const int team = th >> 4, h = th & 15;
    const TeamParams P = team ? tp1 : tp0;
    const float* wp = &P.Win[((size_t)h * DPROJ + 192 + row) * HD + k8 * 8];
    half8 v;
#pragma unroll
    for (int j = 0; j < 8; ++j) v[j] = (_Float16)wp[j];
    *reinterpret_cast<half8*>(&WdtF[(size_t)r * 16 + k8 * 8]) = v;
  }
  for (int i = gid; i < 2 * NHEADS * HD * DIN / 8; i += gsz) {   // 2048
    const int dn8 = (i & 3) * 8;
    const int o = (i >> 2) & 15;
    const int th = i >> 6;
    const int team = th >> 4, h = th & 15;
    const TeamParams P = team ? tp1 : tp0;
    half8 v;
#pragma unroll
    for (int j = 0; j < 8; ++j)
      v[j] = (_Float16)(P.Wout[((size_t)h * HD + o) * DIN + dn8 + j] * P.nw[h * DIN + dn8 + j]);
    *reinterpret_cast<half8*>(&wnH[((size_t)th * HD + o) * DIN + dn8]) = v;
  }
}

// ---------------------------------------------------------------------------
// K1: conv-fused in-proj MFMA + SSD chunk computation. LDS-aliased buffers,
// 3 barriers, wave-specialized phases. (unchanged from prior round)
// ---------------------------------------------------------------------------
__global__ __launch_bounds__(256, 7)
void k1_proj_ssd(const _Float16* __restrict__ xH, const _Float16* __restrict__ WcF,
                 const _Float16* __restrict__ WdtF, TeamParams tp0, TeamParams tp1,
                 _Float16* __restrict__ Sg, float* __restrict__ Pbuf,
                 float2* __restrict__ cumsg, _Float16* __restrict__ xgC,
                 _Float16* __restrict__ yintra)
{
  __shared__ _Float16 xvT[32][36];
  __shared__ _Float16 BmT[64][36];
  __shared__ _Float16 bufA[2][32][36];   // ph1-2: actB ; ph3+: Gm
  __shared__ _Float16 bufB[32][68];      // ph1-2: actC ; ph4: StL
  __shared__ _Float16 XtL[32][36];
  __shared__ _Float16 WXt[32][36];
  __shared__ float    dtraw[32][2];
  __shared__ float    clL[2][32], dtL2[2][32], dwL[2][32];

  _Float16 (*actB)[68] = reinterpret_cast<_Float16(*)[68]>(&bufA[0][0][0]);
  _Float16 (*actC)[68] = bufB;
  _Float16 (*Gm)[32][36] = bufA;
  _Float16 (*StL)[68] = bufB;

  const int tid  = threadIdx.x;
  const int wg   = blockIdx.x;
  const int c    = wg % NCHUNK;
  const int b    = (wg / NCHUNK) % BBATCH;
  const int h    = (wg / (NCHUNK * BBATCH)) % NHEADS;
  const int team = wg / (NCHUNK * BBATCH * NHEADS);
  const TeamParams P = team ? tp1 : tp0;
  const int th = team * NHEADS + h;
  const int c0 = c * CHUNK;
  const size_t base0 = ((size_t)team * NHEADS + h) * BBATCH + b;

  const int lane = tid & 63;
  const int wv   = tid >> 6;
  const int lrow = lane & 31;
  const int kg   = lane >> 5;

  f32x16 z16;
#pragma unroll
  for (int i = 0; i < 16; ++i) z16[i] = 0.0f;
  f32x16 g = z16;

  half8 afr[4];
#pragma unroll
  for (int j = 0; j < 4; ++j) {
    const int tp = c0 + lrow - 3 + j;
    afr[j] = (tp >= 0)
        ? *reinterpret_cast<const half8*>(&xH[((size_t)b * TSEQ + tp) * DMODEL + h * HD + kg * 8])
        : zero_h8();
  }

  auto doTile = [&](int tile) {
    const int ch = tile * 32 + lrow;
    const float cb = P.convb[h * CONVD + ch];
    f32x16 acc = z16;
#pragma unroll
    for (int j = 0; j < 4; ++j) {
      const half8 bf = *reinterpret_cast<const half8*>(
          &WcF[((size_t)(th * 4 + j) * CONVD + ch) * 16 + kg * 8]);
      acc = __builtin_amdgcn_mfma_f32_32x32x16_f16(afr[j], bf, acc, 0, 0, 0);
    }
    _Float16 sv[16];
#pragma unroll
    for (int rg = 0; rg < 16; ++rg) {
      const float vv = acc[rg] + cb;
      sv[rg] = (_Float16)(vv * sigm(vv));
    }
    if (tile == 0) {
#pragma unroll
      for (int m = 0; m < 4; ++m) {
        half4 v; v[0] = sv[4*m]; v[1] = sv[4*m+1]; v[2] = sv[4*m+2]; v[3] = sv[4*m+3];
        *reinterpret_cast<half4*>(&xvT[lrow][4 * kg + 8 * m]) = v;
      }
    } else if (tile <= 2) {
      const int n = ch - 32;
#pragma unroll
      for (int m = 0; m < 4; ++m) {
        half4 v; v[0] = sv[4*m]; v[1] = sv[4*m+1]; v[2] = sv[4*m+2]; v[3] = sv[4*m+3];
        *reinterpret_cast<half4*>(&BmT[n][4 * kg + 8 * m]) = v;
      }
#pragma unroll
      for (int rg = 0; rg < 16; ++rg) {
        const int t = (rg & 3) + 8 * (rg >> 2) + 4 * kg;
        actB[t][n] = sv[rg];
      }
    } else {
      const int n = ch - 96;
#pragma unroll
      for (int rg = 0; rg < 16; ++rg) {
        const int t = (rg & 3) + 8 * (rg >> 2) + 4 * kg;
        actC[t][n] = sv[rg];
      }
    }
  };

  if (wv == 0) {
    doTile(0);
    half8 bf5 = zero_h8();
    if (lrow < 2)
      bf5 = *reinterpret_cast<const half8*>(&WdtF[((size_t)th * 2 + lrow) * 16 + kg * 8]);
    const f32x16 a5 = __builtin_amdgcn_mfma_f32_32x32x16_f16(afr[3], bf5, z16, 0, 0, 0);
    if (lrow < 2) {
#pragma unroll
      for (int rg = 0; rg < 16; ++rg) {
        const int t = (rg & 3) + 8 * (rg >> 2) + 4 * kg;
        dtraw[t][lrow] = a5[rg];
      }
    }
  } else if (wv == 1) {
    doTile(1);
  } else if (wv == 2) {
    doTile(2);
  } else {
    doTile(3);
    doTile(4);
  }
  __syncthreads();   // B1

  if (wv == 0) {
#pragma unroll
    for (int kk = 0; kk < 4; ++kk) {
      const half8 af = ld8(&actC[lrow][kk * 16 + kg * 8]);
      const half8 bf = ld8(&actB[lrow][kk * 16 + kg * 8]);
      g = __builtin_amdgcn_mfma_f32_32x32x16_f16(af, bf, g, 0, 0, 0);
    }
  } else if (wv == 1) {
    const int t = lane & 31, hi = lane >> 5;
    const float dtbias = P.dtb[h * NHIN + hi];
    const float Ah = -__expf(P.Alog[h * NHIN + hi]);
    const float raw = dtraw[t][hi] + dtbias;
    const float dtv = (raw > 20.f) ? raw : log1pf(__expf(raw));
    float s = dtv * Ah;
#pragma unroll
    for (int d = 1; d < 32; d <<= 1) {
      const float v = __shfl_up(s, d, 32);
      if (t >= d) s += v;
    }
    const float cl31 = __shfl(s, 31, 32);
    const float w = __expf(cl31 - s);
    const float ecl = __expf(s);
    clL[hi][t] = s;
    dtL2[hi][t] = dtv;
    dwL[hi][t] = w * dtv;
    const float eo = __shfl(ecl, (lane & 31) + 32, 64);
    if (lane < 32) cumsg[(size_t)wg * CHUNK + t] = make_float2(ecl, eo);
    if (t == 31) Pbuf[(base0 * NCHUNK + c) * NHIN + hi] = ecl;
  } else if (wv == 2) {
#pragma unroll
    for (int k = 0; k < 8; ++k) {
      const int idx = lane + k * 64;
      const int t = idx >> 4, c4 = (idx & 15) * 4;
      *reinterpret_cast<ushort4*>(&xgC[(size_t)wg * (CHUNK * DST) + t * DST + c4]) =
          *reinterpret_cast<const ushort4*>(&actC[t][c4]);
    }
  }
  __syncthreads();   // B2

  if (wv == 0) {
    const float cls0 = clL[0][lrow], cls1 = clL[1][lrow];
#pragma unroll
    for (int rg = 0; rg < 16; ++rg) {
      const int t = (rg & 3) + 8 * (rg >> 2) + 4 * kg;
      const float gg = g[rg];
      float l0 = 0.f, l1 = 0.f;
      if (lrow <= t) { l0 = __expf(clL[0][t] - cls0); l1 = __expf(clL[1][t] - cls1); }
      Gm[0][t][lrow] = (_Float16)(l0 * gg);
      Gm[1][t][lrow] = (_Float16)(l1 * gg);
    }
  } else if (wv == 1 || wv == 2) {
    const int idx = tid - 64;
    const int ch = idx & 31, tq = idx >> 5;
    const int hi = ch >> 4;
#pragma unroll
    for (int hh = 0; hh < 2; ++hh) {
      const int t4 = tq * 8 + hh * 4;
      const half4 xv4 = *reinterpret_cast<const half4*>(&xvT[ch][t4]);
      half4 xt, wx;
#pragma unroll
      for (int i = 0; i < 4; ++i) {
        const int t = t4 + i;
        const float xv = (float)xv4[i];
        xt[i] = (_Float16)(dtL2[hi][t] * xv);
        wx[i] = (_Float16)(dwL[hi][t] * xv);
      }
      *reinterpret_cast<half4*>(&XtL[ch][t4]) = xt;
      *reinterpret_cast<half4*>(&WXt[ch][t4]) = wx;
    }
  }
  __syncthreads();   // B3

  if (wv == 0 || wv == 3) {
    const int hi = (wv == 0) ? 0 : 1;
    const half8 xb0 = ld8(&XtL[lrow][kg * 8]);
    const half8 xb1 = ld8(&XtL[lrow][16 + kg * 8]);
    f32x16 acc = z16;
    acc = __builtin_amdgcn_mfma_f32_32x32x16_f16(ld8(&Gm[hi][lrow][kg * 8]), xb0, acc, 0, 0, 0);
    acc = __builtin_amdgcn_mfma_f32_32x32x16_f16(ld8(&Gm[hi][lrow][16 + kg * 8]), xb1, acc, 0, 0, 0);
    if ((lrow >> 4) == hi) {
      const float Dp = P.Dp[h * NHIN + hi];
      _Float16* yo = &yintra[(size_t)wg * (CHUNK * DIN)];
#pragma unroll
      for (int rg = 0; rg < 16; ++rg) {
        const int t = (rg & 3) + 8 * (rg >> 2) + 4 * kg;
        yo[t * DIN + lrow] = (_Float16)(acc[rg] + Dp * (float)xvT[lrow][t]);
      }
    }
  } else {
    const int nhalf = (wv - 1) * 32;
    const half8 wa0 = ld8(&WXt[lrow][kg * 8]);
    const half8 wa1 = ld8(&WXt[lrow][16 + kg * 8]);
    f32x16 acc = z16;
    acc = __builtin_amdgcn_mfma_f32_32x32x16_f16(
        wa0, ld8(&BmT[nhalf + lrow][kg * 8]), acc, 0, 0, 0);
    acc = __builtin_amdgcn_mfma_f32_32x32x16_f16(
        wa1, ld8(&BmT[nhalf + lrow][16 + kg * 8]), acc, 0, 0, 0);
#pragma unroll
    for (int rg = 0; rg < 16; ++rg) {
      const int m = (rg & 3) + 8 * (rg >> 2) + 4 * kg;
      StL[m][nhalf + lrow] = (_Float16)acc[rg];
    }
    const size_t base2 = (base0 * NCHUNK + c) * (NHIN * HD * DST);
#pragma unroll
    for (int k = 0; k < 4; ++k) {
      const int idx = lane + k * 64;
      const int row = idx >> 3, c4 = (idx & 7) * 4 + nhalf;
      *reinterpret_cast<ushort4*>(&Sg[base2 + row * DST + c4]) =
          *reinterpret_cast<const ushort4*>(&StL[row][c4]);
    }
  }
}

// ---------------------------------------------------------------------------
// Carry: 256 wgs x 64 threads; 8-deep prefetch.
// ---------------------------------------------------------------------------
__global__ __launch_bounds__(64)
void carry_kernel(_Float16* __restrict__ Sg, const float* __restrict__ Pbuf)
{
  const int wg = blockIdx.x;
  const int q = wg & 3;
  const int rest = wg >> 2;
  const int b = rest % BBATCH;
  const int h = (rest / BBATCH) % NHEADS;
  const int team = rest / (BBATCH * NHEADS);
  const int lane = threadIdx.x;
  const int off = q * 512 + lane * 8;
  const int hi = q >> 1;
  const size_t base0 = ((size_t)team * NHEADS + h) * BBATCH + b;

  float hc[8] = {0, 0, 0, 0, 0, 0, 0, 0};
  for (int cb = 0; cb < NCHUNK; cb += 8) {
    half8 a[8];
    float Pv[8];
#pragma unroll
    for (int j = 0; j < 8; ++j) {
      const size_t sb = (base0 * NCHUNK + cb + j) * (NHIN * HD * DST) + off;
      a[j] = *reinterpret_cast<const half8*>(&Sg[sb]);
      Pv[j] = Pbuf[(base0 * NCHUNK + cb + j) * NHIN + hi];
    }
#pragma unroll
    for (int j = 0; j < 8; ++j) {
      const size_t sb = (base0 * NCHUNK + cb + j) * (NHIN * HD * DST) + off;
      half8 o;
#pragma unroll
      for (int k = 0; k < 8; ++k) o[k] = (_Float16)hc[k];
      *reinterpret_cast<half8*>(&Sg[sb]) = o;
#pragma unroll
      for (int k = 0; k < 8; ++k) hc[k] = fmaf(Pv[j], hc[k], (float)a[j][k]);
    }
  }
}

// ---------------------------------------------------------------------------
// K3 fused: C·H_in + z MFMAs, gate+rms (-> f16), MFMA out-proj, diff, stats.
// ---------------------------------------------------------------------------
__global__ __launch_bounds__(256)
void k3_fused(const _Float16* __restrict__ Sg, const float2* __restrict__ cumsg,
              const _Float16* __restrict__ xgC, const _Float16* __restrict__ xH,
              const _Float16* __restrict__ WzF, const _Float16* __restrict__ wnH,
              const _Float16* __restrict__ yintra, const float* __restrict__ lam,
              float* __restrict__ diffb, float2* __restrict__ pstat)
{
  __shared__ float    ysh[2][CHUNK][YS];
  __shared__ float    cums2[2][CHUNK][2];
  __shared__ _Float16 zsh[2][32][40];
  __shared__ _Float16 ygH[2][32][36];
  __shared__ float    youtL[2][CHUNK][20];
  __shared__ float    red2[8];

  const int tid  = threadIdx.x;
  const int wg   = blockIdx.x;
  const int c    = wg % NCHUNK;
  const int b    = (wg / NCHUNK) % BBATCH;
  const int h    = wg / (NCHUNK * BBATCH);
  const int c0 = c * CHUNK;
  const int lane = tid & 63;
  const int wv   = tid >> 6;
  const int lrow = lane & 31;
  const int kg   = lane >> 5;

  const size_t wgT0 = (((size_t)0 * NHEADS + h) * BBATCH + b) * NCHUNK + c;
  const size_t wgT1 = (((size_t)1 * NHEADS + h) * BBATCH + b) * NCHUNK + c;

  f32x16 acc;
  if (wv < 2) {
    // ---- C · H_in for team wv ----
    const size_t wgT = wv ? wgT1 : wgT0;
    const _Float16* ca = &xgC[wgT * (CHUNK * DST) + (size_t)lrow * DST + kg * 8];
    const _Float16* hb = &Sg[wgT * (NHIN * HD * DST) + (size_t)lrow * DST + kg * 8];
#pragma unroll
    for (int i = 0; i < 16; ++i) acc[i] = 0.0f;
    acc = __builtin_amdgcn_mfma_f32_32x32x16_f16(
        *reinterpret_cast<const half8*>(ca), *reinterpret_cast<const half8*>(hb), acc, 0, 0, 0);
    acc = __builtin_amdgcn_mfma_f32_32x32x16_f16(
        *reinterpret_cast<const half8*>(ca + 16), *reinterpret_cast<const half8*>(hb + 16), acc, 0, 0, 0);
    acc = __builtin_amdgcn_mfma_f32_32x32x16_f16(
        *reinterpret_cast<const half8*>(ca + 32), *reinterpret_cast<const half8*>(hb + 32), acc, 0, 0, 0);
    acc = __builtin_amdgcn_mfma_f32_32x32x16_f16(
        *reinterpret_cast<const half8*>(ca + 48), *reinterpret_cast<const half8*>(hb + 48), acc, 0, 0, 0);
  } else {
    // ---- z = silu(x · Win_z^T) for team wv-2 ----
    const int team = wv - 2;
    const int th = team * NHEADS + h;
    const half8 afr = *reinterpret_cast<const half8*>(
        &xH[((size_t)b * TSEQ + c0 + lrow) * DMODEL + h * HD + kg * 8]);
    const half8 bfr = *reinterpret_cast<const half8*>(
        &WzF[((size_t)th * 32 + lrow) * 16 + kg * 8]);
    f32x16 zacc;
#pragma unroll
    for (int i = 0; i < 16; ++i) zacc[i] = 0.0f;
    zacc = __builtin_amdgcn_mfma_f32_32x32x16_f16(afr, bfr, zacc, 0, 0, 0);
#pragma unroll
    for (int rg = 0; rg < 16; ++rg) {
      const int t = (rg & 3) + 8 * (rg >> 2) + 4 * kg;
      const float v = zacc[rg];
      zsh[team][t][lrow] = (_Float16)(v * sigm(v));
    }
  }

  // ---- staging (all threads) ----
  {
    const int tm = tid >> 7, li = tid & 127;
    const int t = li >> 2, c8 = (li & 3) * 8;
    const size_t wgT = tm ? wgT1 : wgT0;
    const half8 v = *reinterpret_cast<const half8*>(&yintra[wgT * (CHUNK * DIN) + li * 8]);
#pragma unroll
    for (int j = 0; j < 8; ++j) ysh[tm][t][c8 + j] = (float)v[j];
  }
  if (tid < 64) {
    const int tm = tid >> 5, t = tid & 31;
    const size_t wgT = tm ? wgT1 : wgT0;
    const float2 v = cumsg[wgT * CHUNK + t];
    cums2[tm][t][0] = v.x; cums2[tm][t][1] = v.y;
  }
  __syncthreads();   // B1

  // ---- combine: ysh += cum * (C·H_in) ----
  if (wv < 2) {
    const int team = wv;
    const int hi = lrow >> 4;
#pragma unroll
    for (int rg = 0; rg < 16; ++rg) {
      const int t = (rg & 3) + 8 * (rg >> 2) + 4 * kg;
      ysh[team][t][lrow] = fmaf(cums2[team][t][hi], acc[rg], ysh[team][t][lrow]);
    }
  }
  __syncthreads();   // B2

  // ---- gate + rms -> ygH (f16) ----
  {
    const int tm = tid >> 7, l = tid & 127;
    const int q = l & 3, tl = l >> 2;
    const int dn0 = q * 8;
    float yg[8];
    float ss = 0.0f;
#pragma unroll
    for (int j = 0; j < 8; ++j) {
      const float g = ysh[tm][tl][dn0 + j] * (float)zsh[tm][tl][dn0 + j];
      yg[j] = g;
      ss += g * g;
    }
    ss += __shfl_xor(ss, 1, 4);
    ss += __shfl_xor(ss, 2, 4);
    const float rms = rsqrtf(ss * (1.0f / DIN) + 1e-5f);
    half4 o0, o1;
#pragma unroll
    for (int j = 0; j < 4; ++j) o0[j] = (_Float16)(yg[j] * rms);
#pragma unroll
    for (int j = 0; j < 4; ++j) o1[j] = (_Float16)(yg[4 + j] * rms);
    *reinterpret_cast<half4*>(&ygH[tm][tl][dn0]) = o0;
    *reinterpret_cast<half4*>(&ygH[tm][tl][dn0 + 4]) = o1;
  }
  __syncthreads();   // B3

  // ---- out-proj via MFMA: wave tm -> yout[t][o] ----
  if (wv < 2) {
    const int tm = wv;
    const int th2 = tm * NHEADS + h;
    const half8 af0 = ld8(&ygH[tm][lrow][kg * 8]);
    const half8 af1 = ld8(&ygH[tm][lrow][16 + kg * 8]);
    half8 bf0 = zero_h8(), bf1 = zero_h8();
    if (lrow < 16) {
      const _Float16* wp = &wnH[((size_t)th2 * HD + lrow) * DIN];
      bf0 = *reinterpret_cast<const half8*>(wp + kg * 8);
      bf1 = *reinterpret_cast<const half8*>(wp + 16 + kg * 8);
    }
    f32x16 oacc;
#pragma unroll
    for (int i = 0; i < 16; ++i) oacc[i] = 0.0f;
    oacc = __builtin_amdgcn_mfma_f32_32x32x16_f16(af0, bf0, oacc, 0, 0, 0);
    oacc = __builtin_amdgcn_mfma_f32_32x32x16_f16(af1, bf1, oacc, 0, 0, 0);
    if (lrow < 16) {
#pragma unroll
      for (int rg = 0; rg < 16; ++rg) {
        const int t = (rg & 3) + 8 * (rg >> 2) + 4 * kg;
        youtL[tm][t][lrow] = oacc[rg];
      }
    }
  }
  __syncthreads();   // B4

  // ---- diff + partial stats ----
  float s = 0.0f, s2 = 0.0f;
  if (tid < 128) {
    const int t = tid >> 2, hd0 = (tid & 3) * 4;
    const float4 l4 = *reinterpret_cast<const float4*>(&lam[h * HD + hd0]);
    const float* y0 = &youtL[0][t][hd0];
    const float* y1 = &youtL[1][t][hd0];
    float4 d;
    d.x = y0[0] - l4.x * y1[0];
    d.y = y0[1] - l4.y * y1[1];
    d.z = y0[2] - l4.z * y1[2];
    d.w = y0[3] - l4.w * y1[3];
    *reinterpret_cast<float4*>(
        &diffb[(((size_t)(h * BBATCH + b)) * TSEQ + c0 + t) * HD + hd0]) = d;
    s = d.x + d.y + d.z + d.w;
    s2 = d.x * d.x + d.y * d.y + d.z * d.z + d.w * d.w;
  }
#pragma unroll
  for (int off = 1; off < 64; off <<= 1) {
    s += __shfl_xor(s, off);
    s2 += __shfl_xor(s2, off);
  }
  if (lane == 0) { red2[wv * 2] = s; red2[wv * 2 + 1] = s2; }
  __syncthreads();
  if (tid == 0) pstat[wg] = make_float2(red2[0] + red2[2], red2[1] + red2[3]);
}

// ---------------------------------------------------------------------------
// Final (MFMA): stats reduce + groupnorm-apply (f16) + [32x256]x[256x256]
// f16 MFMA GEMM + bias + residual.
// ---------------------------------------------------------------------------
#define NFW (BBATCH * (TSEQ / 32) * 2)   // 256
__global__ __launch_bounds__(256)
void final_mfma(const float* __restrict__ x, const float* __restrict__ diffb,
                const float2* __restrict__ pstat, const float* __restrict__ gnw,
                const float* __restrict__ gnb, const float* __restrict__ projw,
                const float* __restrict__ projb, float* __restrict__ out)
{
  __shared__ _Float16 ndH[32][268];
  __shared__ float statL[NHEADS][2];

  const int wg = blockIdx.x;
  const int chalf = wg & 1;
  const int tt = (wg >> 1) & 63;
  const int b = wg >> 7;
  const int t0 = tt * 32;
  const int tid = threadIdx.x;
  const int lane = tid & 63;
  const int wv = tid >> 6;

  {
    const int h = tid >> 4, k0 = tid & 15;
    float s = 0.0f, s2 = 0.0f;
    for (int k = k0; k < NCHUNK; k += 16) {
      const float2 v = pstat[((size_t)h * BBATCH + b) * NCHUNK + k];
      s += v.x; s2 += v.y;
    }
    s += __shfl_xor(s, 1, 16);  s2 += __shfl_xor(s2, 1, 16);
    s += __shfl_xor(s, 2, 16);  s2 += __shfl_xor(s2, 2, 16);
    s += __shfl_xor(s, 4, 16);  s2 += __shfl_xor(s2, 4, 16);
    s += __shfl_xor(s, 8, 16);  s2 += __shfl_xor(s2, 8, 16);
    if (k0 == 0) {
      const float inv = 1.0f / (TSEQ * HD);
      const float mean = s * inv;
      const float var = s2 * inv - mean * mean;
      statL[h][0] = mean;
      statL[h][1] = rsqrtf(var + 1e-5f);
    }
  }
  __syncthreads();

  {
    const int d = tid, h = d >> 4, hd = d & 15;
    const float mean = statL[h][0];
    const float rstd = statL[h][1];
    const float g = gnw[d];
    const float be = gnb[d];
    const float* dp = &diffb[((size_t)(h * BBATCH + b) * TSEQ + t0) * HD + hd];
#pragma unroll
    for (int t = 0; t < 32; ++t)
      ndH[t][d] = (_Float16)((dp[t * HD] - mean) * rstd * g + be);
  }
  __syncthreads();

  const int lrow = lane & 31, kg = lane >> 5;
  const int n0 = chalf * 128 + wv * 32;
  const int d = n0 + lrow;
  f32x16 acc;
#pragma unroll
  for (int i = 0; i < 16; ++i) acc[i] = 0.0f;
  const float* wp0 = &projw[(size_t)d * DMODEL + kg * 8];
#pragma unroll
  for (int kt = 0; kt < DMODEL; kt += 16) {
    const half8 af = ld8(&ndH[lrow][kt + kg * 8]);
    const half8 bf = pack_h8(*reinterpret_cast<const float4*>(wp0 + kt),
                             *reinterpret_cast<const float4*>(wp0 + kt + 4));
    acc = __builtin_amdgcn_mfma_f32_32x32x16_f16(af, bf, acc, 0, 0, 0);
  }

  const float pb = projb[d];
#pragma unroll
  for (int rg = 0; rg < 16; ++rg) {
    const int t = (rg & 3) + 8 * (rg >> 2) + 4 * kg;
    const size_t o = ((size_t)b * TSEQ + t0 + t) * DMODEL + d;
    out[o] = x[o] + pb + acc[rg];
  }
}

// ---------------------------------------------------------------------------
extern "C" void kernel_launch(void* const* d_in, const int* in_sizes, int n_in,
                              void* d_out, int out_size, void* d_ws, size_t ws_size,
                              hipStream_t stream)
{
  const float* x = (const float*)d_in[0];
  TeamParams tp0 { (const float*)d_in[1], (const float*)d_in[2], (const float*)d_in[3],
                   (const float*)d_in[4], (const float*)d_in[5], (const float*)d_in[6],
                   (const float*)d_in[7], (const float*)d_in[8] };
  TeamParams tp1 { (const float*)d_in[9], (const float*)d_in[10], (const float*)d_in[11],
                   (const float*)d_in[12], (const float*)d_in[13], (const float*)d_in[14],
                   (const float*)d_in[15], (const float*)d_in[16] };
  const float* lam   = (const float*)d_in[17];
  const float* gnw   = (const float*)d_in[18];
  const float* gnb   = (const float*)d_in[19];
  const float* projw = (const float*)d_in[20];
  const float* projb = (const float*)d_in[21];

  // ws layout (bytes):
  //   Sg      @ 0           16,777,216
  //   Pbuf    @ 16,777,216      32,768
  //   cumsg   @ 16,809,984   1,048,576
  //   xgC     @ 17,858,560  16,777,216
  //   yintra  @ 34,635,776   8,388,608
  //   diffb   @ 43,024,384   4,194,304
  //   pstat   @ 47,218,688      16,384
  //   xH      @ 47,235,072   2,097,152
  //   WcF     @ 49,332,224     655,360
  //   WzF     @ 49,987,584      32,768
  //   WdtF    @ 50,020,352       2,048
  //   wnH     @ 50,022,400      32,768   (total ~50.1 MB)
  char* wsb = (char*)d_ws;
  _Float16* Sg    = (_Float16*)wsb;
  float* Pbuf     = (float*)(wsb + 16777216);
  float2* cumsg   = (float2*)(wsb + 16809984);
  _Float16* xgC   = (_Float16*)(wsb + 17858560);
  _Float16* yintra= (_Float16*)(wsb + 34635776);
  float* diffb    = (float*)(wsb + 43024384);
  float2* pstat   = (float2*)(wsb + 47218688);
  _Float16* xH    = (_Float16*)(wsb + 47235072);
  _Float16* WcF   = (_Float16*)(wsb + 49332224);
  _Float16* WzF   = (_Float16*)(wsb + 49987584);
  _Float16* WdtF  = (_Float16*)(wsb + 50020352);
  _Float16* wnH   = (_Float16*)(wsb + 50022400);

  prep_kernel<<<dim3(320), dim3(256), 0, stream>>>(x, tp0, tp1, xH, WcF, WzF, WdtF, wnH);
  k1_proj_ssd<<<dim3(NWG), dim3(256), 0, stream>>>(xH, WcF, WdtF, tp0, tp1, Sg, Pbuf, cumsg, xgC, yintra);
  carry_kernel<<<dim3(2 * NHEADS * BBATCH * 4), dim3(64), 0, stream>>>(Sg, Pbuf);
  k3_fused<<<dim3(NWG3), dim3(256), 0, stream>>>(Sg, cumsg, xgC, xH, WzF, wnH, yintra, lam, diffb, pstat);
  final_mfma<<<dim3(NFW), dim3(256), 0, stream>>>(
      x, diffb, pstat, gnw, gnb, projw, projb, (float*)d_out);
}

// Round 14
// 77.133 us; speedup vs baseline: 5.4350x; 1.0318x over previous
//
#include <hip/hip_runtime.h>
#include <math.h>

#define NHEADS 16
#define BBATCH 2
#define TSEQ   2048
#define HD     16
#define DIN    32
#define DST    64
#define CONVD  160
#define DPROJ  194
#define NHIN   2
#define DMODEL 256
#define CHUNK  32
#define NCHUNK (TSEQ / CHUNK)                  // 64
#define NWG    (2 * NHEADS * BBATCH * NCHUNK)  // 4096 (k1)
#define NWG3   (NHEADS * BBATCH * NCHUNK)      // 2048 (k3 fused)
#define YS     36

struct TeamParams {
  const float *Win, *convw, *convb, *dtb, *Alog, *Dp, *nw, *Wout;
};

typedef __attribute__((ext_vector_type(4)))  _Float16 half4;
typedef __attribute__((ext_vector_type(8)))  _Float16 half8;
typedef __attribute__((ext_vector_type(16))) float    f32x16;

// fast silu: v_rcp_f32 (~1ulp) instead of precise divide; outputs hit f16 anyway
__device__ __forceinline__ float sigm(float v) {
  return __builtin_amdgcn_rcpf(1.0f + __expf(-v));
}

__device__ __forceinline__ half8 pack_h8(float4 a, float4 b) {
  half8 r;
  r[0] = (_Float16)a.x; r[1] = (_Float16)a.y; r[2] = (_Float16)a.z; r[3] = (_Float16)a.w;
  r[4] = (_Float16)b.x; r[5] = (_Float16)b.y; r[6] = (_Float16)b.z; r[7] = (_Float16)b.w;
  return r;
}
__device__ __forceinline__ half8 zero_h8() {
  half8 r;
#pragma unroll
  for (int i = 0; i < 8; ++i) r[i] = (_Float16)0.f;
  return r;
}
__device__ __forceinline__ half8 ld8(const _Float16* p) {
  const half4 a = *reinterpret_cast<const half4*>(p);
  const half4 b = *reinterpret_cast<const half4*>(p + 4);
  half8 r;
  r[0] = a[0]; r[1] = a[1]; r[2] = a[2]; r[3] = a[3];
  r[4] = b[0]; r[5] = b[1]; r[6] = b[2]; r[7] = b[3];
  return r;
}

// ---------------------------------------------------------------------------
// Prep: hoist all wg-invariant packing to global f16 tensors.
// ---------------------------------------------------------------------------
__global__ __launch_bounds__(256)
void prep_kernel(const float* __restrict__ x, TeamParams tp0, TeamParams tp1,
                 _Float16* __restrict__ xH, _Float16* __restrict__ WcF,
                 _Float16* __restrict__ WzF, _Float16* __restrict__ WdtF,
                 _Float16* __restrict__ wnH)
{
  const int gid = blockIdx.x * 256 + threadIdx.x;
  const int gsz = gridDim.x * 256;
  for (int i = gid; i < (BBATCH * TSEQ * DMODEL) / 8; i += gsz) {
    const float4 a = *reinterpret_cast<const float4*>(&x[(size_t)i * 8]);
    const float4 b = *reinterpret_cast<const float4*>(&x[(size_t)i * 8 + 4]);
    *reinterpret_cast<half8*>(&xH[(size_t)i * 8]) = pack_h8(a, b);
  }
  for (int i = gid; i < 2 * NHEADS * 4 * CONVD * 2; i += gsz) {
    const int k8 = i & 1;
    const int r = i >> 1;
    const int ch = r % CONVD;
    const int tap = (r / CONVD) & 3;
    const int th = r / (CONVD * 4);
    const int team = th >> 4, h = th & 15;
    const TeamParams P = team ? tp1 : tp0;
    const float cw = P.convw[((size_t)h * CONVD + ch) * 4 + tap];
    const float* wp = &P.Win[((size_t)h * DPROJ + 32 + ch) * HD + k8 * 8];
    half8 v;
#pragma unroll
    for (int j = 0; j < 8; ++j) v[j] = (_Float16)(cw * wp[j]);
    *reinterpret_cast<half8*>(&WcF[(size_t)r * 16 + k8 * 8]) = v;
  }
  for (int i = gid; i < 2 * NHEADS * 32 * 2; i += gsz) {
    const int k8 = i & 1;
    const int r = i >> 1;
    const int row = r & 31;
    const int th = r >> 5;
    const int team = th >> 4, h = th & 15;
    const TeamParams P = team ? tp1 : tp0;
    const float* wp = &P.Win[((size_t)h * DPROJ + row) * HD + k8 * 8];
    half8 v;
#pragma unroll
    for (int j = 0; j < 8; ++j) v[j] = (_Float16)wp[j];
    *reinterpret_cast<half8*>(&WzF[(size_t)r * 16 + k8 * 8]) = v;
  }
  for (int i = gid; i < 2 * NHEADS * 2 * 2; i += gsz) {
    const int k8 = i & 1;
    const int r = i >> 1;
    const int row = r & 1;
    const int th = r >> 1;
    const int team = th >> 4, h = th & 15;
    const TeamParams P = team ? tp1 : tp0;
    const float* wp = &P.Win[((size_t)h * DPROJ + 192 + row) * HD + k8 * 8];
    half8 v;
#pragma unroll
    for (int j = 0; j < 8; ++j) v[j] = (_Float16)wp[j];
    *reinterpret_cast<half8*>(&WdtF[(size_t)r * 16 + k8 * 8]) = v;
  }
  for (int i = gid; i < 2 * NHEADS * HD * DIN / 8; i += gsz) {
    const int dn8 = (i & 3) * 8;
    const int o = (i >> 2) & 15;
    const int th = i >> 6;
    const int team = th >> 4, h = th & 15;
    const TeamParams P = team ? tp1 : tp0;
    half8 v;
#pragma unroll
    for (int j = 0; j < 8; ++j)
      v[j] = (_Float16)(P.Wout[((size_t)h * HD + o) * DIN + dn8 + j] * P.nw[h * DIN + dn8 + j]);
    *reinterpret_cast<half8*>(&wnH[((size_t)th * HD + o) * DIN + dn8]) = v;
  }
}

// ---------------------------------------------------------------------------
// K1: conv-fused in-proj MFMA + SSD chunk computation. LDS-aliased buffers,
// 3 barriers, wave-specialized phases. Phase-1 rebalanced (dt on wv2).
// ---------------------------------------------------------------------------
__global__ __launch_bounds__(256, 7)
void k1_proj_ssd(const _Float16* __restrict__ xH, const _Float16* __restrict__ WcF,
                 const _Float16* __restrict__ WdtF, TeamParams tp0, TeamParams tp1,
                 _Float16* __restrict__ Sg, float* __restrict__ Pbuf,
                 float2* __restrict__ cumsg, _Float16* __restrict__ xgC,
                 _Float16* __restrict__ yintra)
{
  __shared__ _Float16 xvT[32][36];
  __shared__ _Float16 BmT[64][36];
  __shared__ _Float16 bufA[2][32][36];   // ph1-2: actB ; ph3+: Gm
  __shared__ _Float16 bufB[32][68];      // ph1-2: actC ; ph4: StL
  __shared__ _Float16 XtL[32][36];
  __shared__ _Float16 WXt[32][36];
  __shared__ float    dtraw[32][2];
  __shared__ float    clL[2][32], dtL2[2][32], dwL[2][32];

  _Float16 (*actB)[68] = reinterpret_cast<_Float16(*)[68]>(&bufA[0][0][0]);
  _Float16 (*actC)[68] = bufB;
  _Float16 (*Gm)[32][36] = bufA;
  _Float16 (*StL)[68] = bufB;

  const int tid  = threadIdx.x;
  const int wg   = blockIdx.x;
  const int c    = wg % NCHUNK;
  const int b    = (wg / NCHUNK) % BBATCH;
  const int h    = (wg / (NCHUNK * BBATCH)) % NHEADS;
  const int team = wg / (NCHUNK * BBATCH * NHEADS);
  const TeamParams P = team ? tp1 : tp0;
  const int th = team * NHEADS + h;
  const int c0 = c * CHUNK;
  const size_t base0 = ((size_t)team * NHEADS + h) * BBATCH + b;

  const int lane = tid & 63;
  const int wv   = tid >> 6;
  const int lrow = lane & 31;
  const int kg   = lane >> 5;

  f32x16 z16;
#pragma unroll
  for (int i = 0; i < 16; ++i) z16[i] = 0.0f;
  f32x16 g = z16;

  half8 afr[4];
#pragma unroll
  for (int j = 0; j < 4; ++j) {
    const int tp = c0 + lrow - 3 + j;
    afr[j] = (tp >= 0)
        ? *reinterpret_cast<const half8*>(&xH[((size_t)b * TSEQ + tp) * DMODEL + h * HD + kg * 8])
        : zero_h8();
  }

  auto doTile = [&](int tile) {
    const int ch = tile * 32 + lrow;
    const float cb = P.convb[h * CONVD + ch];
    f32x16 acc = z16;
#pragma unroll
    for (int j = 0; j < 4; ++j) {
      const half8 bf = *reinterpret_cast<const half8*>(
          &WcF[((size_t)(th * 4 + j) * CONVD + ch) * 16 + kg * 8]);
      acc = __builtin_amdgcn_mfma_f32_32x32x16_f16(afr[j], bf, acc, 0, 0, 0);
    }
    _Float16 sv[16];
#pragma unroll
    for (int rg = 0; rg < 16; ++rg) {
      const float vv = acc[rg] + cb;
      sv[rg] = (_Float16)(vv * sigm(vv));
    }
    if (tile == 0) {
#pragma unroll
      for (int m = 0; m < 4; ++m) {
        half4 v; v[0] = sv[4*m]; v[1] = sv[4*m+1]; v[2] = sv[4*m+2]; v[3] = sv[4*m+3];
        *reinterpret_cast<half4*>(&xvT[lrow][4 * kg + 8 * m]) = v;
      }
    } else if (tile <= 2) {
      const int n = ch - 32;
#pragma unroll
      for (int m = 0; m < 4; ++m) {
        half4 v; v[0] = sv[4*m]; v[1] = sv[4*m+1]; v[2] = sv[4*m+2]; v[3] = sv[4*m+3];
        *reinterpret_cast<half4*>(&BmT[n][4 * kg + 8 * m]) = v;
      }
#pragma unroll
      for (int rg = 0; rg < 16; ++rg) {
        const int t = (rg & 3) + 8 * (rg >> 2) + 4 * kg;
        actB[t][n] = sv[rg];
      }
    } else {
      const int n = ch - 96;
#pragma unroll
      for (int rg = 0; rg < 16; ++rg) {
        const int t = (rg & 3) + 8 * (rg >> 2) + 4 * kg;
        actC[t][n] = sv[rg];
      }
    }
  };

  if (wv == 0) {
    doTile(0);
  } else if (wv == 1) {
    doTile(1);
  } else if (wv == 2) {
    doTile(2);
    half8 bf5 = zero_h8();
    if (lrow < 2)
      bf5 = *reinterpret_cast<const half8*>(&WdtF[((size_t)th * 2 + lrow) * 16 + kg * 8]);
    const f32x16 a5 = __builtin_amdgcn_mfma_f32_32x32x16_f16(afr[3], bf5, z16, 0, 0, 0);
    if (lrow < 2) {
#pragma unroll
      for (int rg = 0; rg < 16; ++rg) {
        const int t = (rg & 3) + 8 * (rg >> 2) + 4 * kg;
        dtraw[t][lrow] = a5[rg];
      }
    }
  } else {
    doTile(3);
    doTile(4);
  }
  __syncthreads();   // B1

  if (wv == 0) {
#pragma unroll
    for (int kk = 0; kk < 4; ++kk) {
      const half8 af = ld8(&actC[lrow][kk * 16 + kg * 8]);
      const half8 bf = ld8(&actB[lrow][kk * 16 + kg * 8]);
      g = __builtin_amdgcn_mfma_f32_32x32x16_f16(af, bf, g, 0, 0, 0);
    }
  } else if (wv == 1) {
    const int t = lane & 31, hi = lane >> 5;
    const float dtbias = P.dtb[h * NHIN + hi];
    const float Ah = -__expf(P.Alog[h * NHIN + hi]);
    const float raw = dtraw[t][hi] + dtbias;
    const float dtv = (raw > 20.f) ? raw : __logf(1.0f + __expf(raw));
    float s = dtv * Ah;
#pragma unroll
    for (int d = 1; d < 32; d <<= 1) {
      const float v = __shfl_up(s, d, 32);
      if (t >= d) s += v;
    }
    const float cl31 = __shfl(s, 31, 32);
    const float w = __expf(cl31 - s);
    const float ecl = __expf(s);
    clL[hi][t] = s;
    dtL2[hi][t] = dtv;
    dwL[hi][t] = w * dtv;
    const float eo = __shfl(ecl, (lane & 31) + 32, 64);
    if (lane < 32) cumsg[(size_t)wg * CHUNK + t] = make_float2(ecl, eo);
    if (t == 31) Pbuf[(base0 * NCHUNK + c) * NHIN + hi] = ecl;
  } else if (wv == 2) {
#pragma unroll
    for (int k = 0; k < 8; ++k) {
      const int idx = lane + k * 64;
      const int t = idx >> 4, c4 = (idx & 15) * 4;
      *reinterpret_cast<ushort4*>(&xgC[(size_t)wg * (CHUNK * DST) + t * DST + c4]) =
          *reinterpret_cast<const ushort4*>(&actC[t][c4]);
    }
  }
  __syncthreads();   // B2

  if (wv == 0) {
    const float cls0 = clL[0][lrow], cls1 = clL[1][lrow];
#pragma unroll
    for (int rg = 0; rg < 16; ++rg) {
      const int t = (rg & 3) + 8 * (rg >> 2) + 4 * kg;
      const float gg = g[rg];
      float l0 = 0.f, l1 = 0.f;
      if (lrow <= t) { l0 = __expf(clL[0][t] - cls0); l1 = __expf(clL[1][t] - cls1); }
      Gm[0][t][lrow] = (_Float16)(l0 * gg);
      Gm[1][t][lrow] = (_Float16)(l1 * gg);
    }
  } else if (wv == 1 || wv == 2) {
    const int idx = tid - 64;
    const int ch = idx & 31, tq = idx >> 5;
    const int hi = ch >> 4;
#pragma unroll
    for (int hh = 0; hh < 2; ++hh) {
      const int t4 = tq * 8 + hh * 4;
      const half4 xv4 = *reinterpret_cast<const half4*>(&xvT[ch][t4]);
      half4 xt, wx;
#pragma unroll
      for (int i = 0; i < 4; ++i) {
        const int t = t4 + i;
        const float xv = (float)xv4[i];
        xt[i] = (_Float16)(dtL2[hi][t] * xv);
        wx[i] = (_Float16)(dwL[hi][t] * xv);
      }
      *reinterpret_cast<half4*>(&XtL[ch][t4]) = xt;
      *reinterpret_cast<half4*>(&WXt[ch][t4]) = wx;
    }
  }
  __syncthreads();   // B3

  if (wv == 0 || wv == 3) {
    const int hi = (wv == 0) ? 0 : 1;
    const half8 xb0 = ld8(&XtL[lrow][kg * 8]);
    const half8 xb1 = ld8(&XtL[lrow][16 + kg * 8]);
    f32x16 acc = z16;
    acc = __builtin_amdgcn_mfma_f32_32x32x16_f16(ld8(&Gm[hi][lrow][kg * 8]), xb0, acc, 0, 0, 0);
    acc = __builtin_amdgcn_mfma_f32_32x32x16_f16(ld8(&Gm[hi][lrow][16 + kg * 8]), xb1, acc, 0, 0, 0);
    if ((lrow >> 4) == hi) {
      const float Dp = P.Dp[h * NHIN + hi];
      _Float16* yo = &yintra[(size_t)wg * (CHUNK * DIN)];
#pragma unroll
      for (int rg = 0; rg < 16; ++rg) {
        const int t = (rg & 3) + 8 * (rg >> 2) + 4 * kg;
        yo[t * DIN + lrow] = (_Float16)(acc[rg] + Dp * (float)xvT[lrow][t]);
      }
    }
  } else {
    const int nhalf = (wv - 1) * 32;
    const half8 wa0 = ld8(&WXt[lrow][kg * 8]);
    const half8 wa1 = ld8(&WXt[lrow][16 + kg * 8]);
    f32x16 acc = z16;
    acc = __builtin_amdgcn_mfma_f32_32x32x16_f16(
        wa0, ld8(&BmT[nhalf + lrow][kg * 8]), acc, 0, 0, 0);
    acc = __builtin_amdgcn_mfma_f32_32x32x16_f16(
        wa1, ld8(&BmT[nhalf + lrow][16 + kg * 8]), acc, 0, 0, 0);
#pragma unroll
    for (int rg = 0; rg < 16; ++rg) {
      const int m = (rg & 3) + 8 * (rg >> 2) + 4 * kg;
      StL[m][nhalf + lrow] = (_Float16)acc[rg];
    }
    const size_t base2 = (base0 * NCHUNK + c) * (NHIN * HD * DST);
#pragma unroll
    for (int k = 0; k < 4; ++k) {
      const int idx = lane + k * 64;
      const int row = idx >> 3, c4 = (idx & 7) * 4 + nhalf;
      *reinterpret_cast<ushort4*>(&Sg[base2 + row * DST + c4]) =
          *reinterpret_cast<const ushort4*>(&StL[row][c4]);
    }
  }
}

// ---------------------------------------------------------------------------
// Carry: 256 wgs x 64 threads; 8-deep prefetch.
// ---------------------------------------------------------------------------
__global__ __launch_bounds__(64)
void carry_kernel(_Float16* __restrict__ Sg, const float* __restrict__ Pbuf)
{
  const int wg = blockIdx.x;
  const int q = wg & 3;
  const int rest = wg >> 2;
  const int b = rest % BBATCH;
  const int h = (rest / BBATCH) % NHEADS;
  const int team = rest / (BBATCH * NHEADS);
  const int lane = threadIdx.x;
  const int off = q * 512 + lane * 8;
  const int hi = q >> 1;
  const size_t base0 = ((size_t)team * NHEADS + h) * BBATCH + b;

  float hc[8] = {0, 0, 0, 0, 0, 0, 0, 0};
  for (int cb = 0; cb < NCHUNK; cb += 8) {
    half8 a[8];
    float Pv[8];
#pragma unroll
    for (int j = 0; j < 8; ++j) {
      const size_t sb = (base0 * NCHUNK + cb + j) * (NHIN * HD * DST) + off;
      a[j] = *reinterpret_cast<const half8*>(&Sg[sb]);
      Pv[j] = Pbuf[(base0 * NCHUNK + cb + j) * NHIN + hi];
    }
#pragma unroll
    for (int j = 0; j < 8; ++j) {
      const size_t sb = (base0 * NCHUNK + cb + j) * (NHIN * HD * DST) + off;
      half8 o;
#pragma unroll
      for (int k = 0; k < 8; ++k) o[k] = (_Float16)hc[k];
      *reinterpret_cast<half8*>(&Sg[sb]) = o;
#pragma unroll
      for (int k = 0; k < 8; ++k) hc[k] = fmaf(Pv[j], hc[k], (float)a[j][k]);
    }
  }
}

// ---------------------------------------------------------------------------
// K3 fused: C·H_in + z MFMAs, gate+rms (-> f16), MFMA out-proj, diff, stats.
// ---------------------------------------------------------------------------
__global__ __launch_bounds__(256)
void k3_fused(const _Float16* __restrict__ Sg, const float2* __restrict__ cumsg,
              const _Float16* __restrict__ xgC, const _Float16* __restrict__ xH,
              const _Float16* __restrict__ WzF, const _Float16* __restrict__ wnH,
              const _Float16* __restrict__ yintra, const float* __restrict__ lam,
              float* __restrict__ diffb, float2* __restrict__ pstat)
{
  __shared__ float    ysh[2][CHUNK][YS];
  __shared__ float    cums2[2][CHUNK][2];
  __shared__ _Float16 zsh[2][32][40];
  __shared__ _Float16 ygH[2][32][36];
  __shared__ float    youtL[2][CHUNK][20];
  __shared__ float    red2[8];

  const int tid  = threadIdx.x;
  const int wg   = blockIdx.x;
  const int c    = wg % NCHUNK;
  const int b    = (wg / NCHUNK) % BBATCH;
  const int h    = wg / (NCHUNK * BBATCH);
  const int c0 = c * CHUNK;
  const int lane = tid & 63;
  const int wv   = tid >> 6;
  const int lrow = lane & 31;
  const int kg   = lane >> 5;

  const size_t wgT0 = (((size_t)0 * NHEADS + h) * BBATCH + b) * NCHUNK + c;
  const size_t wgT1 = (((size_t)1 * NHEADS + h) * BBATCH + b) * NCHUNK + c;

  f32x16 acc;
  if (wv < 2) {
    const size_t wgT = wv ? wgT1 : wgT0;
    const _Float16* ca = &xgC[wgT * (CHUNK * DST) + (size_t)lrow * DST + kg * 8];
    const _Float16* hb = &Sg[wgT * (NHIN * HD * DST) + (size_t)lrow * DST + kg * 8];
#pragma unroll
    for (int i = 0; i < 16; ++i) acc[i] = 0.0f;
    acc = __builtin_amdgcn_mfma_f32_32x32x16_f16(
        *reinterpret_cast<const half8*>(ca), *reinterpret_cast<const half8*>(hb), acc, 0, 0, 0);
    acc = __builtin_amdgcn_mfma_f32_32x32x16_f16(
        *reinterpret_cast<const half8*>(ca + 16), *reinterpret_cast<const half8*>(hb + 16), acc, 0, 0, 0);
    acc = __builtin_amdgcn_mfma_f32_32x32x16_f16(
        *reinterpret_cast<const half8*>(ca + 32), *reinterpret_cast<const half8*>(hb + 32), acc, 0, 0, 0);
    acc = __builtin_amdgcn_mfma_f32_32x32x16_f16(
        *reinterpret_cast<const half8*>(ca + 48), *reinterpret_cast<const half8*>(hb + 48), acc, 0, 0, 0);
  } else {
    const int team = wv - 2;
    const int th = team * NHEADS + h;
    const half8 afr = *reinterpret_cast<const half8*>(
        &xH[((size_t)b * TSEQ + c0 + lrow) * DMODEL + h * HD + kg * 8]);
    const half8 bfr = *reinterpret_cast<const half8*>(
        &WzF[((size_t)th * 32 + lrow) * 16 + kg * 8]);
    f32x16 zacc;
#pragma unroll
    for (int i = 0; i < 16; ++i) zacc[i] = 0.0f;
    zacc = __builtin_amdgcn_mfma_f32_32x32x16_f16(afr, bfr, zacc, 0, 0, 0);
#pragma unroll
    for (int rg = 0; rg < 16; ++rg) {
      const int t = (rg & 3) + 8 * (rg >> 2) + 4 * kg;
      const float v = zacc[rg];
      zsh[team][t][lrow] = (_Float16)(v * sigm(v));
    }
  }

  {
    const int tm = tid >> 7, li = tid & 127;
    const int t = li >> 2, c8 = (li & 3) * 8;
    const size_t wgT = tm ? wgT1 : wgT0;
    const half8 v = *reinterpret_cast<const half8*>(&yintra[wgT * (CHUNK * DIN) + li * 8]);
#pragma unroll
    for (int j = 0; j < 8; ++j) ysh[tm][t][c8 + j] = (float)v[j];
  }
  if (tid < 64) {
    const int tm = tid >> 5, t = tid & 31;
    const size_t wgT = tm ? wgT1 : wgT0;
    const float2 v = cumsg[wgT * CHUNK + t];
    cums2[tm][t][0] = v.x; cums2[tm][t][1] = v.y;
  }
  __syncthreads();   // B1

  if (wv < 2) {
    const int team = wv;
    const int hi = lrow >> 4;
#pragma unroll
    for (int rg = 0; rg < 16; ++rg) {
      const int t = (rg & 3) + 8 * (rg >> 2) + 4 * kg;
      ysh[team][t][lrow] = fmaf(cums2[team][t][hi], acc[rg], ysh[team][t][lrow]);
    }
  }
  __syncthreads();   // B2

  {
    const int tm = tid >> 7, l = tid & 127;
    const int q = l & 3, tl = l >> 2;
    const int dn0 = q * 8;
    float yg[8];
    float ss = 0.0f;
#pragma unroll
    for (int j = 0; j < 8; ++j) {
      const float g = ysh[tm][tl][dn0 + j] * (float)zsh[tm][tl][dn0 + j];
      yg[j] = g;
      ss += g * g;
    }
    ss += __shfl_xor(ss, 1, 4);
    ss += __shfl_xor(ss, 2, 4);
    const float rms = rsqrtf(ss * (1.0f / DIN) + 1e-5f);
    half4 o0, o1;
#pragma unroll
    for (int j = 0; j < 4; ++j) o0[j] = (_Float16)(yg[j] * rms);
#pragma unroll
    for (int j = 0; j < 4; ++j) o1[j] = (_Float16)(yg[4 + j] * rms);
    *reinterpret_cast<half4*>(&ygH[tm][tl][dn0]) = o0;
    *reinterpret_cast<half4*>(&ygH[tm][tl][dn0 + 4]) = o1;
  }
  __syncthreads();   // B3

  if (wv < 2) {
    const int tm = wv;
    const int th2 = tm * NHEADS + h;
    const half8 af0 = ld8(&ygH[tm][lrow][kg * 8]);
    const half8 af1 = ld8(&ygH[tm][lrow][16 + kg * 8]);
    half8 bf0 = zero_h8(), bf1 = zero_h8();
    if (lrow < 16) {
      const _Float16* wp = &wnH[((size_t)th2 * HD + lrow) * DIN];
      bf0 = *reinterpret_cast<const half8*>(wp + kg * 8);
      bf1 = *reinterpret_cast<const half8*>(wp + 16 + kg * 8);
    }
    f32x16 oacc;
#pragma unroll
    for (int i = 0; i < 16; ++i) oacc[i] = 0.0f;
    oacc = __builtin_amdgcn_mfma_f32_32x32x16_f16(af0, bf0, oacc, 0, 0, 0);
    oacc = __builtin_amdgcn_mfma_f32_32x32x16_f16(af1, bf1, oacc, 0, 0, 0);
    if (lrow < 16) {
#pragma unroll
      for (int rg = 0; rg < 16; ++rg) {
        const int t = (rg & 3) + 8 * (rg >> 2) + 4 * kg;
        youtL[tm][t][lrow] = oacc[rg];
      }
    }
  }
  __syncthreads();   // B4

  float s = 0.0f, s2 = 0.0f;
  if (tid < 128) {
    const int t = tid >> 2, hd0 = (tid & 3) * 4;
    const float4 l4 = *reinterpret_cast<const float4*>(&lam[h * HD + hd0]);
    const float* y0 = &youtL[0][t][hd0];
    const float* y1 = &youtL[1][t][hd0];
    float4 d;
    d.x = y0[0] - l4.x * y1[0];
    d.y = y0[1] - l4.y * y1[1];
    d.z = y0[2] - l4.z * y1[2];
    d.w = y0[3] - l4.w * y1[3];
    *reinterpret_cast<float4*>(
        &diffb[(((size_t)(h * BBATCH + b)) * TSEQ + c0 + t) * HD + hd0]) = d;
    s = d.x + d.y + d.z + d.w;
    s2 = d.x * d.x + d.y * d.y + d.z * d.z + d.w * d.w;
  }
#pragma unroll
  for (int off = 1; off < 64; off <<= 1) {
    s += __shfl_xor(s, off);
    s2 += __shfl_xor(s2, off);
  }
  if (lane == 0) { red2[wv * 2] = s; red2[wv * 2 + 1] = s2; }
  __syncthreads();
  if (tid == 0) pstat[wg] = make_float2(red2[0] + red2[2], red2[1] + red2[3]);
}

// ---------------------------------------------------------------------------
// Final (MFMA): stats reduce + groupnorm-apply (f16) + [32x256]x[256x256]
// f16 MFMA GEMM + bias + residual.
// ---------------------------------------------------------------------------
#define NFW (BBATCH * (TSEQ / 32) * 2)   // 256
__global__ __launch_bounds__(256)
void final_mfma(const float* __restrict__ x, const float* __restrict__ diffb,
                const float2* __restrict__ pstat, const float* __restrict__ gnw,
                const float* __restrict__ gnb, const float* __restrict__ projw,
                const float* __restrict__ projb, float* __restrict__ out)
{
  __shared__ _Float16 ndH[32][268];
  __shared__ float statL[NHEADS][2];

  const int wg = blockIdx.x;
  const int chalf = wg & 1;
  const int tt = (wg >> 1) & 63;
  const int b = wg >> 7;
  const int t0 = tt * 32;
  const int tid = threadIdx.x;
  const int lane = tid & 63;
  const int wv = tid >> 6;

  {
    const int h = tid >> 4, k0 = tid & 15;
    float s = 0.0f, s2 = 0.0f;
    for (int k = k0; k < NCHUNK; k += 16) {
      const float2 v = pstat[((size_t)h * BBATCH + b) * NCHUNK + k];
      s += v.x; s2 += v.y;
    }
    s += __shfl_xor(s, 1, 16);  s2 += __shfl_xor(s2, 1, 16);
    s += __shfl_xor(s, 2, 16);  s2 += __shfl_xor(s2, 2, 16);
    s += __shfl_xor(s, 4, 16);  s2 += __shfl_xor(s2, 4, 16);
    s += __shfl_xor(s, 8, 16);  s2 += __shfl_xor(s2, 8, 16);
    if (k0 == 0) {
      const float inv = 1.0f / (TSEQ * HD);
      const float mean = s * inv;
      const float var = s2 * inv - mean * mean;
      statL[h][0] = mean;
      statL[h][1] = rsqrtf(var + 1e-5f);
    }
  }
  __syncthreads();

  {
    const int d = tid, h = d >> 4, hd = d & 15;
    const float mean = statL[h][0];
    const float rstd = statL[h][1];
    const float g = gnw[d];
    const float be = gnb[d];
    const float* dp = &diffb[((size_t)(h * BBATCH + b) * TSEQ + t0) * HD + hd];
#pragma unroll
    for (int t = 0; t < 32; ++t)
      ndH[t][d] = (_Float16)((dp[t * HD] - mean) * rstd * g + be);
  }
  __syncthreads();

  const int lrow = lane & 31, kg = lane >> 5;
  const int n0 = chalf * 128 + wv * 32;
  const int d = n0 + lrow;
  f32x16 acc;
#pragma unroll
  for (int i = 0; i < 16; ++i) acc[i] = 0.0f;
  const float* wp0 = &projw[(size_t)d * DMODEL + kg * 8];
#pragma unroll
  for (int kt = 0; kt < DMODEL; kt += 16) {
    const half8 af = ld8(&ndH[lrow][kt + kg * 8]);
    const half8 bf = pack_h8(*reinterpret_cast<const float4*>(wp0 + kt),
                             *reinterpret_cast<const float4*>(wp0 + kt + 4));
    acc = __builtin_amdgcn_mfma_f32_32x32x16_f16(af, bf, acc, 0, 0, 0);
  }

  const float pb = projb[d];
#pragma unroll
  for (int rg = 0; rg < 16; ++rg) {
    const int t = (rg & 3) + 8 * (rg >> 2) + 4 * kg;
    const size_t o = ((size_t)b * TSEQ + t0 + t) * DMODEL + d;
    out[o] = x[o] + pb + acc[rg];
  }
}

// ---------------------------------------------------------------------------
extern "C" void kernel_launch(void* const* d_in, const int* in_sizes, int n_in,
                              void* d_out, int out_size, void* d_ws, size_t ws_size,
                              hipStream_t stream)
{
  const float* x = (const float*)d_in[0];
  TeamParams tp0 { (const float*)d_in[1], (const float*)d_in[2], (const float*)d_in[3],
                   (const float*)d_in[4], (const float*)d_in[5], (const float*)d_in[6],
                   (const float*)d_in[7], (const float*)d_in[8] };
  TeamParams tp1 { (const float*)d_in[9], (const float*)d_in[10], (const float*)d_in[11],
                   (const float*)d_in[12], (const float*)d_in[13], (const float*)d_in[14],
                   (const float*)d_in[15], (const float*)d_in[16] };
  const float* lam   = (const float*)d_in[17];
  const float* gnw   = (const float*)d_in[18];
  const float* gnb   = (const float*)d_in[19];
  const float* projw = (const float*)d_in[20];
  const float* projb = (const float*)d_in[21];

  // ws layout (bytes):
  //   Sg      @ 0           16,777,216
  //   Pbuf    @ 16,777,216      32,768
  //   cumsg   @ 16,809,984   1,048,576
  //   xgC     @ 17,858,560  16,777,216
  //   yintra  @ 34,635,776   8,388,608
  //   diffb   @ 43,024,384   4,194,304
  //   pstat   @ 47,218,688      16,384
  //   xH      @ 47,235,072   2,097,152
  //   WcF     @ 49,332,224     655,360
  //   WzF     @ 49,987,584      32,768
  //   WdtF    @ 50,020,352       2,048
  //   wnH     @ 50,022,400      32,768   (total ~50.1 MB)
  char* wsb = (char*)d_ws;
  _Float16* Sg    = (_Float16*)wsb;
  float* Pbuf     = (float*)(wsb + 16777216);
  float2* cumsg   = (float2*)(wsb + 16809984);
  _Float16* xgC   = (_Float16*)(wsb + 17858560);
  _Float16* yintra= (_Float16*)(wsb + 34635776);
  float* diffb    = (float*)(wsb + 43024384);
  float2* pstat   = (float2*)(wsb + 47218688);
  _Float16* xH    = (_Float16*)(wsb + 47235072);
  _Float16* WcF   = (_Float16*)(wsb + 49332224);
  _Float16* WzF   = (_Float16*)(wsb + 49987584);
  _Float16* WdtF  = (_Float16*)(wsb + 50020352);
  _Float16* wnH   = (_Float16*)(wsb + 50022400);

  prep_kernel<<<dim3(320), dim3(256), 0, stream>>>(x, tp0, tp1, xH, WcF, WzF, WdtF, wnH);
  k1_proj_ssd<<<dim3(NWG), dim3(256), 0, stream>>>(xH, WcF, WdtF, tp0, tp1, Sg, Pbuf, cumsg, xgC, yintra);
  carry_kernel<<<dim3(2 * NHEADS * BBATCH * 4), dim3(64), 0, stream>>>(Sg, Pbuf);
  k3_fused<<<dim3(NWG3), dim3(256), 0, stream>>>(Sg, cumsg, xgC, xH, WzF, wnH, yintra, lam, diffb, pstat);
  final_mfma<<<dim3(NFW), dim3(256), 0, stream>>>(
      x, diffb, pstat, gnw, gnb, projw, projb, (float*)d_out);
}